// Round 6
// baseline (800.257 us; speedup 1.0000x reference)
//
#include <hip/hip_runtime.h>
#include <hip/hip_bf16.h>
#include <math.h>

#define L_SEQ   2048
#define M_ROWS  4096            // B*L
#define DPROJ   4384
#define DPROJP  4480            // padded to 35*128 for MFMA GEMM
#define DINNER  2048
#define CONVDIM 2304
#define NST     128
#define NH      32
#define SEGLEN  256
#define NSEG    8
#define SC      8               // scan sub-chunk (steps per LDS stage)

typedef __attribute__((ext_vector_type(8))) short short8;
typedef __attribute__((ext_vector_type(4))) float f32x4;

union bf8u { short8 v; __hip_bfloat16 e[8]; };

static __device__ __forceinline__ unsigned short bf16bits(float v) {
    __hip_bfloat16 t = __float2bfloat16(v);
    return *(unsigned short*)&t;
}

// ---------------------------------------------------------------------------
// f32 -> bf16 conversion pre-passes
// ---------------------------------------------------------------------------
__global__ __launch_bounds__(256) void cvt_x_kernel(
    const float* __restrict__ x, __hip_bfloat16* __restrict__ xbf)
{
    const int i = (blockIdx.x * 256 + threadIdx.x) * 4;
    const float4 v = *(const float4*)(x + i);
    xbf[i + 0] = __float2bfloat16(v.x);
    xbf[i + 1] = __float2bfloat16(v.y);
    xbf[i + 2] = __float2bfloat16(v.z);
    xbf[i + 3] = __float2bfloat16(v.w);
}

__global__ __launch_bounds__(256) void cvt_win_kernel(
    const float* __restrict__ w0, const float* __restrict__ w1,
    __hip_bfloat16* __restrict__ dst)
{
    const int dir = blockIdx.y;
    const float* __restrict__ w = dir ? w1 : w0;
    __hip_bfloat16* __restrict__ d = dst + (size_t)dir * DPROJP * 512;
    const int i = (blockIdx.x * 256 + threadIdx.x) * 4;
    const int row = i >> 9;
    if (row < DPROJ) {
        const float4 v = *(const float4*)(w + i);
        d[i + 0] = __float2bfloat16(v.x);
        d[i + 1] = __float2bfloat16(v.y);
        d[i + 2] = __float2bfloat16(v.z);
        d[i + 3] = __float2bfloat16(v.w);
    } else {
        d[i + 0] = __float2bfloat16(0.f); d[i + 1] = __float2bfloat16(0.f);
        d[i + 2] = __float2bfloat16(0.f); d[i + 3] = __float2bfloat16(0.f);
    }
}

__global__ __launch_bounds__(256) void cvt_wout_kernel(
    const float* __restrict__ w0, const float* __restrict__ w1,
    __hip_bfloat16* __restrict__ dst)
{
    const int dir = blockIdx.y;
    const float* __restrict__ w = dir ? w1 : w0;
    __hip_bfloat16* __restrict__ d = dst + (size_t)dir * 512 * DINNER;
    const int i = (blockIdx.x * 256 + threadIdx.x) * 4;
    const float4 v = *(const float4*)(w + i);
    d[i + 0] = __float2bfloat16(v.x);
    d[i + 1] = __float2bfloat16(v.y);
    d[i + 2] = __float2bfloat16(v.z);
    d[i + 3] = __float2bfloat16(v.w);
}

// ---------------------------------------------------------------------------
// MFMA bf16 GEMM: C[M][N] = A[M][K] @ B[N][K]^T (+ optional f32 addsrc).
// 128x128 tile, BK=64, 256 threads. LDS XOR-swizzled.
// ---------------------------------------------------------------------------
template<bool AF32>
__global__ __launch_bounds__(256) void gemm_mfma(
    const __hip_bfloat16* __restrict__ Abf,
    const float* __restrict__ Af0, const float* __restrict__ Af1, int lda_f,
    const __hip_bfloat16* __restrict__ Bw, long long b_dir_off,
    float* __restrict__ C, long long c_dir_off, int ldc,
    const float* __restrict__ addsrc, int add_ld,
    int K)
{
    const int dir = blockIdx.z;
    const int m0 = blockIdx.y * 128;
    const int n0 = blockIdx.x * 128;
    const __hip_bfloat16* __restrict__ B = Bw + (size_t)dir * b_dir_off;
    const float* __restrict__ Af = dir ? Af1 : Af0;
    float* __restrict__ Cp = C + (size_t)dir * c_dir_off;

    __shared__ __hip_bfloat16 Asl[128 * 64];
    __shared__ __hip_bfloat16 Bsl[128 * 64];

    const int tid  = threadIdx.x;
    const int lane = tid & 63;
    const int wid  = tid >> 6;
    const int wr   = (wid >> 1) << 6;
    const int wc   = (wid & 1) << 6;
    const int l15  = lane & 15;
    const int l4   = lane >> 4;

    f32x4 acc[4][4];
#pragma unroll
    for (int m = 0; m < 4; ++m)
#pragma unroll
        for (int n = 0; n < 4; ++n) acc[m][n] = (f32x4)0.f;

    for (int k0 = 0; k0 < K; k0 += 64) {
        __syncthreads();
#pragma unroll
        for (int i = 0; i < 4; ++i) {
            const int c    = tid + (i << 8);
            const int row  = c >> 3;
            const int slot = c & 7;
            const int dst  = (row << 7) + ((slot ^ (row & 7)) << 4);
            if (AF32) {
                const float* s = Af + (size_t)(m0 + row) * lda_f + k0 + (slot << 3);
                const float4 lo = *(const float4*)(s);
                const float4 hi = *(const float4*)(s + 4);
                bf8u u;
                u.e[0] = __float2bfloat16(lo.x); u.e[1] = __float2bfloat16(lo.y);
                u.e[2] = __float2bfloat16(lo.z); u.e[3] = __float2bfloat16(lo.w);
                u.e[4] = __float2bfloat16(hi.x); u.e[5] = __float2bfloat16(hi.y);
                u.e[6] = __float2bfloat16(hi.z); u.e[7] = __float2bfloat16(hi.w);
                *(short8*)((char*)Asl + dst) = u.v;
            } else {
                *(short8*)((char*)Asl + dst) =
                    *(const short8*)(Abf + (size_t)(m0 + row) * K + k0 + (slot << 3));
            }
            *(short8*)((char*)Bsl + dst) =
                *(const short8*)(B + (size_t)(n0 + row) * K + k0 + (slot << 3));
        }
        __syncthreads();

#pragma unroll
        for (int kh = 0; kh < 2; ++kh) {
            const int ks = (kh << 2) + l4;
            short8 a[4], b[4];
#pragma unroll
            for (int m = 0; m < 4; ++m) {
                const int R = wr + (m << 4) + l15;
                a[m] = *(const short8*)((const char*)Asl + (R << 7) + ((ks ^ (R & 7)) << 4));
            }
#pragma unroll
            for (int n = 0; n < 4; ++n) {
                const int R = wc + (n << 4) + l15;
                b[n] = *(const short8*)((const char*)Bsl + (R << 7) + ((ks ^ (R & 7)) << 4));
            }
#pragma unroll
            for (int m = 0; m < 4; ++m)
#pragma unroll
                for (int n = 0; n < 4; ++n)
                    acc[m][n] = __builtin_amdgcn_mfma_f32_16x16x32_bf16(
                        a[m], b[n], acc[m][n], 0, 0, 0);
        }
    }

#pragma unroll
    for (int m = 0; m < 4; ++m) {
        const int row0 = m0 + wr + (m << 4) + (l4 << 2);
#pragma unroll
        for (int n = 0; n < 4; ++n) {
            const int col = n0 + wc + (n << 4) + l15;
#pragma unroll
            for (int r = 0; r < 4; ++r) {
                float v = acc[m][n][r];
                if (addsrc) v += addsrc[(size_t)(row0 + r) * add_ld + col];
                Cp[(size_t)(row0 + r) * ldc + col] = v;
            }
        }
    }
}

// ---------------------------------------------------------------------------
// Depthwise causal conv(4) + SiLU (float4 over channels); exact-f32 dt;
// softplus; dA = exp(dt * -exp(A_log)).
// ---------------------------------------------------------------------------
__global__ __launch_bounds__(256) void conv_dt_kernel(
    const float* __restrict__ zx, const float* __restrict__ x,
    const float* __restrict__ inw0, const float* __restrict__ inw1,
    const float* __restrict__ cw0, const float* __restrict__ cw1,
    const float* __restrict__ cb0, const float* __restrict__ cb1,
    const float* __restrict__ dtbias0, const float* __restrict__ dtbias1,
    const float* __restrict__ Alog0, const float* __restrict__ Alog1,
    __hip_bfloat16* __restrict__ xs, float* __restrict__ Bcb, float* __restrict__ Ccb,
    float* __restrict__ dtb, float* __restrict__ dab)
{
    const int dir = blockIdx.y;
    const int row = blockIdx.x;
    const int b = row >> 11;
    const int l = row & (L_SEQ - 1);

    const float* __restrict__ cw = dir ? cw1 : cw0;
    const float* __restrict__ cb = dir ? cb1 : cb0;
    const float* __restrict__ zbase = zx + (size_t)dir * M_ROWS * DPROJP;
    const size_t orow = (size_t)(dir * M_ROWS + row);

    for (int c4 = threadIdx.x; c4 < CONVDIM / 4; c4 += 256) {
        const int c = c4 << 2;
        float4 acc = *(const float4*)(cb + c);
        const float4 wch0 = *(const float4*)(cw + (c + 0) * 4);
        const float4 wch1 = *(const float4*)(cw + (c + 1) * 4);
        const float4 wch2 = *(const float4*)(cw + (c + 2) * 4);
        const float4 wch3 = *(const float4*)(cw + (c + 3) * 4);
#pragma unroll
        for (int k = 0; k < 4; ++k) {
            const int p = dir ? (l + 3 - k) : (l - 3 + k);
            const bool ok = dir ? (p < L_SEQ) : (p >= 0);
            if (ok) {
                const float4 z = *(const float4*)(zbase
                    + (size_t)(b * L_SEQ + p) * DPROJP + DINNER + c);
                const float t0 = (k == 0) ? wch0.x : (k == 1) ? wch0.y : (k == 2) ? wch0.z : wch0.w;
                const float t1 = (k == 0) ? wch1.x : (k == 1) ? wch1.y : (k == 2) ? wch1.z : wch1.w;
                const float t2 = (k == 0) ? wch2.x : (k == 1) ? wch2.y : (k == 2) ? wch2.z : wch2.w;
                const float t3 = (k == 0) ? wch3.x : (k == 1) ? wch3.y : (k == 2) ? wch3.z : wch3.w;
                acc.x = fmaf(z.x, t0, acc.x);
                acc.y = fmaf(z.y, t1, acc.y);
                acc.z = fmaf(z.z, t2, acc.z);
                acc.w = fmaf(z.w, t3, acc.w);
            }
        }
        float4 s;
        s.x = acc.x / (1.f + expf(-acc.x));
        s.y = acc.y / (1.f + expf(-acc.y));
        s.z = acc.z / (1.f + expf(-acc.z));
        s.w = acc.w / (1.f + expf(-acc.w));
        if (c < DINNER) {
            ushort4 us;
            us.x = bf16bits(s.x); us.y = bf16bits(s.y);
            us.z = bf16bits(s.z); us.w = bf16bits(s.w);
            *(ushort4*)((unsigned short*)xs + orow * DINNER + c) = us;
        } else if (c < DINNER + NST) {
            *(float4*)(Bcb + orow * NST + (c - DINNER)) = s;
        } else {
            *(float4*)(Ccb + orow * NST + (c - DINNER - NST)) = s;
        }
    }

    {   // exact f32 dt: 8 threads per head, float4 dot
        const int h = threadIdx.x >> 3;
        const int part = threadIdx.x & 7;
        const float4* __restrict__ xr4 = (const float4*)(x + (size_t)row * 512 + part * 64);
        const float4* __restrict__ wr4 = (const float4*)((dir ? inw1 : inw0)
            + (size_t)(DINNER + CONVDIM + h) * 512 + part * 64);
        float s = 0.f;
#pragma unroll
        for (int k = 0; k < 16; ++k) {
            const float4 a = xr4[k], w = wr4[k];
            s = fmaf(a.x, w.x, s); s = fmaf(a.y, w.y, s);
            s = fmaf(a.z, w.z, s); s = fmaf(a.w, w.w, s);
        }
        s += __shfl_xor(s, 1);
        s += __shfl_xor(s, 2);
        s += __shfl_xor(s, 4);
        if (part == 0) {
            const float v = s + (dir ? dtbias1 : dtbias0)[h];
            const float sp = (v > 20.f) ? v : log1pf(expf(v));
            const float a = -expf((dir ? Alog1 : Alog0)[h]);
            dtb[orow * NH + h] = sp;
            dab[orow * NH + h] = expf(sp * a);
        }
    }
}

// ---------------------------------------------------------------------------
// Pass A: segment-local scan. Depth-2 pipelined: 3-buffer LDS ring, per chunk
// {issue c+2 -> regs; compute c; write regs(c+1) -> LDS; barrier}. x kept as
// raw bf16 bits until the LDS write (no early waitcnt).
// ---------------------------------------------------------------------------
__global__ __launch_bounds__(512) void scan_seg_kernel(
    const __hip_bfloat16* __restrict__ xs, const float* __restrict__ Bcb,
    const float* __restrict__ Ccb, const float* __restrict__ dtb,
    const float* __restrict__ dab,
    const float* __restrict__ D0, const float* __restrict__ D1,
    float* __restrict__ zx, __hip_bfloat16* __restrict__ stateC,
    float* __restrict__ betac)
{
    const int dir = blockIdx.y;
    const int bx  = blockIdx.x;
    const int bh  = bx >> 3;
    const int seg = bx & 7;
    const int b = bh >> 5, h = bh & 31;
    const int tid = threadIdx.x;
    const int p = tid >> 3;
    const int g = tid & 7;
    const float Dv = (dir ? D1 : D0)[h];
    const int base_bh = (dir * 2 + b) * 32 + h;
    const int t0 = seg * SEGLEN;
    const int NC = SEGLEN / SC;

    __shared__ float sx[3][SC][64];
    __shared__ float sB[3][SC][8][20];
    __shared__ float sC[3][SC][8][20];
    __shared__ float sS[3][SC][2];

    float hst[16];
#pragma unroll
    for (int i = 0; i < 16; ++i) hst[i] = 0.f;
    float beta = 1.f;

    const size_t dbase = (size_t)(dir * M_ROWS + b * L_SEQ);
    float* __restrict__ ybase = zx + (size_t)dir * M_ROWS * DPROJP + DINNER;
    const unsigned short* __restrict__ xsu = (const unsigned short*)xs;

    auto lidx = [&](int t) { return dir ? (L_SEQ - 1 - t) : t; };

    // issue: global loads for chunk starting at step-offset tb -> regs (raw)
    auto issue_chunk = [&](int tb, float (&dst)[SC]) {
        if (tid < 64) {
#pragma unroll
            for (int s = 0; s < SC; ++s) {
                const unsigned v = xsu[(dbase + lidx(tb + s)) * DINNER + h * 64 + tid];
                dst[s] = __uint_as_float(v);
            }
        } else if (tid < 192) {
            const int n = tid - 64;
#pragma unroll
            for (int s = 0; s < SC; ++s)
                dst[s] = Bcb[(dbase + lidx(tb + s)) * NST + n];
        } else if (tid < 320) {
            const int n = tid - 192;
#pragma unroll
            for (int s = 0; s < SC; ++s)
                dst[s] = Ccb[(dbase + lidx(tb + s)) * NST + n];
        } else if (tid < 336) {
            const int q = tid - 320;
            const int s = q >> 1;
            dst[0] = ((q & 1) ? dab : dtb)[(dbase + lidx(tb + s)) * NH + h];
        }
    };

    auto write_chunk = [&](int bw, float (&src)[SC]) {
        if (tid < 64) {
#pragma unroll
            for (int s = 0; s < SC; ++s)
                sx[bw][s][tid] = __uint_as_float(__float_as_uint(src[s]) << 16);
        } else if (tid < 192) {
            const int n = tid - 64;
#pragma unroll
            for (int s = 0; s < SC; ++s) sB[bw][s][n >> 4][n & 15] = src[s];
        } else if (tid < 320) {
            const int n = tid - 192;
#pragma unroll
            for (int s = 0; s < SC; ++s) sC[bw][s][n >> 4][n & 15] = src[s];
        } else if (tid < 336) {
            const int q = tid - 320;
            sS[bw][q >> 1][q & 1] = src[0];
        }
    };

    float pvA[SC], pvB[SC];

    // prologue: chunk 0 direct to buf 0; issue chunk 1 -> pvA
    issue_chunk(t0, pvA);
    write_chunk(0, pvA);
    if (NC > 1) issue_chunk(t0 + SC, pvA);
    __syncthreads();

    auto body = [&](int c, float (&wrv)[SC], float (&issv)[SC]) {
        const int bm = c % 3;
        const int bw = (c + 1) % 3;
        if (c + 2 < NC) issue_chunk(t0 + (c + 2) * SC, issv);

        // compute SC steps from buf bm
#pragma unroll
        for (int s = 0; s < SC; ++s) {
            const int t = t0 + c * SC + s;
            const float dtv = sS[bm][s][0];
            const float dav = sS[bm][s][1];
            const float xv  = sx[bm][s][p];
            const float sxv = dtv * xv;
            const float4* __restrict__ Bp4 = (const float4*)sB[bm][s][g];
            const float4* __restrict__ Cp4 = (const float4*)sC[bm][s][g];
            float acc0 = 0.f, acc1 = 0.f;
#pragma unroll
            for (int q4 = 0; q4 < 4; ++q4) {
                const float4 bv = Bp4[q4];
                const float4 cv = Cp4[q4];
                float* hj = &hst[q4 * 4];
                hj[0] = fmaf(hj[0], dav, sxv * bv.x); acc0 = fmaf(hj[0], cv.x, acc0);
                hj[1] = fmaf(hj[1], dav, sxv * bv.y); acc1 = fmaf(hj[1], cv.y, acc1);
                hj[2] = fmaf(hj[2], dav, sxv * bv.z); acc0 = fmaf(hj[2], cv.z, acc0);
                hj[3] = fmaf(hj[3], dav, sxv * bv.w); acc1 = fmaf(hj[3], cv.w, acc1);
            }
            float acc = acc0 + acc1;
            acc += __shfl_xor(acc, 1);
            acc += __shfl_xor(acc, 2);
            acc += __shfl_xor(acc, 4);
            beta *= dav;
            if (tid == 0) betac[(size_t)base_bh * L_SEQ + t] = beta;
            if (g == 0) {
                ybase[(size_t)(b * L_SEQ + lidx(t)) * DPROJP + h * 64 + p] = acc + Dv * xv;
            }
        }

        if (c + 1 < NC) write_chunk(bw, wrv);
        __syncthreads();
    };

    for (int cc = 0; cc < NC; cc += 2) {
        body(cc, pvA, pvB);
        body(cc + 1, pvB, pvA);
    }

    const size_t soff = ((size_t)(base_bh * NSEG + seg)) * 8192 + (size_t)tid * 16;
#pragma unroll
    for (int j = 0; j < 16; ++j)
        stateC[soff + j] = __float2bfloat16(hst[j]);
}

// ---------------------------------------------------------------------------
// Pass B: sequential combine over segments (in place).
// ---------------------------------------------------------------------------
__global__ __launch_bounds__(512) void combine_kernel(
    __hip_bfloat16* __restrict__ stateC, const float* __restrict__ betac)
{
    const int dir = blockIdx.y;
    const int bh  = blockIdx.x;
    const int base_bh = (dir * 2 + (bh >> 5)) * 32 + (bh & 31);
    const int tid = threadIdx.x;

    float hrun[16];
#pragma unroll
    for (int j = 0; j < 16; ++j) hrun[j] = 0.f;

    for (int s = 0; s < NSEG; ++s) {
        const size_t off = ((size_t)(base_bh * NSEG + s)) * 8192 + (size_t)tid * 16;
        float c[16];
#pragma unroll
        for (int j = 0; j < 16; ++j) c[j] = __bfloat162float(stateC[off + j]);
#pragma unroll
        for (int j = 0; j < 16; ++j) stateC[off + j] = __float2bfloat16(hrun[j]);
        const float alpha = betac[(size_t)base_bh * L_SEQ + s * SEGLEN + (SEGLEN - 1)];
#pragma unroll
        for (int j = 0; j < 16; ++j) hrun[j] = fmaf(alpha, hrun[j], c[j]);
    }
}

// ---------------------------------------------------------------------------
// Pass C: y_t += betac[t] * (C_t . h_in[p,:]). Depth-2 pipelined like Pass A.
// ---------------------------------------------------------------------------
__global__ __launch_bounds__(512) void correct_kernel(
    const float* __restrict__ Ccb, const float* __restrict__ betac,
    const __hip_bfloat16* __restrict__ stateC, float* __restrict__ zx)
{
    const int dir = blockIdx.y;
    const int bx  = blockIdx.x;
    const int bh  = bx >> 3;
    const int seg = bx & 7;
    if (seg == 0) return;
    const int b = bh >> 5, h = bh & 31;
    const int tid = threadIdx.x;
    const int p = tid >> 3;
    const int g = tid & 7;
    const int base_bh = (dir * 2 + b) * 32 + h;
    const int t0 = seg * SEGLEN;
    const int NC = SEGLEN / SC;

    float hin[16];
    {
        const size_t off = ((size_t)(base_bh * NSEG + seg)) * 8192 + (size_t)tid * 16;
#pragma unroll
        for (int j = 0; j < 16; ++j) hin[j] = __bfloat162float(stateC[off + j]);
    }

    __shared__ float sCt[3][SC][8][20];
    __shared__ float sbet[3][SC];

    const size_t dbase = (size_t)(dir * M_ROWS + b * L_SEQ);
    float* __restrict__ ybase = zx + (size_t)dir * M_ROWS * DPROJP + DINNER;

    auto lidx = [&](int t) { return dir ? (L_SEQ - 1 - t) : t; };

    auto issue_chunk = [&](int tb, float (&dst)[SC]) {
        if (tid < 128) {
#pragma unroll
            for (int s = 0; s < SC; ++s)
                dst[s] = Ccb[(dbase + lidx(tb + s)) * NST + tid];
        } else if (tid < 136) {
            dst[0] = betac[(size_t)base_bh * L_SEQ + tb + (tid - 128)];
        }
    };
    auto write_chunk = [&](int bw, float (&src)[SC]) {
        if (tid < 128) {
#pragma unroll
            for (int s = 0; s < SC; ++s) sCt[bw][s][tid >> 4][tid & 15] = src[s];
        } else if (tid < 136) {
            sbet[bw][tid - 128] = src[0];
        }
    };

    float pvA[SC], pvB[SC];
    issue_chunk(t0, pvA);
    write_chunk(0, pvA);
    if (NC > 1) issue_chunk(t0 + SC, pvA);
    __syncthreads();

    auto body = [&](int c, float (&wrv)[SC], float (&issv)[SC]) {
        const int bm = c % 3;
        const int bw = (c + 1) % 3;
        if (c + 2 < NC) issue_chunk(t0 + (c + 2) * SC, issv);

#pragma unroll
        for (int s = 0; s < SC; ++s) {
            const int t = t0 + c * SC + s;
            const float4* __restrict__ Cp4 = (const float4*)sCt[bm][s][g];
            float acc0 = 0.f, acc1 = 0.f;
#pragma unroll
            for (int q4 = 0; q4 < 4; ++q4) {
                const float4 cv = Cp4[q4];
                const float* hj = &hin[q4 * 4];
                acc0 = fmaf(hj[0], cv.x, acc0);
                acc1 = fmaf(hj[1], cv.y, acc1);
                acc0 = fmaf(hj[2], cv.z, acc0);
                acc1 = fmaf(hj[3], cv.w, acc1);
            }
            float acc = acc0 + acc1;
            acc += __shfl_xor(acc, 1);
            acc += __shfl_xor(acc, 2);
            acc += __shfl_xor(acc, 4);
            if (g == 0) {
                ybase[(size_t)(b * L_SEQ + lidx(t)) * DPROJP + h * 64 + p] += sbet[bm][s] * acc;
            }
        }

        if (c + 1 < NC) write_chunk(bw, wrv);
        __syncthreads();
    };

    for (int cc = 0; cc < NC; cc += 2) {
        body(cc, pvA, pvB);
        body(cc + 1, pvB, pvA);
    }
}

// ---------------------------------------------------------------------------
// y = y * silu(z); RMSNorm(2048) * norm_w, in place on y slice of zx.
// float4 loads/stores.
// ---------------------------------------------------------------------------
__global__ __launch_bounds__(256) void gatenorm_kernel(
    float* __restrict__ zx,
    const float* __restrict__ nw0, const float* __restrict__ nw1)
{
    const int dir = blockIdx.y;
    const int row = blockIdx.x;
    const float* __restrict__ nw = dir ? nw1 : nw0;
    float* __restrict__ rowp = zx + (size_t)dir * M_ROWS * DPROJP + (size_t)row * DPROJP;
    const int tid = threadIdx.x;
    const int c0 = tid * 8;

    const float4 y0 = *(const float4*)(rowp + DINNER + c0);
    const float4 y1 = *(const float4*)(rowp + DINNER + c0 + 4);
    const float4 z0 = *(const float4*)(rowp + c0);
    const float4 z1 = *(const float4*)(rowp + c0 + 4);

    float4 g0, g1;
    g0.x = y0.x * (z0.x / (1.f + expf(-z0.x)));
    g0.y = y0.y * (z0.y / (1.f + expf(-z0.y)));
    g0.z = y0.z * (z0.z / (1.f + expf(-z0.z)));
    g0.w = y0.w * (z0.w / (1.f + expf(-z0.w)));
    g1.x = y1.x * (z1.x / (1.f + expf(-z1.x)));
    g1.y = y1.y * (z1.y / (1.f + expf(-z1.y)));
    g1.z = y1.z * (z1.z / (1.f + expf(-z1.z)));
    g1.w = y1.w * (z1.w / (1.f + expf(-z1.w)));

    float ss = g0.x * g0.x + g0.y * g0.y + g0.z * g0.z + g0.w * g0.w
             + g1.x * g1.x + g1.y * g1.y + g1.z * g1.z + g1.w * g1.w;
#pragma unroll
    for (int off = 1; off < 64; off <<= 1) ss += __shfl_xor(ss, off);
    __shared__ float red[4];
    if ((tid & 63) == 0) red[tid >> 6] = ss;
    __syncthreads();
    const float total = red[0] + red[1] + red[2] + red[3];
    const float rs = rsqrtf(total * (1.f / (float)DINNER) + 1e-5f);

    const float4 w0 = *(const float4*)(nw + c0);
    const float4 w1 = *(const float4*)(nw + c0 + 4);
    float4 o0, o1;
    o0.x = g0.x * rs * w0.x; o0.y = g0.y * rs * w0.y;
    o0.z = g0.z * rs * w0.z; o0.w = g0.w * rs * w0.w;
    o1.x = g1.x * rs * w1.x; o1.y = g1.y * rs * w1.y;
    o1.z = g1.z * rs * w1.z; o1.w = g1.w * rs * w1.w;
    *(float4*)(rowp + DINNER + c0)     = o0;
    *(float4*)(rowp + DINNER + c0 + 4) = o1;
}

// ---------------------------------------------------------------------------
extern "C" void kernel_launch(void* const* d_in, const int* in_sizes, int n_in,
                              void* d_out, int out_size, void* d_ws, size_t ws_size,
                              hipStream_t stream)
{
    (void)in_sizes; (void)n_in; (void)out_size; (void)ws_size;
    const float* x        = (const float*)d_in[0];
    const float* f_in_w   = (const float*)d_in[1];
    const float* f_conv_w = (const float*)d_in[2];
    const float* f_conv_b = (const float*)d_in[3];
    const float* f_dtbias = (const float*)d_in[4];
    const float* f_Alog   = (const float*)d_in[5];
    const float* f_D      = (const float*)d_in[6];
    const float* f_nw     = (const float*)d_in[7];
    const float* f_out_w  = (const float*)d_in[8];
    const float* b_in_w   = (const float*)d_in[9];
    const float* b_conv_w = (const float*)d_in[10];
    const float* b_conv_b = (const float*)d_in[11];
    const float* b_dtbias = (const float*)d_in[12];
    const float* b_Alog   = (const float*)d_in[13];
    const float* b_D      = (const float*)d_in[14];
    const float* b_nw     = (const float*)d_in[15];
    const float* b_out_w  = (const float*)d_in[16];

    float* ws  = (float*)d_ws;
    float* zx  = ws;
    __hip_bfloat16* xs = (__hip_bfloat16*)(zx + (size_t)2 * M_ROWS * DPROJP);
    float* Bcb = (float*)(xs + (size_t)2 * M_ROWS * DINNER);
    float* Ccb = Bcb + (size_t)2 * M_ROWS * NST;
    float* dtb = Ccb + (size_t)2 * M_ROWS * NST;
    float* dab = dtb + (size_t)2 * M_ROWS * NH;
    __hip_bfloat16* stateC = (__hip_bfloat16*)(dab + (size_t)2 * M_ROWS * NH);
    float* betac = (float*)(stateC + (size_t)128 * NSEG * 8192);
    __hip_bfloat16* x_bf    = (__hip_bfloat16*)(betac + (size_t)128 * L_SEQ);
    __hip_bfloat16* w_in_bf = x_bf + (size_t)M_ROWS * 512;
    __hip_bfloat16* w_out_bf = w_in_bf + (size_t)2 * DPROJP * 512;

    // 0) dtype conversions
    cvt_x_kernel<<<dim3(M_ROWS * 512 / 1024), 256, 0, stream>>>(x, x_bf);
    cvt_win_kernel<<<dim3(DPROJP * 512 / 1024, 2), 256, 0, stream>>>(f_in_w, b_in_w, w_in_bf);
    cvt_wout_kernel<<<dim3(512 * DINNER / 1024, 2), 256, 0, stream>>>(f_out_w, b_out_w, w_out_bf);

    // 1) in_proj (MFMA): zx[dir] = x @ in_w[dir]^T
    gemm_mfma<false><<<dim3(DPROJP / 128, M_ROWS / 128, 2), 256, 0, stream>>>(
        x_bf, nullptr, nullptr, 0,
        w_in_bf, (long long)DPROJP * 512,
        zx, (long long)M_ROWS * DPROJP, DPROJP,
        nullptr, 0, 512);

    // 2) conv + SiLU + exact-f32 dt/dA
    conv_dt_kernel<<<dim3(M_ROWS, 2), 256, 0, stream>>>(
        zx, x, f_in_w, b_in_w,
        f_conv_w, b_conv_w, f_conv_b, b_conv_b,
        f_dtbias, b_dtbias, f_Alog, b_Alog,
        xs, Bcb, Ccb, dtb, dab);

    // 3a) segment-local scans (+ D-skip into y slice of zx)
    scan_seg_kernel<<<dim3(64 * NSEG, 2), 512, 0, stream>>>(
        xs, Bcb, Ccb, dtb, dab, f_D, b_D, zx, stateC, betac);

    // 3b) combine segment states
    combine_kernel<<<dim3(64, 2), 512, 0, stream>>>(stateC, betac);

    // 3c) inter-segment correction
    correct_kernel<<<dim3(64 * NSEG, 2), 512, 0, stream>>>(Ccb, betac, stateC, zx);

    // 4) gate + RMSNorm in place on y slice
    gatenorm_kernel<<<dim3(M_ROWS, 2), 256, 0, stream>>>(zx, f_nw, b_nw);

    // 5) out_proj (MFMA) + residual + concat
    gemm_mfma<true><<<dim3(512 / 128, M_ROWS / 128, 2), 256, 0, stream>>>(
        nullptr, zx + DINNER, zx + (size_t)M_ROWS * DPROJP + DINNER, DPROJP,
        w_out_bf, (long long)512 * DINNER,
        (float*)d_out, 512, 1024,
        x, 512, DINNER);
}

// Round 7
// 508.217 us; speedup vs baseline: 1.5746x; 1.5746x over previous
//
#include <hip/hip_runtime.h>
#include <hip/hip_bf16.h>
#include <math.h>

#define L_SEQ   2048
#define M_ROWS  4096            // B*L
#define DPROJ   4384
#define DPROJP  4480            // padded to 35*128 for MFMA GEMM
#define DINNER  2048
#define CONVDIM 2304
#define NST     128
#define NH      32
#define CHUNK   128             // SSD chunk length
#define NCH     16              // L_SEQ / CHUNK

typedef __attribute__((ext_vector_type(8))) short short8;
typedef __attribute__((ext_vector_type(4))) float f32x4;
typedef unsigned short u16;

union bf8u { short8 v; __hip_bfloat16 e[8]; };

static __device__ __forceinline__ u16 bf16bits(float v) {
    __hip_bfloat16 t = __float2bfloat16(v);
    return *(u16*)&t;
}
static __device__ __forceinline__ float bits2f(u16 u) {
    return __uint_as_float((unsigned)u << 16);
}
// element index into a [rows][128] bf16 LDS buffer with 16B-slot XOR swizzle
static __device__ __forceinline__ int sidx(int row, int s) {
    return (row << 7) + ((((s >> 3) ^ (row & 7)) << 3) | (s & 7));
}
static __device__ __forceinline__ int sslot(int row, int ks) {  // ks = 16B slot 0..15
    return (row << 7) + ((ks ^ (row & 7)) << 3);
}

// ---------------------------------------------------------------------------
// f32 -> bf16 conversion pre-passes
// ---------------------------------------------------------------------------
__global__ __launch_bounds__(256) void cvt_x_kernel(
    const float* __restrict__ x, __hip_bfloat16* __restrict__ xbf)
{
    const int i = (blockIdx.x * 256 + threadIdx.x) * 4;
    const float4 v = *(const float4*)(x + i);
    xbf[i + 0] = __float2bfloat16(v.x);
    xbf[i + 1] = __float2bfloat16(v.y);
    xbf[i + 2] = __float2bfloat16(v.z);
    xbf[i + 3] = __float2bfloat16(v.w);
}

__global__ __launch_bounds__(256) void cvt_win_kernel(
    const float* __restrict__ w0, const float* __restrict__ w1,
    __hip_bfloat16* __restrict__ dst)
{
    const int dir = blockIdx.y;
    const float* __restrict__ w = dir ? w1 : w0;
    __hip_bfloat16* __restrict__ d = dst + (size_t)dir * DPROJP * 512;
    const int i = (blockIdx.x * 256 + threadIdx.x) * 4;
    const int row = i >> 9;
    if (row < DPROJ) {
        const float4 v = *(const float4*)(w + i);
        d[i + 0] = __float2bfloat16(v.x);
        d[i + 1] = __float2bfloat16(v.y);
        d[i + 2] = __float2bfloat16(v.z);
        d[i + 3] = __float2bfloat16(v.w);
    } else {
        d[i + 0] = __float2bfloat16(0.f); d[i + 1] = __float2bfloat16(0.f);
        d[i + 2] = __float2bfloat16(0.f); d[i + 3] = __float2bfloat16(0.f);
    }
}

__global__ __launch_bounds__(256) void cvt_wout_kernel(
    const float* __restrict__ w0, const float* __restrict__ w1,
    __hip_bfloat16* __restrict__ dst)
{
    const int dir = blockIdx.y;
    const float* __restrict__ w = dir ? w1 : w0;
    __hip_bfloat16* __restrict__ d = dst + (size_t)dir * 512 * DINNER;
    const int i = (blockIdx.x * 256 + threadIdx.x) * 4;
    const float4 v = *(const float4*)(w + i);
    d[i + 0] = __float2bfloat16(v.x);
    d[i + 1] = __float2bfloat16(v.y);
    d[i + 2] = __float2bfloat16(v.z);
    d[i + 3] = __float2bfloat16(v.w);
}

// ---------------------------------------------------------------------------
// MFMA bf16 GEMM: C[M][N] = A[M][K] @ B[N][K]^T (+ optional f32 addsrc).
// 128x128 tile, BK=64, 256 threads. LDS XOR-swizzled.
// ---------------------------------------------------------------------------
template<bool AF32>
__global__ __launch_bounds__(256) void gemm_mfma(
    const __hip_bfloat16* __restrict__ Abf,
    const float* __restrict__ Af0, const float* __restrict__ Af1, int lda_f,
    const __hip_bfloat16* __restrict__ Bw, long long b_dir_off,
    float* __restrict__ C, long long c_dir_off, int ldc,
    const float* __restrict__ addsrc, int add_ld,
    int K)
{
    const int dir = blockIdx.z;
    const int m0 = blockIdx.y * 128;
    const int n0 = blockIdx.x * 128;
    const __hip_bfloat16* __restrict__ B = Bw + (size_t)dir * b_dir_off;
    const float* __restrict__ Af = dir ? Af1 : Af0;
    float* __restrict__ Cp = C + (size_t)dir * c_dir_off;

    __shared__ __hip_bfloat16 Asl[128 * 64];
    __shared__ __hip_bfloat16 Bsl[128 * 64];

    const int tid  = threadIdx.x;
    const int lane = tid & 63;
    const int wid  = tid >> 6;
    const int wr   = (wid >> 1) << 6;
    const int wc   = (wid & 1) << 6;
    const int l15  = lane & 15;
    const int l4   = lane >> 4;

    f32x4 acc[4][4];
#pragma unroll
    for (int m = 0; m < 4; ++m)
#pragma unroll
        for (int n = 0; n < 4; ++n) acc[m][n] = (f32x4)0.f;

    for (int k0 = 0; k0 < K; k0 += 64) {
        __syncthreads();
#pragma unroll
        for (int i = 0; i < 4; ++i) {
            const int c    = tid + (i << 8);
            const int row  = c >> 3;
            const int slot = c & 7;
            const int dst  = (row << 7) + ((slot ^ (row & 7)) << 4);
            if (AF32) {
                const float* s = Af + (size_t)(m0 + row) * lda_f + k0 + (slot << 3);
                const float4 lo = *(const float4*)(s);
                const float4 hi = *(const float4*)(s + 4);
                bf8u u;
                u.e[0] = __float2bfloat16(lo.x); u.e[1] = __float2bfloat16(lo.y);
                u.e[2] = __float2bfloat16(lo.z); u.e[3] = __float2bfloat16(lo.w);
                u.e[4] = __float2bfloat16(hi.x); u.e[5] = __float2bfloat16(hi.y);
                u.e[6] = __float2bfloat16(hi.z); u.e[7] = __float2bfloat16(hi.w);
                *(short8*)((char*)Asl + dst) = u.v;
            } else {
                *(short8*)((char*)Asl + dst) =
                    *(const short8*)(Abf + (size_t)(m0 + row) * K + k0 + (slot << 3));
            }
            *(short8*)((char*)Bsl + dst) =
                *(const short8*)(B + (size_t)(n0 + row) * K + k0 + (slot << 3));
        }
        __syncthreads();

#pragma unroll
        for (int kh = 0; kh < 2; ++kh) {
            const int ks = (kh << 2) + l4;
            short8 a[4], b[4];
#pragma unroll
            for (int m = 0; m < 4; ++m) {
                const int R = wr + (m << 4) + l15;
                a[m] = *(const short8*)((const char*)Asl + (R << 7) + ((ks ^ (R & 7)) << 4));
            }
#pragma unroll
            for (int n = 0; n < 4; ++n) {
                const int R = wc + (n << 4) + l15;
                b[n] = *(const short8*)((const char*)Bsl + (R << 7) + ((ks ^ (R & 7)) << 4));
            }
#pragma unroll
            for (int m = 0; m < 4; ++m)
#pragma unroll
                for (int n = 0; n < 4; ++n)
                    acc[m][n] = __builtin_amdgcn_mfma_f32_16x16x32_bf16(
                        a[m], b[n], acc[m][n], 0, 0, 0);
        }
    }

#pragma unroll
    for (int m = 0; m < 4; ++m) {
        const int row0 = m0 + wr + (m << 4) + (l4 << 2);
#pragma unroll
        for (int n = 0; n < 4; ++n) {
            const int col = n0 + wc + (n << 4) + l15;
#pragma unroll
            for (int r = 0; r < 4; ++r) {
                float v = acc[m][n][r];
                if (addsrc) v += addsrc[(size_t)(row0 + r) * add_ld + col];
                Cp[(size_t)(row0 + r) * ldc + col] = v;
            }
        }
    }
}

// ---------------------------------------------------------------------------
// Depthwise causal conv(4) + SiLU; B/C emitted bf16; exact-f32 dt; softplus;
// dta = dt * (-exp(A_log)) stored as LOG-decay (not exponentiated).
// ---------------------------------------------------------------------------
__global__ __launch_bounds__(256) void conv_dt_kernel(
    const float* __restrict__ zx, const float* __restrict__ x,
    const float* __restrict__ inw0, const float* __restrict__ inw1,
    const float* __restrict__ cw0, const float* __restrict__ cw1,
    const float* __restrict__ cb0, const float* __restrict__ cb1,
    const float* __restrict__ dtbias0, const float* __restrict__ dtbias1,
    const float* __restrict__ Alog0, const float* __restrict__ Alog1,
    u16* __restrict__ xs, u16* __restrict__ Bbf, u16* __restrict__ Cbf,
    float* __restrict__ dtb, float* __restrict__ dta)
{
    const int dir = blockIdx.y;
    const int row = blockIdx.x;
    const int b = row >> 11;
    const int l = row & (L_SEQ - 1);

    const float* __restrict__ cw = dir ? cw1 : cw0;
    const float* __restrict__ cb = dir ? cb1 : cb0;
    const float* __restrict__ zbase = zx + (size_t)dir * M_ROWS * DPROJP;
    const size_t orow = (size_t)(dir * M_ROWS + row);

    for (int c4 = threadIdx.x; c4 < CONVDIM / 4; c4 += 256) {
        const int c = c4 << 2;
        float4 acc = *(const float4*)(cb + c);
        const float4 wch0 = *(const float4*)(cw + (c + 0) * 4);
        const float4 wch1 = *(const float4*)(cw + (c + 1) * 4);
        const float4 wch2 = *(const float4*)(cw + (c + 2) * 4);
        const float4 wch3 = *(const float4*)(cw + (c + 3) * 4);
#pragma unroll
        for (int k = 0; k < 4; ++k) {
            const int p = dir ? (l + 3 - k) : (l - 3 + k);
            const bool ok = dir ? (p < L_SEQ) : (p >= 0);
            if (ok) {
                const float4 z = *(const float4*)(zbase
                    + (size_t)(b * L_SEQ + p) * DPROJP + DINNER + c);
                const float t0 = (k == 0) ? wch0.x : (k == 1) ? wch0.y : (k == 2) ? wch0.z : wch0.w;
                const float t1 = (k == 0) ? wch1.x : (k == 1) ? wch1.y : (k == 2) ? wch1.z : wch1.w;
                const float t2 = (k == 0) ? wch2.x : (k == 1) ? wch2.y : (k == 2) ? wch2.z : wch2.w;
                const float t3 = (k == 0) ? wch3.x : (k == 1) ? wch3.y : (k == 2) ? wch3.z : wch3.w;
                acc.x = fmaf(z.x, t0, acc.x);
                acc.y = fmaf(z.y, t1, acc.y);
                acc.z = fmaf(z.z, t2, acc.z);
                acc.w = fmaf(z.w, t3, acc.w);
            }
        }
        ushort4 us;
        us.x = bf16bits(acc.x / (1.f + expf(-acc.x)));
        us.y = bf16bits(acc.y / (1.f + expf(-acc.y)));
        us.z = bf16bits(acc.z / (1.f + expf(-acc.z)));
        us.w = bf16bits(acc.w / (1.f + expf(-acc.w)));
        if (c < DINNER) {
            *(ushort4*)(xs + orow * DINNER + c) = us;
        } else if (c < DINNER + NST) {
            *(ushort4*)(Bbf + orow * NST + (c - DINNER)) = us;
        } else {
            *(ushort4*)(Cbf + orow * NST + (c - DINNER - NST)) = us;
        }
    }

    {   // exact f32 dt: 8 threads per head, float4 dot
        const int h = threadIdx.x >> 3;
        const int part = threadIdx.x & 7;
        const float4* __restrict__ xr4 = (const float4*)(x + (size_t)row * 512 + part * 64);
        const float4* __restrict__ wr4 = (const float4*)((dir ? inw1 : inw0)
            + (size_t)(DINNER + CONVDIM + h) * 512 + part * 64);
        float s = 0.f;
#pragma unroll
        for (int k = 0; k < 16; ++k) {
            const float4 a = xr4[k], w = wr4[k];
            s = fmaf(a.x, w.x, s); s = fmaf(a.y, w.y, s);
            s = fmaf(a.z, w.z, s); s = fmaf(a.w, w.w, s);
        }
        s += __shfl_xor(s, 1);
        s += __shfl_xor(s, 2);
        s += __shfl_xor(s, 4);
        if (part == 0) {
            const float v = s + (dir ? dtbias1 : dtbias0)[h];
            const float sp = (v > 20.f) ? v : log1pf(expf(v));
            const float a = -expf((dir ? Alog1 : Alog0)[h]);
            dtb[orow * NH + h] = sp;
            dta[orow * NH + h] = sp * a;     // log-decay
        }
    }
}

// ---------------------------------------------------------------------------
// SSD chunk kernel. Block = (bh, chunk), 256 threads (4 waves).
//   cumA  = inclusive prefix of log-decay (chunk-local), stored to betac.
//   X~T   = LDS [p=64][s=128] bf16, X~ = dt_s * x
//   WBT   = LDS [n=128][s=128] bf16, r_s * B,  r_s = exp(cumA[127]-cumA[s])
//   STATE: c[p][n] = X~T @ WBT^T   -> stateC (bf16, [p][n])
//   S     = C @ B^T (global bf16 operands), scale by Gamma=exp(cumA_t-cumA_s)
//   P~    -> LDS (over WBT), Y = P~ @ X~T^T; y = Y + D*x -> zx y-slice
// ---------------------------------------------------------------------------
__global__ __launch_bounds__(256) void ssd_chunk_kernel(
    const u16* __restrict__ xs, const u16* __restrict__ Bbf,
    const u16* __restrict__ Cbf,
    const float* __restrict__ dtb, const float* __restrict__ dta,
    const float* __restrict__ D0, const float* __restrict__ D1,
    float* __restrict__ zx, u16* __restrict__ stateC,
    float* __restrict__ betac)
{
    const int bx  = blockIdx.x;
    const int ch  = bx & (NCH - 1);
    const int bh  = bx >> 4;
    const int dir = bh >> 6;
    const int bb  = (bh >> 5) & 1;
    const int h   = bh & 31;
    const int tid = threadIdx.x;
    const int wid = tid >> 6;
    const int lane = tid & 63;
    const int l15 = lane & 15;
    const int l4  = lane >> 4;
    const int t0  = ch * CHUNK;
    const size_t dbase = (size_t)(dir * M_ROWS + bb * L_SEQ);
    const float Dv = (dir ? D1 : D0)[h];

    __shared__ u16 XT[64 * 128];
    __shared__ u16 WBT[128 * 128];     // reused as P~ after state/S phases
    __shared__ float scum[CHUNK];
    __shared__ float sdt[CHUNK];

    auto lidx = [&](int t) { return dir ? (L_SEQ - 1 - t) : t; };

    // ---- phase A: dt loads + cumA prefix-sum (wave 0) ----
    if (tid >= 128) {
        const int s = tid - 128;
        sdt[s] = dtb[(dbase + lidx(t0 + s)) * NH + h];
    }
    if (wid == 0) {
        float a0 = dta[(dbase + lidx(t0 + lane)) * NH + h];
        float a1 = dta[(dbase + lidx(t0 + 64 + lane)) * NH + h];
#pragma unroll
        for (int off = 1; off < 64; off <<= 1) {
            const float u0 = __shfl_up(a0, off);
            const float u1 = __shfl_up(a1, off);
            if (lane >= off) { a0 += u0; a1 += u1; }
        }
        a1 += __shfl(a0, 63);
        scum[lane] = a0; scum[64 + lane] = a1;
        betac[(size_t)bh * L_SEQ + t0 + lane] = a0;
        betac[(size_t)bh * L_SEQ + t0 + 64 + lane] = a1;
    }
    __syncthreads();

    // ---- phase B: build X~T and WBT ----
    {
        const int s = tid >> 1;
        const float dts = sdt[s];
        const float rs = expf(scum[CHUNK - 1] - scum[s]);
        const size_t grow = dbase + lidx(t0 + s);
        const int p0 = (tid & 1) * 32;
        const u16* __restrict__ xp = xs + grow * DINNER + h * 64 + p0;
#pragma unroll
        for (int q = 0; q < 4; ++q) {
            short8 v = *(const short8*)(xp + q * 8);
#pragma unroll
            for (int j = 0; j < 8; ++j) {
                const int p = p0 + q * 8 + j;
                XT[sidx(p, s)] = bf16bits(dts * bits2f((u16)v[j]));
            }
        }
        const int n0 = (tid & 1) * 64;
        const u16* __restrict__ bp = Bbf + grow * NST + n0;
#pragma unroll
        for (int q = 0; q < 8; ++q) {
            short8 v = *(const short8*)(bp + q * 8);
#pragma unroll
            for (int j = 0; j < 8; ++j) {
                const int n = n0 + q * 8 + j;
                WBT[sidx(n, s)] = bf16bits(rs * bits2f((u16)v[j]));
            }
        }
    }
    __syncthreads();

    // ---- phase C1: STATE GEMM c[p][n] (wave w owns p-rows 16w..16w+16) ----
    {
        const int pw = wid * 16;
        const int prow = pw + l15;
        short8 xa[4];
#pragma unroll
        for (int kk = 0; kk < 4; ++kk)
            xa[kk] = *(const short8*)(XT + sslot(prow, kk * 4 + l4));
        const size_t sbase = ((size_t)bh * NCH + ch) * 8192;
#pragma unroll
        for (int jn = 0; jn < 8; ++jn) {
            const int nrow = jn * 16 + l15;
            f32x4 acc = (f32x4)0.f;
#pragma unroll
            for (int kk = 0; kk < 4; ++kk) {
                const short8 wb = *(const short8*)(WBT + sslot(nrow, kk * 4 + l4));
                acc = __builtin_amdgcn_mfma_f32_16x16x32_bf16(xa[kk], wb, acc, 0, 0, 0);
            }
#pragma unroll
            for (int r = 0; r < 4; ++r)
                stateC[sbase + (size_t)(pw + l4 * 4 + r) * 128 + jn * 16 + l15] =
                    bf16bits(acc[r]);
        }
    }

    // ---- phase C2: S GEMM (global bf16 operands) ----
    f32x4 accs[2][8];
#pragma unroll
    for (int m = 0; m < 2; ++m)
#pragma unroll
        for (int j = 0; j < 8; ++j) accs[m][j] = (f32x4)0.f;
    {
        short8 af[2][4];
#pragma unroll
        for (int m = 0; m < 2; ++m) {
            const size_t crow = dbase + lidx(t0 + wid * 32 + m * 16 + l15);
#pragma unroll
            for (int kk = 0; kk < 4; ++kk)
                af[m][kk] = *(const short8*)(Cbf + crow * NST + kk * 32 + l4 * 8);
        }
#pragma unroll
        for (int j = 0; j < 8; ++j) {
            const size_t brow = dbase + lidx(t0 + j * 16 + l15);
            short8 bf_[4];
#pragma unroll
            for (int kk = 0; kk < 4; ++kk)
                bf_[kk] = *(const short8*)(Bbf + brow * NST + kk * 32 + l4 * 8);
#pragma unroll
            for (int m = 0; m < 2; ++m)
#pragma unroll
                for (int kk = 0; kk < 4; ++kk)
                    accs[m][j] = __builtin_amdgcn_mfma_f32_16x16x32_bf16(
                        af[m][kk], bf_[kk], accs[m][j], 0, 0, 0);
        }
    }
    __syncthreads();   // all waves done with WBT (state phase reads)

    // ---- phase C3: Gamma-scale, write P~ over WBT ----
    u16* __restrict__ PT = WBT;
#pragma unroll
    for (int m = 0; m < 2; ++m) {
#pragma unroll
        for (int r = 0; r < 4; ++r) {
            const int t = wid * 32 + m * 16 + l4 * 4 + r;
            const float ct = scum[t];
#pragma unroll
            for (int j = 0; j < 8; ++j) {
                const int s = j * 16 + l15;
                const float g = (s <= t) ? expf(ct - scum[s]) : 0.f;
                PT[sidx(t, s)] = bf16bits(accs[m][j][r] * g);
            }
        }
    }
    __syncthreads();

    // ---- phase D: Y = P~ @ X~T^T, + D-skip, store ----
    {
        float* __restrict__ ybase = zx + (size_t)dir * M_ROWS * DPROJP + DINNER;
        short8 pa[2][4];
#pragma unroll
        for (int m = 0; m < 2; ++m) {
            const int trow = wid * 32 + m * 16 + l15;
#pragma unroll
            for (int kk = 0; kk < 4; ++kk)
                pa[m][kk] = *(const short8*)(PT + sslot(trow, kk * 4 + l4));
        }
#pragma unroll
        for (int jp = 0; jp < 4; ++jp) {
            const int prow = jp * 16 + l15;
            short8 xb[4];
#pragma unroll
            for (int kk = 0; kk < 4; ++kk)
                xb[kk] = *(const short8*)(XT + sslot(prow, kk * 4 + l4));
#pragma unroll
            for (int m = 0; m < 2; ++m) {
                f32x4 acc = (f32x4)0.f;
#pragma unroll
                for (int kk = 0; kk < 4; ++kk)
                    acc = __builtin_amdgcn_mfma_f32_16x16x32_bf16(
                        pa[m][kk], xb[kk], acc, 0, 0, 0);
                const int p = jp * 16 + l15;
#pragma unroll
                for (int r = 0; r < 4; ++r) {
                    const int t = wid * 32 + m * 16 + l4 * 4 + r;
                    const int lg = lidx(t0 + t);
                    const float xv = bits2f(xs[(dbase + lg) * DINNER + h * 64 + p]);
                    ybase[(size_t)(bb * L_SEQ + lg) * DPROJP + h * 64 + p] =
                        acc[r] + Dv * xv;
                }
            }
        }
    }
}

// ---------------------------------------------------------------------------
// Combine: sequential over NCH chunks per bh (in place on stateC).
// ---------------------------------------------------------------------------
__global__ __launch_bounds__(512) void combine_kernel(
    u16* __restrict__ stateC, const float* __restrict__ betac)
{
    const int bh  = blockIdx.x;
    const int tid = threadIdx.x;

    float hrun[16];
#pragma unroll
    for (int j = 0; j < 16; ++j) hrun[j] = 0.f;

    for (int s = 0; s < NCH; ++s) {
        const size_t off = ((size_t)bh * NCH + s) * 8192 + (size_t)tid * 16;
        float c[16];
#pragma unroll
        for (int j = 0; j < 16; ++j) c[j] = bits2f(stateC[off + j]);
#pragma unroll
        for (int j = 0; j < 16; ++j) stateC[off + j] = bf16bits(hrun[j]);
        const float alpha = expf(betac[(size_t)bh * L_SEQ + s * CHUNK + (CHUNK - 1)]);
#pragma unroll
        for (int j = 0; j < 16; ++j) hrun[j] = fmaf(alpha, hrun[j], c[j]);
    }
}

// ---------------------------------------------------------------------------
// Correction: y[t] += exp(cumA_t) * (C_t . h_in). MFMA, chunk>0 only.
// ---------------------------------------------------------------------------
__global__ __launch_bounds__(256) void correct_kernel(
    const u16* __restrict__ Cbf, const float* __restrict__ betac,
    const u16* __restrict__ stateC, float* __restrict__ zx)
{
    const int bx  = blockIdx.x;
    const int ch  = bx & (NCH - 1);
    if (ch == 0) return;
    const int bh  = bx >> 4;
    const int dir = bh >> 6;
    const int bb  = (bh >> 5) & 1;
    const int h   = bh & 31;
    const int tid = threadIdx.x;
    const int wid = tid >> 6;
    const int lane = tid & 63;
    const int l15 = lane & 15;
    const int l4  = lane >> 4;
    const int t0  = ch * CHUNK;
    const size_t dbase = (size_t)(dir * M_ROWS + bb * L_SEQ);
    const size_t sbase = ((size_t)bh * NCH + ch) * 8192;

    auto lidx = [&](int t) { return dir ? (L_SEQ - 1 - t) : t; };

    short8 af[2][4];
#pragma unroll
    for (int m = 0; m < 2; ++m) {
        const size_t crow = dbase + lidx(t0 + wid * 32 + m * 16 + l15);
#pragma unroll
        for (int kk = 0; kk < 4; ++kk)
            af[m][kk] = *(const short8*)(Cbf + crow * NST + kk * 32 + l4 * 8);
    }

    f32x4 acc[2][4];
#pragma unroll
    for (int m = 0; m < 2; ++m)
#pragma unroll
        for (int jp = 0; jp < 4; ++jp) acc[m][jp] = (f32x4)0.f;

#pragma unroll
    for (int jp = 0; jp < 4; ++jp) {
        const int prow = jp * 16 + l15;
        short8 hb[4];
#pragma unroll
        for (int kk = 0; kk < 4; ++kk)
            hb[kk] = *(const short8*)(stateC + sbase + (size_t)prow * 128 + kk * 32 + l4 * 8);
#pragma unroll
        for (int m = 0; m < 2; ++m)
#pragma unroll
            for (int kk = 0; kk < 4; ++kk)
                acc[m][jp] = __builtin_amdgcn_mfma_f32_16x16x32_bf16(
                    af[m][kk], hb[kk], acc[m][jp], 0, 0, 0);
    }

    float* __restrict__ ybase = zx + (size_t)dir * M_ROWS * DPROJP + DINNER;
#pragma unroll
    for (int m = 0; m < 2; ++m) {
#pragma unroll
        for (int r = 0; r < 4; ++r) {
            const int t = wid * 32 + m * 16 + l4 * 4 + r;
            const float g = expf(betac[(size_t)bh * L_SEQ + t0 + t]);
            const int lg = lidx(t0 + t);
#pragma unroll
            for (int jp = 0; jp < 4; ++jp) {
                const int p = jp * 16 + l15;
                ybase[(size_t)(bb * L_SEQ + lg) * DPROJP + h * 64 + p] += g * acc[m][jp][r];
            }
        }
    }
}

// ---------------------------------------------------------------------------
// y = y * silu(z); RMSNorm(2048) * norm_w, in place on y slice of zx.
// ---------------------------------------------------------------------------
__global__ __launch_bounds__(256) void gatenorm_kernel(
    float* __restrict__ zx,
    const float* __restrict__ nw0, const float* __restrict__ nw1)
{
    const int dir = blockIdx.y;
    const int row = blockIdx.x;
    const float* __restrict__ nw = dir ? nw1 : nw0;
    float* __restrict__ rowp = zx + (size_t)dir * M_ROWS * DPROJP + (size_t)row * DPROJP;
    const int tid = threadIdx.x;
    const int c0 = tid * 8;

    const float4 y0 = *(const float4*)(rowp + DINNER + c0);
    const float4 y1 = *(const float4*)(rowp + DINNER + c0 + 4);
    const float4 z0 = *(const float4*)(rowp + c0);
    const float4 z1 = *(const float4*)(rowp + c0 + 4);

    float4 g0, g1;
    g0.x = y0.x * (z0.x / (1.f + expf(-z0.x)));
    g0.y = y0.y * (z0.y / (1.f + expf(-z0.y)));
    g0.z = y0.z * (z0.z / (1.f + expf(-z0.z)));
    g0.w = y0.w * (z0.w / (1.f + expf(-z0.w)));
    g1.x = y1.x * (z1.x / (1.f + expf(-z1.x)));
    g1.y = y1.y * (z1.y / (1.f + expf(-z1.y)));
    g1.z = y1.z * (z1.z / (1.f + expf(-z1.z)));
    g1.w = y1.w * (z1.w / (1.f + expf(-z1.w)));

    float ss = g0.x * g0.x + g0.y * g0.y + g0.z * g0.z + g0.w * g0.w
             + g1.x * g1.x + g1.y * g1.y + g1.z * g1.z + g1.w * g1.w;
#pragma unroll
    for (int off = 1; off < 64; off <<= 1) ss += __shfl_xor(ss, off);
    __shared__ float red[4];
    if ((tid & 63) == 0) red[tid >> 6] = ss;
    __syncthreads();
    const float total = red[0] + red[1] + red[2] + red[3];
    const float rs = rsqrtf(total * (1.f / (float)DINNER) + 1e-5f);

    const float4 w0 = *(const float4*)(nw + c0);
    const float4 w1 = *(const float4*)(nw + c0 + 4);
    float4 o0, o1;
    o0.x = g0.x * rs * w0.x; o0.y = g0.y * rs * w0.y;
    o0.z = g0.z * rs * w0.z; o0.w = g0.w * rs * w0.w;
    o1.x = g1.x * rs * w1.x; o1.y = g1.y * rs * w1.y;
    o1.z = g1.z * rs * w1.z; o1.w = g1.w * rs * w1.w;
    *(float4*)(rowp + DINNER + c0)     = o0;
    *(float4*)(rowp + DINNER + c0 + 4) = o1;
}

// ---------------------------------------------------------------------------
extern "C" void kernel_launch(void* const* d_in, const int* in_sizes, int n_in,
                              void* d_out, int out_size, void* d_ws, size_t ws_size,
                              hipStream_t stream)
{
    (void)in_sizes; (void)n_in; (void)out_size; (void)ws_size;
    const float* x        = (const float*)d_in[0];
    const float* f_in_w   = (const float*)d_in[1];
    const float* f_conv_w = (const float*)d_in[2];
    const float* f_conv_b = (const float*)d_in[3];
    const float* f_dtbias = (const float*)d_in[4];
    const float* f_Alog   = (const float*)d_in[5];
    const float* f_D      = (const float*)d_in[6];
    const float* f_nw     = (const float*)d_in[7];
    const float* f_out_w  = (const float*)d_in[8];
    const float* b_in_w   = (const float*)d_in[9];
    const float* b_conv_w = (const float*)d_in[10];
    const float* b_conv_b = (const float*)d_in[11];
    const float* b_dtbias = (const float*)d_in[12];
    const float* b_Alog   = (const float*)d_in[13];
    const float* b_D      = (const float*)d_in[14];
    const float* b_nw     = (const float*)d_in[15];
    const float* b_out_w  = (const float*)d_in[16];

    // Workspace (~239 MB): zx 146.8 | xs 33.6 | Bbf 2.1 | Cbf 2.1 | dtb 1.05
    //   | dta 1.05 | stateC 33.6 | betac 1.05 | x_bf 4.2 | w_in 9.2 | w_out 4.2
    float* ws  = (float*)d_ws;
    float* zx  = ws;
    u16* xs  = (u16*)(zx + (size_t)2 * M_ROWS * DPROJP);
    u16* Bbf = xs + (size_t)2 * M_ROWS * DINNER;
    u16* Cbf = Bbf + (size_t)2 * M_ROWS * NST;
    float* dtb = (float*)(Cbf + (size_t)2 * M_ROWS * NST);
    float* dta = dtb + (size_t)2 * M_ROWS * NH;
    u16* stateC = (u16*)(dta + (size_t)2 * M_ROWS * NH);
    float* betac = (float*)(stateC + (size_t)128 * NCH * 8192);
    __hip_bfloat16* x_bf    = (__hip_bfloat16*)(betac + (size_t)128 * L_SEQ);
    __hip_bfloat16* w_in_bf = x_bf + (size_t)M_ROWS * 512;
    __hip_bfloat16* w_out_bf = w_in_bf + (size_t)2 * DPROJP * 512;

    // 0) dtype conversions
    cvt_x_kernel<<<dim3(M_ROWS * 512 / 1024), 256, 0, stream>>>(x, x_bf);
    cvt_win_kernel<<<dim3(DPROJP * 512 / 1024, 2), 256, 0, stream>>>(f_in_w, b_in_w, w_in_bf);
    cvt_wout_kernel<<<dim3(512 * DINNER / 1024, 2), 256, 0, stream>>>(f_out_w, b_out_w, w_out_bf);

    // 1) in_proj (MFMA): zx[dir] = x @ in_w[dir]^T
    gemm_mfma<false><<<dim3(DPROJP / 128, M_ROWS / 128, 2), 256, 0, stream>>>(
        (const __hip_bfloat16*)x_bf, nullptr, nullptr, 0,
        w_in_bf, (long long)DPROJP * 512,
        zx, (long long)M_ROWS * DPROJP, DPROJP,
        nullptr, 0, 512);

    // 2) conv + SiLU (bf16 x/B/C) + exact-f32 dt / log-decay
    conv_dt_kernel<<<dim3(M_ROWS, 2), 256, 0, stream>>>(
        zx, x, f_in_w, b_in_w,
        f_conv_w, b_conv_w, f_conv_b, b_conv_b,
        f_dtbias, b_dtbias, f_Alog, b_Alog,
        xs, Bbf, Cbf, dtb, dta);

    // 3a) SSD chunk kernel (local Y + D-skip + chunk states + cumA)
    ssd_chunk_kernel<<<dim3(128 * NCH), 256, 0, stream>>>(
        xs, Bbf, Cbf, dtb, dta, f_D, b_D, zx, stateC, betac);

    // 3b) combine chunk states
    combine_kernel<<<dim3(128), 512, 0, stream>>>(stateC, betac);

    // 3c) inter-chunk correction (MFMA)
    correct_kernel<<<dim3(128 * NCH), 256, 0, stream>>>(Cbf, betac, stateC, zx);

    // 4) gate + RMSNorm in place on y slice
    gatenorm_kernel<<<dim3(M_ROWS, 2), 256, 0, stream>>>(zx, f_nw, b_nw);

    // 5) out_proj (MFMA) + residual + concat
    gemm_mfma<true><<<dim3(512 / 128, M_ROWS / 128, 2), 256, 0, stream>>>(
        nullptr, zx + DINNER, zx + (size_t)M_ROWS * DPROJP + DINNER, DPROJP,
        w_out_bf, (long long)512 * DINNER,
        (float*)d_out, 512, 1024,
        x, 512, DINNER);
}

// Round 8
// 493.503 us; speedup vs baseline: 1.6216x; 1.0298x over previous
//
#include <hip/hip_runtime.h>
#include <hip/hip_bf16.h>
#include <math.h>

#define L_SEQ   2048
#define M_ROWS  4096            // B*L
#define DPROJ   4384
#define DPROJP  4480            // padded to 35*128 for MFMA GEMM
#define DINNER  2048
#define CONVDIM 2304
#define NST     128
#define NH      32
#define CHUNK   128             // SSD chunk length
#define NCH     16              // L_SEQ / CHUNK
#define CTR     128             // conv rows per tile

typedef __attribute__((ext_vector_type(8))) short short8;
typedef __attribute__((ext_vector_type(4))) float f32x4;
typedef unsigned short u16;

union bf8u { short8 v; __hip_bfloat16 e[8]; };

static __device__ __forceinline__ u16 bf16bits(float v) {
    __hip_bfloat16 t = __float2bfloat16(v);
    return *(u16*)&t;
}
static __device__ __forceinline__ float bits2f(u16 u) {
    return __uint_as_float((unsigned)u << 16);
}
// element index into a [rows][128] bf16 LDS buffer with 16B-slot XOR swizzle
static __device__ __forceinline__ int sidx(int row, int s) {
    return (row << 7) + ((((s >> 3) ^ (row & 7)) << 3) | (s & 7));
}
static __device__ __forceinline__ int sslot(int row, int ks) {  // ks = 16B slot 0..15
    return (row << 7) + ((ks ^ (row & 7)) << 3);
}

// ---------------------------------------------------------------------------
// f32 -> bf16 conversion pre-passes
// ---------------------------------------------------------------------------
__global__ __launch_bounds__(256) void cvt_x_kernel(
    const float* __restrict__ x, __hip_bfloat16* __restrict__ xbf)
{
    const int i = (blockIdx.x * 256 + threadIdx.x) * 4;
    const float4 v = *(const float4*)(x + i);
    xbf[i + 0] = __float2bfloat16(v.x);
    xbf[i + 1] = __float2bfloat16(v.y);
    xbf[i + 2] = __float2bfloat16(v.z);
    xbf[i + 3] = __float2bfloat16(v.w);
}

__global__ __launch_bounds__(256) void cvt_win_kernel(
    const float* __restrict__ w0, const float* __restrict__ w1,
    __hip_bfloat16* __restrict__ dst)
{
    const int dir = blockIdx.y;
    const float* __restrict__ w = dir ? w1 : w0;
    __hip_bfloat16* __restrict__ d = dst + (size_t)dir * DPROJP * 512;
    const int i = (blockIdx.x * 256 + threadIdx.x) * 4;
    const int row = i >> 9;
    if (row < DPROJ) {
        const float4 v = *(const float4*)(w + i);
        d[i + 0] = __float2bfloat16(v.x);
        d[i + 1] = __float2bfloat16(v.y);
        d[i + 2] = __float2bfloat16(v.z);
        d[i + 3] = __float2bfloat16(v.w);
    } else {
        d[i + 0] = __float2bfloat16(0.f); d[i + 1] = __float2bfloat16(0.f);
        d[i + 2] = __float2bfloat16(0.f); d[i + 3] = __float2bfloat16(0.f);
    }
}

__global__ __launch_bounds__(256) void cvt_wout_kernel(
    const float* __restrict__ w0, const float* __restrict__ w1,
    __hip_bfloat16* __restrict__ dst)
{
    const int dir = blockIdx.y;
    const float* __restrict__ w = dir ? w1 : w0;
    __hip_bfloat16* __restrict__ d = dst + (size_t)dir * 512 * DINNER;
    const int i = (blockIdx.x * 256 + threadIdx.x) * 4;
    const float4 v = *(const float4*)(w + i);
    d[i + 0] = __float2bfloat16(v.x);
    d[i + 1] = __float2bfloat16(v.y);
    d[i + 2] = __float2bfloat16(v.z);
    d[i + 3] = __float2bfloat16(v.w);
}

// ---------------------------------------------------------------------------
// MFMA bf16 GEMM: C[M][N] = A[M][K] @ B[N][K]^T (+ optional f32 addsrc).
// 128x128 tile, BK=64, 256 threads. LDS XOR-swizzled.
// ---------------------------------------------------------------------------
template<bool AF32>
__global__ __launch_bounds__(256) void gemm_mfma(
    const __hip_bfloat16* __restrict__ Abf,
    const float* __restrict__ Af0, const float* __restrict__ Af1, int lda_f,
    const __hip_bfloat16* __restrict__ Bw, long long b_dir_off,
    float* __restrict__ C, long long c_dir_off, int ldc,
    const float* __restrict__ addsrc, int add_ld,
    int K)
{
    const int dir = blockIdx.z;
    const int m0 = blockIdx.y * 128;
    const int n0 = blockIdx.x * 128;
    const __hip_bfloat16* __restrict__ B = Bw + (size_t)dir * b_dir_off;
    const float* __restrict__ Af = dir ? Af1 : Af0;
    float* __restrict__ Cp = C + (size_t)dir * c_dir_off;

    __shared__ __hip_bfloat16 Asl[128 * 64];
    __shared__ __hip_bfloat16 Bsl[128 * 64];

    const int tid  = threadIdx.x;
    const int lane = tid & 63;
    const int wid  = tid >> 6;
    const int wr   = (wid >> 1) << 6;
    const int wc   = (wid & 1) << 6;
    const int l15  = lane & 15;
    const int l4   = lane >> 4;

    f32x4 acc[4][4];
#pragma unroll
    for (int m = 0; m < 4; ++m)
#pragma unroll
        for (int n = 0; n < 4; ++n) acc[m][n] = (f32x4)0.f;

    for (int k0 = 0; k0 < K; k0 += 64) {
        __syncthreads();
#pragma unroll
        for (int i = 0; i < 4; ++i) {
            const int c    = tid + (i << 8);
            const int row  = c >> 3;
            const int slot = c & 7;
            const int dst  = (row << 7) + ((slot ^ (row & 7)) << 4);
            if (AF32) {
                const float* s = Af + (size_t)(m0 + row) * lda_f + k0 + (slot << 3);
                const float4 lo = *(const float4*)(s);
                const float4 hi = *(const float4*)(s + 4);
                bf8u u;
                u.e[0] = __float2bfloat16(lo.x); u.e[1] = __float2bfloat16(lo.y);
                u.e[2] = __float2bfloat16(lo.z); u.e[3] = __float2bfloat16(lo.w);
                u.e[4] = __float2bfloat16(hi.x); u.e[5] = __float2bfloat16(hi.y);
                u.e[6] = __float2bfloat16(hi.z); u.e[7] = __float2bfloat16(hi.w);
                *(short8*)((char*)Asl + dst) = u.v;
            } else {
                *(short8*)((char*)Asl + dst) =
                    *(const short8*)(Abf + (size_t)(m0 + row) * K + k0 + (slot << 3));
            }
            *(short8*)((char*)Bsl + dst) =
                *(const short8*)(B + (size_t)(n0 + row) * K + k0 + (slot << 3));
        }
        __syncthreads();

#pragma unroll
        for (int kh = 0; kh < 2; ++kh) {
            const int ks = (kh << 2) + l4;
            short8 a[4], b[4];
#pragma unroll
            for (int m = 0; m < 4; ++m) {
                const int R = wr + (m << 4) + l15;
                a[m] = *(const short8*)((const char*)Asl + (R << 7) + ((ks ^ (R & 7)) << 4));
            }
#pragma unroll
            for (int n = 0; n < 4; ++n) {
                const int R = wc + (n << 4) + l15;
                b[n] = *(const short8*)((const char*)Bsl + (R << 7) + ((ks ^ (R & 7)) << 4));
            }
#pragma unroll
            for (int m = 0; m < 4; ++m)
#pragma unroll
                for (int n = 0; n < 4; ++n)
                    acc[m][n] = __builtin_amdgcn_mfma_f32_16x16x32_bf16(
                        a[m], b[n], acc[m][n], 0, 0, 0);
        }
    }

#pragma unroll
    for (int m = 0; m < 4; ++m) {
        const int row0 = m0 + wr + (m << 4) + (l4 << 2);
#pragma unroll
        for (int n = 0; n < 4; ++n) {
            const int col = n0 + wc + (n << 4) + l15;
#pragma unroll
            for (int r = 0; r < 4; ++r) {
                float v = acc[m][n][r];
                if (addsrc) v += addsrc[(size_t)(row0 + r) * add_ld + col];
                Cp[(size_t)(row0 + r) * ldc + col] = v;
            }
        }
    }
}

// ---------------------------------------------------------------------------
// Sliding-window depthwise conv(4) + SiLU. Thread owns one channel column,
// walks CTR consecutive rows keeping 3-tap history in registers: each zx
// element read exactly once, coalesced across 256-channel strips.
// Bwd dir walks l descending with reversed taps. B/C/x emitted bf16.
// ---------------------------------------------------------------------------
__global__ __launch_bounds__(256) void conv_kernel(
    const float* __restrict__ zx,
    const float* __restrict__ cw0, const float* __restrict__ cw1,
    const float* __restrict__ cb0, const float* __restrict__ cb1,
    u16* __restrict__ xs, u16* __restrict__ Bbf, u16* __restrict__ Cbf)
{
    const int dir = blockIdx.z;
    const int c   = blockIdx.x * 256 + threadIdx.x;     // channel 0..2303
    const int b   = blockIdx.y >> 4;
    const int r0  = (blockIdx.y & 15) * CTR;

    const float* __restrict__ cw = dir ? cw1 : cw0;
    const float w0 = cw[c * 4 + 0], w1 = cw[c * 4 + 1];
    const float w2 = cw[c * 4 + 2], w3 = cw[c * 4 + 3];
    const float bias = (dir ? cb1 : cb0)[c];

    const float* __restrict__ zcol = zx + (size_t)dir * M_ROWS * DPROJP
        + (size_t)(b * L_SEQ) * DPROJP + DINNER + c;
    const size_t obase = (size_t)(dir * M_ROWS + b * L_SEQ);

    auto emit = [&](int l, float acc) {
        const float s = acc / (1.f + expf(-acc));
        const size_t orow = obase + l;
        if (c < DINNER)            xs[orow * DINNER + c] = bf16bits(s);
        else if (c < DINNER + NST) Bbf[orow * NST + (c - DINNER)] = bf16bits(s);
        else                       Cbf[orow * NST + (c - DINNER - NST)] = bf16bits(s);
    };

    if (dir == 0) {
        // out[l] = w0*z[l-3] + w1*z[l-2] + w2*z[l-1] + w3*z[l]
        float h0 = (r0 - 3 >= 0) ? zcol[(size_t)(r0 - 3) * DPROJP] : 0.f;
        float h1 = (r0 - 2 >= 0) ? zcol[(size_t)(r0 - 2) * DPROJP] : 0.f;
        float h2 = (r0 - 1 >= 0) ? zcol[(size_t)(r0 - 1) * DPROJP] : 0.f;
#pragma unroll 4
        for (int l = r0; l < r0 + CTR; ++l) {
            const float zl = zcol[(size_t)l * DPROJP];
            float acc = bias;
            acc = fmaf(w0, h0, acc);
            acc = fmaf(w1, h1, acc);
            acc = fmaf(w2, h2, acc);
            acc = fmaf(w3, zl, acc);
            emit(l, acc);
            h0 = h1; h1 = h2; h2 = zl;
        }
    } else {
        // out[l] = w3*z[l] + w2*z[l+1] + w1*z[l+2] + w0*z[l+3]
        const int le = r0 + CTR - 1;
        float h1 = (le + 1 < L_SEQ) ? zcol[(size_t)(le + 1) * DPROJP] : 0.f;
        float h2 = (le + 2 < L_SEQ) ? zcol[(size_t)(le + 2) * DPROJP] : 0.f;
        float h3 = (le + 3 < L_SEQ) ? zcol[(size_t)(le + 3) * DPROJP] : 0.f;
#pragma unroll 4
        for (int l = le; l >= r0; --l) {
            const float zl = zcol[(size_t)l * DPROJP];
            float acc = bias;
            acc = fmaf(w3, zl, acc);
            acc = fmaf(w2, h1, acc);
            acc = fmaf(w1, h2, acc);
            acc = fmaf(w0, h3, acc);
            emit(l, acc);
            h3 = h2; h2 = h1; h1 = zl;
        }
    }
}

// ---------------------------------------------------------------------------
// Exact-f32 dt: softplus(x @ in_w_dt + bias); dta = dt * (-exp(A_log)) as
// LOG-decay. 8 threads per head.
// ---------------------------------------------------------------------------
__global__ __launch_bounds__(256) void dt_kernel(
    const float* __restrict__ x,
    const float* __restrict__ inw0, const float* __restrict__ inw1,
    const float* __restrict__ dtbias0, const float* __restrict__ dtbias1,
    const float* __restrict__ Alog0, const float* __restrict__ Alog1,
    float* __restrict__ dtb, float* __restrict__ dta)
{
    const int dir = blockIdx.y;
    const int row = blockIdx.x;
    const size_t orow = (size_t)(dir * M_ROWS + row);
    const int h = threadIdx.x >> 3;
    const int part = threadIdx.x & 7;

    const float4* __restrict__ xr4 = (const float4*)(x + (size_t)row * 512 + part * 64);
    const float4* __restrict__ wr4 = (const float4*)((dir ? inw1 : inw0)
        + (size_t)(DINNER + CONVDIM + h) * 512 + part * 64);
    float s = 0.f;
#pragma unroll
    for (int k = 0; k < 16; ++k) {
        const float4 a = xr4[k], w = wr4[k];
        s = fmaf(a.x, w.x, s); s = fmaf(a.y, w.y, s);
        s = fmaf(a.z, w.z, s); s = fmaf(a.w, w.w, s);
    }
    s += __shfl_xor(s, 1);
    s += __shfl_xor(s, 2);
    s += __shfl_xor(s, 4);
    if (part == 0) {
        const float v = s + (dir ? dtbias1 : dtbias0)[h];
        const float sp = (v > 20.f) ? v : log1pf(expf(v));
        const float a = -expf((dir ? Alog1 : Alog0)[h]);
        dtb[orow * NH + h] = sp;
        dta[orow * NH + h] = sp * a;     // log-decay
    }
}

// ---------------------------------------------------------------------------
// SSD chunk kernel. Block = (bh, chunk), 256 threads (4 waves).
// ---------------------------------------------------------------------------
__global__ __launch_bounds__(256) void ssd_chunk_kernel(
    const u16* __restrict__ xs, const u16* __restrict__ Bbf,
    const u16* __restrict__ Cbf,
    const float* __restrict__ dtb, const float* __restrict__ dta,
    const float* __restrict__ D0, const float* __restrict__ D1,
    float* __restrict__ zx, u16* __restrict__ stateC,
    float* __restrict__ betac)
{
    const int bx  = blockIdx.x;
    const int ch  = bx & (NCH - 1);
    const int bh  = bx >> 4;
    const int dir = bh >> 6;
    const int bb  = (bh >> 5) & 1;
    const int h   = bh & 31;
    const int tid = threadIdx.x;
    const int wid = tid >> 6;
    const int lane = tid & 63;
    const int l15 = lane & 15;
    const int l4  = lane >> 4;
    const int t0  = ch * CHUNK;
    const size_t dbase = (size_t)(dir * M_ROWS + bb * L_SEQ);
    const float Dv = (dir ? D1 : D0)[h];

    __shared__ u16 XT[64 * 128];
    __shared__ u16 WBT[128 * 128];     // reused as P~ after state/S phases
    __shared__ float scum[CHUNK];
    __shared__ float sdt[CHUNK];

    auto lidx = [&](int t) { return dir ? (L_SEQ - 1 - t) : t; };

    // ---- phase A: dt loads + cumA prefix-sum (wave 0) ----
    if (tid >= 128) {
        const int s = tid - 128;
        sdt[s] = dtb[(dbase + lidx(t0 + s)) * NH + h];
    }
    if (wid == 0) {
        float a0 = dta[(dbase + lidx(t0 + lane)) * NH + h];
        float a1 = dta[(dbase + lidx(t0 + 64 + lane)) * NH + h];
#pragma unroll
        for (int off = 1; off < 64; off <<= 1) {
            const float u0 = __shfl_up(a0, off);
            const float u1 = __shfl_up(a1, off);
            if (lane >= off) { a0 += u0; a1 += u1; }
        }
        a1 += __shfl(a0, 63);
        scum[lane] = a0; scum[64 + lane] = a1;
        betac[(size_t)bh * L_SEQ + t0 + lane] = a0;
        betac[(size_t)bh * L_SEQ + t0 + 64 + lane] = a1;
    }
    __syncthreads();

    // ---- phase B: build X~T and WBT ----
    {
        const int s = tid >> 1;
        const float dts = sdt[s];
        const float rs = expf(scum[CHUNK - 1] - scum[s]);
        const size_t grow = dbase + lidx(t0 + s);
        const int p0 = (tid & 1) * 32;
        const u16* __restrict__ xp = xs + grow * DINNER + h * 64 + p0;
#pragma unroll
        for (int q = 0; q < 4; ++q) {
            short8 v = *(const short8*)(xp + q * 8);
#pragma unroll
            for (int j = 0; j < 8; ++j) {
                const int p = p0 + q * 8 + j;
                XT[sidx(p, s)] = bf16bits(dts * bits2f((u16)v[j]));
            }
        }
        const int n0 = (tid & 1) * 64;
        const u16* __restrict__ bp = Bbf + grow * NST + n0;
#pragma unroll
        for (int q = 0; q < 8; ++q) {
            short8 v = *(const short8*)(bp + q * 8);
#pragma unroll
            for (int j = 0; j < 8; ++j) {
                const int n = n0 + q * 8 + j;
                WBT[sidx(n, s)] = bf16bits(rs * bits2f((u16)v[j]));
            }
        }
    }
    __syncthreads();

    // ---- phase C1: STATE GEMM c[p][n] ----
    {
        const int pw = wid * 16;
        const int prow = pw + l15;
        short8 xa[4];
#pragma unroll
        for (int kk = 0; kk < 4; ++kk)
            xa[kk] = *(const short8*)(XT + sslot(prow, kk * 4 + l4));
        const size_t sbase = ((size_t)bh * NCH + ch) * 8192;
#pragma unroll
        for (int jn = 0; jn < 8; ++jn) {
            const int nrow = jn * 16 + l15;
            f32x4 acc = (f32x4)0.f;
#pragma unroll
            for (int kk = 0; kk < 4; ++kk) {
                const short8 wb = *(const short8*)(WBT + sslot(nrow, kk * 4 + l4));
                acc = __builtin_amdgcn_mfma_f32_16x16x32_bf16(xa[kk], wb, acc, 0, 0, 0);
            }
#pragma unroll
            for (int r = 0; r < 4; ++r)
                stateC[sbase + (size_t)(pw + l4 * 4 + r) * 128 + jn * 16 + l15] =
                    bf16bits(acc[r]);
        }
    }

    // ---- phase C2: S GEMM (global bf16 operands) ----
    f32x4 accs[2][8];
#pragma unroll
    for (int m = 0; m < 2; ++m)
#pragma unroll
        for (int j = 0; j < 8; ++j) accs[m][j] = (f32x4)0.f;
    {
        short8 af[2][4];
#pragma unroll
        for (int m = 0; m < 2; ++m) {
            const size_t crow = dbase + lidx(t0 + wid * 32 + m * 16 + l15);
#pragma unroll
            for (int kk = 0; kk < 4; ++kk)
                af[m][kk] = *(const short8*)(Cbf + crow * NST + kk * 32 + l4 * 8);
        }
#pragma unroll
        for (int j = 0; j < 8; ++j) {
            const size_t brow = dbase + lidx(t0 + j * 16 + l15);
            short8 bf_[4];
#pragma unroll
            for (int kk = 0; kk < 4; ++kk)
                bf_[kk] = *(const short8*)(Bbf + brow * NST + kk * 32 + l4 * 8);
#pragma unroll
            for (int m = 0; m < 2; ++m)
#pragma unroll
                for (int kk = 0; kk < 4; ++kk)
                    accs[m][j] = __builtin_amdgcn_mfma_f32_16x16x32_bf16(
                        af[m][kk], bf_[kk], accs[m][j], 0, 0, 0);
        }
    }
    __syncthreads();   // all waves done with WBT (state phase reads)

    // ---- phase C3: Gamma-scale, write P~ over WBT ----
    u16* __restrict__ PT = WBT;
#pragma unroll
    for (int m = 0; m < 2; ++m) {
#pragma unroll
        for (int r = 0; r < 4; ++r) {
            const int t = wid * 32 + m * 16 + l4 * 4 + r;
            const float ct = scum[t];
#pragma unroll
            for (int j = 0; j < 8; ++j) {
                const int s = j * 16 + l15;
                const float g = (s <= t) ? expf(ct - scum[s]) : 0.f;
                PT[sidx(t, s)] = bf16bits(accs[m][j][r] * g);
            }
        }
    }
    __syncthreads();

    // ---- phase D: Y = P~ @ X~T^T, + D-skip, store ----
    {
        float* __restrict__ ybase = zx + (size_t)dir * M_ROWS * DPROJP + DINNER;
        short8 pa[2][4];
#pragma unroll
        for (int m = 0; m < 2; ++m) {
            const int trow = wid * 32 + m * 16 + l15;
#pragma unroll
            for (int kk = 0; kk < 4; ++kk)
                pa[m][kk] = *(const short8*)(PT + sslot(trow, kk * 4 + l4));
        }
#pragma unroll
        for (int jp = 0; jp < 4; ++jp) {
            const int prow = jp * 16 + l15;
            short8 xb[4];
#pragma unroll
            for (int kk = 0; kk < 4; ++kk)
                xb[kk] = *(const short8*)(XT + sslot(prow, kk * 4 + l4));
#pragma unroll
            for (int m = 0; m < 2; ++m) {
                f32x4 acc = (f32x4)0.f;
#pragma unroll
                for (int kk = 0; kk < 4; ++kk)
                    acc = __builtin_amdgcn_mfma_f32_16x16x32_bf16(
                        pa[m][kk], xb[kk], acc, 0, 0, 0);
                const int p = jp * 16 + l15;
#pragma unroll
                for (int r = 0; r < 4; ++r) {
                    const int t = wid * 32 + m * 16 + l4 * 4 + r;
                    const int lg = lidx(t0 + t);
                    const float xv = bits2f(xs[(dbase + lg) * DINNER + h * 64 + p]);
                    ybase[(size_t)(bb * L_SEQ + lg) * DPROJP + h * 64 + p] =
                        acc[r] + Dv * xv;
                }
            }
        }
    }
}

// ---------------------------------------------------------------------------
// Combine: sequential over NCH chunks per bh (in place on stateC).
// ---------------------------------------------------------------------------
__global__ __launch_bounds__(512) void combine_kernel(
    u16* __restrict__ stateC, const float* __restrict__ betac)
{
    const int bh  = blockIdx.x;
    const int tid = threadIdx.x;

    float hrun[16];
#pragma unroll
    for (int j = 0; j < 16; ++j) hrun[j] = 0.f;

    for (int s = 0; s < NCH; ++s) {
        const size_t off = ((size_t)bh * NCH + s) * 8192 + (size_t)tid * 16;
        float c[16];
#pragma unroll
        for (int j = 0; j < 16; ++j) c[j] = bits2f(stateC[off + j]);
#pragma unroll
        for (int j = 0; j < 16; ++j) stateC[off + j] = bf16bits(hrun[j]);
        const float alpha = expf(betac[(size_t)bh * L_SEQ + s * CHUNK + (CHUNK - 1)]);
#pragma unroll
        for (int j = 0; j < 16; ++j) hrun[j] = fmaf(alpha, hrun[j], c[j]);
    }
}

// ---------------------------------------------------------------------------
// Correction: y[t] += exp(cumA_t) * (C_t . h_in). MFMA, chunk>0 only.
// ---------------------------------------------------------------------------
__global__ __launch_bounds__(256) void correct_kernel(
    const u16* __restrict__ Cbf, const float* __restrict__ betac,
    const u16* __restrict__ stateC, float* __restrict__ zx)
{
    const int bx  = blockIdx.x;
    const int ch  = bx & (NCH - 1);
    if (ch == 0) return;
    const int bh  = bx >> 4;
    const int dir = bh >> 6;
    const int bb  = (bh >> 5) & 1;
    const int h   = bh & 31;
    const int tid = threadIdx.x;
    const int wid = tid >> 6;
    const int lane = tid & 63;
    const int l15 = lane & 15;
    const int l4  = lane >> 4;
    const int t0  = ch * CHUNK;
    const size_t dbase = (size_t)(dir * M_ROWS + bb * L_SEQ);
    const size_t sbase = ((size_t)bh * NCH + ch) * 8192;

    auto lidx = [&](int t) { return dir ? (L_SEQ - 1 - t) : t; };

    short8 af[2][4];
#pragma unroll
    for (int m = 0; m < 2; ++m) {
        const size_t crow = dbase + lidx(t0 + wid * 32 + m * 16 + l15);
#pragma unroll
        for (int kk = 0; kk < 4; ++kk)
            af[m][kk] = *(const short8*)(Cbf + crow * NST + kk * 32 + l4 * 8);
    }

    f32x4 acc[2][4];
#pragma unroll
    for (int m = 0; m < 2; ++m)
#pragma unroll
        for (int jp = 0; jp < 4; ++jp) acc[m][jp] = (f32x4)0.f;

#pragma unroll
    for (int jp = 0; jp < 4; ++jp) {
        const int prow = jp * 16 + l15;
        short8 hb[4];
#pragma unroll
        for (int kk = 0; kk < 4; ++kk)
            hb[kk] = *(const short8*)(stateC + sbase + (size_t)prow * 128 + kk * 32 + l4 * 8);
#pragma unroll
        for (int m = 0; m < 2; ++m)
#pragma unroll
            for (int kk = 0; kk < 4; ++kk)
                acc[m][jp] = __builtin_amdgcn_mfma_f32_16x16x32_bf16(
                    af[m][kk], hb[kk], acc[m][jp], 0, 0, 0);
    }

    float* __restrict__ ybase = zx + (size_t)dir * M_ROWS * DPROJP + DINNER;
#pragma unroll
    for (int m = 0; m < 2; ++m) {
#pragma unroll
        for (int r = 0; r < 4; ++r) {
            const int t = wid * 32 + m * 16 + l4 * 4 + r;
            const float g = expf(betac[(size_t)bh * L_SEQ + t0 + t]);
            const int lg = lidx(t0 + t);
#pragma unroll
            for (int jp = 0; jp < 4; ++jp) {
                const int p = jp * 16 + l15;
                ybase[(size_t)(bb * L_SEQ + lg) * DPROJP + h * 64 + p] += g * acc[m][jp][r];
            }
        }
    }
}

// ---------------------------------------------------------------------------
// y = y * silu(z); RMSNorm(2048) * norm_w, in place on y slice of zx.
// ---------------------------------------------------------------------------
__global__ __launch_bounds__(256) void gatenorm_kernel(
    float* __restrict__ zx,
    const float* __restrict__ nw0, const float* __restrict__ nw1)
{
    const int dir = blockIdx.y;
    const int row = blockIdx.x;
    const float* __restrict__ nw = dir ? nw1 : nw0;
    float* __restrict__ rowp = zx + (size_t)dir * M_ROWS * DPROJP + (size_t)row * DPROJP;
    const int tid = threadIdx.x;
    const int c0 = tid * 8;

    const float4 y0 = *(const float4*)(rowp + DINNER + c0);
    const float4 y1 = *(const float4*)(rowp + DINNER + c0 + 4);
    const float4 z0 = *(const float4*)(rowp + c0);
    const float4 z1 = *(const float4*)(rowp + c0 + 4);

    float4 g0, g1;
    g0.x = y0.x * (z0.x / (1.f + expf(-z0.x)));
    g0.y = y0.y * (z0.y / (1.f + expf(-z0.y)));
    g0.z = y0.z * (z0.z / (1.f + expf(-z0.z)));
    g0.w = y0.w * (z0.w / (1.f + expf(-z0.w)));
    g1.x = y1.x * (z1.x / (1.f + expf(-z1.x)));
    g1.y = y1.y * (z1.y / (1.f + expf(-z1.y)));
    g1.z = y1.z * (z1.z / (1.f + expf(-z1.z)));
    g1.w = y1.w * (z1.w / (1.f + expf(-z1.w)));

    float ss = g0.x * g0.x + g0.y * g0.y + g0.z * g0.z + g0.w * g0.w
             + g1.x * g1.x + g1.y * g1.y + g1.z * g1.z + g1.w * g1.w;
#pragma unroll
    for (int off = 1; off < 64; off <<= 1) ss += __shfl_xor(ss, off);
    __shared__ float red[4];
    if ((tid & 63) == 0) red[tid >> 6] = ss;
    __syncthreads();
    const float total = red[0] + red[1] + red[2] + red[3];
    const float rs = rsqrtf(total * (1.f / (float)DINNER) + 1e-5f);

    const float4 w0 = *(const float4*)(nw + c0);
    const float4 w1 = *(const float4*)(nw + c0 + 4);
    float4 o0, o1;
    o0.x = g0.x * rs * w0.x; o0.y = g0.y * rs * w0.y;
    o0.z = g0.z * rs * w0.z; o0.w = g0.w * rs * w0.w;
    o1.x = g1.x * rs * w1.x; o1.y = g1.y * rs * w1.y;
    o1.z = g1.z * rs * w1.z; o1.w = g1.w * rs * w1.w;
    *(float4*)(rowp + DINNER + c0)     = o0;
    *(float4*)(rowp + DINNER + c0 + 4) = o1;
}

// ---------------------------------------------------------------------------
extern "C" void kernel_launch(void* const* d_in, const int* in_sizes, int n_in,
                              void* d_out, int out_size, void* d_ws, size_t ws_size,
                              hipStream_t stream)
{
    (void)in_sizes; (void)n_in; (void)out_size; (void)ws_size;
    const float* x        = (const float*)d_in[0];
    const float* f_in_w   = (const float*)d_in[1];
    const float* f_conv_w = (const float*)d_in[2];
    const float* f_conv_b = (const float*)d_in[3];
    const float* f_dtbias = (const float*)d_in[4];
    const float* f_Alog   = (const float*)d_in[5];
    const float* f_D      = (const float*)d_in[6];
    const float* f_nw     = (const float*)d_in[7];
    const float* f_out_w  = (const float*)d_in[8];
    const float* b_in_w   = (const float*)d_in[9];
    const float* b_conv_w = (const float*)d_in[10];
    const float* b_conv_b = (const float*)d_in[11];
    const float* b_dtbias = (const float*)d_in[12];
    const float* b_Alog   = (const float*)d_in[13];
    const float* b_D      = (const float*)d_in[14];
    const float* b_nw     = (const float*)d_in[15];
    const float* b_out_w  = (const float*)d_in[16];

    float* ws  = (float*)d_ws;
    float* zx  = ws;
    u16* xs  = (u16*)(zx + (size_t)2 * M_ROWS * DPROJP);
    u16* Bbf = xs + (size_t)2 * M_ROWS * DINNER;
    u16* Cbf = Bbf + (size_t)2 * M_ROWS * NST;
    float* dtb = (float*)(Cbf + (size_t)2 * M_ROWS * NST);
    float* dta = dtb + (size_t)2 * M_ROWS * NH;
    u16* stateC = (u16*)(dta + (size_t)2 * M_ROWS * NH);
    float* betac = (float*)(stateC + (size_t)128 * NCH * 8192);
    __hip_bfloat16* x_bf    = (__hip_bfloat16*)(betac + (size_t)128 * L_SEQ);
    __hip_bfloat16* w_in_bf = x_bf + (size_t)M_ROWS * 512;
    __hip_bfloat16* w_out_bf = w_in_bf + (size_t)2 * DPROJP * 512;

    // 0) dtype conversions
    cvt_x_kernel<<<dim3(M_ROWS * 512 / 1024), 256, 0, stream>>>(x, x_bf);
    cvt_win_kernel<<<dim3(DPROJP * 512 / 1024, 2), 256, 0, stream>>>(f_in_w, b_in_w, w_in_bf);
    cvt_wout_kernel<<<dim3(512 * DINNER / 1024, 2), 256, 0, stream>>>(f_out_w, b_out_w, w_out_bf);

    // 1) in_proj (MFMA): zx[dir] = x @ in_w[dir]^T
    gemm_mfma<false><<<dim3(DPROJP / 128, M_ROWS / 128, 2), 256, 0, stream>>>(
        (const __hip_bfloat16*)x_bf, nullptr, nullptr, 0,
        w_in_bf, (long long)DPROJP * 512,
        zx, (long long)M_ROWS * DPROJP, DPROJP,
        nullptr, 0, 512);

    // 2a) sliding-window conv + SiLU (bf16 x/B/C out)
    conv_kernel<<<dim3(CONVDIM / 256, 32, 2), 256, 0, stream>>>(
        zx, f_conv_w, b_conv_w, f_conv_b, b_conv_b, xs, Bbf, Cbf);

    // 2b) exact-f32 dt / log-decay
    dt_kernel<<<dim3(M_ROWS, 2), 256, 0, stream>>>(
        x, f_in_w, b_in_w, f_dtbias, b_dtbias, f_Alog, b_Alog, dtb, dta);

    // 3a) SSD chunk kernel (local Y + D-skip + chunk states + cumA)
    ssd_chunk_kernel<<<dim3(128 * NCH), 256, 0, stream>>>(
        xs, Bbf, Cbf, dtb, dta, f_D, b_D, zx, stateC, betac);

    // 3b) combine chunk states
    combine_kernel<<<dim3(128), 512, 0, stream>>>(stateC, betac);

    // 3c) inter-chunk correction (MFMA)
    correct_kernel<<<dim3(128 * NCH), 256, 0, stream>>>(Cbf, betac, stateC, zx);

    // 4) gate + RMSNorm in place on y slice
    gatenorm_kernel<<<dim3(M_ROWS, 2), 256, 0, stream>>>(zx, f_nw, b_nw);

    // 5) out_proj (MFMA) + residual + concat
    gemm_mfma<true><<<dim3(512 / 128, M_ROWS / 128, 2), 256, 0, stream>>>(
        nullptr, zx + DINNER, zx + (size_t)M_ROWS * DPROJP + DINNER, DPROJP,
        w_out_bf, (long long)512 * DINNER,
        (float*)d_out, 512, 1024,
        x, 512, DINNER);
}

// Round 9
// 420.546 us; speedup vs baseline: 1.9029x; 1.1735x over previous
//
#include <hip/hip_runtime.h>
#include <hip/hip_bf16.h>
#include <math.h>

#define L_SEQ   2048
#define M_ROWS  4096            // B*L
#define DPROJ   4384
#define DPROJP  4480            // padded to 35*128 for MFMA GEMM
#define DINNER  2048
#define CONVDIM 2304
#define NST     128
#define NH      32
#define CHUNK   128             // SSD chunk length
#define NCH     16              // L_SEQ / CHUNK
#define CTR     128             // conv rows per tile

typedef __attribute__((ext_vector_type(8))) short short8;
typedef __attribute__((ext_vector_type(4))) float f32x4;
typedef unsigned short u16;

union bf8u { short8 v; __hip_bfloat16 e[8]; };

static __device__ __forceinline__ u16 bf16bits(float v) {
    __hip_bfloat16 t = __float2bfloat16(v);
    return *(u16*)&t;
}
static __device__ __forceinline__ float bits2f(u16 u) {
    return __uint_as_float((unsigned)u << 16);
}
// element index into a [rows][128] bf16 LDS buffer with 16B-slot XOR swizzle
static __device__ __forceinline__ int sidx(int row, int s) {
    return (row << 7) + ((((s >> 3) ^ (row & 7)) << 3) | (s & 7));
}
static __device__ __forceinline__ int sslot(int row, int ks) {  // ks = 16B slot 0..15
    return (row << 7) + ((ks ^ (row & 7)) << 3);
}

// ---------------------------------------------------------------------------
// f32 -> bf16 conversion pre-passes
// ---------------------------------------------------------------------------
__global__ __launch_bounds__(256) void cvt_x_kernel(
    const float* __restrict__ x, __hip_bfloat16* __restrict__ xbf)
{
    const int i = (blockIdx.x * 256 + threadIdx.x) * 4;
    const float4 v = *(const float4*)(x + i);
    xbf[i + 0] = __float2bfloat16(v.x);
    xbf[i + 1] = __float2bfloat16(v.y);
    xbf[i + 2] = __float2bfloat16(v.z);
    xbf[i + 3] = __float2bfloat16(v.w);
}

__global__ __launch_bounds__(256) void cvt_win_kernel(
    const float* __restrict__ w0, const float* __restrict__ w1,
    __hip_bfloat16* __restrict__ dst)
{
    const int dir = blockIdx.y;
    const float* __restrict__ w = dir ? w1 : w0;
    __hip_bfloat16* __restrict__ d = dst + (size_t)dir * DPROJP * 512;
    const int i = (blockIdx.x * 256 + threadIdx.x) * 4;
    const int row = i >> 9;
    if (row < DPROJ) {
        const float4 v = *(const float4*)(w + i);
        d[i + 0] = __float2bfloat16(v.x);
        d[i + 1] = __float2bfloat16(v.y);
        d[i + 2] = __float2bfloat16(v.z);
        d[i + 3] = __float2bfloat16(v.w);
    } else {
        d[i + 0] = __float2bfloat16(0.f); d[i + 1] = __float2bfloat16(0.f);
        d[i + 2] = __float2bfloat16(0.f); d[i + 3] = __float2bfloat16(0.f);
    }
}

__global__ __launch_bounds__(256) void cvt_wout_kernel(
    const float* __restrict__ w0, const float* __restrict__ w1,
    __hip_bfloat16* __restrict__ dst)
{
    const int dir = blockIdx.y;
    const float* __restrict__ w = dir ? w1 : w0;
    __hip_bfloat16* __restrict__ d = dst + (size_t)dir * 512 * DINNER;
    const int i = (blockIdx.x * 256 + threadIdx.x) * 4;
    const float4 v = *(const float4*)(w + i);
    d[i + 0] = __float2bfloat16(v.x);
    d[i + 1] = __float2bfloat16(v.y);
    d[i + 2] = __float2bfloat16(v.z);
    d[i + 3] = __float2bfloat16(v.w);
}

// ---------------------------------------------------------------------------
// MFMA bf16 GEMM: C[M][N] = A[M][K] @ B[N][K]^T (+ optional f32 addsrc).
// 128x128 tile, BK=64, 256 threads. LDS XOR-swizzled.
// ---------------------------------------------------------------------------
template<bool AF32>
__global__ __launch_bounds__(256) void gemm_mfma(
    const __hip_bfloat16* __restrict__ Abf,
    const float* __restrict__ Af0, const float* __restrict__ Af1, int lda_f,
    const __hip_bfloat16* __restrict__ Bw, long long b_dir_off,
    float* __restrict__ C, long long c_dir_off, int ldc,
    const float* __restrict__ addsrc, int add_ld,
    int K)
{
    const int dir = blockIdx.z;
    const int m0 = blockIdx.y * 128;
    const int n0 = blockIdx.x * 128;
    const __hip_bfloat16* __restrict__ B = Bw + (size_t)dir * b_dir_off;
    const float* __restrict__ Af = dir ? Af1 : Af0;
    float* __restrict__ Cp = C + (size_t)dir * c_dir_off;

    __shared__ __hip_bfloat16 Asl[128 * 64];
    __shared__ __hip_bfloat16 Bsl[128 * 64];

    const int tid  = threadIdx.x;
    const int lane = tid & 63;
    const int wid  = tid >> 6;
    const int wr   = (wid >> 1) << 6;
    const int wc   = (wid & 1) << 6;
    const int l15  = lane & 15;
    const int l4   = lane >> 4;

    f32x4 acc[4][4];
#pragma unroll
    for (int m = 0; m < 4; ++m)
#pragma unroll
        for (int n = 0; n < 4; ++n) acc[m][n] = (f32x4)0.f;

    for (int k0 = 0; k0 < K; k0 += 64) {
        __syncthreads();
#pragma unroll
        for (int i = 0; i < 4; ++i) {
            const int c    = tid + (i << 8);
            const int row  = c >> 3;
            const int slot = c & 7;
            const int dst  = (row << 7) + ((slot ^ (row & 7)) << 4);
            if (AF32) {
                const float* s = Af + (size_t)(m0 + row) * lda_f + k0 + (slot << 3);
                const float4 lo = *(const float4*)(s);
                const float4 hi = *(const float4*)(s + 4);
                bf8u u;
                u.e[0] = __float2bfloat16(lo.x); u.e[1] = __float2bfloat16(lo.y);
                u.e[2] = __float2bfloat16(lo.z); u.e[3] = __float2bfloat16(lo.w);
                u.e[4] = __float2bfloat16(hi.x); u.e[5] = __float2bfloat16(hi.y);
                u.e[6] = __float2bfloat16(hi.z); u.e[7] = __float2bfloat16(hi.w);
                *(short8*)((char*)Asl + dst) = u.v;
            } else {
                *(short8*)((char*)Asl + dst) =
                    *(const short8*)(Abf + (size_t)(m0 + row) * K + k0 + (slot << 3));
            }
            *(short8*)((char*)Bsl + dst) =
                *(const short8*)(B + (size_t)(n0 + row) * K + k0 + (slot << 3));
        }
        __syncthreads();

#pragma unroll
        for (int kh = 0; kh < 2; ++kh) {
            const int ks = (kh << 2) + l4;
            short8 a[4], b[4];
#pragma unroll
            for (int m = 0; m < 4; ++m) {
                const int R = wr + (m << 4) + l15;
                a[m] = *(const short8*)((const char*)Asl + (R << 7) + ((ks ^ (R & 7)) << 4));
            }
#pragma unroll
            for (int n = 0; n < 4; ++n) {
                const int R = wc + (n << 4) + l15;
                b[n] = *(const short8*)((const char*)Bsl + (R << 7) + ((ks ^ (R & 7)) << 4));
            }
#pragma unroll
            for (int m = 0; m < 4; ++m)
#pragma unroll
                for (int n = 0; n < 4; ++n)
                    acc[m][n] = __builtin_amdgcn_mfma_f32_16x16x32_bf16(
                        a[m], b[n], acc[m][n], 0, 0, 0);
        }
    }

#pragma unroll
    for (int m = 0; m < 4; ++m) {
        const int row0 = m0 + wr + (m << 4) + (l4 << 2);
#pragma unroll
        for (int n = 0; n < 4; ++n) {
            const int col = n0 + wc + (n << 4) + l15;
#pragma unroll
            for (int r = 0; r < 4; ++r) {
                float v = acc[m][n][r];
                if (addsrc) v += addsrc[(size_t)(row0 + r) * add_ld + col];
                Cp[(size_t)(row0 + r) * ldc + col] = v;
            }
        }
    }
}

// ---------------------------------------------------------------------------
// Sliding-window depthwise conv(4) + SiLU. Thread owns one channel column,
// walks CTR consecutive rows keeping 3-tap history in registers.
// ---------------------------------------------------------------------------
__global__ __launch_bounds__(256) void conv_kernel(
    const float* __restrict__ zx,
    const float* __restrict__ cw0, const float* __restrict__ cw1,
    const float* __restrict__ cb0, const float* __restrict__ cb1,
    u16* __restrict__ xs, u16* __restrict__ Bbf, u16* __restrict__ Cbf)
{
    const int dir = blockIdx.z;
    const int c   = blockIdx.x * 256 + threadIdx.x;     // channel 0..2303
    const int b   = blockIdx.y >> 4;
    const int r0  = (blockIdx.y & 15) * CTR;

    const float* __restrict__ cw = dir ? cw1 : cw0;
    const float w0 = cw[c * 4 + 0], w1 = cw[c * 4 + 1];
    const float w2 = cw[c * 4 + 2], w3 = cw[c * 4 + 3];
    const float bias = (dir ? cb1 : cb0)[c];

    const float* __restrict__ zcol = zx + (size_t)dir * M_ROWS * DPROJP
        + (size_t)(b * L_SEQ) * DPROJP + DINNER + c;
    const size_t obase = (size_t)(dir * M_ROWS + b * L_SEQ);

    auto emit = [&](int l, float acc) {
        const float s = acc / (1.f + expf(-acc));
        const size_t orow = obase + l;
        if (c < DINNER)            xs[orow * DINNER + c] = bf16bits(s);
        else if (c < DINNER + NST) Bbf[orow * NST + (c - DINNER)] = bf16bits(s);
        else                       Cbf[orow * NST + (c - DINNER - NST)] = bf16bits(s);
    };

    if (dir == 0) {
        float h0 = (r0 - 3 >= 0) ? zcol[(size_t)(r0 - 3) * DPROJP] : 0.f;
        float h1 = (r0 - 2 >= 0) ? zcol[(size_t)(r0 - 2) * DPROJP] : 0.f;
        float h2 = (r0 - 1 >= 0) ? zcol[(size_t)(r0 - 1) * DPROJP] : 0.f;
#pragma unroll 4
        for (int l = r0; l < r0 + CTR; ++l) {
            const float zl = zcol[(size_t)l * DPROJP];
            float acc = bias;
            acc = fmaf(w0, h0, acc);
            acc = fmaf(w1, h1, acc);
            acc = fmaf(w2, h2, acc);
            acc = fmaf(w3, zl, acc);
            emit(l, acc);
            h0 = h1; h1 = h2; h2 = zl;
        }
    } else {
        const int le = r0 + CTR - 1;
        float h1 = (le + 1 < L_SEQ) ? zcol[(size_t)(le + 1) * DPROJP] : 0.f;
        float h2 = (le + 2 < L_SEQ) ? zcol[(size_t)(le + 2) * DPROJP] : 0.f;
        float h3 = (le + 3 < L_SEQ) ? zcol[(size_t)(le + 3) * DPROJP] : 0.f;
#pragma unroll 4
        for (int l = le; l >= r0; --l) {
            const float zl = zcol[(size_t)l * DPROJP];
            float acc = bias;
            acc = fmaf(w3, zl, acc);
            acc = fmaf(w2, h1, acc);
            acc = fmaf(w1, h2, acc);
            acc = fmaf(w0, h3, acc);
            emit(l, acc);
            h3 = h2; h2 = h1; h1 = zl;
        }
    }
}

// ---------------------------------------------------------------------------
// Exact-f32 dt as LDS-staged block GEMV. 64 rows x 512 threads per block.
// Weights staged transposed [k4][h][4] once per block: coalesced global
// float4 loads, conflict-free ds_read_b128 (lanes h*16B apart), x loads are
// wave-broadcast (all 32 lanes same address). dta = dt * (-exp(A_log)).
// ---------------------------------------------------------------------------
__global__ __launch_bounds__(512) void dt_kernel(
    const float* __restrict__ x,
    const float* __restrict__ inw0, const float* __restrict__ inw1,
    const float* __restrict__ dtbias0, const float* __restrict__ dtbias1,
    const float* __restrict__ Alog0, const float* __restrict__ Alog1,
    float* __restrict__ dtb, float* __restrict__ dta)
{
    const int dir = blockIdx.y;
    const int r0  = blockIdx.x * 64;
    const int tid = threadIdx.x;

    __shared__ float wT[512 * 32];   // [k4][h][j]  (= w[h][k4*4+j]), 64 KB
    __shared__ float sbias[NH], sa[NH];

    const float* __restrict__ w = (dir ? inw1 : inw0) + (size_t)(DINNER + CONVDIM) * 512;
    for (int i = tid; i < 4096; i += 512) {
        const int flat = i * 4;              // element index h*512 + k
        const int h = flat >> 9;
        const int k = flat & 511;
        const float4 v = *(const float4*)(w + flat);
        *(float4*)&wT[(k >> 2) * 128 + h * 4] = v;
    }
    if (tid < NH) {
        sbias[tid] = (dir ? dtbias1 : dtbias0)[tid];
        sa[tid] = -expf((dir ? Alog1 : Alog0)[tid]);
    }
    __syncthreads();

    const int h  = tid & 31;
    const int rr = tid >> 5;                 // 0..15
    const float bias = sbias[h];
    const float a = sa[h];

    for (int rp = 0; rp < 64; rp += 16) {
        const int row = r0 + rp + rr;
        const float4* __restrict__ xr = (const float4*)(x + (size_t)row * 512);
        float4 s4 = make_float4(0.f, 0.f, 0.f, 0.f);
#pragma unroll 8
        for (int k4 = 0; k4 < 128; ++k4) {
            const float4 xv = xr[k4];
            const float4 wv = *(const float4*)&wT[k4 * 128 + h * 4];
            s4.x = fmaf(xv.x, wv.x, s4.x);
            s4.y = fmaf(xv.y, wv.y, s4.y);
            s4.z = fmaf(xv.z, wv.z, s4.z);
            s4.w = fmaf(xv.w, wv.w, s4.w);
        }
        const float v = (s4.x + s4.y) + (s4.z + s4.w) + bias;
        const float sp = (v > 20.f) ? v : log1pf(expf(v));
        const size_t orow = (size_t)(dir * M_ROWS + row);
        dtb[orow * NH + h] = sp;
        dta[orow * NH + h] = sp * a;         // log-decay
    }
}

// ---------------------------------------------------------------------------
// SSD chunk kernel. Block = (bh, chunk), 256 threads (4 waves).
// ---------------------------------------------------------------------------
__global__ __launch_bounds__(256) void ssd_chunk_kernel(
    const u16* __restrict__ xs, const u16* __restrict__ Bbf,
    const u16* __restrict__ Cbf,
    const float* __restrict__ dtb, const float* __restrict__ dta,
    const float* __restrict__ D0, const float* __restrict__ D1,
    float* __restrict__ zx, u16* __restrict__ stateC,
    float* __restrict__ betac)
{
    const int bx  = blockIdx.x;
    const int ch  = bx & (NCH - 1);
    const int bh  = bx >> 4;
    const int dir = bh >> 6;
    const int bb  = (bh >> 5) & 1;
    const int h   = bh & 31;
    const int tid = threadIdx.x;
    const int wid = tid >> 6;
    const int lane = tid & 63;
    const int l15 = lane & 15;
    const int l4  = lane >> 4;
    const int t0  = ch * CHUNK;
    const size_t dbase = (size_t)(dir * M_ROWS + bb * L_SEQ);
    const float Dv = (dir ? D1 : D0)[h];

    __shared__ u16 XT[64 * 128];
    __shared__ u16 WBT[128 * 128];     // reused as P~ after state/S phases
    __shared__ float scum[CHUNK];
    __shared__ float sdt[CHUNK];

    auto lidx = [&](int t) { return dir ? (L_SEQ - 1 - t) : t; };

    // ---- phase A: dt loads + cumA prefix-sum (wave 0) ----
    if (tid >= 128) {
        const int s = tid - 128;
        sdt[s] = dtb[(dbase + lidx(t0 + s)) * NH + h];
    }
    if (wid == 0) {
        float a0 = dta[(dbase + lidx(t0 + lane)) * NH + h];
        float a1 = dta[(dbase + lidx(t0 + 64 + lane)) * NH + h];
#pragma unroll
        for (int off = 1; off < 64; off <<= 1) {
            const float u0 = __shfl_up(a0, off);
            const float u1 = __shfl_up(a1, off);
            if (lane >= off) { a0 += u0; a1 += u1; }
        }
        a1 += __shfl(a0, 63);
        scum[lane] = a0; scum[64 + lane] = a1;
        betac[(size_t)bh * L_SEQ + t0 + lane] = a0;
        betac[(size_t)bh * L_SEQ + t0 + 64 + lane] = a1;
    }
    __syncthreads();

    // ---- phase B: build X~T and WBT ----
    {
        const int s = tid >> 1;
        const float dts = sdt[s];
        const float rs = expf(scum[CHUNK - 1] - scum[s]);
        const size_t grow = dbase + lidx(t0 + s);
        const int p0 = (tid & 1) * 32;
        const u16* __restrict__ xp = xs + grow * DINNER + h * 64 + p0;
#pragma unroll
        for (int q = 0; q < 4; ++q) {
            short8 v = *(const short8*)(xp + q * 8);
#pragma unroll
            for (int j = 0; j < 8; ++j) {
                const int p = p0 + q * 8 + j;
                XT[sidx(p, s)] = bf16bits(dts * bits2f((u16)v[j]));
            }
        }
        const int n0 = (tid & 1) * 64;
        const u16* __restrict__ bp = Bbf + grow * NST + n0;
#pragma unroll
        for (int q = 0; q < 8; ++q) {
            short8 v = *(const short8*)(bp + q * 8);
#pragma unroll
            for (int j = 0; j < 8; ++j) {
                const int n = n0 + q * 8 + j;
                WBT[sidx(n, s)] = bf16bits(rs * bits2f((u16)v[j]));
            }
        }
    }
    __syncthreads();

    // ---- phase C1: STATE GEMM c[p][n] ----
    {
        const int pw = wid * 16;
        const int prow = pw + l15;
        short8 xa[4];
#pragma unroll
        for (int kk = 0; kk < 4; ++kk)
            xa[kk] = *(const short8*)(XT + sslot(prow, kk * 4 + l4));
        const size_t sbase = ((size_t)bh * NCH + ch) * 8192;
#pragma unroll
        for (int jn = 0; jn < 8; ++jn) {
            const int nrow = jn * 16 + l15;
            f32x4 acc = (f32x4)0.f;
#pragma unroll
            for (int kk = 0; kk < 4; ++kk) {
                const short8 wb = *(const short8*)(WBT + sslot(nrow, kk * 4 + l4));
                acc = __builtin_amdgcn_mfma_f32_16x16x32_bf16(xa[kk], wb, acc, 0, 0, 0);
            }
#pragma unroll
            for (int r = 0; r < 4; ++r)
                stateC[sbase + (size_t)(pw + l4 * 4 + r) * 128 + jn * 16 + l15] =
                    bf16bits(acc[r]);
        }
    }

    // ---- phase C2: S GEMM (global bf16 operands) ----
    f32x4 accs[2][8];
#pragma unroll
    for (int m = 0; m < 2; ++m)
#pragma unroll
        for (int j = 0; j < 8; ++j) accs[m][j] = (f32x4)0.f;
    {
        short8 af[2][4];
#pragma unroll
        for (int m = 0; m < 2; ++m) {
            const size_t crow = dbase + lidx(t0 + wid * 32 + m * 16 + l15);
#pragma unroll
            for (int kk = 0; kk < 4; ++kk)
                af[m][kk] = *(const short8*)(Cbf + crow * NST + kk * 32 + l4 * 8);
        }
#pragma unroll
        for (int j = 0; j < 8; ++j) {
            const size_t brow = dbase + lidx(t0 + j * 16 + l15);
            short8 bf_[4];
#pragma unroll
            for (int kk = 0; kk < 4; ++kk)
                bf_[kk] = *(const short8*)(Bbf + brow * NST + kk * 32 + l4 * 8);
#pragma unroll
            for (int m = 0; m < 2; ++m)
#pragma unroll
                for (int kk = 0; kk < 4; ++kk)
                    accs[m][j] = __builtin_amdgcn_mfma_f32_16x16x32_bf16(
                        af[m][kk], bf_[kk], accs[m][j], 0, 0, 0);
        }
    }
    __syncthreads();   // all waves done with WBT (state phase reads)

    // ---- phase C3: Gamma-scale, write P~ over WBT ----
    u16* __restrict__ PT = WBT;
#pragma unroll
    for (int m = 0; m < 2; ++m) {
#pragma unroll
        for (int r = 0; r < 4; ++r) {
            const int t = wid * 32 + m * 16 + l4 * 4 + r;
            const float ct = scum[t];
#pragma unroll
            for (int j = 0; j < 8; ++j) {
                const int s = j * 16 + l15;
                const float g = (s <= t) ? expf(ct - scum[s]) : 0.f;
                PT[sidx(t, s)] = bf16bits(accs[m][j][r] * g);
            }
        }
    }
    __syncthreads();

    // ---- phase D: Y = P~ @ X~T^T, + D-skip, store ----
    {
        float* __restrict__ ybase = zx + (size_t)dir * M_ROWS * DPROJP + DINNER;
        short8 pa[2][4];
#pragma unroll
        for (int m = 0; m < 2; ++m) {
            const int trow = wid * 32 + m * 16 + l15;
#pragma unroll
            for (int kk = 0; kk < 4; ++kk)
                pa[m][kk] = *(const short8*)(PT + sslot(trow, kk * 4 + l4));
        }
#pragma unroll
        for (int jp = 0; jp < 4; ++jp) {
            const int prow = jp * 16 + l15;
            short8 xb[4];
#pragma unroll
            for (int kk = 0; kk < 4; ++kk)
                xb[kk] = *(const short8*)(XT + sslot(prow, kk * 4 + l4));
#pragma unroll
            for (int m = 0; m < 2; ++m) {
                f32x4 acc = (f32x4)0.f;
#pragma unroll
                for (int kk = 0; kk < 4; ++kk)
                    acc = __builtin_amdgcn_mfma_f32_16x16x32_bf16(
                        pa[m][kk], xb[kk], acc, 0, 0, 0);
                const int p = jp * 16 + l15;
#pragma unroll
                for (int r = 0; r < 4; ++r) {
                    const int t = wid * 32 + m * 16 + l4 * 4 + r;
                    const int lg = lidx(t0 + t);
                    const float xv = bits2f(xs[(dbase + lg) * DINNER + h * 64 + p]);
                    ybase[(size_t)(bb * L_SEQ + lg) * DPROJP + h * 64 + p] =
                        acc[r] + Dv * xv;
                }
            }
        }
    }
}

// ---------------------------------------------------------------------------
// Combine: sequential over NCH chunks per bh (in place on stateC).
// ---------------------------------------------------------------------------
__global__ __launch_bounds__(512) void combine_kernel(
    u16* __restrict__ stateC, const float* __restrict__ betac)
{
    const int bh  = blockIdx.x;
    const int tid = threadIdx.x;

    float hrun[16];
#pragma unroll
    for (int j = 0; j < 16; ++j) hrun[j] = 0.f;

    for (int s = 0; s < NCH; ++s) {
        const size_t off = ((size_t)bh * NCH + s) * 8192 + (size_t)tid * 16;
        float c[16];
#pragma unroll
        for (int j = 0; j < 16; ++j) c[j] = bits2f(stateC[off + j]);
#pragma unroll
        for (int j = 0; j < 16; ++j) stateC[off + j] = bf16bits(hrun[j]);
        const float alpha = expf(betac[(size_t)bh * L_SEQ + s * CHUNK + (CHUNK - 1)]);
#pragma unroll
        for (int j = 0; j < 16; ++j) hrun[j] = fmaf(alpha, hrun[j], c[j]);
    }
}

// ---------------------------------------------------------------------------
// Correction: y[t] += exp(cumA_t) * (C_t . h_in). MFMA, chunk>0 only.
// ---------------------------------------------------------------------------
__global__ __launch_bounds__(256) void correct_kernel(
    const u16* __restrict__ Cbf, const float* __restrict__ betac,
    const u16* __restrict__ stateC, float* __restrict__ zx)
{
    const int bx  = blockIdx.x;
    const int ch  = bx & (NCH - 1);
    if (ch == 0) return;
    const int bh  = bx >> 4;
    const int dir = bh >> 6;
    const int bb  = (bh >> 5) & 1;
    const int h   = bh & 31;
    const int tid = threadIdx.x;
    const int wid = tid >> 6;
    const int lane = tid & 63;
    const int l15 = lane & 15;
    const int l4  = lane >> 4;
    const int t0  = ch * CHUNK;
    const size_t dbase = (size_t)(dir * M_ROWS + bb * L_SEQ);
    const size_t sbase = ((size_t)bh * NCH + ch) * 8192;

    auto lidx = [&](int t) { return dir ? (L_SEQ - 1 - t) : t; };

    short8 af[2][4];
#pragma unroll
    for (int m = 0; m < 2; ++m) {
        const size_t crow = dbase + lidx(t0 + wid * 32 + m * 16 + l15);
#pragma unroll
        for (int kk = 0; kk < 4; ++kk)
            af[m][kk] = *(const short8*)(Cbf + crow * NST + kk * 32 + l4 * 8);
    }

    f32x4 acc[2][4];
#pragma unroll
    for (int m = 0; m < 2; ++m)
#pragma unroll
        for (int jp = 0; jp < 4; ++jp) acc[m][jp] = (f32x4)0.f;

#pragma unroll
    for (int jp = 0; jp < 4; ++jp) {
        const int prow = jp * 16 + l15;
        short8 hb[4];
#pragma unroll
        for (int kk = 0; kk < 4; ++kk)
            hb[kk] = *(const short8*)(stateC + sbase + (size_t)prow * 128 + kk * 32 + l4 * 8);
#pragma unroll
        for (int m = 0; m < 2; ++m)
#pragma unroll
            for (int kk = 0; kk < 4; ++kk)
                acc[m][jp] = __builtin_amdgcn_mfma_f32_16x16x32_bf16(
                    af[m][kk], hb[kk], acc[m][jp], 0, 0, 0);
    }

    float* __restrict__ ybase = zx + (size_t)dir * M_ROWS * DPROJP + DINNER;
#pragma unroll
    for (int m = 0; m < 2; ++m) {
#pragma unroll
        for (int r = 0; r < 4; ++r) {
            const int t = wid * 32 + m * 16 + l4 * 4 + r;
            const float g = expf(betac[(size_t)bh * L_SEQ + t0 + t]);
            const int lg = lidx(t0 + t);
#pragma unroll
            for (int jp = 0; jp < 4; ++jp) {
                const int p = jp * 16 + l15;
                ybase[(size_t)(bb * L_SEQ + lg) * DPROJP + h * 64 + p] += g * acc[m][jp][r];
            }
        }
    }
}

// ---------------------------------------------------------------------------
// y = y * silu(z); RMSNorm(2048) * norm_w, in place on y slice of zx.
// ---------------------------------------------------------------------------
__global__ __launch_bounds__(256) void gatenorm_kernel(
    float* __restrict__ zx,
    const float* __restrict__ nw0, const float* __restrict__ nw1)
{
    const int dir = blockIdx.y;
    const int row = blockIdx.x;
    const float* __restrict__ nw = dir ? nw1 : nw0;
    float* __restrict__ rowp = zx + (size_t)dir * M_ROWS * DPROJP + (size_t)row * DPROJP;
    const int tid = threadIdx.x;
    const int c0 = tid * 8;

    const float4 y0 = *(const float4*)(rowp + DINNER + c0);
    const float4 y1 = *(const float4*)(rowp + DINNER + c0 + 4);
    const float4 z0 = *(const float4*)(rowp + c0);
    const float4 z1 = *(const float4*)(rowp + c0 + 4);

    float4 g0, g1;
    g0.x = y0.x * (z0.x / (1.f + expf(-z0.x)));
    g0.y = y0.y * (z0.y / (1.f + expf(-z0.y)));
    g0.z = y0.z * (z0.z / (1.f + expf(-z0.z)));
    g0.w = y0.w * (z0.w / (1.f + expf(-z0.w)));
    g1.x = y1.x * (z1.x / (1.f + expf(-z1.x)));
    g1.y = y1.y * (z1.y / (1.f + expf(-z1.y)));
    g1.z = y1.z * (z1.z / (1.f + expf(-z1.z)));
    g1.w = y1.w * (z1.w / (1.f + expf(-z1.w)));

    float ss = g0.x * g0.x + g0.y * g0.y + g0.z * g0.z + g0.w * g0.w
             + g1.x * g1.x + g1.y * g1.y + g1.z * g1.z + g1.w * g1.w;
#pragma unroll
    for (int off = 1; off < 64; off <<= 1) ss += __shfl_xor(ss, off);
    __shared__ float red[4];
    if ((tid & 63) == 0) red[tid >> 6] = ss;
    __syncthreads();
    const float total = red[0] + red[1] + red[2] + red[3];
    const float rs = rsqrtf(total * (1.f / (float)DINNER) + 1e-5f);

    const float4 w0 = *(const float4*)(nw + c0);
    const float4 w1 = *(const float4*)(nw + c0 + 4);
    float4 o0, o1;
    o0.x = g0.x * rs * w0.x; o0.y = g0.y * rs * w0.y;
    o0.z = g0.z * rs * w0.z; o0.w = g0.w * rs * w0.w;
    o1.x = g1.x * rs * w1.x; o1.y = g1.y * rs * w1.y;
    o1.z = g1.z * rs * w1.z; o1.w = g1.w * rs * w1.w;
    *(float4*)(rowp + DINNER + c0)     = o0;
    *(float4*)(rowp + DINNER + c0 + 4) = o1;
}

// ---------------------------------------------------------------------------
extern "C" void kernel_launch(void* const* d_in, const int* in_sizes, int n_in,
                              void* d_out, int out_size, void* d_ws, size_t ws_size,
                              hipStream_t stream)
{
    (void)in_sizes; (void)n_in; (void)out_size; (void)ws_size;
    const float* x        = (const float*)d_in[0];
    const float* f_in_w   = (const float*)d_in[1];
    const float* f_conv_w = (const float*)d_in[2];
    const float* f_conv_b = (const float*)d_in[3];
    const float* f_dtbias = (const float*)d_in[4];
    const float* f_Alog   = (const float*)d_in[5];
    const float* f_D      = (const float*)d_in[6];
    const float* f_nw     = (const float*)d_in[7];
    const float* f_out_w  = (const float*)d_in[8];
    const float* b_in_w   = (const float*)d_in[9];
    const float* b_conv_w = (const float*)d_in[10];
    const float* b_conv_b = (const float*)d_in[11];
    const float* b_dtbias = (const float*)d_in[12];
    const float* b_Alog   = (const float*)d_in[13];
    const float* b_D      = (const float*)d_in[14];
    const float* b_nw     = (const float*)d_in[15];
    const float* b_out_w  = (const float*)d_in[16];

    float* ws  = (float*)d_ws;
    float* zx  = ws;
    u16* xs  = (u16*)(zx + (size_t)2 * M_ROWS * DPROJP);
    u16* Bbf = xs + (size_t)2 * M_ROWS * DINNER;
    u16* Cbf = Bbf + (size_t)2 * M_ROWS * NST;
    float* dtb = (float*)(Cbf + (size_t)2 * M_ROWS * NST);
    float* dta = dtb + (size_t)2 * M_ROWS * NH;
    u16* stateC = (u16*)(dta + (size_t)2 * M_ROWS * NH);
    float* betac = (float*)(stateC + (size_t)128 * NCH * 8192);
    __hip_bfloat16* x_bf    = (__hip_bfloat16*)(betac + (size_t)128 * L_SEQ);
    __hip_bfloat16* w_in_bf = x_bf + (size_t)M_ROWS * 512;
    __hip_bfloat16* w_out_bf = w_in_bf + (size_t)2 * DPROJP * 512;

    // 0) dtype conversions
    cvt_x_kernel<<<dim3(M_ROWS * 512 / 1024), 256, 0, stream>>>(x, x_bf);
    cvt_win_kernel<<<dim3(DPROJP * 512 / 1024, 2), 256, 0, stream>>>(f_in_w, b_in_w, w_in_bf);
    cvt_wout_kernel<<<dim3(512 * DINNER / 1024, 2), 256, 0, stream>>>(f_out_w, b_out_w, w_out_bf);

    // 1) in_proj (MFMA): zx[dir] = x @ in_w[dir]^T
    gemm_mfma<false><<<dim3(DPROJP / 128, M_ROWS / 128, 2), 256, 0, stream>>>(
        (const __hip_bfloat16*)x_bf, nullptr, nullptr, 0,
        w_in_bf, (long long)DPROJP * 512,
        zx, (long long)M_ROWS * DPROJP, DPROJP,
        nullptr, 0, 512);

    // 2a) sliding-window conv + SiLU (bf16 x/B/C out)
    conv_kernel<<<dim3(CONVDIM / 256, 32, 2), 256, 0, stream>>>(
        zx, f_conv_w, b_conv_w, f_conv_b, b_conv_b, xs, Bbf, Cbf);

    // 2b) exact-f32 dt / log-decay (LDS-staged GEMV)
    dt_kernel<<<dim3(M_ROWS / 64, 2), 512, 0, stream>>>(
        x, f_in_w, b_in_w, f_dtbias, b_dtbias, f_Alog, b_Alog, dtb, dta);

    // 3a) SSD chunk kernel (local Y + D-skip + chunk states + cumA)
    ssd_chunk_kernel<<<dim3(128 * NCH), 256, 0, stream>>>(
        xs, Bbf, Cbf, dtb, dta, f_D, b_D, zx, stateC, betac);

    // 3b) combine chunk states
    combine_kernel<<<dim3(128), 512, 0, stream>>>(stateC, betac);

    // 3c) inter-chunk correction (MFMA)
    correct_kernel<<<dim3(128 * NCH), 256, 0, stream>>>(Cbf, betac, stateC, zx);

    // 4) gate + RMSNorm in place on y slice
    gatenorm_kernel<<<dim3(M_ROWS, 2), 256, 0, stream>>>(zx, f_nw, b_nw);

    // 5) out_proj (MFMA) + residual + concat
    gemm_mfma<true><<<dim3(512 / 128, M_ROWS / 128, 2), 256, 0, stream>>>(
        nullptr, zx + DINNER, zx + (size_t)M_ROWS * DPROJP + DINNER, DPROJP,
        w_out_bf, (long long)512 * DINNER,
        (float*)d_out, 512, 1024,
        x, 512, DINNER);
}

// Round 10
// 379.385 us; speedup vs baseline: 2.1094x; 1.1085x over previous
//
#include <hip/hip_runtime.h>
#include <hip/hip_bf16.h>
#include <math.h>

#define L_SEQ   2048
#define M_ROWS  4096            // B*L
#define DPROJ   4384
#define DPROJP  4480            // padded to 35*128 for MFMA GEMM
#define DINNER  2048
#define CONVDIM 2304
#define NST     128
#define NH      32
#define CHUNK   128             // SSD chunk length
#define NCH     16              // L_SEQ / CHUNK
#define CTR     128             // conv rows per tile

typedef __attribute__((ext_vector_type(8))) short short8;
typedef __attribute__((ext_vector_type(4))) float f32x4;
typedef unsigned short u16;

static __device__ __forceinline__ u16 bf16bits(float v) {
    __hip_bfloat16 t = __float2bfloat16(v);
    return *(u16*)&t;
}
static __device__ __forceinline__ float bits2f(u16 u) {
    return __uint_as_float((unsigned)u << 16);
}
// element index into a [rows][128] bf16 LDS buffer with 16B-slot XOR swizzle
static __device__ __forceinline__ int sidx(int row, int s) {
    return (row << 7) + ((((s >> 3) ^ (row & 7)) << 3) | (s & 7));
}
static __device__ __forceinline__ int sslot(int row, int ks) {  // ks = 16B slot 0..15
    return (row << 7) + ((ks ^ (row & 7)) << 3);
}

// ---------------------------------------------------------------------------
// f32 -> bf16 conversion pre-passes
// ---------------------------------------------------------------------------
__global__ __launch_bounds__(256) void cvt_x_kernel(
    const float* __restrict__ x, u16* __restrict__ xbf)
{
    const int i = (blockIdx.x * 256 + threadIdx.x) * 4;
    const float4 v = *(const float4*)(x + i);
    xbf[i + 0] = bf16bits(v.x);
    xbf[i + 1] = bf16bits(v.y);
    xbf[i + 2] = bf16bits(v.z);
    xbf[i + 3] = bf16bits(v.w);
}

__global__ __launch_bounds__(256) void cvt_win_kernel(
    const float* __restrict__ w0, const float* __restrict__ w1,
    u16* __restrict__ dst)
{
    const int dir = blockIdx.y;
    const float* __restrict__ w = dir ? w1 : w0;
    u16* __restrict__ d = dst + (size_t)dir * DPROJP * 512;
    const int i = (blockIdx.x * 256 + threadIdx.x) * 4;
    const int row = i >> 9;
    if (row < DPROJ) {
        const float4 v = *(const float4*)(w + i);
        d[i + 0] = bf16bits(v.x);
        d[i + 1] = bf16bits(v.y);
        d[i + 2] = bf16bits(v.z);
        d[i + 3] = bf16bits(v.w);
    } else {
        d[i + 0] = 0; d[i + 1] = 0; d[i + 2] = 0; d[i + 3] = 0;
    }
}

__global__ __launch_bounds__(256) void cvt_wout_kernel(
    const float* __restrict__ w0, const float* __restrict__ w1,
    u16* __restrict__ dst)
{
    const int dir = blockIdx.y;
    const float* __restrict__ w = dir ? w1 : w0;
    u16* __restrict__ d = dst + (size_t)dir * 512 * DINNER;
    const int i = (blockIdx.x * 256 + threadIdx.x) * 4;
    const float4 v = *(const float4*)(w + i);
    d[i + 0] = bf16bits(v.x);
    d[i + 1] = bf16bits(v.y);
    d[i + 2] = bf16bits(v.z);
    d[i + 3] = bf16bits(v.w);
}

// ---------------------------------------------------------------------------
// MFMA bf16 GEMM: C[M][N] = A[M][K] @ B[N][K]^T. A bf16 with arbitrary lda.
// OUTBF: write bf16 (no addsrc). else: f32 + optional addsrc epilogue.
// 128x128 tile, BK=64, 256 threads. LDS XOR-swizzled.
// ---------------------------------------------------------------------------
template<bool OUTBF>
__global__ __launch_bounds__(256) void gemm_mfma(
    const u16* __restrict__ A0, const u16* __restrict__ A1, int lda,
    const u16* __restrict__ Bw, long long b_dir_off,
    float* __restrict__ Cf, u16* __restrict__ Cb, long long c_dir_off, int ldc,
    const float* __restrict__ addsrc, int add_ld,
    int K)
{
    const int dir = blockIdx.z;
    const int m0 = blockIdx.y * 128;
    const int n0 = blockIdx.x * 128;
    const u16* __restrict__ A = dir ? A1 : A0;
    const u16* __restrict__ B = Bw + (size_t)dir * b_dir_off;

    __shared__ u16 Asl[128 * 64];
    __shared__ u16 Bsl[128 * 64];

    const int tid  = threadIdx.x;
    const int lane = tid & 63;
    const int wid  = tid >> 6;
    const int wr   = (wid >> 1) << 6;
    const int wc   = (wid & 1) << 6;
    const int l15  = lane & 15;
    const int l4   = lane >> 4;

    f32x4 acc[4][4];
#pragma unroll
    for (int m = 0; m < 4; ++m)
#pragma unroll
        for (int n = 0; n < 4; ++n) acc[m][n] = (f32x4)0.f;

    for (int k0 = 0; k0 < K; k0 += 64) {
        __syncthreads();
#pragma unroll
        for (int i = 0; i < 4; ++i) {
            const int c    = tid + (i << 8);
            const int row  = c >> 3;
            const int slot = c & 7;
            const int dst  = (row << 7) + ((slot ^ (row & 7)) << 4);
            *(short8*)((char*)Asl + dst) =
                *(const short8*)(A + (size_t)(m0 + row) * lda + k0 + (slot << 3));
            *(short8*)((char*)Bsl + dst) =
                *(const short8*)(B + (size_t)(n0 + row) * K + k0 + (slot << 3));
        }
        __syncthreads();

#pragma unroll
        for (int kh = 0; kh < 2; ++kh) {
            const int ks = (kh << 2) + l4;
            short8 a[4], b[4];
#pragma unroll
            for (int m = 0; m < 4; ++m) {
                const int R = wr + (m << 4) + l15;
                a[m] = *(const short8*)((const char*)Asl + (R << 7) + ((ks ^ (R & 7)) << 4));
            }
#pragma unroll
            for (int n = 0; n < 4; ++n) {
                const int R = wc + (n << 4) + l15;
                b[n] = *(const short8*)((const char*)Bsl + (R << 7) + ((ks ^ (R & 7)) << 4));
            }
#pragma unroll
            for (int m = 0; m < 4; ++m)
#pragma unroll
                for (int n = 0; n < 4; ++n)
                    acc[m][n] = __builtin_amdgcn_mfma_f32_16x16x32_bf16(
                        a[m], b[n], acc[m][n], 0, 0, 0);
        }
    }

#pragma unroll
    for (int m = 0; m < 4; ++m) {
        const int row0 = m0 + wr + (m << 4) + (l4 << 2);
#pragma unroll
        for (int n = 0; n < 4; ++n) {
            const int col = n0 + wc + (n << 4) + l15;
#pragma unroll
            for (int r = 0; r < 4; ++r) {
                if (OUTBF) {
                    Cb[(size_t)dir * c_dir_off + (size_t)(row0 + r) * ldc + col] =
                        bf16bits(acc[m][n][r]);
                } else {
                    float v = acc[m][n][r];
                    if (addsrc) v += addsrc[(size_t)(row0 + r) * add_ld + col];
                    Cf[(size_t)dir * c_dir_off + (size_t)(row0 + r) * ldc + col] = v;
                }
            }
        }
    }
}

// ---------------------------------------------------------------------------
// Sliding-window depthwise conv(4) + SiLU over bf16 zx columns. Thread owns
// one channel column, walks CTR rows keeping 3-tap history in registers.
// ---------------------------------------------------------------------------
__global__ __launch_bounds__(256) void conv_kernel(
    const u16* __restrict__ zx,
    const float* __restrict__ cw0, const float* __restrict__ cw1,
    const float* __restrict__ cb0, const float* __restrict__ cb1,
    u16* __restrict__ xs, u16* __restrict__ Bbf, u16* __restrict__ Cbf)
{
    const int dir = blockIdx.z;
    const int c   = blockIdx.x * 256 + threadIdx.x;     // channel 0..2303
    const int b   = blockIdx.y >> 4;
    const int r0  = (blockIdx.y & 15) * CTR;

    const float* __restrict__ cw = dir ? cw1 : cw0;
    const float w0 = cw[c * 4 + 0], w1 = cw[c * 4 + 1];
    const float w2 = cw[c * 4 + 2], w3 = cw[c * 4 + 3];
    const float bias = (dir ? cb1 : cb0)[c];

    const u16* __restrict__ zcol = zx + (size_t)dir * M_ROWS * DPROJP
        + (size_t)(b * L_SEQ) * DPROJP + DINNER + c;
    const size_t obase = (size_t)(dir * M_ROWS + b * L_SEQ);

    auto emit = [&](int l, float acc) {
        const float s = acc / (1.f + expf(-acc));
        const size_t orow = obase + l;
        if (c < DINNER)            xs[orow * DINNER + c] = bf16bits(s);
        else if (c < DINNER + NST) Bbf[orow * NST + (c - DINNER)] = bf16bits(s);
        else                       Cbf[orow * NST + (c - DINNER - NST)] = bf16bits(s);
    };

    if (dir == 0) {
        float h0 = (r0 - 3 >= 0) ? bits2f(zcol[(size_t)(r0 - 3) * DPROJP]) : 0.f;
        float h1 = (r0 - 2 >= 0) ? bits2f(zcol[(size_t)(r0 - 2) * DPROJP]) : 0.f;
        float h2 = (r0 - 1 >= 0) ? bits2f(zcol[(size_t)(r0 - 1) * DPROJP]) : 0.f;
#pragma unroll 4
        for (int l = r0; l < r0 + CTR; ++l) {
            const float zl = bits2f(zcol[(size_t)l * DPROJP]);
            float acc = bias;
            acc = fmaf(w0, h0, acc);
            acc = fmaf(w1, h1, acc);
            acc = fmaf(w2, h2, acc);
            acc = fmaf(w3, zl, acc);
            emit(l, acc);
            h0 = h1; h1 = h2; h2 = zl;
        }
    } else {
        const int le = r0 + CTR - 1;
        float h1 = (le + 1 < L_SEQ) ? bits2f(zcol[(size_t)(le + 1) * DPROJP]) : 0.f;
        float h2 = (le + 2 < L_SEQ) ? bits2f(zcol[(size_t)(le + 2) * DPROJP]) : 0.f;
        float h3 = (le + 3 < L_SEQ) ? bits2f(zcol[(size_t)(le + 3) * DPROJP]) : 0.f;
#pragma unroll 4
        for (int l = le; l >= r0; --l) {
            const float zl = bits2f(zcol[(size_t)l * DPROJP]);
            float acc = bias;
            acc = fmaf(w3, zl, acc);
            acc = fmaf(w2, h1, acc);
            acc = fmaf(w1, h2, acc);
            acc = fmaf(w0, h3, acc);
            emit(l, acc);
            h3 = h2; h2 = h1; h1 = zl;
        }
    }
}

// ---------------------------------------------------------------------------
// Exact-f32 dt as LDS-staged block GEMV (unchanged from round 8).
// ---------------------------------------------------------------------------
__global__ __launch_bounds__(512) void dt_kernel(
    const float* __restrict__ x,
    const float* __restrict__ inw0, const float* __restrict__ inw1,
    const float* __restrict__ dtbias0, const float* __restrict__ dtbias1,
    const float* __restrict__ Alog0, const float* __restrict__ Alog1,
    float* __restrict__ dtb, float* __restrict__ dta)
{
    const int dir = blockIdx.y;
    const int r0  = blockIdx.x * 64;
    const int tid = threadIdx.x;

    __shared__ float wT[512 * 32];   // [k4][h][j], 64 KB
    __shared__ float sbias[NH], sa[NH];

    const float* __restrict__ w = (dir ? inw1 : inw0) + (size_t)(DINNER + CONVDIM) * 512;
    for (int i = tid; i < 4096; i += 512) {
        const int flat = i * 4;
        const int h = flat >> 9;
        const int k = flat & 511;
        const float4 v = *(const float4*)(w + flat);
        *(float4*)&wT[(k >> 2) * 128 + h * 4] = v;
    }
    if (tid < NH) {
        sbias[tid] = (dir ? dtbias1 : dtbias0)[tid];
        sa[tid] = -expf((dir ? Alog1 : Alog0)[tid]);
    }
    __syncthreads();

    const int h  = tid & 31;
    const int rr = tid >> 5;
    const float bias = sbias[h];
    const float a = sa[h];

    for (int rp = 0; rp < 64; rp += 16) {
        const int row = r0 + rp + rr;
        const float4* __restrict__ xr = (const float4*)(x + (size_t)row * 512);
        float4 s4 = make_float4(0.f, 0.f, 0.f, 0.f);
#pragma unroll 8
        for (int k4 = 0; k4 < 128; ++k4) {
            const float4 xv = xr[k4];
            const float4 wv = *(const float4*)&wT[k4 * 128 + h * 4];
            s4.x = fmaf(xv.x, wv.x, s4.x);
            s4.y = fmaf(xv.y, wv.y, s4.y);
            s4.z = fmaf(xv.z, wv.z, s4.z);
            s4.w = fmaf(xv.w, wv.w, s4.w);
        }
        const float v = (s4.x + s4.y) + (s4.z + s4.w) + bias;
        const float sp = (v > 20.f) ? v : log1pf(expf(v));
        const size_t orow = (size_t)(dir * M_ROWS + row);
        dtb[orow * NH + h] = sp;
        dta[orow * NH + h] = sp * a;         // log-decay
    }
}

// ---------------------------------------------------------------------------
// SSD chunk kernel (y -> compact f32 yf).
// ---------------------------------------------------------------------------
__global__ __launch_bounds__(256) void ssd_chunk_kernel(
    const u16* __restrict__ xs, const u16* __restrict__ Bbf,
    const u16* __restrict__ Cbf,
    const float* __restrict__ dtb, const float* __restrict__ dta,
    const float* __restrict__ D0, const float* __restrict__ D1,
    float* __restrict__ yf, u16* __restrict__ stateC,
    float* __restrict__ betac)
{
    const int bx  = blockIdx.x;
    const int ch  = bx & (NCH - 1);
    const int bh  = bx >> 4;
    const int dir = bh >> 6;
    const int bb  = (bh >> 5) & 1;
    const int h   = bh & 31;
    const int tid = threadIdx.x;
    const int wid = tid >> 6;
    const int lane = tid & 63;
    const int l15 = lane & 15;
    const int l4  = lane >> 4;
    const int t0  = ch * CHUNK;
    const size_t dbase = (size_t)(dir * M_ROWS + bb * L_SEQ);
    const float Dv = (dir ? D1 : D0)[h];

    __shared__ u16 XT[64 * 128];
    __shared__ u16 WBT[128 * 128];     // reused as P~ after state/S phases
    __shared__ float scum[CHUNK];
    __shared__ float sdt[CHUNK];

    auto lidx = [&](int t) { return dir ? (L_SEQ - 1 - t) : t; };

    // ---- phase A: dt loads + cumA prefix-sum (wave 0) ----
    if (tid >= 128) {
        const int s = tid - 128;
        sdt[s] = dtb[(dbase + lidx(t0 + s)) * NH + h];
    }
    if (wid == 0) {
        float a0 = dta[(dbase + lidx(t0 + lane)) * NH + h];
        float a1 = dta[(dbase + lidx(t0 + 64 + lane)) * NH + h];
#pragma unroll
        for (int off = 1; off < 64; off <<= 1) {
            const float u0 = __shfl_up(a0, off);
            const float u1 = __shfl_up(a1, off);
            if (lane >= off) { a0 += u0; a1 += u1; }
        }
        a1 += __shfl(a0, 63);
        scum[lane] = a0; scum[64 + lane] = a1;
        betac[(size_t)bh * L_SEQ + t0 + lane] = a0;
        betac[(size_t)bh * L_SEQ + t0 + 64 + lane] = a1;
    }
    __syncthreads();

    // ---- phase B: build X~T and WBT ----
    {
        const int s = tid >> 1;
        const float dts = sdt[s];
        const float rs = expf(scum[CHUNK - 1] - scum[s]);
        const size_t grow = dbase + lidx(t0 + s);
        const int p0 = (tid & 1) * 32;
        const u16* __restrict__ xp = xs + grow * DINNER + h * 64 + p0;
#pragma unroll
        for (int q = 0; q < 4; ++q) {
            short8 v = *(const short8*)(xp + q * 8);
#pragma unroll
            for (int j = 0; j < 8; ++j) {
                const int p = p0 + q * 8 + j;
                XT[sidx(p, s)] = bf16bits(dts * bits2f((u16)v[j]));
            }
        }
        const int n0 = (tid & 1) * 64;
        const u16* __restrict__ bp = Bbf + grow * NST + n0;
#pragma unroll
        for (int q = 0; q < 8; ++q) {
            short8 v = *(const short8*)(bp + q * 8);
#pragma unroll
            for (int j = 0; j < 8; ++j) {
                const int n = n0 + q * 8 + j;
                WBT[sidx(n, s)] = bf16bits(rs * bits2f((u16)v[j]));
            }
        }
    }
    __syncthreads();

    // ---- phase C1: STATE GEMM c[p][n] ----
    {
        const int pw = wid * 16;
        const int prow = pw + l15;
        short8 xa[4];
#pragma unroll
        for (int kk = 0; kk < 4; ++kk)
            xa[kk] = *(const short8*)(XT + sslot(prow, kk * 4 + l4));
        const size_t sbase = ((size_t)bh * NCH + ch) * 8192;
#pragma unroll
        for (int jn = 0; jn < 8; ++jn) {
            const int nrow = jn * 16 + l15;
            f32x4 acc = (f32x4)0.f;
#pragma unroll
            for (int kk = 0; kk < 4; ++kk) {
                const short8 wb = *(const short8*)(WBT + sslot(nrow, kk * 4 + l4));
                acc = __builtin_amdgcn_mfma_f32_16x16x32_bf16(xa[kk], wb, acc, 0, 0, 0);
            }
#pragma unroll
            for (int r = 0; r < 4; ++r)
                stateC[sbase + (size_t)(pw + l4 * 4 + r) * 128 + jn * 16 + l15] =
                    bf16bits(acc[r]);
        }
    }

    // ---- phase C2: S GEMM (global bf16 operands) ----
    f32x4 accs[2][8];
#pragma unroll
    for (int m = 0; m < 2; ++m)
#pragma unroll
        for (int j = 0; j < 8; ++j) accs[m][j] = (f32x4)0.f;
    {
        short8 af[2][4];
#pragma unroll
        for (int m = 0; m < 2; ++m) {
            const size_t crow = dbase + lidx(t0 + wid * 32 + m * 16 + l15);
#pragma unroll
            for (int kk = 0; kk < 4; ++kk)
                af[m][kk] = *(const short8*)(Cbf + crow * NST + kk * 32 + l4 * 8);
        }
#pragma unroll
        for (int j = 0; j < 8; ++j) {
            const size_t brow = dbase + lidx(t0 + j * 16 + l15);
            short8 bf_[4];
#pragma unroll
            for (int kk = 0; kk < 4; ++kk)
                bf_[kk] = *(const short8*)(Bbf + brow * NST + kk * 32 + l4 * 8);
#pragma unroll
            for (int m = 0; m < 2; ++m)
#pragma unroll
                for (int kk = 0; kk < 4; ++kk)
                    accs[m][j] = __builtin_amdgcn_mfma_f32_16x16x32_bf16(
                        af[m][kk], bf_[kk], accs[m][j], 0, 0, 0);
        }
    }
    __syncthreads();   // all waves done with WBT (state phase reads)

    // ---- phase C3: Gamma-scale, write P~ over WBT ----
    u16* __restrict__ PT = WBT;
#pragma unroll
    for (int m = 0; m < 2; ++m) {
#pragma unroll
        for (int r = 0; r < 4; ++r) {
            const int t = wid * 32 + m * 16 + l4 * 4 + r;
            const float ct = scum[t];
#pragma unroll
            for (int j = 0; j < 8; ++j) {
                const int s = j * 16 + l15;
                const float g = (s <= t) ? expf(ct - scum[s]) : 0.f;
                PT[sidx(t, s)] = bf16bits(accs[m][j][r] * g);
            }
        }
    }
    __syncthreads();

    // ---- phase D: Y = P~ @ X~T^T, + D-skip, store to compact yf ----
    {
        float* __restrict__ ybase = yf + (size_t)dir * M_ROWS * DINNER;
        short8 pa[2][4];
#pragma unroll
        for (int m = 0; m < 2; ++m) {
            const int trow = wid * 32 + m * 16 + l15;
#pragma unroll
            for (int kk = 0; kk < 4; ++kk)
                pa[m][kk] = *(const short8*)(PT + sslot(trow, kk * 4 + l4));
        }
#pragma unroll
        for (int jp = 0; jp < 4; ++jp) {
            const int prow = jp * 16 + l15;
            short8 xb[4];
#pragma unroll
            for (int kk = 0; kk < 4; ++kk)
                xb[kk] = *(const short8*)(XT + sslot(prow, kk * 4 + l4));
#pragma unroll
            for (int m = 0; m < 2; ++m) {
                f32x4 acc = (f32x4)0.f;
#pragma unroll
                for (int kk = 0; kk < 4; ++kk)
                    acc = __builtin_amdgcn_mfma_f32_16x16x32_bf16(
                        pa[m][kk], xb[kk], acc, 0, 0, 0);
                const int p = jp * 16 + l15;
#pragma unroll
                for (int r = 0; r < 4; ++r) {
                    const int t = wid * 32 + m * 16 + l4 * 4 + r;
                    const int lg = lidx(t0 + t);
                    const float xv = bits2f(xs[(dbase + lg) * DINNER + h * 64 + p]);
                    ybase[(size_t)(bb * L_SEQ + lg) * DINNER + h * 64 + p] =
                        acc[r] + Dv * xv;
                }
            }
        }
    }
}

// ---------------------------------------------------------------------------
// Combine: sequential over NCH chunks per bh (in place on stateC).
// ---------------------------------------------------------------------------
__global__ __launch_bounds__(512) void combine_kernel(
    u16* __restrict__ stateC, const float* __restrict__ betac)
{
    const int bh  = blockIdx.x;
    const int tid = threadIdx.x;

    float hrun[16];
#pragma unroll
    for (int j = 0; j < 16; ++j) hrun[j] = 0.f;

    for (int s = 0; s < NCH; ++s) {
        const size_t off = ((size_t)bh * NCH + s) * 8192 + (size_t)tid * 16;
        float c[16];
#pragma unroll
        for (int j = 0; j < 16; ++j) c[j] = bits2f(stateC[off + j]);
#pragma unroll
        for (int j = 0; j < 16; ++j) stateC[off + j] = bf16bits(hrun[j]);
        const float alpha = expf(betac[(size_t)bh * L_SEQ + s * CHUNK + (CHUNK - 1)]);
#pragma unroll
        for (int j = 0; j < 16; ++j) hrun[j] = fmaf(alpha, hrun[j], c[j]);
    }
}

// ---------------------------------------------------------------------------
// Correction: y[t] += exp(cumA_t) * (C_t . h_in). MFMA, chunk>0 only.
// ---------------------------------------------------------------------------
__global__ __launch_bounds__(256) void correct_kernel(
    const u16* __restrict__ Cbf, const float* __restrict__ betac,
    const u16* __restrict__ stateC, float* __restrict__ yf)
{
    const int bx  = blockIdx.x;
    const int ch  = bx & (NCH - 1);
    if (ch == 0) return;
    const int bh  = bx >> 4;
    const int dir = bh >> 6;
    const int bb  = (bh >> 5) & 1;
    const int h   = bh & 31;
    const int tid = threadIdx.x;
    const int wid = tid >> 6;
    const int lane = tid & 63;
    const int l15 = lane & 15;
    const int l4  = lane >> 4;
    const int t0  = ch * CHUNK;
    const size_t dbase = (size_t)(dir * M_ROWS + bb * L_SEQ);
    const size_t sbase = ((size_t)bh * NCH + ch) * 8192;

    auto lidx = [&](int t) { return dir ? (L_SEQ - 1 - t) : t; };

    short8 af[2][4];
#pragma unroll
    for (int m = 0; m < 2; ++m) {
        const size_t crow = dbase + lidx(t0 + wid * 32 + m * 16 + l15);
#pragma unroll
        for (int kk = 0; kk < 4; ++kk)
            af[m][kk] = *(const short8*)(Cbf + crow * NST + kk * 32 + l4 * 8);
    }

    f32x4 acc[2][4];
#pragma unroll
    for (int m = 0; m < 2; ++m)
#pragma unroll
        for (int jp = 0; jp < 4; ++jp) acc[m][jp] = (f32x4)0.f;

#pragma unroll
    for (int jp = 0; jp < 4; ++jp) {
        const int prow = jp * 16 + l15;
        short8 hb[4];
#pragma unroll
        for (int kk = 0; kk < 4; ++kk)
            hb[kk] = *(const short8*)(stateC + sbase + (size_t)prow * 128 + kk * 32 + l4 * 8);
#pragma unroll
        for (int m = 0; m < 2; ++m)
#pragma unroll
            for (int kk = 0; kk < 4; ++kk)
                acc[m][jp] = __builtin_amdgcn_mfma_f32_16x16x32_bf16(
                    af[m][kk], hb[kk], acc[m][jp], 0, 0, 0);
    }

    float* __restrict__ ybase = yf + (size_t)dir * M_ROWS * DINNER;
#pragma unroll
    for (int m = 0; m < 2; ++m) {
#pragma unroll
        for (int r = 0; r < 4; ++r) {
            const int t = wid * 32 + m * 16 + l4 * 4 + r;
            const float g = expf(betac[(size_t)bh * L_SEQ + t0 + t]);
            const int lg = lidx(t0 + t);
#pragma unroll
            for (int jp = 0; jp < 4; ++jp) {
                const int p = jp * 16 + l15;
                ybase[(size_t)(bb * L_SEQ + lg) * DINNER + h * 64 + p] += g * acc[m][jp][r];
            }
        }
    }
}

// ---------------------------------------------------------------------------
// gate + RMSNorm: reads bf16 z (zx cols [0,2048)) + f32 y (compact), writes
// bf16 gated/normalized y into zx cols [2048,4096) (dead xBC slice).
// ---------------------------------------------------------------------------
__global__ __launch_bounds__(256) void gatenorm_kernel(
    u16* __restrict__ zx, const float* __restrict__ yf,
    const float* __restrict__ nw0, const float* __restrict__ nw1)
{
    const int dir = blockIdx.y;
    const int row = blockIdx.x;
    const float* __restrict__ nw = dir ? nw1 : nw0;
    u16* __restrict__ zrow = zx + (size_t)dir * M_ROWS * DPROJP + (size_t)row * DPROJP;
    const float* __restrict__ yrow = yf + (size_t)dir * M_ROWS * DINNER + (size_t)row * DINNER;
    const int tid = threadIdx.x;
    const int c0 = tid * 8;

    const short8 zv = *(const short8*)(zrow + c0);
    const float4 y0 = *(const float4*)(yrow + c0);
    const float4 y1 = *(const float4*)(yrow + c0 + 4);

    float g[8];
    {
        const float yv[8] = {y0.x, y0.y, y0.z, y0.w, y1.x, y1.y, y1.z, y1.w};
#pragma unroll
        for (int j = 0; j < 8; ++j) {
            const float z = bits2f((u16)zv[j]);
            g[j] = yv[j] * (z / (1.f + expf(-z)));
        }
    }

    float ss = 0.f;
#pragma unroll
    for (int j = 0; j < 8; ++j) ss = fmaf(g[j], g[j], ss);
#pragma unroll
    for (int off = 1; off < 64; off <<= 1) ss += __shfl_xor(ss, off);
    __shared__ float red[4];
    if ((tid & 63) == 0) red[tid >> 6] = ss;
    __syncthreads();
    const float total = red[0] + red[1] + red[2] + red[3];
    const float rs = rsqrtf(total * (1.f / (float)DINNER) + 1e-5f);

    const float4 w0 = *(const float4*)(nw + c0);
    const float4 w1 = *(const float4*)(nw + c0 + 4);
    const float wv[8] = {w0.x, w0.y, w0.z, w0.w, w1.x, w1.y, w1.z, w1.w};
    short8 outv;
#pragma unroll
    for (int j = 0; j < 8; ++j) outv[j] = (short)bf16bits(g[j] * rs * wv[j]);
    *(short8*)(zrow + DINNER + c0) = outv;
}

// ---------------------------------------------------------------------------
extern "C" void kernel_launch(void* const* d_in, const int* in_sizes, int n_in,
                              void* d_out, int out_size, void* d_ws, size_t ws_size,
                              hipStream_t stream)
{
    (void)in_sizes; (void)n_in; (void)out_size; (void)ws_size;
    const float* x        = (const float*)d_in[0];
    const float* f_in_w   = (const float*)d_in[1];
    const float* f_conv_w = (const float*)d_in[2];
    const float* f_conv_b = (const float*)d_in[3];
    const float* f_dtbias = (const float*)d_in[4];
    const float* f_Alog   = (const float*)d_in[5];
    const float* f_D      = (const float*)d_in[6];
    const float* f_nw     = (const float*)d_in[7];
    const float* f_out_w  = (const float*)d_in[8];
    const float* b_in_w   = (const float*)d_in[9];
    const float* b_conv_w = (const float*)d_in[10];
    const float* b_conv_b = (const float*)d_in[11];
    const float* b_dtbias = (const float*)d_in[12];
    const float* b_Alog   = (const float*)d_in[13];
    const float* b_D      = (const float*)d_in[14];
    const float* b_nw     = (const float*)d_in[15];
    const float* b_out_w  = (const float*)d_in[16];

    // Workspace (~233 MB): zx bf16 73.4 | xs 33.6 | Bbf 2.1 | Cbf 2.1
    //   | dtb 1.05 | dta 1.05 | stateC 33.6 | betac 1.05 | yf f32 67.1
    //   | x_bf 4.2 | w_in 9.2 | w_out 4.2
    u16* zx  = (u16*)d_ws;
    u16* xs  = zx + (size_t)2 * M_ROWS * DPROJP;
    u16* Bbf = xs + (size_t)2 * M_ROWS * DINNER;
    u16* Cbf = Bbf + (size_t)2 * M_ROWS * NST;
    float* dtb = (float*)(Cbf + (size_t)2 * M_ROWS * NST);
    float* dta = dtb + (size_t)2 * M_ROWS * NH;
    u16* stateC = (u16*)(dta + (size_t)2 * M_ROWS * NH);
    float* betac = (float*)(stateC + (size_t)128 * NCH * 8192);
    float* yf = betac + (size_t)128 * L_SEQ;
    u16* x_bf   = (u16*)(yf + (size_t)2 * M_ROWS * DINNER);
    u16* w_in_bf  = x_bf + (size_t)M_ROWS * 512;
    u16* w_out_bf = w_in_bf + (size_t)2 * DPROJP * 512;

    // 0) dtype conversions
    cvt_x_kernel<<<dim3(M_ROWS * 512 / 1024), 256, 0, stream>>>(x, x_bf);
    cvt_win_kernel<<<dim3(DPROJP * 512 / 1024, 2), 256, 0, stream>>>(f_in_w, b_in_w, w_in_bf);
    cvt_wout_kernel<<<dim3(512 * DINNER / 1024, 2), 256, 0, stream>>>(f_out_w, b_out_w, w_out_bf);

    // 1) in_proj (MFMA, bf16 out): zx[dir] = x @ in_w[dir]^T
    gemm_mfma<true><<<dim3(DPROJP / 128, M_ROWS / 128, 2), 256, 0, stream>>>(
        x_bf, x_bf, 512,
        w_in_bf, (long long)DPROJP * 512,
        nullptr, zx, (long long)M_ROWS * DPROJP, DPROJP,
        nullptr, 0, 512);

    // 2a) sliding-window conv + SiLU (bf16 in/out)
    conv_kernel<<<dim3(CONVDIM / 256, 32, 2), 256, 0, stream>>>(
        zx, f_conv_w, b_conv_w, f_conv_b, b_conv_b, xs, Bbf, Cbf);

    // 2b) exact-f32 dt / log-decay (LDS-staged GEMV)
    dt_kernel<<<dim3(M_ROWS / 64, 2), 512, 0, stream>>>(
        x, f_in_w, b_in_w, f_dtbias, b_dtbias, f_Alog, b_Alog, dtb, dta);

    // 3a) SSD chunk kernel (local Y + D-skip -> yf, chunk states, cumA)
    ssd_chunk_kernel<<<dim3(128 * NCH), 256, 0, stream>>>(
        xs, Bbf, Cbf, dtb, dta, f_D, b_D, yf, stateC, betac);

    // 3b) combine chunk states
    combine_kernel<<<dim3(128), 512, 0, stream>>>(stateC, betac);

    // 3c) inter-chunk correction (MFMA) on yf
    correct_kernel<<<dim3(128 * NCH), 256, 0, stream>>>(Cbf, betac, stateC, yf);

    // 4) gate + RMSNorm: bf16 result into zx cols [2048,4096)
    gatenorm_kernel<<<dim3(M_ROWS, 2), 256, 0, stream>>>(zx, yf, f_nw, b_nw);

    // 5) out_proj (MFMA, bf16 A from zx) + residual + concat
    gemm_mfma<false><<<dim3(512 / 128, M_ROWS / 128, 2), 256, 0, stream>>>(
        zx + DINNER, zx + (size_t)M_ROWS * DPROJP + DINNER, DPROJP,
        w_out_bf, (long long)512 * DINNER,
        (float*)d_out, nullptr, 512, 1024,
        x, 512, DINNER);
}

// Round 11
// 352.428 us; speedup vs baseline: 2.2707x; 1.0765x over previous
//
#include <hip/hip_runtime.h>
#include <hip/hip_bf16.h>
#include <math.h>

#define L_SEQ   2048
#define M_ROWS  4096            // B*L
#define DPROJ   4384
#define DPROJP  4480            // padded to 35*128 for MFMA GEMM
#define DINNER  2048
#define CONVDIM 2304
#define NST     128
#define NH      32
#define CHUNK   128             // SSD chunk length
#define NCH     16              // L_SEQ / CHUNK
#define CTR     128             // conv rows per tile

typedef __attribute__((ext_vector_type(8))) short short8;
typedef __attribute__((ext_vector_type(4))) float f32x4;
typedef unsigned short u16;

static __device__ __forceinline__ u16 bf16bits(float v) {
    __hip_bfloat16 t = __float2bfloat16(v);
    return *(u16*)&t;
}
static __device__ __forceinline__ float bits2f(u16 u) {
    return __uint_as_float((unsigned)u << 16);
}
// element index into a [rows][128] bf16 LDS buffer with 16B-slot XOR swizzle
static __device__ __forceinline__ int sidx(int row, int s) {
    return (row << 7) + ((((s >> 3) ^ (row & 7)) << 3) | (s & 7));
}
static __device__ __forceinline__ int sslot(int row, int ks) {  // ks = 16B slot 0..15
    return (row << 7) + ((ks ^ (row & 7)) << 3);
}

// ---------------------------------------------------------------------------
// f32 -> bf16 conversion pre-passes
// ---------------------------------------------------------------------------
__global__ __launch_bounds__(256) void cvt_x_kernel(
    const float* __restrict__ x, u16* __restrict__ xbf)
{
    const int i = (blockIdx.x * 256 + threadIdx.x) * 4;
    const float4 v = *(const float4*)(x + i);
    xbf[i + 0] = bf16bits(v.x);
    xbf[i + 1] = bf16bits(v.y);
    xbf[i + 2] = bf16bits(v.z);
    xbf[i + 3] = bf16bits(v.w);
}

__global__ __launch_bounds__(256) void cvt_win_kernel(
    const float* __restrict__ w0, const float* __restrict__ w1,
    u16* __restrict__ dst)
{
    const int dir = blockIdx.y;
    const float* __restrict__ w = dir ? w1 : w0;
    u16* __restrict__ d = dst + (size_t)dir * DPROJP * 512;
    const int i = (blockIdx.x * 256 + threadIdx.x) * 4;
    const int row = i >> 9;
    if (row < DPROJ) {
        const float4 v = *(const float4*)(w + i);
        d[i + 0] = bf16bits(v.x);
        d[i + 1] = bf16bits(v.y);
        d[i + 2] = bf16bits(v.z);
        d[i + 3] = bf16bits(v.w);
    } else {
        d[i + 0] = 0; d[i + 1] = 0; d[i + 2] = 0; d[i + 3] = 0;
    }
}

__global__ __launch_bounds__(256) void cvt_wout_kernel(
    const float* __restrict__ w0, const float* __restrict__ w1,
    u16* __restrict__ dst)
{
    const int dir = blockIdx.y;
    const float* __restrict__ w = dir ? w1 : w0;
    u16* __restrict__ d = dst + (size_t)dir * 512 * DINNER;
    const int i = (blockIdx.x * 256 + threadIdx.x) * 4;
    const float4 v = *(const float4*)(w + i);
    d[i + 0] = bf16bits(v.x);
    d[i + 1] = bf16bits(v.y);
    d[i + 2] = bf16bits(v.z);
    d[i + 3] = bf16bits(v.w);
}

// ---------------------------------------------------------------------------
// MFMA bf16 GEMM: C[M][N] = A[M][K] @ B[N][K]^T. A bf16 with arbitrary lda.
// OUTBF: write bf16 (no addsrc). else: f32 + optional addsrc epilogue.
// ---------------------------------------------------------------------------
template<bool OUTBF>
__global__ __launch_bounds__(256) void gemm_mfma(
    const u16* __restrict__ A0, const u16* __restrict__ A1, int lda,
    const u16* __restrict__ Bw, long long b_dir_off,
    float* __restrict__ Cf, u16* __restrict__ Cb, long long c_dir_off, int ldc,
    const float* __restrict__ addsrc, int add_ld,
    int K)
{
    const int dir = blockIdx.z;
    const int m0 = blockIdx.y * 128;
    const int n0 = blockIdx.x * 128;
    const u16* __restrict__ A = dir ? A1 : A0;
    const u16* __restrict__ B = Bw + (size_t)dir * b_dir_off;

    __shared__ u16 Asl[128 * 64];
    __shared__ u16 Bsl[128 * 64];

    const int tid  = threadIdx.x;
    const int lane = tid & 63;
    const int wid  = tid >> 6;
    const int wr   = (wid >> 1) << 6;
    const int wc   = (wid & 1) << 6;
    const int l15  = lane & 15;
    const int l4   = lane >> 4;

    f32x4 acc[4][4];
#pragma unroll
    for (int m = 0; m < 4; ++m)
#pragma unroll
        for (int n = 0; n < 4; ++n) acc[m][n] = (f32x4)0.f;

    for (int k0 = 0; k0 < K; k0 += 64) {
        __syncthreads();
#pragma unroll
        for (int i = 0; i < 4; ++i) {
            const int c    = tid + (i << 8);
            const int row  = c >> 3;
            const int slot = c & 7;
            const int dst  = (row << 7) + ((slot ^ (row & 7)) << 4);
            *(short8*)((char*)Asl + dst) =
                *(const short8*)(A + (size_t)(m0 + row) * lda + k0 + (slot << 3));
            *(short8*)((char*)Bsl + dst) =
                *(const short8*)(B + (size_t)(n0 + row) * K + k0 + (slot << 3));
        }
        __syncthreads();

#pragma unroll
        for (int kh = 0; kh < 2; ++kh) {
            const int ks = (kh << 2) + l4;
            short8 a[4], b[4];
#pragma unroll
            for (int m = 0; m < 4; ++m) {
                const int R = wr + (m << 4) + l15;
                a[m] = *(const short8*)((const char*)Asl + (R << 7) + ((ks ^ (R & 7)) << 4));
            }
#pragma unroll
            for (int n = 0; n < 4; ++n) {
                const int R = wc + (n << 4) + l15;
                b[n] = *(const short8*)((const char*)Bsl + (R << 7) + ((ks ^ (R & 7)) << 4));
            }
#pragma unroll
            for (int m = 0; m < 4; ++m)
#pragma unroll
                for (int n = 0; n < 4; ++n)
                    acc[m][n] = __builtin_amdgcn_mfma_f32_16x16x32_bf16(
                        a[m], b[n], acc[m][n], 0, 0, 0);
        }
    }

#pragma unroll
    for (int m = 0; m < 4; ++m) {
        const int row0 = m0 + wr + (m << 4) + (l4 << 2);
#pragma unroll
        for (int n = 0; n < 4; ++n) {
            const int col = n0 + wc + (n << 4) + l15;
#pragma unroll
            for (int r = 0; r < 4; ++r) {
                if (OUTBF) {
                    Cb[(size_t)dir * c_dir_off + (size_t)(row0 + r) * ldc + col] =
                        bf16bits(acc[m][n][r]);
                } else {
                    float v = acc[m][n][r];
                    if (addsrc) v += addsrc[(size_t)(row0 + r) * add_ld + col];
                    Cf[(size_t)dir * c_dir_off + (size_t)(row0 + r) * ldc + col] = v;
                }
            }
        }
    }
}

// ---------------------------------------------------------------------------
// Sliding-window depthwise conv(4) + SiLU over bf16 zx columns.
// ---------------------------------------------------------------------------
__global__ __launch_bounds__(256) void conv_kernel(
    const u16* __restrict__ zx,
    const float* __restrict__ cw0, const float* __restrict__ cw1,
    const float* __restrict__ cb0, const float* __restrict__ cb1,
    u16* __restrict__ xs, u16* __restrict__ Bbf, u16* __restrict__ Cbf)
{
    const int dir = blockIdx.z;
    const int c   = blockIdx.x * 256 + threadIdx.x;     // channel 0..2303
    const int b   = blockIdx.y >> 4;
    const int r0  = (blockIdx.y & 15) * CTR;

    const float* __restrict__ cw = dir ? cw1 : cw0;
    const float w0 = cw[c * 4 + 0], w1 = cw[c * 4 + 1];
    const float w2 = cw[c * 4 + 2], w3 = cw[c * 4 + 3];
    const float bias = (dir ? cb1 : cb0)[c];

    const u16* __restrict__ zcol = zx + (size_t)dir * M_ROWS * DPROJP
        + (size_t)(b * L_SEQ) * DPROJP + DINNER + c;
    const size_t obase = (size_t)(dir * M_ROWS + b * L_SEQ);

    auto emit = [&](int l, float acc) {
        const float s = acc / (1.f + expf(-acc));
        const size_t orow = obase + l;
        if (c < DINNER)            xs[orow * DINNER + c] = bf16bits(s);
        else if (c < DINNER + NST) Bbf[orow * NST + (c - DINNER)] = bf16bits(s);
        else                       Cbf[orow * NST + (c - DINNER - NST)] = bf16bits(s);
    };

    if (dir == 0) {
        float h0 = (r0 - 3 >= 0) ? bits2f(zcol[(size_t)(r0 - 3) * DPROJP]) : 0.f;
        float h1 = (r0 - 2 >= 0) ? bits2f(zcol[(size_t)(r0 - 2) * DPROJP]) : 0.f;
        float h2 = (r0 - 1 >= 0) ? bits2f(zcol[(size_t)(r0 - 1) * DPROJP]) : 0.f;
#pragma unroll 4
        for (int l = r0; l < r0 + CTR; ++l) {
            const float zl = bits2f(zcol[(size_t)l * DPROJP]);
            float acc = bias;
            acc = fmaf(w0, h0, acc);
            acc = fmaf(w1, h1, acc);
            acc = fmaf(w2, h2, acc);
            acc = fmaf(w3, zl, acc);
            emit(l, acc);
            h0 = h1; h1 = h2; h2 = zl;
        }
    } else {
        const int le = r0 + CTR - 1;
        float h1 = (le + 1 < L_SEQ) ? bits2f(zcol[(size_t)(le + 1) * DPROJP]) : 0.f;
        float h2 = (le + 2 < L_SEQ) ? bits2f(zcol[(size_t)(le + 2) * DPROJP]) : 0.f;
        float h3 = (le + 3 < L_SEQ) ? bits2f(zcol[(size_t)(le + 3) * DPROJP]) : 0.f;
#pragma unroll 4
        for (int l = le; l >= r0; --l) {
            const float zl = bits2f(zcol[(size_t)l * DPROJP]);
            float acc = bias;
            acc = fmaf(w3, zl, acc);
            acc = fmaf(w2, h1, acc);
            acc = fmaf(w1, h2, acc);
            acc = fmaf(w0, h3, acc);
            emit(l, acc);
            h3 = h2; h2 = h1; h1 = zl;
        }
    }
}

// ---------------------------------------------------------------------------
// Exact-f32 dt as LDS-staged block GEMV.
// ---------------------------------------------------------------------------
__global__ __launch_bounds__(512) void dt_kernel(
    const float* __restrict__ x,
    const float* __restrict__ inw0, const float* __restrict__ inw1,
    const float* __restrict__ dtbias0, const float* __restrict__ dtbias1,
    const float* __restrict__ Alog0, const float* __restrict__ Alog1,
    float* __restrict__ dtb, float* __restrict__ dta)
{
    const int dir = blockIdx.y;
    const int r0  = blockIdx.x * 64;
    const int tid = threadIdx.x;

    __shared__ float wT[512 * 32];   // [k4][h][j], 64 KB
    __shared__ float sbias[NH], sa[NH];

    const float* __restrict__ w = (dir ? inw1 : inw0) + (size_t)(DINNER + CONVDIM) * 512;
    for (int i = tid; i < 4096; i += 512) {
        const int flat = i * 4;
        const int h = flat >> 9;
        const int k = flat & 511;
        const float4 v = *(const float4*)(w + flat);
        *(float4*)&wT[(k >> 2) * 128 + h * 4] = v;
    }
    if (tid < NH) {
        sbias[tid] = (dir ? dtbias1 : dtbias0)[tid];
        sa[tid] = -expf((dir ? Alog1 : Alog0)[tid]);
    }
    __syncthreads();

    const int h  = tid & 31;
    const int rr = tid >> 5;
    const float bias = sbias[h];
    const float a = sa[h];

    for (int rp = 0; rp < 64; rp += 16) {
        const int row = r0 + rp + rr;
        const float4* __restrict__ xr = (const float4*)(x + (size_t)row * 512);
        float4 s4 = make_float4(0.f, 0.f, 0.f, 0.f);
#pragma unroll 8
        for (int k4 = 0; k4 < 128; ++k4) {
            const float4 xv = xr[k4];
            const float4 wv = *(const float4*)&wT[k4 * 128 + h * 4];
            s4.x = fmaf(xv.x, wv.x, s4.x);
            s4.y = fmaf(xv.y, wv.y, s4.y);
            s4.z = fmaf(xv.z, wv.z, s4.z);
            s4.w = fmaf(xv.w, wv.w, s4.w);
        }
        const float v = (s4.x + s4.y) + (s4.z + s4.w) + bias;
        const float sp = (v > 20.f) ? v : log1pf(expf(v));
        const size_t orow = (size_t)(dir * M_ROWS + row);
        dtb[orow * NH + h] = sp;
        dta[orow * NH + h] = sp * a;         // log-decay
    }
}

// ---------------------------------------------------------------------------
// S_raw = C @ B^T per (dir,b,chunk) — head-independent (ngroups=1), computed
// ONCE instead of 32x. 64 blocks, bf16 out [db][ch][t][s].
// ---------------------------------------------------------------------------
__global__ __launch_bounds__(256) void sraw_kernel(
    const u16* __restrict__ Bbf, const u16* __restrict__ Cbf,
    u16* __restrict__ Sraw)
{
    const int bx  = blockIdx.x;            // db*NCH + ch
    const int ch  = bx & (NCH - 1);
    const int db  = bx >> 4;               // dir*2+b
    const int dir = db >> 1, bb = db & 1;
    const int tid = threadIdx.x;
    const int wid = tid >> 6;
    const int lane = tid & 63;
    const int l15 = lane & 15, l4 = lane >> 4;
    const int t0  = ch * CHUNK;
    const size_t dbase = (size_t)(dir * M_ROWS + bb * L_SEQ);
    const size_t base  = ((size_t)bx) << 14;     // *128*128

    auto lidx = [&](int t) { return dir ? (L_SEQ - 1 - t) : t; };

    f32x4 accs[2][8];
#pragma unroll
    for (int m = 0; m < 2; ++m)
#pragma unroll
        for (int j = 0; j < 8; ++j) accs[m][j] = (f32x4)0.f;

    short8 af[2][4];
#pragma unroll
    for (int m = 0; m < 2; ++m) {
        const size_t crow = dbase + lidx(t0 + wid * 32 + m * 16 + l15);
#pragma unroll
        for (int kk = 0; kk < 4; ++kk)
            af[m][kk] = *(const short8*)(Cbf + crow * NST + kk * 32 + l4 * 8);
    }
#pragma unroll
    for (int j = 0; j < 8; ++j) {
        const size_t brow = dbase + lidx(t0 + j * 16 + l15);
        short8 bf_[4];
#pragma unroll
        for (int kk = 0; kk < 4; ++kk)
            bf_[kk] = *(const short8*)(Bbf + brow * NST + kk * 32 + l4 * 8);
#pragma unroll
        for (int m = 0; m < 2; ++m)
#pragma unroll
            for (int kk = 0; kk < 4; ++kk)
                accs[m][j] = __builtin_amdgcn_mfma_f32_16x16x32_bf16(
                    af[m][kk], bf_[kk], accs[m][j], 0, 0, 0);
    }

#pragma unroll
    for (int m = 0; m < 2; ++m)
#pragma unroll
        for (int j = 0; j < 8; ++j)
#pragma unroll
            for (int r = 0; r < 4; ++r) {
                const int t = wid * 32 + m * 16 + l4 * 4 + r;
                const int s = j * 16 + l15;
                Sraw[base + (size_t)t * 128 + s] = bf16bits(accs[m][j][r]);
            }
}

// ---------------------------------------------------------------------------
// SSD state pass: cumA prefix (-> betac) + chunk state = X~T @ (r∘B)^T.
// Block = (bh, chunk). 2 barriers.
// ---------------------------------------------------------------------------
__global__ __launch_bounds__(256) void ssd_state_kernel(
    const u16* __restrict__ xs, const u16* __restrict__ Bbf,
    const float* __restrict__ dtb, const float* __restrict__ dta,
    u16* __restrict__ stateC, float* __restrict__ betac)
{
    const int bx  = blockIdx.x;
    const int ch  = bx & (NCH - 1);
    const int bh  = bx >> 4;
    const int dir = bh >> 6;
    const int bb  = (bh >> 5) & 1;
    const int h   = bh & 31;
    const int tid = threadIdx.x;
    const int wid = tid >> 6;
    const int lane = tid & 63;
    const int l15 = lane & 15;
    const int l4  = lane >> 4;
    const int t0  = ch * CHUNK;
    const size_t dbase = (size_t)(dir * M_ROWS + bb * L_SEQ);

    __shared__ u16 XT[64 * 128];
    __shared__ u16 WBT[128 * 128];
    __shared__ float scum[CHUNK];
    __shared__ float sdt[CHUNK];

    auto lidx = [&](int t) { return dir ? (L_SEQ - 1 - t) : t; };

    // phase A: dt loads + cumA prefix-sum (wave 0)
    if (tid >= 128) {
        const int s = tid - 128;
        sdt[s] = dtb[(dbase + lidx(t0 + s)) * NH + h];
    }
    if (wid == 0) {
        float a0 = dta[(dbase + lidx(t0 + lane)) * NH + h];
        float a1 = dta[(dbase + lidx(t0 + 64 + lane)) * NH + h];
#pragma unroll
        for (int off = 1; off < 64; off <<= 1) {
            const float u0 = __shfl_up(a0, off);
            const float u1 = __shfl_up(a1, off);
            if (lane >= off) { a0 += u0; a1 += u1; }
        }
        a1 += __shfl(a0, 63);
        scum[lane] = a0; scum[64 + lane] = a1;
        betac[(size_t)bh * L_SEQ + t0 + lane] = a0;
        betac[(size_t)bh * L_SEQ + t0 + 64 + lane] = a1;
    }
    __syncthreads();

    // phase B: build X~T and WBT
    {
        const int s = tid >> 1;
        const float dts = sdt[s];
        const float rs = expf(scum[CHUNK - 1] - scum[s]);
        const size_t grow = dbase + lidx(t0 + s);
        const int p0 = (tid & 1) * 32;
        const u16* __restrict__ xp = xs + grow * DINNER + h * 64 + p0;
#pragma unroll
        for (int q = 0; q < 4; ++q) {
            short8 v = *(const short8*)(xp + q * 8);
#pragma unroll
            for (int j = 0; j < 8; ++j) {
                const int p = p0 + q * 8 + j;
                XT[sidx(p, s)] = bf16bits(dts * bits2f((u16)v[j]));
            }
        }
        const int n0 = (tid & 1) * 64;
        const u16* __restrict__ bp = Bbf + grow * NST + n0;
#pragma unroll
        for (int q = 0; q < 8; ++q) {
            short8 v = *(const short8*)(bp + q * 8);
#pragma unroll
            for (int j = 0; j < 8; ++j) {
                const int n = n0 + q * 8 + j;
                WBT[sidx(n, s)] = bf16bits(rs * bits2f((u16)v[j]));
            }
        }
    }
    __syncthreads();

    // phase C: STATE GEMM c[p][n] -> stateC
    {
        const int pw = wid * 16;
        const int prow = pw + l15;
        short8 xa[4];
#pragma unroll
        for (int kk = 0; kk < 4; ++kk)
            xa[kk] = *(const short8*)(XT + sslot(prow, kk * 4 + l4));
        const size_t sbase = ((size_t)bh * NCH + ch) * 8192;
#pragma unroll
        for (int jn = 0; jn < 8; ++jn) {
            const int nrow = jn * 16 + l15;
            f32x4 acc = (f32x4)0.f;
#pragma unroll
            for (int kk = 0; kk < 4; ++kk) {
                const short8 wb = *(const short8*)(WBT + sslot(nrow, kk * 4 + l4));
                acc = __builtin_amdgcn_mfma_f32_16x16x32_bf16(xa[kk], wb, acc, 0, 0, 0);
            }
#pragma unroll
            for (int r = 0; r < 4; ++r)
                stateC[sbase + (size_t)(pw + l4 * 4 + r) * 128 + jn * 16 + l15] =
                    bf16bits(acc[r]);
        }
    }
}

// ---------------------------------------------------------------------------
// Combine: sequential over NCH chunks per bh (in place on stateC).
// ---------------------------------------------------------------------------
__global__ __launch_bounds__(512) void combine_kernel(
    u16* __restrict__ stateC, const float* __restrict__ betac)
{
    const int bh  = blockIdx.x;
    const int tid = threadIdx.x;

    float hrun[16];
#pragma unroll
    for (int j = 0; j < 16; ++j) hrun[j] = 0.f;

    for (int s = 0; s < NCH; ++s) {
        const size_t off = ((size_t)bh * NCH + s) * 8192 + (size_t)tid * 16;
        float c[16];
#pragma unroll
        for (int j = 0; j < 16; ++j) c[j] = bits2f(stateC[off + j]);
#pragma unroll
        for (int j = 0; j < 16; ++j) stateC[off + j] = bf16bits(hrun[j]);
        const float alpha = expf(betac[(size_t)bh * L_SEQ + s * CHUNK + (CHUNK - 1)]);
#pragma unroll
        for (int j = 0; j < 16; ++j) hrun[j] = fmaf(alpha, hrun[j], c[j]);
    }
}

// ---------------------------------------------------------------------------
// SSD output pass: P~ = Γ∘S_raw (from global, L2-hot); X~ staged;
// Y = P~@X~^T + (exp(cumA)∘C)@h_in^T + D*x  -> yf (written once; correction
// fused into the same MFMA accumulator). 2 barriers.
// ---------------------------------------------------------------------------
__global__ __launch_bounds__(256) void ssd_out_kernel(
    const u16* __restrict__ xs, const u16* __restrict__ Cbf,
    const u16* __restrict__ Sraw, const u16* __restrict__ stateC,
    const float* __restrict__ dtb, const float* __restrict__ betac,
    const float* __restrict__ D0, const float* __restrict__ D1,
    float* __restrict__ yf)
{
    const int bx  = blockIdx.x;
    const int ch  = bx & (NCH - 1);
    const int bh  = bx >> 4;
    const int dir = bh >> 6;
    const int bb  = (bh >> 5) & 1;
    const int h   = bh & 31;
    const int tid = threadIdx.x;
    const int wid = tid >> 6;
    const int lane = tid & 63;
    const int l15 = lane & 15;
    const int l4  = lane >> 4;
    const int t0  = ch * CHUNK;
    const size_t dbase = (size_t)(dir * M_ROWS + bb * L_SEQ);
    const float Dv = (dir ? D1 : D0)[h];

    __shared__ u16 XT[64 * 128];
    __shared__ u16 PT[128 * 128];
    __shared__ float scum[CHUNK];
    __shared__ float sdt[CHUNK];

    auto lidx = [&](int t) { return dir ? (L_SEQ - 1 - t) : t; };

    // phase A: reload cumA (betac) + dt
    if (tid < 128) {
        scum[tid] = betac[(size_t)bh * L_SEQ + t0 + tid];
    } else {
        const int s = tid - 128;
        sdt[s] = dtb[(dbase + lidx(t0 + s)) * NH + h];
    }
    __syncthreads();

    // phase B: build X~T and P~ (Γ-scaled S_raw)
    {
        const int s = tid >> 1;
        const float dts = sdt[s];
        const size_t grow = dbase + lidx(t0 + s);
        const int p0 = (tid & 1) * 32;
        const u16* __restrict__ xp = xs + grow * DINNER + h * 64 + p0;
#pragma unroll
        for (int q = 0; q < 4; ++q) {
            short8 v = *(const short8*)(xp + q * 8);
#pragma unroll
            for (int j = 0; j < 8; ++j) {
                const int p = p0 + q * 8 + j;
                XT[sidx(p, s)] = bf16bits(dts * bits2f((u16)v[j]));
            }
        }
    }
    {
        const size_t sbraw = ((size_t)(((bh >> 5) * NCH) + ch)) << 14;
#pragma unroll
        for (int i = 0; i < 8; ++i) {
            const int flat = tid + (i << 8);       // 0..2047
            const int t  = flat >> 4;
            const int sl = flat & 15;
            const short8 v = *(const short8*)(Sraw + sbraw + (size_t)t * 128 + sl * 8);
            const float ct = scum[t];
            short8 o;
#pragma unroll
            for (int j = 0; j < 8; ++j) {
                const int s2 = sl * 8 + j;
                const float g = (s2 <= t) ? expf(ct - scum[s2]) : 0.f;
                o[j] = (short)bf16bits(bits2f((u16)v[j]) * g);
            }
            *(short8*)(PT + (t << 7) + ((sl ^ (t & 7)) << 3)) = o;
        }
    }
    __syncthreads();

    // phase C: Y = P~@X~^T + G@h_in^T + D*x
    {
        float* __restrict__ ybase = yf + (size_t)dir * M_ROWS * DINNER;
        const size_t sbase = ((size_t)bh * NCH + ch) * 8192;

        short8 pa[2][4], ga[2][4];
#pragma unroll
        for (int m = 0; m < 2; ++m) {
            const int trow = wid * 32 + m * 16 + l15;
#pragma unroll
            for (int kk = 0; kk < 4; ++kk)
                pa[m][kk] = *(const short8*)(PT + sslot(trow, kk * 4 + l4));
            const float gs = expf(scum[trow]);
            const size_t crow = dbase + lidx(t0 + trow);
#pragma unroll
            for (int kk = 0; kk < 4; ++kk) {
                const short8 c8 = *(const short8*)(Cbf + crow * NST + kk * 32 + l4 * 8);
                short8 o;
#pragma unroll
                for (int j = 0; j < 8; ++j)
                    o[j] = (short)bf16bits(bits2f((u16)c8[j]) * gs);
                ga[m][kk] = o;
            }
        }

#pragma unroll
        for (int jp = 0; jp < 4; ++jp) {
            const int prow = jp * 16 + l15;
            short8 xb[4], hb[4];
#pragma unroll
            for (int kk = 0; kk < 4; ++kk) {
                xb[kk] = *(const short8*)(XT + sslot(prow, kk * 4 + l4));
                hb[kk] = *(const short8*)(stateC + sbase + (size_t)prow * 128 + kk * 32 + l4 * 8);
            }
#pragma unroll
            for (int m = 0; m < 2; ++m) {
                f32x4 acc = (f32x4)0.f;
#pragma unroll
                for (int kk = 0; kk < 4; ++kk)
                    acc = __builtin_amdgcn_mfma_f32_16x16x32_bf16(
                        pa[m][kk], xb[kk], acc, 0, 0, 0);
#pragma unroll
                for (int kk = 0; kk < 4; ++kk)
                    acc = __builtin_amdgcn_mfma_f32_16x16x32_bf16(
                        ga[m][kk], hb[kk], acc, 0, 0, 0);
                const int p = prow;
#pragma unroll
                for (int r = 0; r < 4; ++r) {
                    const int t = wid * 32 + m * 16 + l4 * 4 + r;
                    const int lg = lidx(t0 + t);
                    const float xv = bits2f(xs[(dbase + lg) * DINNER + h * 64 + p]);
                    ybase[(size_t)(bb * L_SEQ + lg) * DINNER + h * 64 + p] =
                        acc[r] + Dv * xv;
                }
            }
        }
    }
}

// ---------------------------------------------------------------------------
// gate + RMSNorm: reads bf16 z (zx cols [0,2048)) + f32 y (compact), writes
// bf16 gated/normalized y into zx cols [2048,4096) (dead xBC slice).
// ---------------------------------------------------------------------------
__global__ __launch_bounds__(256) void gatenorm_kernel(
    u16* __restrict__ zx, const float* __restrict__ yf,
    const float* __restrict__ nw0, const float* __restrict__ nw1)
{
    const int dir = blockIdx.y;
    const int row = blockIdx.x;
    const float* __restrict__ nw = dir ? nw1 : nw0;
    u16* __restrict__ zrow = zx + (size_t)dir * M_ROWS * DPROJP + (size_t)row * DPROJP;
    const float* __restrict__ yrow = yf + (size_t)dir * M_ROWS * DINNER + (size_t)row * DINNER;
    const int tid = threadIdx.x;
    const int c0 = tid * 8;

    const short8 zv = *(const short8*)(zrow + c0);
    const float4 y0 = *(const float4*)(yrow + c0);
    const float4 y1 = *(const float4*)(yrow + c0 + 4);

    float g[8];
    {
        const float yv[8] = {y0.x, y0.y, y0.z, y0.w, y1.x, y1.y, y1.z, y1.w};
#pragma unroll
        for (int j = 0; j < 8; ++j) {
            const float z = bits2f((u16)zv[j]);
            g[j] = yv[j] * (z / (1.f + expf(-z)));
        }
    }

    float ss = 0.f;
#pragma unroll
    for (int j = 0; j < 8; ++j) ss = fmaf(g[j], g[j], ss);
#pragma unroll
    for (int off = 1; off < 64; off <<= 1) ss += __shfl_xor(ss, off);
    __shared__ float red[4];
    if ((tid & 63) == 0) red[tid >> 6] = ss;
    __syncthreads();
    const float total = red[0] + red[1] + red[2] + red[3];
    const float rs = rsqrtf(total * (1.f / (float)DINNER) + 1e-5f);

    const float4 w0 = *(const float4*)(nw + c0);
    const float4 w1 = *(const float4*)(nw + c0 + 4);
    const float wv[8] = {w0.x, w0.y, w0.z, w0.w, w1.x, w1.y, w1.z, w1.w};
    short8 outv;
#pragma unroll
    for (int j = 0; j < 8; ++j) outv[j] = (short)bf16bits(g[j] * rs * wv[j]);
    *(short8*)(zrow + DINNER + c0) = outv;
}

// ---------------------------------------------------------------------------
extern "C" void kernel_launch(void* const* d_in, const int* in_sizes, int n_in,
                              void* d_out, int out_size, void* d_ws, size_t ws_size,
                              hipStream_t stream)
{
    (void)in_sizes; (void)n_in; (void)out_size; (void)ws_size;
    const float* x        = (const float*)d_in[0];
    const float* f_in_w   = (const float*)d_in[1];
    const float* f_conv_w = (const float*)d_in[2];
    const float* f_conv_b = (const float*)d_in[3];
    const float* f_dtbias = (const float*)d_in[4];
    const float* f_Alog   = (const float*)d_in[5];
    const float* f_D      = (const float*)d_in[6];
    const float* f_nw     = (const float*)d_in[7];
    const float* f_out_w  = (const float*)d_in[8];
    const float* b_in_w   = (const float*)d_in[9];
    const float* b_conv_w = (const float*)d_in[10];
    const float* b_conv_b = (const float*)d_in[11];
    const float* b_dtbias = (const float*)d_in[12];
    const float* b_Alog   = (const float*)d_in[13];
    const float* b_D      = (const float*)d_in[14];
    const float* b_nw     = (const float*)d_in[15];
    const float* b_out_w  = (const float*)d_in[16];

    // Workspace (~235 MB): zx bf16 73.4 | xs 33.6 | Bbf 2.1 | Cbf 2.1
    //   | dtb 1.05 | dta 1.05 | stateC 33.6 | betac 1.05 | yf f32 67.1
    //   | x_bf 4.2 | w_in 9.2 | w_out 4.2 | Sraw 2.1
    u16* zx  = (u16*)d_ws;
    u16* xs  = zx + (size_t)2 * M_ROWS * DPROJP;
    u16* Bbf = xs + (size_t)2 * M_ROWS * DINNER;
    u16* Cbf = Bbf + (size_t)2 * M_ROWS * NST;
    float* dtb = (float*)(Cbf + (size_t)2 * M_ROWS * NST);
    float* dta = dtb + (size_t)2 * M_ROWS * NH;
    u16* stateC = (u16*)(dta + (size_t)2 * M_ROWS * NH);
    float* betac = (float*)(stateC + (size_t)128 * NCH * 8192);
    float* yf = betac + (size_t)128 * L_SEQ;
    u16* x_bf   = (u16*)(yf + (size_t)2 * M_ROWS * DINNER);
    u16* w_in_bf  = x_bf + (size_t)M_ROWS * 512;
    u16* w_out_bf = w_in_bf + (size_t)2 * DPROJP * 512;
    u16* Sraw = w_out_bf + (size_t)2 * 512 * DINNER;

    // 0) dtype conversions
    cvt_x_kernel<<<dim3(M_ROWS * 512 / 1024), 256, 0, stream>>>(x, x_bf);
    cvt_win_kernel<<<dim3(DPROJP * 512 / 1024, 2), 256, 0, stream>>>(f_in_w, b_in_w, w_in_bf);
    cvt_wout_kernel<<<dim3(512 * DINNER / 1024, 2), 256, 0, stream>>>(f_out_w, b_out_w, w_out_bf);

    // 1) in_proj (MFMA, bf16 out): zx[dir] = x @ in_w[dir]^T
    gemm_mfma<true><<<dim3(DPROJP / 128, M_ROWS / 128, 2), 256, 0, stream>>>(
        x_bf, x_bf, 512,
        w_in_bf, (long long)DPROJP * 512,
        nullptr, zx, (long long)M_ROWS * DPROJP, DPROJP,
        nullptr, 0, 512);

    // 2a) sliding-window conv + SiLU (bf16 in/out)
    conv_kernel<<<dim3(CONVDIM / 256, 32, 2), 256, 0, stream>>>(
        zx, f_conv_w, b_conv_w, f_conv_b, b_conv_b, xs, Bbf, Cbf);

    // 2b) exact-f32 dt / log-decay (LDS-staged GEMV)
    dt_kernel<<<dim3(M_ROWS / 64, 2), 512, 0, stream>>>(
        x, f_in_w, b_in_w, f_dtbias, b_dtbias, f_Alog, b_Alog, dtb, dta);

    // 3a) head-independent S_raw = C @ B^T (once per dir,b,chunk)
    sraw_kernel<<<dim3(4 * NCH), 256, 0, stream>>>(Bbf, Cbf, Sraw);

    // 3b) state pass (cumA -> betac, chunk states -> stateC)
    ssd_state_kernel<<<dim3(128 * NCH), 256, 0, stream>>>(
        xs, Bbf, dtb, dta, stateC, betac);

    // 3c) combine chunk states (stateC becomes h_in per chunk)
    combine_kernel<<<dim3(128), 512, 0, stream>>>(stateC, betac);

    // 3d) output pass: local Y + fused correction + D-skip -> yf
    ssd_out_kernel<<<dim3(128 * NCH), 256, 0, stream>>>(
        xs, Cbf, Sraw, stateC, dtb, betac, f_D, b_D, yf);

    // 4) gate + RMSNorm: bf16 result into zx cols [2048,4096)
    gatenorm_kernel<<<dim3(M_ROWS, 2), 256, 0, stream>>>(zx, yf, f_nw, b_nw);

    // 5) out_proj (MFMA, bf16 A from zx) + residual + concat
    gemm_mfma<false><<<dim3(512 / 128, M_ROWS / 128, 2), 256, 0, stream>>>(
        zx + DINNER, zx + (size_t)M_ROWS * DPROJP + DINNER, DPROJP,
        w_out_bf, (long long)512 * DINNER,
        (float*)d_out, nullptr, 512, 1024,
        x, 512, DINNER);
}

// Round 12
// 336.475 us; speedup vs baseline: 2.3784x; 1.0474x over previous
//
#include <hip/hip_runtime.h>
#include <hip/hip_bf16.h>
#include <math.h>

#define L_SEQ   2048
#define M_ROWS  4096            // B*L
#define DPROJ   4384
#define DPROJP  4480            // padded to 35*128 for MFMA GEMM
#define DINNER  2048
#define CONVDIM 2304
#define NST     128
#define NH      32
#define CHUNK   128             // SSD chunk length
#define NCH     16              // L_SEQ / CHUNK
#define CTR     128             // conv rows per tile
#define LOG2E   1.4426950408889634f

typedef __attribute__((ext_vector_type(8))) short short8;
typedef __attribute__((ext_vector_type(4))) float f32x4;
typedef unsigned short u16;

static __device__ __forceinline__ u16 bf16bits(float v) {
    __hip_bfloat16 t = __float2bfloat16(v);
    return *(u16*)&t;
}
static __device__ __forceinline__ float bits2f(u16 u) {
    return __uint_as_float((unsigned)u << 16);
}
// element index into a [rows][128] bf16 LDS buffer with 16B-slot XOR swizzle
static __device__ __forceinline__ int sidx(int row, int s) {
    return (row << 7) + ((((s >> 3) ^ (row & 7)) << 3) | (s & 7));
}
static __device__ __forceinline__ int sslot(int row, int ks) {  // ks = 16B slot 0..15
    return (row << 7) + ((ks ^ (row & 7)) << 3);
}

// ---------------------------------------------------------------------------
// f32 -> bf16 conversion pre-passes
// ---------------------------------------------------------------------------
__global__ __launch_bounds__(256) void cvt_x_kernel(
    const float* __restrict__ x, u16* __restrict__ xbf)
{
    const int i = (blockIdx.x * 256 + threadIdx.x) * 4;
    const float4 v = *(const float4*)(x + i);
    xbf[i + 0] = bf16bits(v.x);
    xbf[i + 1] = bf16bits(v.y);
    xbf[i + 2] = bf16bits(v.z);
    xbf[i + 3] = bf16bits(v.w);
}

__global__ __launch_bounds__(256) void cvt_win_kernel(
    const float* __restrict__ w0, const float* __restrict__ w1,
    u16* __restrict__ dst)
{
    const int dir = blockIdx.y;
    const float* __restrict__ w = dir ? w1 : w0;
    u16* __restrict__ d = dst + (size_t)dir * DPROJP * 512;
    const int i = (blockIdx.x * 256 + threadIdx.x) * 4;
    const int row = i >> 9;
    if (row < DPROJ) {
        const float4 v = *(const float4*)(w + i);
        d[i + 0] = bf16bits(v.x);
        d[i + 1] = bf16bits(v.y);
        d[i + 2] = bf16bits(v.z);
        d[i + 3] = bf16bits(v.w);
    } else {
        d[i + 0] = 0; d[i + 1] = 0; d[i + 2] = 0; d[i + 3] = 0;
    }
}

__global__ __launch_bounds__(256) void cvt_wout_kernel(
    const float* __restrict__ w0, const float* __restrict__ w1,
    u16* __restrict__ dst)
{
    const int dir = blockIdx.y;
    const float* __restrict__ w = dir ? w1 : w0;
    u16* __restrict__ d = dst + (size_t)dir * 512 * DINNER;
    const int i = (blockIdx.x * 256 + threadIdx.x) * 4;
    const float4 v = *(const float4*)(w + i);
    d[i + 0] = bf16bits(v.x);
    d[i + 1] = bf16bits(v.y);
    d[i + 2] = bf16bits(v.z);
    d[i + 3] = bf16bits(v.w);
}

// ---------------------------------------------------------------------------
// MFMA bf16 GEMM: C[M][N] = A[M][K] @ B[N][K]^T. A bf16 with arbitrary lda.
// OUTBF: write bf16 (no addsrc). else: f32 + optional addsrc epilogue.
// ---------------------------------------------------------------------------
template<bool OUTBF>
__global__ __launch_bounds__(256) void gemm_mfma(
    const u16* __restrict__ A0, const u16* __restrict__ A1, int lda,
    const u16* __restrict__ Bw, long long b_dir_off,
    float* __restrict__ Cf, u16* __restrict__ Cb, long long c_dir_off, int ldc,
    const float* __restrict__ addsrc, int add_ld,
    int K)
{
    const int dir = blockIdx.z;
    const int m0 = blockIdx.y * 128;
    const int n0 = blockIdx.x * 128;
    const u16* __restrict__ A = dir ? A1 : A0;
    const u16* __restrict__ B = Bw + (size_t)dir * b_dir_off;

    __shared__ u16 Asl[128 * 64];
    __shared__ u16 Bsl[128 * 64];

    const int tid  = threadIdx.x;
    const int lane = tid & 63;
    const int wid  = tid >> 6;
    const int wr   = (wid >> 1) << 6;
    const int wc   = (wid & 1) << 6;
    const int l15  = lane & 15;
    const int l4   = lane >> 4;

    f32x4 acc[4][4];
#pragma unroll
    for (int m = 0; m < 4; ++m)
#pragma unroll
        for (int n = 0; n < 4; ++n) acc[m][n] = (f32x4)0.f;

    for (int k0 = 0; k0 < K; k0 += 64) {
        __syncthreads();
#pragma unroll
        for (int i = 0; i < 4; ++i) {
            const int c    = tid + (i << 8);
            const int row  = c >> 3;
            const int slot = c & 7;
            const int dst  = (row << 7) + ((slot ^ (row & 7)) << 4);
            *(short8*)((char*)Asl + dst) =
                *(const short8*)(A + (size_t)(m0 + row) * lda + k0 + (slot << 3));
            *(short8*)((char*)Bsl + dst) =
                *(const short8*)(B + (size_t)(n0 + row) * K + k0 + (slot << 3));
        }
        __syncthreads();

#pragma unroll
        for (int kh = 0; kh < 2; ++kh) {
            const int ks = (kh << 2) + l4;
            short8 a[4], b[4];
#pragma unroll
            for (int m = 0; m < 4; ++m) {
                const int R = wr + (m << 4) + l15;
                a[m] = *(const short8*)((const char*)Asl + (R << 7) + ((ks ^ (R & 7)) << 4));
            }
#pragma unroll
            for (int n = 0; n < 4; ++n) {
                const int R = wc + (n << 4) + l15;
                b[n] = *(const short8*)((const char*)Bsl + (R << 7) + ((ks ^ (R & 7)) << 4));
            }
#pragma unroll
            for (int m = 0; m < 4; ++m)
#pragma unroll
                for (int n = 0; n < 4; ++n)
                    acc[m][n] = __builtin_amdgcn_mfma_f32_16x16x32_bf16(
                        a[m], b[n], acc[m][n], 0, 0, 0);
        }
    }

#pragma unroll
    for (int m = 0; m < 4; ++m) {
        const int row0 = m0 + wr + (m << 4) + (l4 << 2);
#pragma unroll
        for (int n = 0; n < 4; ++n) {
            const int col = n0 + wc + (n << 4) + l15;
#pragma unroll
            for (int r = 0; r < 4; ++r) {
                if (OUTBF) {
                    Cb[(size_t)dir * c_dir_off + (size_t)(row0 + r) * ldc + col] =
                        bf16bits(acc[m][n][r]);
                } else {
                    float v = acc[m][n][r];
                    if (addsrc) v += addsrc[(size_t)(row0 + r) * add_ld + col];
                    Cf[(size_t)dir * c_dir_off + (size_t)(row0 + r) * ldc + col] = v;
                }
            }
        }
    }
}

// ---------------------------------------------------------------------------
// Sliding-window depthwise conv(4) + SiLU over bf16 zx columns.
// ---------------------------------------------------------------------------
__global__ __launch_bounds__(256) void conv_kernel(
    const u16* __restrict__ zx,
    const float* __restrict__ cw0, const float* __restrict__ cw1,
    const float* __restrict__ cb0, const float* __restrict__ cb1,
    u16* __restrict__ xs, u16* __restrict__ Bbf, u16* __restrict__ Cbf)
{
    const int dir = blockIdx.z;
    const int c   = blockIdx.x * 256 + threadIdx.x;     // channel 0..2303
    const int b   = blockIdx.y >> 4;
    const int r0  = (blockIdx.y & 15) * CTR;

    const float* __restrict__ cw = dir ? cw1 : cw0;
    const float w0 = cw[c * 4 + 0], w1 = cw[c * 4 + 1];
    const float w2 = cw[c * 4 + 2], w3 = cw[c * 4 + 3];
    const float bias = (dir ? cb1 : cb0)[c];

    const u16* __restrict__ zcol = zx + (size_t)dir * M_ROWS * DPROJP
        + (size_t)(b * L_SEQ) * DPROJP + DINNER + c;
    const size_t obase = (size_t)(dir * M_ROWS + b * L_SEQ);

    auto emit = [&](int l, float acc) {
        const float s = acc / (1.f + expf(-acc));
        const size_t orow = obase + l;
        if (c < DINNER)            xs[orow * DINNER + c] = bf16bits(s);
        else if (c < DINNER + NST) Bbf[orow * NST + (c - DINNER)] = bf16bits(s);
        else                       Cbf[orow * NST + (c - DINNER - NST)] = bf16bits(s);
    };

    if (dir == 0) {
        float h0 = (r0 - 3 >= 0) ? bits2f(zcol[(size_t)(r0 - 3) * DPROJP]) : 0.f;
        float h1 = (r0 - 2 >= 0) ? bits2f(zcol[(size_t)(r0 - 2) * DPROJP]) : 0.f;
        float h2 = (r0 - 1 >= 0) ? bits2f(zcol[(size_t)(r0 - 1) * DPROJP]) : 0.f;
#pragma unroll 4
        for (int l = r0; l < r0 + CTR; ++l) {
            const float zl = bits2f(zcol[(size_t)l * DPROJP]);
            float acc = bias;
            acc = fmaf(w0, h0, acc);
            acc = fmaf(w1, h1, acc);
            acc = fmaf(w2, h2, acc);
            acc = fmaf(w3, zl, acc);
            emit(l, acc);
            h0 = h1; h1 = h2; h2 = zl;
        }
    } else {
        const int le = r0 + CTR - 1;
        float h1 = (le + 1 < L_SEQ) ? bits2f(zcol[(size_t)(le + 1) * DPROJP]) : 0.f;
        float h2 = (le + 2 < L_SEQ) ? bits2f(zcol[(size_t)(le + 2) * DPROJP]) : 0.f;
        float h3 = (le + 3 < L_SEQ) ? bits2f(zcol[(size_t)(le + 3) * DPROJP]) : 0.f;
#pragma unroll 4
        for (int l = le; l >= r0; --l) {
            const float zl = bits2f(zcol[(size_t)l * DPROJP]);
            float acc = bias;
            acc = fmaf(w3, zl, acc);
            acc = fmaf(w2, h1, acc);
            acc = fmaf(w1, h2, acc);
            acc = fmaf(w0, h3, acc);
            emit(l, acc);
            h3 = h2; h2 = h1; h1 = zl;
        }
    }
}

// ---------------------------------------------------------------------------
// Exact-f32 dt as LDS-staged block GEMV. dta in BASE-2 log-decay.
// ---------------------------------------------------------------------------
__global__ __launch_bounds__(512) void dt_kernel(
    const float* __restrict__ x,
    const float* __restrict__ inw0, const float* __restrict__ inw1,
    const float* __restrict__ dtbias0, const float* __restrict__ dtbias1,
    const float* __restrict__ Alog0, const float* __restrict__ Alog1,
    float* __restrict__ dtb, float* __restrict__ dta)
{
    const int dir = blockIdx.y;
    const int r0  = blockIdx.x * 64;
    const int tid = threadIdx.x;

    __shared__ float wT[512 * 32];   // [k4][h][j], 64 KB
    __shared__ float sbias[NH], sa[NH];

    const float* __restrict__ w = (dir ? inw1 : inw0) + (size_t)(DINNER + CONVDIM) * 512;
    for (int i = tid; i < 4096; i += 512) {
        const int flat = i * 4;
        const int h = flat >> 9;
        const int k = flat & 511;
        const float4 v = *(const float4*)(w + flat);
        *(float4*)&wT[(k >> 2) * 128 + h * 4] = v;
    }
    if (tid < NH) {
        sbias[tid] = (dir ? dtbias1 : dtbias0)[tid];
        sa[tid] = -expf((dir ? Alog1 : Alog0)[tid]) * LOG2E;
    }
    __syncthreads();

    const int h  = tid & 31;
    const int rr = tid >> 5;
    const float bias = sbias[h];
    const float a = sa[h];

    for (int rp = 0; rp < 64; rp += 16) {
        const int row = r0 + rp + rr;
        const float4* __restrict__ xr = (const float4*)(x + (size_t)row * 512);
        float4 s4 = make_float4(0.f, 0.f, 0.f, 0.f);
#pragma unroll 8
        for (int k4 = 0; k4 < 128; ++k4) {
            const float4 xv = xr[k4];
            const float4 wv = *(const float4*)&wT[k4 * 128 + h * 4];
            s4.x = fmaf(xv.x, wv.x, s4.x);
            s4.y = fmaf(xv.y, wv.y, s4.y);
            s4.z = fmaf(xv.z, wv.z, s4.z);
            s4.w = fmaf(xv.w, wv.w, s4.w);
        }
        const float v = (s4.x + s4.y) + (s4.z + s4.w) + bias;
        const float sp = (v > 20.f) ? v : log1pf(expf(v));
        const size_t orow = (size_t)(dir * M_ROWS + row);
        dtb[orow * NH + h] = sp;
        dta[orow * NH + h] = sp * a;         // base-2 log-decay
    }
}

// ---------------------------------------------------------------------------
// S_raw = C @ B^T per (dir,b,chunk) — head-independent, computed once.
// ---------------------------------------------------------------------------
__global__ __launch_bounds__(256) void sraw_kernel(
    const u16* __restrict__ Bbf, const u16* __restrict__ Cbf,
    u16* __restrict__ Sraw)
{
    const int bx  = blockIdx.x;            // db*NCH + ch
    const int ch  = bx & (NCH - 1);
    const int db  = bx >> 4;               // dir*2+b
    const int dir = db >> 1, bb = db & 1;
    const int tid = threadIdx.x;
    const int wid = tid >> 6;
    const int lane = tid & 63;
    const int l15 = lane & 15, l4 = lane >> 4;
    const int t0  = ch * CHUNK;
    const size_t dbase = (size_t)(dir * M_ROWS + bb * L_SEQ);
    const size_t base  = ((size_t)bx) << 14;     // *128*128

    auto lidx = [&](int t) { return dir ? (L_SEQ - 1 - t) : t; };

    f32x4 accs[2][8];
#pragma unroll
    for (int m = 0; m < 2; ++m)
#pragma unroll
        for (int j = 0; j < 8; ++j) accs[m][j] = (f32x4)0.f;

    short8 af[2][4];
#pragma unroll
    for (int m = 0; m < 2; ++m) {
        const size_t crow = dbase + lidx(t0 + wid * 32 + m * 16 + l15);
#pragma unroll
        for (int kk = 0; kk < 4; ++kk)
            af[m][kk] = *(const short8*)(Cbf + crow * NST + kk * 32 + l4 * 8);
    }
#pragma unroll
    for (int j = 0; j < 8; ++j) {
        const size_t brow = dbase + lidx(t0 + j * 16 + l15);
        short8 bf_[4];
#pragma unroll
        for (int kk = 0; kk < 4; ++kk)
            bf_[kk] = *(const short8*)(Bbf + brow * NST + kk * 32 + l4 * 8);
#pragma unroll
        for (int m = 0; m < 2; ++m)
#pragma unroll
            for (int kk = 0; kk < 4; ++kk)
                accs[m][j] = __builtin_amdgcn_mfma_f32_16x16x32_bf16(
                    af[m][kk], bf_[kk], accs[m][j], 0, 0, 0);
    }

#pragma unroll
    for (int m = 0; m < 2; ++m)
#pragma unroll
        for (int j = 0; j < 8; ++j)
#pragma unroll
            for (int r = 0; r < 4; ++r) {
                const int t = wid * 32 + m * 16 + l4 * 4 + r;
                const int s = j * 16 + l15;
                Sraw[base + (size_t)t * 128 + s] = bf16bits(accs[m][j][r]);
            }
}

// ---------------------------------------------------------------------------
// SSD state pass: cumA prefix (-> betac) + chunk state = X~T @ (r∘B)^T.
// WBT halved (two-pass over n-halves): 33 KB LDS -> 4 blocks/CU.
// ---------------------------------------------------------------------------
__global__ __launch_bounds__(256) void ssd_state_kernel(
    const u16* __restrict__ xs, const u16* __restrict__ Bbf,
    const float* __restrict__ dtb, const float* __restrict__ dta,
    u16* __restrict__ stateC, float* __restrict__ betac)
{
    const int bx  = blockIdx.x;
    const int ch  = bx & (NCH - 1);
    const int bh  = bx >> 4;
    const int dir = bh >> 6;
    const int bb  = (bh >> 5) & 1;
    const int h   = bh & 31;
    const int tid = threadIdx.x;
    const int wid = tid >> 6;
    const int lane = tid & 63;
    const int l15 = lane & 15;
    const int l4  = lane >> 4;
    const int t0  = ch * CHUNK;
    const size_t dbase = (size_t)(dir * M_ROWS + bb * L_SEQ);

    __shared__ u16 XT[64 * 128];
    __shared__ u16 WBT[64 * 128];
    __shared__ float scum[CHUNK];
    __shared__ float sdt[CHUNK];

    auto lidx = [&](int t) { return dir ? (L_SEQ - 1 - t) : t; };

    // phase A: dt loads + base-2 cumA prefix-sum (wave 0)
    if (tid >= 128) {
        const int s = tid - 128;
        sdt[s] = dtb[(dbase + lidx(t0 + s)) * NH + h];
    }
    if (wid == 0) {
        float a0 = dta[(dbase + lidx(t0 + lane)) * NH + h];
        float a1 = dta[(dbase + lidx(t0 + 64 + lane)) * NH + h];
#pragma unroll
        for (int off = 1; off < 64; off <<= 1) {
            const float u0 = __shfl_up(a0, off);
            const float u1 = __shfl_up(a1, off);
            if (lane >= off) { a0 += u0; a1 += u1; }
        }
        a1 += __shfl(a0, 63);
        scum[lane] = a0; scum[64 + lane] = a1;
        betac[(size_t)bh * L_SEQ + t0 + lane] = a0;
        betac[(size_t)bh * L_SEQ + t0 + 64 + lane] = a1;
    }
    __syncthreads();

    // build X~T once
    {
        const int s = tid >> 1;
        const float dts = sdt[s];
        const size_t grow = dbase + lidx(t0 + s);
        const int p0 = (tid & 1) * 32;
        const u16* __restrict__ xp = xs + grow * DINNER + h * 64 + p0;
#pragma unroll
        for (int q = 0; q < 4; ++q) {
            short8 v = *(const short8*)(xp + q * 8);
#pragma unroll
            for (int j = 0; j < 8; ++j) {
                const int p = p0 + q * 8 + j;
                XT[sidx(p, s)] = bf16bits(dts * bits2f((u16)v[j]));
            }
        }
    }

    const size_t sbase = ((size_t)bh * NCH + ch) * 8192;

#pragma unroll
    for (int half = 0; half < 2; ++half) {
        const int noff = half * 64;
        // build WBT rows [noff, noff+64)
        {
            const int s = tid >> 1;
            const float rs = exp2f(scum[CHUNK - 1] - scum[s]);
            const size_t grow = dbase + lidx(t0 + s);
            const int n0l = (tid & 1) * 32;
            const u16* __restrict__ bp = Bbf + grow * NST + noff + n0l;
#pragma unroll
            for (int q = 0; q < 4; ++q) {
                short8 v = *(const short8*)(bp + q * 8);
#pragma unroll
                for (int j = 0; j < 8; ++j) {
                    const int nl = n0l + q * 8 + j;
                    WBT[sidx(nl, s)] = bf16bits(rs * bits2f((u16)v[j]));
                }
            }
        }
        __syncthreads();

        // STATE GEMM for this n-half
        {
            const int pw = wid * 16;
            const int prow = pw + l15;
            short8 xa[4];
#pragma unroll
            for (int kk = 0; kk < 4; ++kk)
                xa[kk] = *(const short8*)(XT + sslot(prow, kk * 4 + l4));
#pragma unroll
            for (int jn = 0; jn < 4; ++jn) {
                const int nl = jn * 16 + l15;
                f32x4 acc = (f32x4)0.f;
#pragma unroll
                for (int kk = 0; kk < 4; ++kk) {
                    const short8 wb = *(const short8*)(WBT + sslot(nl, kk * 4 + l4));
                    acc = __builtin_amdgcn_mfma_f32_16x16x32_bf16(xa[kk], wb, acc, 0, 0, 0);
                }
#pragma unroll
                for (int r = 0; r < 4; ++r)
                    stateC[sbase + (size_t)(pw + l4 * 4 + r) * 128 + noff + jn * 16 + l15] =
                        bf16bits(acc[r]);
            }
        }
        __syncthreads();
    }
}

// ---------------------------------------------------------------------------
// Combine: sequential over NCH chunks per bh (in place on stateC).
// ---------------------------------------------------------------------------
__global__ __launch_bounds__(512) void combine_kernel(
    u16* __restrict__ stateC, const float* __restrict__ betac)
{
    const int bh  = blockIdx.x;
    const int tid = threadIdx.x;

    float hrun[16];
#pragma unroll
    for (int j = 0; j < 16; ++j) hrun[j] = 0.f;

    for (int s = 0; s < NCH; ++s) {
        const size_t off = ((size_t)bh * NCH + s) * 8192 + (size_t)tid * 16;
        float c[16];
#pragma unroll
        for (int j = 0; j < 16; ++j) c[j] = bits2f(stateC[off + j]);
#pragma unroll
        for (int j = 0; j < 16; ++j) stateC[off + j] = bf16bits(hrun[j]);
        const float alpha = exp2f(betac[(size_t)bh * L_SEQ + s * CHUNK + (CHUNK - 1)]);
#pragma unroll
        for (int j = 0; j < 16; ++j) hrun[j] = fmaf(alpha, hrun[j], c[j]);
    }
}

// ---------------------------------------------------------------------------
// SSD output pass: PT halved (two-pass over t-halves): 33 KB LDS -> 4/CU.
// Y = P~@X~^T + (2^cumA ∘ C)@h_in^T + D*x -> yb (bf16, written once).
// ---------------------------------------------------------------------------
__global__ __launch_bounds__(256) void ssd_out_kernel(
    const u16* __restrict__ xs, const u16* __restrict__ Cbf,
    const u16* __restrict__ Sraw, const u16* __restrict__ stateC,
    const float* __restrict__ dtb, const float* __restrict__ betac,
    const float* __restrict__ D0, const float* __restrict__ D1,
    u16* __restrict__ yb)
{
    const int bx  = blockIdx.x;
    const int ch  = bx & (NCH - 1);
    const int bh  = bx >> 4;
    const int dir = bh >> 6;
    const int bb  = (bh >> 5) & 1;
    const int h   = bh & 31;
    const int tid = threadIdx.x;
    const int wid = tid >> 6;
    const int lane = tid & 63;
    const int l15 = lane & 15;
    const int l4  = lane >> 4;
    const int t0  = ch * CHUNK;
    const size_t dbase = (size_t)(dir * M_ROWS + bb * L_SEQ);
    const float Dv = (dir ? D1 : D0)[h];

    __shared__ u16 XT[64 * 128];
    __shared__ u16 PT[64 * 128];
    __shared__ float scum[CHUNK];
    __shared__ float sdt[CHUNK];

    auto lidx = [&](int t) { return dir ? (L_SEQ - 1 - t) : t; };

    // phase A: reload base-2 cumA (betac) + dt
    if (tid < 128) {
        scum[tid] = betac[(size_t)bh * L_SEQ + t0 + tid];
    } else {
        const int s = tid - 128;
        sdt[s] = dtb[(dbase + lidx(t0 + s)) * NH + h];
    }
    __syncthreads();

    // build X~T once
    {
        const int s = tid >> 1;
        const float dts = sdt[s];
        const size_t grow = dbase + lidx(t0 + s);
        const int p0 = (tid & 1) * 32;
        const u16* __restrict__ xp = xs + grow * DINNER + h * 64 + p0;
#pragma unroll
        for (int q = 0; q < 4; ++q) {
            short8 v = *(const short8*)(xp + q * 8);
#pragma unroll
            for (int j = 0; j < 8; ++j) {
                const int p = p0 + q * 8 + j;
                XT[sidx(p, s)] = bf16bits(dts * bits2f((u16)v[j]));
            }
        }
    }

    u16* __restrict__ ybase = yb + (size_t)dir * M_ROWS * DINNER;
    const size_t sbase = ((size_t)bh * NCH + ch) * 8192;
    const size_t sbraw = ((size_t)(((bh >> 5) * NCH) + ch)) << 14;

#pragma unroll
    for (int half = 0; half < 2; ++half) {
        const int toff = half * 64;
        // build P~ rows [toff, toff+64): Γ-scaled S_raw (exp2)
#pragma unroll
        for (int i = 0; i < 4; ++i) {
            const int flat = tid + (i << 8);       // 0..1023
            const int lt = flat >> 4;              // 0..63
            const int t  = toff + lt;
            const int sl = flat & 15;
            const short8 v = *(const short8*)(Sraw + sbraw + (size_t)t * 128 + sl * 8);
            const float ct = scum[t];
            short8 o;
#pragma unroll
            for (int j = 0; j < 8; ++j) {
                const int s2 = sl * 8 + j;
                const float g = (s2 <= t) ? exp2f(ct - scum[s2]) : 0.f;
                o[j] = (short)bf16bits(bits2f((u16)v[j]) * g);
            }
            *(short8*)(PT + (lt << 7) + ((sl ^ (lt & 7)) << 3)) = o;
        }
        __syncthreads();

        // Y rows [toff, toff+64): each wave owns 16 t-rows
        {
            const int lt = wid * 16 + l15;
            const int tg = toff + lt;
            short8 pa[4], ga[4];
#pragma unroll
            for (int kk = 0; kk < 4; ++kk)
                pa[kk] = *(const short8*)(PT + sslot(lt, kk * 4 + l4));
            const float gs = exp2f(scum[tg]);
            const size_t crow = dbase + lidx(t0 + tg);
#pragma unroll
            for (int kk = 0; kk < 4; ++kk) {
                const short8 c8 = *(const short8*)(Cbf + crow * NST + kk * 32 + l4 * 8);
                short8 o;
#pragma unroll
                for (int j = 0; j < 8; ++j)
                    o[j] = (short)bf16bits(bits2f((u16)c8[j]) * gs);
                ga[kk] = o;
            }

#pragma unroll
            for (int jp = 0; jp < 4; ++jp) {
                const int prow = jp * 16 + l15;
                short8 xb[4], hb[4];
#pragma unroll
                for (int kk = 0; kk < 4; ++kk) {
                    xb[kk] = *(const short8*)(XT + sslot(prow, kk * 4 + l4));
                    hb[kk] = *(const short8*)(stateC + sbase + (size_t)prow * 128 + kk * 32 + l4 * 8);
                }
                f32x4 acc = (f32x4)0.f;
#pragma unroll
                for (int kk = 0; kk < 4; ++kk)
                    acc = __builtin_amdgcn_mfma_f32_16x16x32_bf16(
                        pa[kk], xb[kk], acc, 0, 0, 0);
#pragma unroll
                for (int kk = 0; kk < 4; ++kk)
                    acc = __builtin_amdgcn_mfma_f32_16x16x32_bf16(
                        ga[kk], hb[kk], acc, 0, 0, 0);
#pragma unroll
                for (int r = 0; r < 4; ++r) {
                    const int t = toff + wid * 16 + l4 * 4 + r;
                    const int lg = lidx(t0 + t);
                    const float xv = bits2f(xs[(dbase + lg) * DINNER + h * 64 + prow]);
                    ybase[(size_t)(bb * L_SEQ + lg) * DINNER + h * 64 + prow] =
                        bf16bits(acc[r] + Dv * xv);
                }
            }
        }
        __syncthreads();
    }
}

// ---------------------------------------------------------------------------
// gate + RMSNorm: reads bf16 z (zx cols [0,2048)) + bf16 y (compact), writes
// bf16 gated/normalized y into zx cols [2048,4096) (dead xBC slice).
// ---------------------------------------------------------------------------
__global__ __launch_bounds__(256) void gatenorm_kernel(
    u16* __restrict__ zx, const u16* __restrict__ yb,
    const float* __restrict__ nw0, const float* __restrict__ nw1)
{
    const int dir = blockIdx.y;
    const int row = blockIdx.x;
    const float* __restrict__ nw = dir ? nw1 : nw0;
    u16* __restrict__ zrow = zx + (size_t)dir * M_ROWS * DPROJP + (size_t)row * DPROJP;
    const u16* __restrict__ yrow = yb + (size_t)dir * M_ROWS * DINNER + (size_t)row * DINNER;
    const int tid = threadIdx.x;
    const int c0 = tid * 8;

    const short8 zv = *(const short8*)(zrow + c0);
    const short8 yv8 = *(const short8*)(yrow + c0);

    float g[8];
#pragma unroll
    for (int j = 0; j < 8; ++j) {
        const float z = bits2f((u16)zv[j]);
        g[j] = bits2f((u16)yv8[j]) * (z / (1.f + expf(-z)));
    }

    float ss = 0.f;
#pragma unroll
    for (int j = 0; j < 8; ++j) ss = fmaf(g[j], g[j], ss);
#pragma unroll
    for (int off = 1; off < 64; off <<= 1) ss += __shfl_xor(ss, off);
    __shared__ float red[4];
    if ((tid & 63) == 0) red[tid >> 6] = ss;
    __syncthreads();
    const float total = red[0] + red[1] + red[2] + red[3];
    const float rs = rsqrtf(total * (1.f / (float)DINNER) + 1e-5f);

    const float4 w0 = *(const float4*)(nw + c0);
    const float4 w1 = *(const float4*)(nw + c0 + 4);
    const float wv[8] = {w0.x, w0.y, w0.z, w0.w, w1.x, w1.y, w1.z, w1.w};
    short8 outv;
#pragma unroll
    for (int j = 0; j < 8; ++j) outv[j] = (short)bf16bits(g[j] * rs * wv[j]);
    *(short8*)(zrow + DINNER + c0) = outv;
}

// ---------------------------------------------------------------------------
extern "C" void kernel_launch(void* const* d_in, const int* in_sizes, int n_in,
                              void* d_out, int out_size, void* d_ws, size_t ws_size,
                              hipStream_t stream)
{
    (void)in_sizes; (void)n_in; (void)out_size; (void)ws_size;
    const float* x        = (const float*)d_in[0];
    const float* f_in_w   = (const float*)d_in[1];
    const float* f_conv_w = (const float*)d_in[2];
    const float* f_conv_b = (const float*)d_in[3];
    const float* f_dtbias = (const float*)d_in[4];
    const float* f_Alog   = (const float*)d_in[5];
    const float* f_D      = (const float*)d_in[6];
    const float* f_nw     = (const float*)d_in[7];
    const float* f_out_w  = (const float*)d_in[8];
    const float* b_in_w   = (const float*)d_in[9];
    const float* b_conv_w = (const float*)d_in[10];
    const float* b_conv_b = (const float*)d_in[11];
    const float* b_dtbias = (const float*)d_in[12];
    const float* b_Alog   = (const float*)d_in[13];
    const float* b_D      = (const float*)d_in[14];
    const float* b_nw     = (const float*)d_in[15];
    const float* b_out_w  = (const float*)d_in[16];

    // Workspace (~201 MB): zx bf16 73.4 | xs 33.6 | Bbf 2.1 | Cbf 2.1
    //   | dtb 1.05 | dta 1.05 | stateC 33.6 | betac 1.05 | yb bf16 33.6
    //   | x_bf 4.2 | w_in 9.2 | w_out 4.2 | Sraw 2.1
    u16* zx  = (u16*)d_ws;
    u16* xs  = zx + (size_t)2 * M_ROWS * DPROJP;
    u16* Bbf = xs + (size_t)2 * M_ROWS * DINNER;
    u16* Cbf = Bbf + (size_t)2 * M_ROWS * NST;
    float* dtb = (float*)(Cbf + (size_t)2 * M_ROWS * NST);
    float* dta = dtb + (size_t)2 * M_ROWS * NH;
    u16* stateC = (u16*)(dta + (size_t)2 * M_ROWS * NH);
    float* betac = (float*)(stateC + (size_t)128 * NCH * 8192);
    u16* yb = (u16*)(betac + (size_t)128 * L_SEQ);
    u16* x_bf   = yb + (size_t)2 * M_ROWS * DINNER;
    u16* w_in_bf  = x_bf + (size_t)M_ROWS * 512;
    u16* w_out_bf = w_in_bf + (size_t)2 * DPROJP * 512;
    u16* Sraw = w_out_bf + (size_t)2 * 512 * DINNER;

    // 0) dtype conversions
    cvt_x_kernel<<<dim3(M_ROWS * 512 / 1024), 256, 0, stream>>>(x, x_bf);
    cvt_win_kernel<<<dim3(DPROJP * 512 / 1024, 2), 256, 0, stream>>>(f_in_w, b_in_w, w_in_bf);
    cvt_wout_kernel<<<dim3(512 * DINNER / 1024, 2), 256, 0, stream>>>(f_out_w, b_out_w, w_out_bf);

    // 1) in_proj (MFMA, bf16 out): zx[dir] = x @ in_w[dir]^T
    gemm_mfma<true><<<dim3(DPROJP / 128, M_ROWS / 128, 2), 256, 0, stream>>>(
        x_bf, x_bf, 512,
        w_in_bf, (long long)DPROJP * 512,
        nullptr, zx, (long long)M_ROWS * DPROJP, DPROJP,
        nullptr, 0, 512);

    // 2a) sliding-window conv + SiLU (bf16 in/out)
    conv_kernel<<<dim3(CONVDIM / 256, 32, 2), 256, 0, stream>>>(
        zx, f_conv_w, b_conv_w, f_conv_b, b_conv_b, xs, Bbf, Cbf);

    // 2b) exact-f32 dt / base-2 log-decay (LDS-staged GEMV)
    dt_kernel<<<dim3(M_ROWS / 64, 2), 512, 0, stream>>>(
        x, f_in_w, b_in_w, f_dtbias, b_dtbias, f_Alog, b_Alog, dtb, dta);

    // 3a) head-independent S_raw = C @ B^T (once per dir,b,chunk)
    sraw_kernel<<<dim3(4 * NCH), 256, 0, stream>>>(Bbf, Cbf, Sraw);

    // 3b) state pass (cumA -> betac, chunk states -> stateC)
    ssd_state_kernel<<<dim3(128 * NCH), 256, 0, stream>>>(
        xs, Bbf, dtb, dta, stateC, betac);

    // 3c) combine chunk states (stateC becomes h_in per chunk)
    combine_kernel<<<dim3(128), 512, 0, stream>>>(stateC, betac);

    // 3d) output pass: local Y + fused correction + D-skip -> yb (bf16)
    ssd_out_kernel<<<dim3(128 * NCH), 256, 0, stream>>>(
        xs, Cbf, Sraw, stateC, dtb, betac, f_D, b_D, yb);

    // 4) gate + RMSNorm: bf16 result into zx cols [2048,4096)
    gatenorm_kernel<<<dim3(M_ROWS, 2), 256, 0, stream>>>(zx, yb, f_nw, b_nw);

    // 5) out_proj (MFMA, bf16 A from zx) + residual + concat
    gemm_mfma<false><<<dim3(512 / 128, M_ROWS / 128, 2), 256, 0, stream>>>(
        zx + DINNER, zx + (size_t)M_ROWS * DPROJP + DINNER, DPROJP,
        w_out_bf, (long long)512 * DINNER,
        (float*)d_out, nullptr, 512, 1024,
        x, 512, DINNER);
}

// Round 13
// 330.919 us; speedup vs baseline: 2.4183x; 1.0168x over previous
//
#include <hip/hip_runtime.h>
#include <hip/hip_bf16.h>
#include <math.h>

#define L_SEQ   2048
#define M_ROWS  4096            // B*L
#define DPROJ   4384
#define DPROJP  4480            // padded to 35*128 for MFMA GEMM
#define DINNER  2048
#define CONVDIM 2304
#define NST     128
#define NH      32
#define CHUNK   128             // SSD chunk length
#define NCH     16              // L_SEQ / CHUNK
#define CTR     128             // conv rows per tile
#define LOG2E   1.4426950408889634f

typedef __attribute__((ext_vector_type(8))) short short8;
typedef __attribute__((ext_vector_type(4))) float f32x4;
typedef unsigned short u16;

static __device__ __forceinline__ u16 bf16bits(float v) {
    __hip_bfloat16 t = __float2bfloat16(v);
    return *(u16*)&t;
}
static __device__ __forceinline__ float bits2f(u16 u) {
    return __uint_as_float((unsigned)u << 16);
}
// element index into a [rows][128] bf16 LDS buffer with 16B-slot XOR swizzle
static __device__ __forceinline__ int sidx(int row, int s) {
    return (row << 7) + ((((s >> 3) ^ (row & 7)) << 3) | (s & 7));
}
static __device__ __forceinline__ int sslot(int row, int ks) {  // ks = 16B slot 0..15
    return (row << 7) + ((ks ^ (row & 7)) << 3);
}
// async 16B global->LDS (wave-uniform LDS base + lane*16; source pre-swizzled)
static __device__ __forceinline__ void gload16(const void* g, void* l) {
    __builtin_amdgcn_global_load_lds(
        (const __attribute__((address_space(1))) void*)g,
        (__attribute__((address_space(3))) void*)l, 16, 0, 0);
}

// ---------------------------------------------------------------------------
// f32 -> bf16 conversion pre-passes
// ---------------------------------------------------------------------------
__global__ __launch_bounds__(256) void cvt_x_kernel(
    const float* __restrict__ x, u16* __restrict__ xbf)
{
    const int i = (blockIdx.x * 256 + threadIdx.x) * 4;
    const float4 v = *(const float4*)(x + i);
    xbf[i + 0] = bf16bits(v.x);
    xbf[i + 1] = bf16bits(v.y);
    xbf[i + 2] = bf16bits(v.z);
    xbf[i + 3] = bf16bits(v.w);
}

__global__ __launch_bounds__(256) void cvt_win_kernel(
    const float* __restrict__ w0, const float* __restrict__ w1,
    u16* __restrict__ dst)
{
    const int dir = blockIdx.y;
    const float* __restrict__ w = dir ? w1 : w0;
    u16* __restrict__ d = dst + (size_t)dir * DPROJP * 512;
    const int i = (blockIdx.x * 256 + threadIdx.x) * 4;
    const int row = i >> 9;
    if (row < DPROJ) {
        const float4 v = *(const float4*)(w + i);
        d[i + 0] = bf16bits(v.x);
        d[i + 1] = bf16bits(v.y);
        d[i + 2] = bf16bits(v.z);
        d[i + 3] = bf16bits(v.w);
    } else {
        d[i + 0] = 0; d[i + 1] = 0; d[i + 2] = 0; d[i + 3] = 0;
    }
}

__global__ __launch_bounds__(256) void cvt_wout_kernel(
    const float* __restrict__ w0, const float* __restrict__ w1,
    u16* __restrict__ dst)
{
    const int dir = blockIdx.y;
    const float* __restrict__ w = dir ? w1 : w0;
    u16* __restrict__ d = dst + (size_t)dir * 512 * DINNER;
    const int i = (blockIdx.x * 256 + threadIdx.x) * 4;
    const float4 v = *(const float4*)(w + i);
    d[i + 0] = bf16bits(v.x);
    d[i + 1] = bf16bits(v.y);
    d[i + 2] = bf16bits(v.z);
    d[i + 3] = bf16bits(v.w);
}

// ---------------------------------------------------------------------------
// MFMA bf16 GEMM: C[M][N] = A[M][K] @ B[N][K]^T. A bf16 with arbitrary lda.
// Staging via global_load_lds (linear LDS dest, inverse-swizzled source);
// reads use the 16B-slot XOR swizzle. XCD-aware bijective block swizzle.
// OUTBF: write bf16. else: f32 + optional addsrc epilogue.
// ---------------------------------------------------------------------------
template<bool OUTBF>
__global__ __launch_bounds__(256) void gemm_mfma(
    const u16* __restrict__ A0, const u16* __restrict__ A1, int lda,
    const u16* __restrict__ Bw, long long b_dir_off,
    float* __restrict__ Cf, u16* __restrict__ Cb, long long c_dir_off, int ldc,
    const float* __restrict__ addsrc, int add_ld,
    int K)
{
    const int dir = blockIdx.z;
    // XCD-aware bijective swizzle (m204), n-fast within each XCD chunk
    const int nwg  = gridDim.x * gridDim.y;
    const int flat = blockIdx.y * gridDim.x + blockIdx.x;
    const int q = nwg >> 3, r = nwg & 7;
    const int xcd = flat & 7, idx = flat >> 3;
    const int wg = (xcd < r) ? xcd * (q + 1) + idx
                             : r * (q + 1) + (xcd - r) * q + idx;
    const int m0 = (wg / gridDim.x) * 128;
    const int n0 = (wg % gridDim.x) * 128;

    const u16* __restrict__ A = dir ? A1 : A0;
    const u16* __restrict__ B = Bw + (size_t)dir * b_dir_off;

    __shared__ u16 Asl[128 * 64];
    __shared__ u16 Bsl[128 * 64];

    const int tid  = threadIdx.x;
    const int lane = tid & 63;
    const int wid  = tid >> 6;
    const int wr   = (wid >> 1) << 6;
    const int wc   = (wid & 1) << 6;
    const int l15  = lane & 15;
    const int l4   = lane >> 4;

    f32x4 acc[4][4];
#pragma unroll
    for (int m = 0; m < 4; ++m)
#pragma unroll
        for (int n = 0; n < 4; ++n) acc[m][n] = (f32x4)0.f;

    for (int k0 = 0; k0 < K; k0 += 64) {
        __syncthreads();   // prior compute done; also drains prior vmcnt
#pragma unroll
        for (int i = 0; i < 4; ++i) {
            const int c    = tid + (i << 8);       // 0..1023 (16B units)
            const int row  = c >> 3;
            const int scol = ((c & 7) ^ (row & 7)) << 3;   // inverse-swizzled source col
            gload16(A + (size_t)(m0 + row) * lda + k0 + scol, (char*)Asl + (c << 4));
            gload16(B + (size_t)(n0 + row) * K   + k0 + scol, (char*)Bsl + (c << 4));
        }
        __syncthreads();   // drains global_load_lds (vmcnt) + barrier

#pragma unroll
        for (int kh = 0; kh < 2; ++kh) {
            const int ks = (kh << 2) + l4;
            short8 a[4], b[4];
#pragma unroll
            for (int m = 0; m < 4; ++m) {
                const int R = wr + (m << 4) + l15;
                a[m] = *(const short8*)((const char*)Asl + (R << 7) + ((ks ^ (R & 7)) << 4));
            }
#pragma unroll
            for (int n = 0; n < 4; ++n) {
                const int R = wc + (n << 4) + l15;
                b[n] = *(const short8*)((const char*)Bsl + (R << 7) + ((ks ^ (R & 7)) << 4));
            }
#pragma unroll
            for (int m = 0; m < 4; ++m)
#pragma unroll
                for (int n = 0; n < 4; ++n)
                    acc[m][n] = __builtin_amdgcn_mfma_f32_16x16x32_bf16(
                        a[m], b[n], acc[m][n], 0, 0, 0);
        }
    }

#pragma unroll
    for (int m = 0; m < 4; ++m) {
        const int row0 = m0 + wr + (m << 4) + (l4 << 2);
#pragma unroll
        for (int n = 0; n < 4; ++n) {
            const int col = n0 + wc + (n << 4) + l15;
#pragma unroll
            for (int r2 = 0; r2 < 4; ++r2) {
                if (OUTBF) {
                    Cb[(size_t)dir * c_dir_off + (size_t)(row0 + r2) * ldc + col] =
                        bf16bits(acc[m][n][r2]);
                } else {
                    float v = acc[m][n][r2];
                    if (addsrc) v += addsrc[(size_t)(row0 + r2) * add_ld + col];
                    Cf[(size_t)dir * c_dir_off + (size_t)(row0 + r2) * ldc + col] = v;
                }
            }
        }
    }
}

// ---------------------------------------------------------------------------
// Sliding-window depthwise conv(4) + SiLU over bf16 zx columns.
// ---------------------------------------------------------------------------
__global__ __launch_bounds__(256) void conv_kernel(
    const u16* __restrict__ zx,
    const float* __restrict__ cw0, const float* __restrict__ cw1,
    const float* __restrict__ cb0, const float* __restrict__ cb1,
    u16* __restrict__ xs, u16* __restrict__ Bbf, u16* __restrict__ Cbf)
{
    const int dir = blockIdx.z;
    const int c   = blockIdx.x * 256 + threadIdx.x;     // channel 0..2303
    const int b   = blockIdx.y >> 4;
    const int r0  = (blockIdx.y & 15) * CTR;

    const float* __restrict__ cw = dir ? cw1 : cw0;
    const float w0 = cw[c * 4 + 0], w1 = cw[c * 4 + 1];
    const float w2 = cw[c * 4 + 2], w3 = cw[c * 4 + 3];
    const float bias = (dir ? cb1 : cb0)[c];

    const u16* __restrict__ zcol = zx + (size_t)dir * M_ROWS * DPROJP
        + (size_t)(b * L_SEQ) * DPROJP + DINNER + c;
    const size_t obase = (size_t)(dir * M_ROWS + b * L_SEQ);

    auto emit = [&](int l, float acc) {
        const float s = acc / (1.f + expf(-acc));
        const size_t orow = obase + l;
        if (c < DINNER)            xs[orow * DINNER + c] = bf16bits(s);
        else if (c < DINNER + NST) Bbf[orow * NST + (c - DINNER)] = bf16bits(s);
        else                       Cbf[orow * NST + (c - DINNER - NST)] = bf16bits(s);
    };

    if (dir == 0) {
        float h0 = (r0 - 3 >= 0) ? bits2f(zcol[(size_t)(r0 - 3) * DPROJP]) : 0.f;
        float h1 = (r0 - 2 >= 0) ? bits2f(zcol[(size_t)(r0 - 2) * DPROJP]) : 0.f;
        float h2 = (r0 - 1 >= 0) ? bits2f(zcol[(size_t)(r0 - 1) * DPROJP]) : 0.f;
#pragma unroll 4
        for (int l = r0; l < r0 + CTR; ++l) {
            const float zl = bits2f(zcol[(size_t)l * DPROJP]);
            float acc = bias;
            acc = fmaf(w0, h0, acc);
            acc = fmaf(w1, h1, acc);
            acc = fmaf(w2, h2, acc);
            acc = fmaf(w3, zl, acc);
            emit(l, acc);
            h0 = h1; h1 = h2; h2 = zl;
        }
    } else {
        const int le = r0 + CTR - 1;
        float h1 = (le + 1 < L_SEQ) ? bits2f(zcol[(size_t)(le + 1) * DPROJP]) : 0.f;
        float h2 = (le + 2 < L_SEQ) ? bits2f(zcol[(size_t)(le + 2) * DPROJP]) : 0.f;
        float h3 = (le + 3 < L_SEQ) ? bits2f(zcol[(size_t)(le + 3) * DPROJP]) : 0.f;
#pragma unroll 4
        for (int l = le; l >= r0; --l) {
            const float zl = bits2f(zcol[(size_t)l * DPROJP]);
            float acc = bias;
            acc = fmaf(w3, zl, acc);
            acc = fmaf(w2, h1, acc);
            acc = fmaf(w1, h2, acc);
            acc = fmaf(w0, h3, acc);
            emit(l, acc);
            h3 = h2; h2 = h1; h1 = zl;
        }
    }
}

// ---------------------------------------------------------------------------
// Exact-f32 dt as LDS-staged block GEMV. dta in BASE-2 log-decay.
// ---------------------------------------------------------------------------
__global__ __launch_bounds__(512) void dt_kernel(
    const float* __restrict__ x,
    const float* __restrict__ inw0, const float* __restrict__ inw1,
    const float* __restrict__ dtbias0, const float* __restrict__ dtbias1,
    const float* __restrict__ Alog0, const float* __restrict__ Alog1,
    float* __restrict__ dtb, float* __restrict__ dta)
{
    const int dir = blockIdx.y;
    const int r0  = blockIdx.x * 64;
    const int tid = threadIdx.x;

    __shared__ float wT[512 * 32];   // [k4][h][j], 64 KB
    __shared__ float sbias[NH], sa[NH];

    const float* __restrict__ w = (dir ? inw1 : inw0) + (size_t)(DINNER + CONVDIM) * 512;
    for (int i = tid; i < 4096; i += 512) {
        const int flat = i * 4;
        const int h = flat >> 9;
        const int k = flat & 511;
        const float4 v = *(const float4*)(w + flat);
        *(float4*)&wT[(k >> 2) * 128 + h * 4] = v;
    }
    if (tid < NH) {
        sbias[tid] = (dir ? dtbias1 : dtbias0)[tid];
        sa[tid] = -expf((dir ? Alog1 : Alog0)[tid]) * LOG2E;
    }
    __syncthreads();

    const int h  = tid & 31;
    const int rr = tid >> 5;
    const float bias = sbias[h];
    const float a = sa[h];

    for (int rp = 0; rp < 64; rp += 16) {
        const int row = r0 + rp + rr;
        const float4* __restrict__ xr = (const float4*)(x + (size_t)row * 512);
        float4 s4 = make_float4(0.f, 0.f, 0.f, 0.f);
#pragma unroll 8
        for (int k4 = 0; k4 < 128; ++k4) {
            const float4 xv = xr[k4];
            const float4 wv = *(const float4*)&wT[k4 * 128 + h * 4];
            s4.x = fmaf(xv.x, wv.x, s4.x);
            s4.y = fmaf(xv.y, wv.y, s4.y);
            s4.z = fmaf(xv.z, wv.z, s4.z);
            s4.w = fmaf(xv.w, wv.w, s4.w);
        }
        const float v = (s4.x + s4.y) + (s4.z + s4.w) + bias;
        const float sp = (v > 20.f) ? v : log1pf(expf(v));
        const size_t orow = (size_t)(dir * M_ROWS + row);
        dtb[orow * NH + h] = sp;
        dta[orow * NH + h] = sp * a;         // base-2 log-decay
    }
}

// ---------------------------------------------------------------------------
// S_raw = C @ B^T per (dir,b,chunk) — head-independent, computed once.
// ---------------------------------------------------------------------------
__global__ __launch_bounds__(256) void sraw_kernel(
    const u16* __restrict__ Bbf, const u16* __restrict__ Cbf,
    u16* __restrict__ Sraw)
{
    const int bx  = blockIdx.x;            // db*NCH + ch
    const int ch  = bx & (NCH - 1);
    const int db  = bx >> 4;               // dir*2+b
    const int dir = db >> 1, bb = db & 1;
    const int tid = threadIdx.x;
    const int wid = tid >> 6;
    const int lane = tid & 63;
    const int l15 = lane & 15, l4 = lane >> 4;
    const int t0  = ch * CHUNK;
    const size_t dbase = (size_t)(dir * M_ROWS + bb * L_SEQ);
    const size_t base  = ((size_t)bx) << 14;     // *128*128

    auto lidx = [&](int t) { return dir ? (L_SEQ - 1 - t) : t; };

    f32x4 accs[2][8];
#pragma unroll
    for (int m = 0; m < 2; ++m)
#pragma unroll
        for (int j = 0; j < 8; ++j) accs[m][j] = (f32x4)0.f;

    short8 af[2][4];
#pragma unroll
    for (int m = 0; m < 2; ++m) {
        const size_t crow = dbase + lidx(t0 + wid * 32 + m * 16 + l15);
#pragma unroll
        for (int kk = 0; kk < 4; ++kk)
            af[m][kk] = *(const short8*)(Cbf + crow * NST + kk * 32 + l4 * 8);
    }
#pragma unroll
    for (int j = 0; j < 8; ++j) {
        const size_t brow = dbase + lidx(t0 + j * 16 + l15);
        short8 bf_[4];
#pragma unroll
        for (int kk = 0; kk < 4; ++kk)
            bf_[kk] = *(const short8*)(Bbf + brow * NST + kk * 32 + l4 * 8);
#pragma unroll
        for (int m = 0; m < 2; ++m)
#pragma unroll
            for (int kk = 0; kk < 4; ++kk)
                accs[m][j] = __builtin_amdgcn_mfma_f32_16x16x32_bf16(
                    af[m][kk], bf_[kk], accs[m][j], 0, 0, 0);
    }

#pragma unroll
    for (int m = 0; m < 2; ++m)
#pragma unroll
        for (int j = 0; j < 8; ++j)
#pragma unroll
            for (int r = 0; r < 4; ++r) {
                const int t = wid * 32 + m * 16 + l4 * 4 + r;
                const int s = j * 16 + l15;
                Sraw[base + (size_t)t * 128 + s] = bf16bits(accs[m][j][r]);
            }
}

// ---------------------------------------------------------------------------
// SSD state pass: cumA prefix (-> betac) + chunk state = X~T @ (r∘B)^T.
// WBT halved (two-pass over n-halves): 33 KB LDS -> 4 blocks/CU.
// ---------------------------------------------------------------------------
__global__ __launch_bounds__(256) void ssd_state_kernel(
    const u16* __restrict__ xs, const u16* __restrict__ Bbf,
    const float* __restrict__ dtb, const float* __restrict__ dta,
    u16* __restrict__ stateC, float* __restrict__ betac)
{
    const int bx  = blockIdx.x;
    const int ch  = bx & (NCH - 1);
    const int bh  = bx >> 4;
    const int dir = bh >> 6;
    const int bb  = (bh >> 5) & 1;
    const int h   = bh & 31;
    const int tid = threadIdx.x;
    const int wid = tid >> 6;
    const int lane = tid & 63;
    const int l15 = lane & 15;
    const int l4  = lane >> 4;
    const int t0  = ch * CHUNK;
    const size_t dbase = (size_t)(dir * M_ROWS + bb * L_SEQ);

    __shared__ u16 XT[64 * 128];
    __shared__ u16 WBT[64 * 128];
    __shared__ float scum[CHUNK];
    __shared__ float sdt[CHUNK];

    auto lidx = [&](int t) { return dir ? (L_SEQ - 1 - t) : t; };

    // phase A: dt loads + base-2 cumA prefix-sum (wave 0)
    if (tid >= 128) {
        const int s = tid - 128;
        sdt[s] = dtb[(dbase + lidx(t0 + s)) * NH + h];
    }
    if (wid == 0) {
        float a0 = dta[(dbase + lidx(t0 + lane)) * NH + h];
        float a1 = dta[(dbase + lidx(t0 + 64 + lane)) * NH + h];
#pragma unroll
        for (int off = 1; off < 64; off <<= 1) {
            const float u0 = __shfl_up(a0, off);
            const float u1 = __shfl_up(a1, off);
            if (lane >= off) { a0 += u0; a1 += u1; }
        }
        a1 += __shfl(a0, 63);
        scum[lane] = a0; scum[64 + lane] = a1;
        betac[(size_t)bh * L_SEQ + t0 + lane] = a0;
        betac[(size_t)bh * L_SEQ + t0 + 64 + lane] = a1;
    }
    __syncthreads();

    // build X~T once
    {
        const int s = tid >> 1;
        const float dts = sdt[s];
        const size_t grow = dbase + lidx(t0 + s);
        const int p0 = (tid & 1) * 32;
        const u16* __restrict__ xp = xs + grow * DINNER + h * 64 + p0;
#pragma unroll
        for (int q = 0; q < 4; ++q) {
            short8 v = *(const short8*)(xp + q * 8);
#pragma unroll
            for (int j = 0; j < 8; ++j) {
                const int p = p0 + q * 8 + j;
                XT[sidx(p, s)] = bf16bits(dts * bits2f((u16)v[j]));
            }
        }
    }

    const size_t sbase = ((size_t)bh * NCH + ch) * 8192;

#pragma unroll
    for (int half = 0; half < 2; ++half) {
        const int noff = half * 64;
        // build WBT rows [noff, noff+64)
        {
            const int s = tid >> 1;
            const float rs = exp2f(scum[CHUNK - 1] - scum[s]);
            const size_t grow = dbase + lidx(t0 + s);
            const int n0l = (tid & 1) * 32;
            const u16* __restrict__ bp = Bbf + grow * NST + noff + n0l;
#pragma unroll
            for (int q = 0; q < 4; ++q) {
                short8 v = *(const short8*)(bp + q * 8);
#pragma unroll
                for (int j = 0; j < 8; ++j) {
                    const int nl = n0l + q * 8 + j;
                    WBT[sidx(nl, s)] = bf16bits(rs * bits2f((u16)v[j]));
                }
            }
        }
        __syncthreads();

        // STATE GEMM for this n-half
        {
            const int pw = wid * 16;
            const int prow = pw + l15;
            short8 xa[4];
#pragma unroll
            for (int kk = 0; kk < 4; ++kk)
                xa[kk] = *(const short8*)(XT + sslot(prow, kk * 4 + l4));
#pragma unroll
            for (int jn = 0; jn < 4; ++jn) {
                const int nl = jn * 16 + l15;
                f32x4 acc = (f32x4)0.f;
#pragma unroll
                for (int kk = 0; kk < 4; ++kk) {
                    const short8 wb = *(const short8*)(WBT + sslot(nl, kk * 4 + l4));
                    acc = __builtin_amdgcn_mfma_f32_16x16x32_bf16(xa[kk], wb, acc, 0, 0, 0);
                }
#pragma unroll
                for (int r = 0; r < 4; ++r)
                    stateC[sbase + (size_t)(pw + l4 * 4 + r) * 128 + noff + jn * 16 + l15] =
                        bf16bits(acc[r]);
            }
        }
        __syncthreads();
    }
}

// ---------------------------------------------------------------------------
// Combine: sequential over NCH chunks per bh (in place on stateC).
// ---------------------------------------------------------------------------
__global__ __launch_bounds__(512) void combine_kernel(
    u16* __restrict__ stateC, const float* __restrict__ betac)
{
    const int bh  = blockIdx.x;
    const int tid = threadIdx.x;

    float hrun[16];
#pragma unroll
    for (int j = 0; j < 16; ++j) hrun[j] = 0.f;

    for (int s = 0; s < NCH; ++s) {
        const size_t off = ((size_t)bh * NCH + s) * 8192 + (size_t)tid * 16;
        float c[16];
#pragma unroll
        for (int j = 0; j < 16; ++j) c[j] = bits2f(stateC[off + j]);
#pragma unroll
        for (int j = 0; j < 16; ++j) stateC[off + j] = bf16bits(hrun[j]);
        const float alpha = exp2f(betac[(size_t)bh * L_SEQ + s * CHUNK + (CHUNK - 1)]);
#pragma unroll
        for (int j = 0; j < 16; ++j) hrun[j] = fmaf(alpha, hrun[j], c[j]);
    }
}

// ---------------------------------------------------------------------------
// SSD output pass: PT halved (two-pass over t-halves): 33 KB LDS -> 4/CU.
// Y = P~@X~^T + (2^cumA ∘ C)@h_in^T + D*x -> yb (bf16, written once).
// ---------------------------------------------------------------------------
__global__ __launch_bounds__(256) void ssd_out_kernel(
    const u16* __restrict__ xs, const u16* __restrict__ Cbf,
    const u16* __restrict__ Sraw, const u16* __restrict__ stateC,
    const float* __restrict__ dtb, const float* __restrict__ betac,
    const float* __restrict__ D0, const float* __restrict__ D1,
    u16* __restrict__ yb)
{
    const int bx  = blockIdx.x;
    const int ch  = bx & (NCH - 1);
    const int bh  = bx >> 4;
    const int dir = bh >> 6;
    const int bb  = (bh >> 5) & 1;
    const int h   = bh & 31;
    const int tid = threadIdx.x;
    const int wid = tid >> 6;
    const int lane = tid & 63;
    const int l15 = lane & 15;
    const int l4  = lane >> 4;
    const int t0  = ch * CHUNK;
    const size_t dbase = (size_t)(dir * M_ROWS + bb * L_SEQ);
    const float Dv = (dir ? D1 : D0)[h];

    __shared__ u16 XT[64 * 128];
    __shared__ u16 PT[64 * 128];
    __shared__ float scum[CHUNK];
    __shared__ float sdt[CHUNK];

    auto lidx = [&](int t) { return dir ? (L_SEQ - 1 - t) : t; };

    // phase A: reload base-2 cumA (betac) + dt
    if (tid < 128) {
        scum[tid] = betac[(size_t)bh * L_SEQ + t0 + tid];
    } else {
        const int s = tid - 128;
        sdt[s] = dtb[(dbase + lidx(t0 + s)) * NH + h];
    }
    __syncthreads();

    // build X~T once
    {
        const int s = tid >> 1;
        const float dts = sdt[s];
        const size_t grow = dbase + lidx(t0 + s);
        const int p0 = (tid & 1) * 32;
        const u16* __restrict__ xp = xs + grow * DINNER + h * 64 + p0;
#pragma unroll
        for (int q = 0; q < 4; ++q) {
            short8 v = *(const short8*)(xp + q * 8);
#pragma unroll
            for (int j = 0; j < 8; ++j) {
                const int p = p0 + q * 8 + j;
                XT[sidx(p, s)] = bf16bits(dts * bits2f((u16)v[j]));
            }
        }
    }

    u16* __restrict__ ybase = yb + (size_t)dir * M_ROWS * DINNER;
    const size_t sbase = ((size_t)bh * NCH + ch) * 8192;
    const size_t sbraw = ((size_t)(((bh >> 5) * NCH) + ch)) << 14;

#pragma unroll
    for (int half = 0; half < 2; ++half) {
        const int toff = half * 64;
        // build P~ rows [toff, toff+64): Γ-scaled S_raw (exp2)
#pragma unroll
        for (int i = 0; i < 4; ++i) {
            const int flat = tid + (i << 8);       // 0..1023
            const int lt = flat >> 4;              // 0..63
            const int t  = toff + lt;
            const int sl = flat & 15;
            const short8 v = *(const short8*)(Sraw + sbraw + (size_t)t * 128 + sl * 8);
            const float ct = scum[t];
            short8 o;
#pragma unroll
            for (int j = 0; j < 8; ++j) {
                const int s2 = sl * 8 + j;
                const float g = (s2 <= t) ? exp2f(ct - scum[s2]) : 0.f;
                o[j] = (short)bf16bits(bits2f((u16)v[j]) * g);
            }
            *(short8*)(PT + (lt << 7) + ((sl ^ (lt & 7)) << 3)) = o;
        }
        __syncthreads();

        // Y rows [toff, toff+64): each wave owns 16 t-rows
        {
            const int lt = wid * 16 + l15;
            const int tg = toff + lt;
            short8 pa[4], ga[4];
#pragma unroll
            for (int kk = 0; kk < 4; ++kk)
                pa[kk] = *(const short8*)(PT + sslot(lt, kk * 4 + l4));
            const float gs = exp2f(scum[tg]);
            const size_t crow = dbase + lidx(t0 + tg);
#pragma unroll
            for (int kk = 0; kk < 4; ++kk) {
                const short8 c8 = *(const short8*)(Cbf + crow * NST + kk * 32 + l4 * 8);
                short8 o;
#pragma unroll
                for (int j = 0; j < 8; ++j)
                    o[j] = (short)bf16bits(bits2f((u16)c8[j]) * gs);
                ga[kk] = o;
            }

#pragma unroll
            for (int jp = 0; jp < 4; ++jp) {
                const int prow = jp * 16 + l15;
                short8 xb[4], hb[4];
#pragma unroll
                for (int kk = 0; kk < 4; ++kk) {
                    xb[kk] = *(const short8*)(XT + sslot(prow, kk * 4 + l4));
                    hb[kk] = *(const short8*)(stateC + sbase + (size_t)prow * 128 + kk * 32 + l4 * 8);
                }
                f32x4 acc = (f32x4)0.f;
#pragma unroll
                for (int kk = 0; kk < 4; ++kk)
                    acc = __builtin_amdgcn_mfma_f32_16x16x32_bf16(
                        pa[kk], xb[kk], acc, 0, 0, 0);
#pragma unroll
                for (int kk = 0; kk < 4; ++kk)
                    acc = __builtin_amdgcn_mfma_f32_16x16x32_bf16(
                        ga[kk], hb[kk], acc, 0, 0, 0);
#pragma unroll
                for (int r = 0; r < 4; ++r) {
                    const int t = toff + wid * 16 + l4 * 4 + r;
                    const int lg = lidx(t0 + t);
                    const float xv = bits2f(xs[(dbase + lg) * DINNER + h * 64 + prow]);
                    ybase[(size_t)(bb * L_SEQ + lg) * DINNER + h * 64 + prow] =
                        bf16bits(acc[r] + Dv * xv);
                }
            }
        }
        __syncthreads();
    }
}

// ---------------------------------------------------------------------------
// gate + RMSNorm: reads bf16 z (zx cols [0,2048)) + bf16 y (compact), writes
// bf16 gated/normalized y into zx cols [2048,4096) (dead xBC slice).
// ---------------------------------------------------------------------------
__global__ __launch_bounds__(256) void gatenorm_kernel(
    u16* __restrict__ zx, const u16* __restrict__ yb,
    const float* __restrict__ nw0, const float* __restrict__ nw1)
{
    const int dir = blockIdx.y;
    const int row = blockIdx.x;
    const float* __restrict__ nw = dir ? nw1 : nw0;
    u16* __restrict__ zrow = zx + (size_t)dir * M_ROWS * DPROJP + (size_t)row * DPROJP;
    const u16* __restrict__ yrow = yb + (size_t)dir * M_ROWS * DINNER + (size_t)row * DINNER;
    const int tid = threadIdx.x;
    const int c0 = tid * 8;

    const short8 zv = *(const short8*)(zrow + c0);
    const short8 yv8 = *(const short8*)(yrow + c0);

    float g[8];
#pragma unroll
    for (int j = 0; j < 8; ++j) {
        const float z = bits2f((u16)zv[j]);
        g[j] = bits2f((u16)yv8[j]) * (z / (1.f + expf(-z)));
    }

    float ss = 0.f;
#pragma unroll
    for (int j = 0; j < 8; ++j) ss = fmaf(g[j], g[j], ss);
#pragma unroll
    for (int off = 1; off < 64; off <<= 1) ss += __shfl_xor(ss, off);
    __shared__ float red[4];
    if ((tid & 63) == 0) red[tid >> 6] = ss;
    __syncthreads();
    const float total = red[0] + red[1] + red[2] + red[3];
    const float rs = rsqrtf(total * (1.f / (float)DINNER) + 1e-5f);

    const float4 w0 = *(const float4*)(nw + c0);
    const float4 w1 = *(const float4*)(nw + c0 + 4);
    const float wv[8] = {w0.x, w0.y, w0.z, w0.w, w1.x, w1.y, w1.z, w1.w};
    short8 outv;
#pragma unroll
    for (int j = 0; j < 8; ++j) outv[j] = (short)bf16bits(g[j] * rs * wv[j]);
    *(short8*)(zrow + DINNER + c0) = outv;
}

// ---------------------------------------------------------------------------
extern "C" void kernel_launch(void* const* d_in, const int* in_sizes, int n_in,
                              void* d_out, int out_size, void* d_ws, size_t ws_size,
                              hipStream_t stream)
{
    (void)in_sizes; (void)n_in; (void)out_size; (void)ws_size;
    const float* x        = (const float*)d_in[0];
    const float* f_in_w   = (const float*)d_in[1];
    const float* f_conv_w = (const float*)d_in[2];
    const float* f_conv_b = (const float*)d_in[3];
    const float* f_dtbias = (const float*)d_in[4];
    const float* f_Alog   = (const float*)d_in[5];
    const float* f_D      = (const float*)d_in[6];
    const float* f_nw     = (const float*)d_in[7];
    const float* f_out_w  = (const float*)d_in[8];
    const float* b_in_w   = (const float*)d_in[9];
    const float* b_conv_w = (const float*)d_in[10];
    const float* b_conv_b = (const float*)d_in[11];
    const float* b_dtbias = (const float*)d_in[12];
    const float* b_Alog   = (const float*)d_in[13];
    const float* b_D      = (const float*)d_in[14];
    const float* b_nw     = (const float*)d_in[15];
    const float* b_out_w  = (const float*)d_in[16];

    // Workspace (~201 MB)
    u16* zx  = (u16*)d_ws;
    u16* xs  = zx + (size_t)2 * M_ROWS * DPROJP;
    u16* Bbf = xs + (size_t)2 * M_ROWS * DINNER;
    u16* Cbf = Bbf + (size_t)2 * M_ROWS * NST;
    float* dtb = (float*)(Cbf + (size_t)2 * M_ROWS * NST);
    float* dta = dtb + (size_t)2 * M_ROWS * NH;
    u16* stateC = (u16*)(dta + (size_t)2 * M_ROWS * NH);
    float* betac = (float*)(stateC + (size_t)128 * NCH * 8192);
    u16* yb = (u16*)(betac + (size_t)128 * L_SEQ);
    u16* x_bf   = yb + (size_t)2 * M_ROWS * DINNER;
    u16* w_in_bf  = x_bf + (size_t)M_ROWS * 512;
    u16* w_out_bf = w_in_bf + (size_t)2 * DPROJP * 512;
    u16* Sraw = w_out_bf + (size_t)2 * 512 * DINNER;

    // 0) dtype conversions
    cvt_x_kernel<<<dim3(M_ROWS * 512 / 1024), 256, 0, stream>>>(x, x_bf);
    cvt_win_kernel<<<dim3(DPROJP * 512 / 1024, 2), 256, 0, stream>>>(f_in_w, b_in_w, w_in_bf);
    cvt_wout_kernel<<<dim3(512 * DINNER / 1024, 2), 256, 0, stream>>>(f_out_w, b_out_w, w_out_bf);

    // 1) in_proj (MFMA, bf16 out): zx[dir] = x @ in_w[dir]^T
    gemm_mfma<true><<<dim3(DPROJP / 128, M_ROWS / 128, 2), 256, 0, stream>>>(
        x_bf, x_bf, 512,
        w_in_bf, (long long)DPROJP * 512,
        nullptr, zx, (long long)M_ROWS * DPROJP, DPROJP,
        nullptr, 0, 512);

    // 2a) sliding-window conv + SiLU (bf16 in/out)
    conv_kernel<<<dim3(CONVDIM / 256, 32, 2), 256, 0, stream>>>(
        zx, f_conv_w, b_conv_w, f_conv_b, b_conv_b, xs, Bbf, Cbf);

    // 2b) exact-f32 dt / base-2 log-decay (LDS-staged GEMV)
    dt_kernel<<<dim3(M_ROWS / 64, 2), 512, 0, stream>>>(
        x, f_in_w, b_in_w, f_dtbias, b_dtbias, f_Alog, b_Alog, dtb, dta);

    // 3a) head-independent S_raw = C @ B^T (once per dir,b,chunk)
    sraw_kernel<<<dim3(4 * NCH), 256, 0, stream>>>(Bbf, Cbf, Sraw);

    // 3b) state pass (cumA -> betac, chunk states -> stateC)
    ssd_state_kernel<<<dim3(128 * NCH), 256, 0, stream>>>(
        xs, Bbf, dtb, dta, stateC, betac);

    // 3c) combine chunk states (stateC becomes h_in per chunk)
    combine_kernel<<<dim3(128), 512, 0, stream>>>(stateC, betac);

    // 3d) output pass: local Y + fused correction + D-skip -> yb (bf16)
    ssd_out_kernel<<<dim3(128 * NCH), 256, 0, stream>>>(
        xs, Cbf, Sraw, stateC, dtb, betac, f_D, b_D, yb);

    // 4) gate + RMSNorm: bf16 result into zx cols [2048,4096)
    gatenorm_kernel<<<dim3(M_ROWS, 2), 256, 0, stream>>>(zx, yb, f_nw, b_nw);

    // 5) out_proj (MFMA, bf16 A from zx) + residual + concat
    gemm_mfma<false><<<dim3(512 / 128, M_ROWS / 128, 2), 256, 0, stream>>>(
        zx + DINNER, zx + (size_t)M_ROWS * DPROJP + DINNER, DPROJP,
        w_out_bf, (long long)512 * DINNER,
        (float*)d_out, nullptr, 512, 1024,
        x, 512, DINNER);
}

// Round 14
// 310.383 us; speedup vs baseline: 2.5783x; 1.0662x over previous
//
#include <hip/hip_runtime.h>
#include <hip/hip_bf16.h>
#include <math.h>

#define L_SEQ   2048
#define M_ROWS  4096            // B*L
#define DPROJ   4384
#define DPROJP  4480            // padded to 35*128 for MFMA GEMM
#define DINNER  2048
#define CONVDIM 2304
#define NST     128
#define NH      32
#define CHUNK   128             // SSD chunk length
#define NCH     16              // L_SEQ / CHUNK
#define CTR     32              // conv rows per tile (parallelism > reuse)
#define NTILE   (L_SEQ / CTR)   // 64
#define LOG2E   1.4426950408889634f

typedef __attribute__((ext_vector_type(8))) short short8;
typedef __attribute__((ext_vector_type(4))) float f32x4;
typedef unsigned short u16;

static __device__ __forceinline__ u16 bf16bits(float v) {
    __hip_bfloat16 t = __float2bfloat16(v);
    return *(u16*)&t;
}
static __device__ __forceinline__ float bits2f(u16 u) {
    return __uint_as_float((unsigned)u << 16);
}
// element index into a [rows][128] bf16 LDS buffer with 16B-slot XOR swizzle
static __device__ __forceinline__ int sidx(int row, int s) {
    return (row << 7) + ((((s >> 3) ^ (row & 7)) << 3) | (s & 7));
}
static __device__ __forceinline__ int sslot(int row, int ks) {  // ks = 16B slot 0..15
    return (row << 7) + ((ks ^ (row & 7)) << 3);
}
// async 16B global->LDS (wave-uniform LDS base + lane*16; source pre-swizzled)
static __device__ __forceinline__ void gload16(const void* g, void* l) {
    __builtin_amdgcn_global_load_lds(
        (const __attribute__((address_space(1))) void*)g,
        (__attribute__((address_space(3))) void*)l, 16, 0, 0);
}

// ---------------------------------------------------------------------------
// f32 -> bf16 conversion pre-passes
// ---------------------------------------------------------------------------
__global__ __launch_bounds__(256) void cvt_x_kernel(
    const float* __restrict__ x, u16* __restrict__ xbf)
{
    const int i = (blockIdx.x * 256 + threadIdx.x) * 4;
    const float4 v = *(const float4*)(x + i);
    xbf[i + 0] = bf16bits(v.x);
    xbf[i + 1] = bf16bits(v.y);
    xbf[i + 2] = bf16bits(v.z);
    xbf[i + 3] = bf16bits(v.w);
}

__global__ __launch_bounds__(256) void cvt_win_kernel(
    const float* __restrict__ w0, const float* __restrict__ w1,
    u16* __restrict__ dst)
{
    const int dir = blockIdx.y;
    const float* __restrict__ w = dir ? w1 : w0;
    u16* __restrict__ d = dst + (size_t)dir * DPROJP * 512;
    const int i = (blockIdx.x * 256 + threadIdx.x) * 4;
    const int row = i >> 9;
    if (row < DPROJ) {
        const float4 v = *(const float4*)(w + i);
        d[i + 0] = bf16bits(v.x);
        d[i + 1] = bf16bits(v.y);
        d[i + 2] = bf16bits(v.z);
        d[i + 3] = bf16bits(v.w);
    } else {
        d[i + 0] = 0; d[i + 1] = 0; d[i + 2] = 0; d[i + 3] = 0;
    }
}

__global__ __launch_bounds__(256) void cvt_wout_kernel(
    const float* __restrict__ w0, const float* __restrict__ w1,
    u16* __restrict__ dst)
{
    const int dir = blockIdx.y;
    const float* __restrict__ w = dir ? w1 : w0;
    u16* __restrict__ d = dst + (size_t)dir * 512 * DINNER;
    const int i = (blockIdx.x * 256 + threadIdx.x) * 4;
    const float4 v = *(const float4*)(w + i);
    d[i + 0] = bf16bits(v.x);
    d[i + 1] = bf16bits(v.y);
    d[i + 2] = bf16bits(v.z);
    d[i + 3] = bf16bits(v.w);
}

// ---------------------------------------------------------------------------
// MFMA bf16 GEMM: C[M][N] = A[M][K] @ B[N][K]^T. global_load_lds staging
// (linear LDS dest, inverse-swizzled source), XCD-aware block swizzle.
// ---------------------------------------------------------------------------
template<bool OUTBF>
__global__ __launch_bounds__(256) void gemm_mfma(
    const u16* __restrict__ A0, const u16* __restrict__ A1, int lda,
    const u16* __restrict__ Bw, long long b_dir_off,
    float* __restrict__ Cf, u16* __restrict__ Cb, long long c_dir_off, int ldc,
    const float* __restrict__ addsrc, int add_ld,
    int K)
{
    const int dir = blockIdx.z;
    const int nwg  = gridDim.x * gridDim.y;
    const int flat = blockIdx.y * gridDim.x + blockIdx.x;
    const int q = nwg >> 3, r = nwg & 7;
    const int xcd = flat & 7, idx = flat >> 3;
    const int wg = (xcd < r) ? xcd * (q + 1) + idx
                             : r * (q + 1) + (xcd - r) * q + idx;
    const int m0 = (wg / gridDim.x) * 128;
    const int n0 = (wg % gridDim.x) * 128;

    const u16* __restrict__ A = dir ? A1 : A0;
    const u16* __restrict__ B = Bw + (size_t)dir * b_dir_off;

    __shared__ u16 Asl[128 * 64];
    __shared__ u16 Bsl[128 * 64];

    const int tid  = threadIdx.x;
    const int lane = tid & 63;
    const int wid  = tid >> 6;
    const int wr   = (wid >> 1) << 6;
    const int wc   = (wid & 1) << 6;
    const int l15  = lane & 15;
    const int l4   = lane >> 4;

    f32x4 acc[4][4];
#pragma unroll
    for (int m = 0; m < 4; ++m)
#pragma unroll
        for (int n = 0; n < 4; ++n) acc[m][n] = (f32x4)0.f;

    for (int k0 = 0; k0 < K; k0 += 64) {
        __syncthreads();
#pragma unroll
        for (int i = 0; i < 4; ++i) {
            const int c    = tid + (i << 8);
            const int row  = c >> 3;
            const int scol = ((c & 7) ^ (row & 7)) << 3;
            gload16(A + (size_t)(m0 + row) * lda + k0 + scol, (char*)Asl + (c << 4));
            gload16(B + (size_t)(n0 + row) * K   + k0 + scol, (char*)Bsl + (c << 4));
        }
        __syncthreads();

#pragma unroll
        for (int kh = 0; kh < 2; ++kh) {
            const int ks = (kh << 2) + l4;
            short8 a[4], b[4];
#pragma unroll
            for (int m = 0; m < 4; ++m) {
                const int R = wr + (m << 4) + l15;
                a[m] = *(const short8*)((const char*)Asl + (R << 7) + ((ks ^ (R & 7)) << 4));
            }
#pragma unroll
            for (int n = 0; n < 4; ++n) {
                const int R = wc + (n << 4) + l15;
                b[n] = *(const short8*)((const char*)Bsl + (R << 7) + ((ks ^ (R & 7)) << 4));
            }
#pragma unroll
            for (int m = 0; m < 4; ++m)
#pragma unroll
                for (int n = 0; n < 4; ++n)
                    acc[m][n] = __builtin_amdgcn_mfma_f32_16x16x32_bf16(
                        a[m], b[n], acc[m][n], 0, 0, 0);
        }
    }

#pragma unroll
    for (int m = 0; m < 4; ++m) {
        const int row0 = m0 + wr + (m << 4) + (l4 << 2);
#pragma unroll
        for (int n = 0; n < 4; ++n) {
            const int col = n0 + wc + (n << 4) + l15;
#pragma unroll
            for (int r2 = 0; r2 < 4; ++r2) {
                if (OUTBF) {
                    Cb[(size_t)dir * c_dir_off + (size_t)(row0 + r2) * ldc + col] =
                        bf16bits(acc[m][n][r2]);
                } else {
                    float v = acc[m][n][r2];
                    if (addsrc) v += addsrc[(size_t)(row0 + r2) * add_ld + col];
                    Cf[(size_t)dir * c_dir_off + (size_t)(row0 + r2) * ldc + col] = v;
                }
            }
        }
    }
}

// ---------------------------------------------------------------------------
// Sliding-window depthwise conv(4) + SiLU over bf16 zx columns. CTR=32 rows
// per tile -> 2304 blocks for latency hiding via occupancy.
// ---------------------------------------------------------------------------
__global__ __launch_bounds__(256) void conv_kernel(
    const u16* __restrict__ zx,
    const float* __restrict__ cw0, const float* __restrict__ cw1,
    const float* __restrict__ cb0, const float* __restrict__ cb1,
    u16* __restrict__ xs, u16* __restrict__ Bbf, u16* __restrict__ Cbf)
{
    const int dir = blockIdx.z;
    const int c   = blockIdx.x * 256 + threadIdx.x;     // channel 0..2303
    const int b   = blockIdx.y >> 6;
    const int r0  = (blockIdx.y & (NTILE - 1)) * CTR;

    const float* __restrict__ cw = dir ? cw1 : cw0;
    const float w0 = cw[c * 4 + 0], w1 = cw[c * 4 + 1];
    const float w2 = cw[c * 4 + 2], w3 = cw[c * 4 + 3];
    const float bias = (dir ? cb1 : cb0)[c];

    const u16* __restrict__ zcol = zx + (size_t)dir * M_ROWS * DPROJP
        + (size_t)(b * L_SEQ) * DPROJP + DINNER + c;
    const size_t obase = (size_t)(dir * M_ROWS + b * L_SEQ);

    auto emit = [&](int l, float acc) {
        const float s = acc / (1.f + expf(-acc));
        const size_t orow = obase + l;
        if (c < DINNER)            xs[orow * DINNER + c] = bf16bits(s);
        else if (c < DINNER + NST) Bbf[orow * NST + (c - DINNER)] = bf16bits(s);
        else                       Cbf[orow * NST + (c - DINNER - NST)] = bf16bits(s);
    };

    if (dir == 0) {
        float h0 = (r0 - 3 >= 0) ? bits2f(zcol[(size_t)(r0 - 3) * DPROJP]) : 0.f;
        float h1 = (r0 - 2 >= 0) ? bits2f(zcol[(size_t)(r0 - 2) * DPROJP]) : 0.f;
        float h2 = (r0 - 1 >= 0) ? bits2f(zcol[(size_t)(r0 - 1) * DPROJP]) : 0.f;
#pragma unroll 8
        for (int l = r0; l < r0 + CTR; ++l) {
            const float zl = bits2f(zcol[(size_t)l * DPROJP]);
            float acc = bias;
            acc = fmaf(w0, h0, acc);
            acc = fmaf(w1, h1, acc);
            acc = fmaf(w2, h2, acc);
            acc = fmaf(w3, zl, acc);
            emit(l, acc);
            h0 = h1; h1 = h2; h2 = zl;
        }
    } else {
        const int le = r0 + CTR - 1;
        float h1 = (le + 1 < L_SEQ) ? bits2f(zcol[(size_t)(le + 1) * DPROJP]) : 0.f;
        float h2 = (le + 2 < L_SEQ) ? bits2f(zcol[(size_t)(le + 2) * DPROJP]) : 0.f;
        float h3 = (le + 3 < L_SEQ) ? bits2f(zcol[(size_t)(le + 3) * DPROJP]) : 0.f;
#pragma unroll 8
        for (int l = le; l >= r0; --l) {
            const float zl = bits2f(zcol[(size_t)l * DPROJP]);
            float acc = bias;
            acc = fmaf(w3, zl, acc);
            acc = fmaf(w2, h1, acc);
            acc = fmaf(w1, h2, acc);
            acc = fmaf(w0, h3, acc);
            emit(l, acc);
            h3 = h2; h2 = h1; h1 = zl;
        }
    }
}

// ---------------------------------------------------------------------------
// Exact-f32 dt as LDS-staged block GEMV. dta in BASE-2 log-decay.
// ---------------------------------------------------------------------------
__global__ __launch_bounds__(512) void dt_kernel(
    const float* __restrict__ x,
    const float* __restrict__ inw0, const float* __restrict__ inw1,
    const float* __restrict__ dtbias0, const float* __restrict__ dtbias1,
    const float* __restrict__ Alog0, const float* __restrict__ Alog1,
    float* __restrict__ dtb, float* __restrict__ dta)
{
    const int dir = blockIdx.y;
    const int r0  = blockIdx.x * 64;
    const int tid = threadIdx.x;

    __shared__ float wT[512 * 32];   // [k4][h][j], 64 KB
    __shared__ float sbias[NH], sa[NH];

    const float* __restrict__ w = (dir ? inw1 : inw0) + (size_t)(DINNER + CONVDIM) * 512;
    for (int i = tid; i < 4096; i += 512) {
        const int flat = i * 4;
        const int h = flat >> 9;
        const int k = flat & 511;
        const float4 v = *(const float4*)(w + flat);
        *(float4*)&wT[(k >> 2) * 128 + h * 4] = v;
    }
    if (tid < NH) {
        sbias[tid] = (dir ? dtbias1 : dtbias0)[tid];
        sa[tid] = -expf((dir ? Alog1 : Alog0)[tid]) * LOG2E;
    }
    __syncthreads();

    const int h  = tid & 31;
    const int rr = tid >> 5;
    const float bias = sbias[h];
    const float a = sa[h];

    for (int rp = 0; rp < 64; rp += 16) {
        const int row = r0 + rp + rr;
        const float4* __restrict__ xr = (const float4*)(x + (size_t)row * 512);
        float4 s4 = make_float4(0.f, 0.f, 0.f, 0.f);
#pragma unroll 8
        for (int k4 = 0; k4 < 128; ++k4) {
            const float4 xv = xr[k4];
            const float4 wv = *(const float4*)&wT[k4 * 128 + h * 4];
            s4.x = fmaf(xv.x, wv.x, s4.x);
            s4.y = fmaf(xv.y, wv.y, s4.y);
            s4.z = fmaf(xv.z, wv.z, s4.z);
            s4.w = fmaf(xv.w, wv.w, s4.w);
        }
        const float v = (s4.x + s4.y) + (s4.z + s4.w) + bias;
        const float sp = (v > 20.f) ? v : log1pf(expf(v));
        const size_t orow = (size_t)(dir * M_ROWS + row);
        dtb[orow * NH + h] = sp;
        dta[orow * NH + h] = sp * a;         // base-2 log-decay
    }
}

// ---------------------------------------------------------------------------
// S_raw = C @ B^T per (dir,b,chunk) — head-independent, computed once.
// ---------------------------------------------------------------------------
__global__ __launch_bounds__(256) void sraw_kernel(
    const u16* __restrict__ Bbf, const u16* __restrict__ Cbf,
    u16* __restrict__ Sraw)
{
    const int bx  = blockIdx.x;            // db*NCH + ch
    const int ch  = bx & (NCH - 1);
    const int db  = bx >> 4;               // dir*2+b
    const int dir = db >> 1, bb = db & 1;
    const int tid = threadIdx.x;
    const int wid = tid >> 6;
    const int lane = tid & 63;
    const int l15 = lane & 15, l4 = lane >> 4;
    const int t0  = ch * CHUNK;
    const size_t dbase = (size_t)(dir * M_ROWS + bb * L_SEQ);
    const size_t base  = ((size_t)bx) << 14;     // *128*128

    auto lidx = [&](int t) { return dir ? (L_SEQ - 1 - t) : t; };

    f32x4 accs[2][8];
#pragma unroll
    for (int m = 0; m < 2; ++m)
#pragma unroll
        for (int j = 0; j < 8; ++j) accs[m][j] = (f32x4)0.f;

    short8 af[2][4];
#pragma unroll
    for (int m = 0; m < 2; ++m) {
        const size_t crow = dbase + lidx(t0 + wid * 32 + m * 16 + l15);
#pragma unroll
        for (int kk = 0; kk < 4; ++kk)
            af[m][kk] = *(const short8*)(Cbf + crow * NST + kk * 32 + l4 * 8);
    }
#pragma unroll
    for (int j = 0; j < 8; ++j) {
        const size_t brow = dbase + lidx(t0 + j * 16 + l15);
        short8 bf_[4];
#pragma unroll
        for (int kk = 0; kk < 4; ++kk)
            bf_[kk] = *(const short8*)(Bbf + brow * NST + kk * 32 + l4 * 8);
#pragma unroll
        for (int m = 0; m < 2; ++m)
#pragma unroll
            for (int kk = 0; kk < 4; ++kk)
                accs[m][j] = __builtin_amdgcn_mfma_f32_16x16x32_bf16(
                    af[m][kk], bf_[kk], accs[m][j], 0, 0, 0);
    }

#pragma unroll
    for (int m = 0; m < 2; ++m)
#pragma unroll
        for (int j = 0; j < 8; ++j)
#pragma unroll
            for (int r = 0; r < 4; ++r) {
                const int t = wid * 32 + m * 16 + l4 * 4 + r;
                const int s = j * 16 + l15;
                Sraw[base + (size_t)t * 128 + s] = bf16bits(accs[m][j][r]);
            }
}

// ---------------------------------------------------------------------------
// SSD state pass: cumA prefix (-> betac) + chunk state = X~T @ (r∘B)^T.
// ---------------------------------------------------------------------------
__global__ __launch_bounds__(256) void ssd_state_kernel(
    const u16* __restrict__ xs, const u16* __restrict__ Bbf,
    const float* __restrict__ dtb, const float* __restrict__ dta,
    u16* __restrict__ stateC, float* __restrict__ betac)
{
    const int bx  = blockIdx.x;
    const int ch  = bx & (NCH - 1);
    const int bh  = bx >> 4;
    const int dir = bh >> 6;
    const int bb  = (bh >> 5) & 1;
    const int h   = bh & 31;
    const int tid = threadIdx.x;
    const int wid = tid >> 6;
    const int lane = tid & 63;
    const int l15 = lane & 15;
    const int l4  = lane >> 4;
    const int t0  = ch * CHUNK;
    const size_t dbase = (size_t)(dir * M_ROWS + bb * L_SEQ);

    __shared__ u16 XT[64 * 128];
    __shared__ u16 WBT[64 * 128];
    __shared__ float scum[CHUNK];
    __shared__ float sdt[CHUNK];

    auto lidx = [&](int t) { return dir ? (L_SEQ - 1 - t) : t; };

    // phase A: dt loads + base-2 cumA prefix-sum (wave 0)
    if (tid >= 128) {
        const int s = tid - 128;
        sdt[s] = dtb[(dbase + lidx(t0 + s)) * NH + h];
    }
    if (wid == 0) {
        float a0 = dta[(dbase + lidx(t0 + lane)) * NH + h];
        float a1 = dta[(dbase + lidx(t0 + 64 + lane)) * NH + h];
#pragma unroll
        for (int off = 1; off < 64; off <<= 1) {
            const float u0 = __shfl_up(a0, off);
            const float u1 = __shfl_up(a1, off);
            if (lane >= off) { a0 += u0; a1 += u1; }
        }
        a1 += __shfl(a0, 63);
        scum[lane] = a0; scum[64 + lane] = a1;
        betac[(size_t)bh * L_SEQ + t0 + lane] = a0;
        betac[(size_t)bh * L_SEQ + t0 + 64 + lane] = a1;
    }
    __syncthreads();

    // build X~T once
    {
        const int s = tid >> 1;
        const float dts = sdt[s];
        const size_t grow = dbase + lidx(t0 + s);
        const int p0 = (tid & 1) * 32;
        const u16* __restrict__ xp = xs + grow * DINNER + h * 64 + p0;
#pragma unroll
        for (int q = 0; q < 4; ++q) {
            short8 v = *(const short8*)(xp + q * 8);
#pragma unroll
            for (int j = 0; j < 8; ++j) {
                const int p = p0 + q * 8 + j;
                XT[sidx(p, s)] = bf16bits(dts * bits2f((u16)v[j]));
            }
        }
    }

    const size_t sbase = ((size_t)bh * NCH + ch) * 8192;

#pragma unroll
    for (int half = 0; half < 2; ++half) {
        const int noff = half * 64;
        {
            const int s = tid >> 1;
            const float rs = exp2f(scum[CHUNK - 1] - scum[s]);
            const size_t grow = dbase + lidx(t0 + s);
            const int n0l = (tid & 1) * 32;
            const u16* __restrict__ bp = Bbf + grow * NST + noff + n0l;
#pragma unroll
            for (int q = 0; q < 4; ++q) {
                short8 v = *(const short8*)(bp + q * 8);
#pragma unroll
                for (int j = 0; j < 8; ++j) {
                    const int nl = n0l + q * 8 + j;
                    WBT[sidx(nl, s)] = bf16bits(rs * bits2f((u16)v[j]));
                }
            }
        }
        __syncthreads();

        {
            const int pw = wid * 16;
            const int prow = pw + l15;
            short8 xa[4];
#pragma unroll
            for (int kk = 0; kk < 4; ++kk)
                xa[kk] = *(const short8*)(XT + sslot(prow, kk * 4 + l4));
#pragma unroll
            for (int jn = 0; jn < 4; ++jn) {
                const int nl = jn * 16 + l15;
                f32x4 acc = (f32x4)0.f;
#pragma unroll
                for (int kk = 0; kk < 4; ++kk) {
                    const short8 wb = *(const short8*)(WBT + sslot(nl, kk * 4 + l4));
                    acc = __builtin_amdgcn_mfma_f32_16x16x32_bf16(xa[kk], wb, acc, 0, 0, 0);
                }
#pragma unroll
                for (int r = 0; r < 4; ++r)
                    stateC[sbase + (size_t)(pw + l4 * 4 + r) * 128 + noff + jn * 16 + l15] =
                        bf16bits(acc[r]);
            }
        }
        __syncthreads();
    }
}

// ---------------------------------------------------------------------------
// Combine: sequential over NCH chunks per bh (in place on stateC).
// ---------------------------------------------------------------------------
__global__ __launch_bounds__(512) void combine_kernel(
    u16* __restrict__ stateC, const float* __restrict__ betac)
{
    const int bh  = blockIdx.x;
    const int tid = threadIdx.x;

    float hrun[16];
#pragma unroll
    for (int j = 0; j < 16; ++j) hrun[j] = 0.f;

    for (int s = 0; s < NCH; ++s) {
        const size_t off = ((size_t)bh * NCH + s) * 8192 + (size_t)tid * 16;
        float c[16];
#pragma unroll
        for (int j = 0; j < 16; ++j) c[j] = bits2f(stateC[off + j]);
#pragma unroll
        for (int j = 0; j < 16; ++j) stateC[off + j] = bf16bits(hrun[j]);
        const float alpha = exp2f(betac[(size_t)bh * L_SEQ + s * CHUNK + (CHUNK - 1)]);
#pragma unroll
        for (int j = 0; j < 16; ++j) hrun[j] = fmaf(alpha, hrun[j], c[j]);
    }
}

// ---------------------------------------------------------------------------
// SSD output pass, register-direct P~: no PT LDS buffer (17.5 KB LDS), one
// barrier. Lane loads its Sraw MFMA fragment from global (L2-hot), applies
// Gamma=2^(ct-cs) in-register. Y = P~@X~^T + (2^cumA ∘ C)@h_in^T + D*x -> yb.
// ---------------------------------------------------------------------------
__global__ __launch_bounds__(256) void ssd_out_kernel(
    const u16* __restrict__ xs, const u16* __restrict__ Cbf,
    const u16* __restrict__ Sraw, const u16* __restrict__ stateC,
    const float* __restrict__ dtb, const float* __restrict__ betac,
    const float* __restrict__ D0, const float* __restrict__ D1,
    u16* __restrict__ yb)
{
    const int bx  = blockIdx.x;
    const int ch  = bx & (NCH - 1);
    const int bh  = bx >> 4;
    const int dir = bh >> 6;
    const int bb  = (bh >> 5) & 1;
    const int h   = bh & 31;
    const int tid = threadIdx.x;
    const int wid = tid >> 6;
    const int lane = tid & 63;
    const int l15 = lane & 15;
    const int l4  = lane >> 4;
    const int t0  = ch * CHUNK;
    const size_t dbase = (size_t)(dir * M_ROWS + bb * L_SEQ);
    const float Dv = (dir ? D1 : D0)[h];

    __shared__ u16 XT[64 * 128];
    __shared__ float scum[CHUNK];
    __shared__ float sdt[CHUNK];

    auto lidx = [&](int t) { return dir ? (L_SEQ - 1 - t) : t; };

    // phase A: reload base-2 cumA (betac) + dt
    if (tid < 128) {
        scum[tid] = betac[(size_t)bh * L_SEQ + t0 + tid];
    } else {
        const int s = tid - 128;
        sdt[s] = dtb[(dbase + lidx(t0 + s)) * NH + h];
    }
    __syncthreads();

    // build X~T
    {
        const int s = tid >> 1;
        const float dts = sdt[s];
        const size_t grow = dbase + lidx(t0 + s);
        const int p0 = (tid & 1) * 32;
        const u16* __restrict__ xp = xs + grow * DINNER + h * 64 + p0;
#pragma unroll
        for (int q = 0; q < 4; ++q) {
            short8 v = *(const short8*)(xp + q * 8);
#pragma unroll
            for (int j = 0; j < 8; ++j) {
                const int p = p0 + q * 8 + j;
                XT[sidx(p, s)] = bf16bits(dts * bits2f((u16)v[j]));
            }
        }
    }
    __syncthreads();

    u16* __restrict__ ybase = yb + (size_t)dir * M_ROWS * DINNER;
    const size_t sbase = ((size_t)bh * NCH + ch) * 8192;
    const size_t sbraw = ((size_t)(((bh >> 5) * NCH) + ch)) << 14;

    // wave owns t-rows [wid*32, wid*32+32), two m-groups of 16
#pragma unroll
    for (int m = 0; m < 2; ++m) {
        const int trow = wid * 32 + m * 16 + l15;
        const float ct = scum[trow];
        const float gs = exp2f(ct);
        const size_t crow = dbase + lidx(t0 + trow);

        short8 pa[4], ga[4];
#pragma unroll
        for (int kk = 0; kk < 4; ++kk) {
            const int sb = kk * 32 + l4 * 8;
            const short8 v = *(const short8*)(Sraw + sbraw + (size_t)trow * 128 + sb);
            const float4 cs0 = *(const float4*)&scum[sb];
            const float4 cs1 = *(const float4*)&scum[sb + 4];
            const float cs[8] = {cs0.x, cs0.y, cs0.z, cs0.w, cs1.x, cs1.y, cs1.z, cs1.w};
            short8 o;
#pragma unroll
            for (int j = 0; j < 8; ++j) {
                const float g = ((sb + j) <= trow) ? exp2f(ct - cs[j]) : 0.f;
                o[j] = (short)bf16bits(bits2f((u16)v[j]) * g);
            }
            pa[kk] = o;

            const short8 c8 = *(const short8*)(Cbf + crow * NST + sb);
            short8 og;
#pragma unroll
            for (int j = 0; j < 8; ++j)
                og[j] = (short)bf16bits(bits2f((u16)c8[j]) * gs);
            ga[kk] = og;
        }

#pragma unroll
        for (int jp = 0; jp < 4; ++jp) {
            const int prow = jp * 16 + l15;
            short8 xb[4], hb[4];
#pragma unroll
            for (int kk = 0; kk < 4; ++kk) {
                xb[kk] = *(const short8*)(XT + sslot(prow, kk * 4 + l4));
                hb[kk] = *(const short8*)(stateC + sbase + (size_t)prow * 128 + kk * 32 + l4 * 8);
            }
            f32x4 acc = (f32x4)0.f;
#pragma unroll
            for (int kk = 0; kk < 4; ++kk)
                acc = __builtin_amdgcn_mfma_f32_16x16x32_bf16(
                    pa[kk], xb[kk], acc, 0, 0, 0);
#pragma unroll
            for (int kk = 0; kk < 4; ++kk)
                acc = __builtin_amdgcn_mfma_f32_16x16x32_bf16(
                    ga[kk], hb[kk], acc, 0, 0, 0);
#pragma unroll
            for (int r = 0; r < 4; ++r) {
                const int t = wid * 32 + m * 16 + l4 * 4 + r;
                const int lg = lidx(t0 + t);
                const float xv = bits2f(xs[(dbase + lg) * DINNER + h * 64 + prow]);
                ybase[(size_t)(bb * L_SEQ + lg) * DINNER + h * 64 + prow] =
                    bf16bits(acc[r] + Dv * xv);
            }
        }
    }
}

// ---------------------------------------------------------------------------
// gate + RMSNorm: reads bf16 z + bf16 y, writes bf16 into zx cols [2048,4096).
// ---------------------------------------------------------------------------
__global__ __launch_bounds__(256) void gatenorm_kernel(
    u16* __restrict__ zx, const u16* __restrict__ yb,
    const float* __restrict__ nw0, const float* __restrict__ nw1)
{
    const int dir = blockIdx.y;
    const int row = blockIdx.x;
    const float* __restrict__ nw = dir ? nw1 : nw0;
    u16* __restrict__ zrow = zx + (size_t)dir * M_ROWS * DPROJP + (size_t)row * DPROJP;
    const u16* __restrict__ yrow = yb + (size_t)dir * M_ROWS * DINNER + (size_t)row * DINNER;
    const int tid = threadIdx.x;
    const int c0 = tid * 8;

    const short8 zv = *(const short8*)(zrow + c0);
    const short8 yv8 = *(const short8*)(yrow + c0);

    float g[8];
#pragma unroll
    for (int j = 0; j < 8; ++j) {
        const float z = bits2f((u16)zv[j]);
        g[j] = bits2f((u16)yv8[j]) * (z / (1.f + expf(-z)));
    }

    float ss = 0.f;
#pragma unroll
    for (int j = 0; j < 8; ++j) ss = fmaf(g[j], g[j], ss);
#pragma unroll
    for (int off = 1; off < 64; off <<= 1) ss += __shfl_xor(ss, off);
    __shared__ float red[4];
    if ((tid & 63) == 0) red[tid >> 6] = ss;
    __syncthreads();
    const float total = red[0] + red[1] + red[2] + red[3];
    const float rs = rsqrtf(total * (1.f / (float)DINNER) + 1e-5f);

    const float4 w0 = *(const float4*)(nw + c0);
    const float4 w1 = *(const float4*)(nw + c0 + 4);
    const float wv[8] = {w0.x, w0.y, w0.z, w0.w, w1.x, w1.y, w1.z, w1.w};
    short8 outv;
#pragma unroll
    for (int j = 0; j < 8; ++j) outv[j] = (short)bf16bits(g[j] * rs * wv[j]);
    *(short8*)(zrow + DINNER + c0) = outv;
}

// ---------------------------------------------------------------------------
extern "C" void kernel_launch(void* const* d_in, const int* in_sizes, int n_in,
                              void* d_out, int out_size, void* d_ws, size_t ws_size,
                              hipStream_t stream)
{
    (void)in_sizes; (void)n_in; (void)out_size; (void)ws_size;
    const float* x        = (const float*)d_in[0];
    const float* f_in_w   = (const float*)d_in[1];
    const float* f_conv_w = (const float*)d_in[2];
    const float* f_conv_b = (const float*)d_in[3];
    const float* f_dtbias = (const float*)d_in[4];
    const float* f_Alog   = (const float*)d_in[5];
    const float* f_D      = (const float*)d_in[6];
    const float* f_nw     = (const float*)d_in[7];
    const float* f_out_w  = (const float*)d_in[8];
    const float* b_in_w   = (const float*)d_in[9];
    const float* b_conv_w = (const float*)d_in[10];
    const float* b_conv_b = (const float*)d_in[11];
    const float* b_dtbias = (const float*)d_in[12];
    const float* b_Alog   = (const float*)d_in[13];
    const float* b_D      = (const float*)d_in[14];
    const float* b_nw     = (const float*)d_in[15];
    const float* b_out_w  = (const float*)d_in[16];

    // Workspace (~201 MB)
    u16* zx  = (u16*)d_ws;
    u16* xs  = zx + (size_t)2 * M_ROWS * DPROJP;
    u16* Bbf = xs + (size_t)2 * M_ROWS * DINNER;
    u16* Cbf = Bbf + (size_t)2 * M_ROWS * NST;
    float* dtb = (float*)(Cbf + (size_t)2 * M_ROWS * NST);
    float* dta = dtb + (size_t)2 * M_ROWS * NH;
    u16* stateC = (u16*)(dta + (size_t)2 * M_ROWS * NH);
    float* betac = (float*)(stateC + (size_t)128 * NCH * 8192);
    u16* yb = (u16*)(betac + (size_t)128 * L_SEQ);
    u16* x_bf   = yb + (size_t)2 * M_ROWS * DINNER;
    u16* w_in_bf  = x_bf + (size_t)M_ROWS * 512;
    u16* w_out_bf = w_in_bf + (size_t)2 * DPROJP * 512;
    u16* Sraw = w_out_bf + (size_t)2 * 512 * DINNER;

    // 0) dtype conversions
    cvt_x_kernel<<<dim3(M_ROWS * 512 / 1024), 256, 0, stream>>>(x, x_bf);
    cvt_win_kernel<<<dim3(DPROJP * 512 / 1024, 2), 256, 0, stream>>>(f_in_w, b_in_w, w_in_bf);
    cvt_wout_kernel<<<dim3(512 * DINNER / 1024, 2), 256, 0, stream>>>(f_out_w, b_out_w, w_out_bf);

    // 1) in_proj (MFMA, bf16 out): zx[dir] = x @ in_w[dir]^T
    gemm_mfma<true><<<dim3(DPROJP / 128, M_ROWS / 128, 2), 256, 0, stream>>>(
        x_bf, x_bf, 512,
        w_in_bf, (long long)DPROJP * 512,
        nullptr, zx, (long long)M_ROWS * DPROJP, DPROJP,
        nullptr, 0, 512);

    // 2a) sliding-window conv + SiLU (bf16 in/out), CTR=32
    conv_kernel<<<dim3(CONVDIM / 256, 2 * NTILE, 2), 256, 0, stream>>>(
        zx, f_conv_w, b_conv_w, f_conv_b, b_conv_b, xs, Bbf, Cbf);

    // 2b) exact-f32 dt / base-2 log-decay (LDS-staged GEMV)
    dt_kernel<<<dim3(M_ROWS / 64, 2), 512, 0, stream>>>(
        x, f_in_w, b_in_w, f_dtbias, b_dtbias, f_Alog, b_Alog, dtb, dta);

    // 3a) head-independent S_raw = C @ B^T (once per dir,b,chunk)
    sraw_kernel<<<dim3(4 * NCH), 256, 0, stream>>>(Bbf, Cbf, Sraw);

    // 3b) state pass (cumA -> betac, chunk states -> stateC)
    ssd_state_kernel<<<dim3(128 * NCH), 256, 0, stream>>>(
        xs, Bbf, dtb, dta, stateC, betac);

    // 3c) combine chunk states (stateC becomes h_in per chunk)
    combine_kernel<<<dim3(128), 512, 0, stream>>>(stateC, betac);

    // 3d) output pass: local Y + fused correction + D-skip -> yb (bf16)
    ssd_out_kernel<<<dim3(128 * NCH), 256, 0, stream>>>(
        xs, Cbf, Sraw, stateC, dtb, betac, f_D, b_D, yb);

    // 4) gate + RMSNorm: bf16 result into zx cols [2048,4096)
    gatenorm_kernel<<<dim3(M_ROWS, 2), 256, 0, stream>>>(zx, yb, f_nw, b_nw);

    // 5) out_proj (MFMA, bf16 A from zx) + residual + concat
    gemm_mfma<false><<<dim3(512 / 128, M_ROWS / 128, 2), 256, 0, stream>>>(
        zx + DINNER, zx + (size_t)M_ROWS * DPROJP + DINNER, DPROJP,
        w_out_bf, (long long)512 * DINNER,
        (float*)d_out, nullptr, 512, 1024,
        x, 512, DINNER);
}

// Round 15
// 303.889 us; speedup vs baseline: 2.6334x; 1.0214x over previous
//
#include <hip/hip_runtime.h>
#include <hip/hip_bf16.h>
#include <math.h>

#define L_SEQ   2048
#define M_ROWS  4096            // B*L
#define DPROJ   4384
#define DPROJP  4480            // padded to 35*128 for MFMA GEMM
#define DINNER  2048
#define CONVDIM 2304
#define NST     128
#define NH      32
#define CHUNK   128             // SSD chunk length
#define NCH     16              // L_SEQ / CHUNK
#define CTR     32              // conv rows per tile
#define NTILE   (L_SEQ / CTR)   // 64
#define LOG2E   1.4426950408889634f

typedef __attribute__((ext_vector_type(8))) short short8;
typedef __attribute__((ext_vector_type(4))) float f32x4;
typedef unsigned short u16;

static __device__ __forceinline__ u16 bf16bits(float v) {
    __hip_bfloat16 t = __float2bfloat16(v);
    return *(u16*)&t;
}
static __device__ __forceinline__ float bits2f(u16 u) {
    return __uint_as_float((unsigned)u << 16);
}
// element index into a [rows][128] bf16 LDS buffer with 16B-slot XOR swizzle
static __device__ __forceinline__ int sidx(int row, int s) {
    return (row << 7) + ((((s >> 3) ^ (row & 7)) << 3) | (s & 7));
}
static __device__ __forceinline__ int sslot(int row, int ks) {  // ks = 16B slot 0..15
    return (row << 7) + ((ks ^ (row & 7)) << 3);
}
// async 16B global->LDS (wave-uniform LDS base + lane*16; source pre-swizzled)
static __device__ __forceinline__ void gload16(const void* g, void* l) {
    __builtin_amdgcn_global_load_lds(
        (const __attribute__((address_space(1))) void*)g,
        (__attribute__((address_space(3))) void*)l, 16, 0, 0);
}

// ---------------------------------------------------------------------------
// f32 -> bf16 conversion pre-passes
// ---------------------------------------------------------------------------
__global__ __launch_bounds__(256) void cvt_x_kernel(
    const float* __restrict__ x, u16* __restrict__ xbf)
{
    const int i = (blockIdx.x * 256 + threadIdx.x) * 4;
    const float4 v = *(const float4*)(x + i);
    xbf[i + 0] = bf16bits(v.x);
    xbf[i + 1] = bf16bits(v.y);
    xbf[i + 2] = bf16bits(v.z);
    xbf[i + 3] = bf16bits(v.w);
}

__global__ __launch_bounds__(256) void cvt_win_kernel(
    const float* __restrict__ w0, const float* __restrict__ w1,
    u16* __restrict__ dst)
{
    const int dir = blockIdx.y;
    const float* __restrict__ w = dir ? w1 : w0;
    u16* __restrict__ d = dst + (size_t)dir * DPROJP * 512;
    const int i = (blockIdx.x * 256 + threadIdx.x) * 4;
    const int row = i >> 9;
    if (row < DPROJ) {
        const float4 v = *(const float4*)(w + i);
        d[i + 0] = bf16bits(v.x);
        d[i + 1] = bf16bits(v.y);
        d[i + 2] = bf16bits(v.z);
        d[i + 3] = bf16bits(v.w);
    } else {
        d[i + 0] = 0; d[i + 1] = 0; d[i + 2] = 0; d[i + 3] = 0;
    }
}

__global__ __launch_bounds__(256) void cvt_wout_kernel(
    const float* __restrict__ w0, const float* __restrict__ w1,
    u16* __restrict__ dst)
{
    const int dir = blockIdx.y;
    const float* __restrict__ w = dir ? w1 : w0;
    u16* __restrict__ d = dst + (size_t)dir * 512 * DINNER;
    const int i = (blockIdx.x * 256 + threadIdx.x) * 4;
    const float4 v = *(const float4*)(w + i);
    d[i + 0] = bf16bits(v.x);
    d[i + 1] = bf16bits(v.y);
    d[i + 2] = bf16bits(v.z);
    d[i + 3] = bf16bits(v.w);
}

// ---------------------------------------------------------------------------
// MFMA bf16 GEMM: C[M][N] = A[M][K] @ B[N][K]^T. global_load_lds staging
// (linear LDS dest, inverse-swizzled source), XCD-aware block swizzle.
// ---------------------------------------------------------------------------
template<bool OUTBF>
__global__ __launch_bounds__(256) void gemm_mfma(
    const u16* __restrict__ A0, const u16* __restrict__ A1, int lda,
    const u16* __restrict__ Bw, long long b_dir_off,
    float* __restrict__ Cf, u16* __restrict__ Cb, long long c_dir_off, int ldc,
    const float* __restrict__ addsrc, int add_ld,
    int K)
{
    const int dir = blockIdx.z;
    const int nwg  = gridDim.x * gridDim.y;
    const int flat = blockIdx.y * gridDim.x + blockIdx.x;
    const int q = nwg >> 3, r = nwg & 7;
    const int xcd = flat & 7, idx = flat >> 3;
    const int wg = (xcd < r) ? xcd * (q + 1) + idx
                             : r * (q + 1) + (xcd - r) * q + idx;
    const int m0 = (wg / gridDim.x) * 128;
    const int n0 = (wg % gridDim.x) * 128;

    const u16* __restrict__ A = dir ? A1 : A0;
    const u16* __restrict__ B = Bw + (size_t)dir * b_dir_off;

    __shared__ u16 Asl[128 * 64];
    __shared__ u16 Bsl[128 * 64];

    const int tid  = threadIdx.x;
    const int lane = tid & 63;
    const int wid  = tid >> 6;
    const int wr   = (wid >> 1) << 6;
    const int wc   = (wid & 1) << 6;
    const int l15  = lane & 15;
    const int l4   = lane >> 4;

    f32x4 acc[4][4];
#pragma unroll
    for (int m = 0; m < 4; ++m)
#pragma unroll
        for (int n = 0; n < 4; ++n) acc[m][n] = (f32x4)0.f;

    for (int k0 = 0; k0 < K; k0 += 64) {
        __syncthreads();
#pragma unroll
        for (int i = 0; i < 4; ++i) {
            const int c    = tid + (i << 8);
            const int row  = c >> 3;
            const int scol = ((c & 7) ^ (row & 7)) << 3;
            gload16(A + (size_t)(m0 + row) * lda + k0 + scol, (char*)Asl + (c << 4));
            gload16(B + (size_t)(n0 + row) * K   + k0 + scol, (char*)Bsl + (c << 4));
        }
        __syncthreads();

#pragma unroll
        for (int kh = 0; kh < 2; ++kh) {
            const int ks = (kh << 2) + l4;
            short8 a[4], b[4];
#pragma unroll
            for (int m = 0; m < 4; ++m) {
                const int R = wr + (m << 4) + l15;
                a[m] = *(const short8*)((const char*)Asl + (R << 7) + ((ks ^ (R & 7)) << 4));
            }
#pragma unroll
            for (int n = 0; n < 4; ++n) {
                const int R = wc + (n << 4) + l15;
                b[n] = *(const short8*)((const char*)Bsl + (R << 7) + ((ks ^ (R & 7)) << 4));
            }
#pragma unroll
            for (int m = 0; m < 4; ++m)
#pragma unroll
                for (int n = 0; n < 4; ++n)
                    acc[m][n] = __builtin_amdgcn_mfma_f32_16x16x32_bf16(
                        a[m], b[n], acc[m][n], 0, 0, 0);
        }
    }

#pragma unroll
    for (int m = 0; m < 4; ++m) {
        const int row0 = m0 + wr + (m << 4) + (l4 << 2);
#pragma unroll
        for (int n = 0; n < 4; ++n) {
            const int col = n0 + wc + (n << 4) + l15;
#pragma unroll
            for (int r2 = 0; r2 < 4; ++r2) {
                if (OUTBF) {
                    Cb[(size_t)dir * c_dir_off + (size_t)(row0 + r2) * ldc + col] =
                        bf16bits(acc[m][n][r2]);
                } else {
                    float v = acc[m][n][r2];
                    if (addsrc) v += addsrc[(size_t)(row0 + r2) * add_ld + col];
                    Cf[(size_t)dir * c_dir_off + (size_t)(row0 + r2) * ldc + col] = v;
                }
            }
        }
    }
}

// ---------------------------------------------------------------------------
// Sliding-window depthwise conv(4) + SiLU over bf16 zx columns. CTR=32.
// ---------------------------------------------------------------------------
__global__ __launch_bounds__(256) void conv_kernel(
    const u16* __restrict__ zx,
    const float* __restrict__ cw0, const float* __restrict__ cw1,
    const float* __restrict__ cb0, const float* __restrict__ cb1,
    u16* __restrict__ xs, u16* __restrict__ Bbf, u16* __restrict__ Cbf)
{
    const int dir = blockIdx.z;
    const int c   = blockIdx.x * 256 + threadIdx.x;     // channel 0..2303
    const int b   = blockIdx.y >> 6;
    const int r0  = (blockIdx.y & (NTILE - 1)) * CTR;

    const float* __restrict__ cw = dir ? cw1 : cw0;
    const float w0 = cw[c * 4 + 0], w1 = cw[c * 4 + 1];
    const float w2 = cw[c * 4 + 2], w3 = cw[c * 4 + 3];
    const float bias = (dir ? cb1 : cb0)[c];

    const u16* __restrict__ zcol = zx + (size_t)dir * M_ROWS * DPROJP
        + (size_t)(b * L_SEQ) * DPROJP + DINNER + c;
    const size_t obase = (size_t)(dir * M_ROWS + b * L_SEQ);

    auto emit = [&](int l, float acc) {
        const float s = acc / (1.f + expf(-acc));
        const size_t orow = obase + l;
        if (c < DINNER)            xs[orow * DINNER + c] = bf16bits(s);
        else if (c < DINNER + NST) Bbf[orow * NST + (c - DINNER)] = bf16bits(s);
        else                       Cbf[orow * NST + (c - DINNER - NST)] = bf16bits(s);
    };

    if (dir == 0) {
        float h0 = (r0 - 3 >= 0) ? bits2f(zcol[(size_t)(r0 - 3) * DPROJP]) : 0.f;
        float h1 = (r0 - 2 >= 0) ? bits2f(zcol[(size_t)(r0 - 2) * DPROJP]) : 0.f;
        float h2 = (r0 - 1 >= 0) ? bits2f(zcol[(size_t)(r0 - 1) * DPROJP]) : 0.f;
#pragma unroll 8
        for (int l = r0; l < r0 + CTR; ++l) {
            const float zl = bits2f(zcol[(size_t)l * DPROJP]);
            float acc = bias;
            acc = fmaf(w0, h0, acc);
            acc = fmaf(w1, h1, acc);
            acc = fmaf(w2, h2, acc);
            acc = fmaf(w3, zl, acc);
            emit(l, acc);
            h0 = h1; h1 = h2; h2 = zl;
        }
    } else {
        const int le = r0 + CTR - 1;
        float h1 = (le + 1 < L_SEQ) ? bits2f(zcol[(size_t)(le + 1) * DPROJP]) : 0.f;
        float h2 = (le + 2 < L_SEQ) ? bits2f(zcol[(size_t)(le + 2) * DPROJP]) : 0.f;
        float h3 = (le + 3 < L_SEQ) ? bits2f(zcol[(size_t)(le + 3) * DPROJP]) : 0.f;
#pragma unroll 8
        for (int l = le; l >= r0; --l) {
            const float zl = bits2f(zcol[(size_t)l * DPROJP]);
            float acc = bias;
            acc = fmaf(w3, zl, acc);
            acc = fmaf(w2, h1, acc);
            acc = fmaf(w1, h2, acc);
            acc = fmaf(w0, h3, acc);
            emit(l, acc);
            h3 = h2; h2 = h1; h1 = zl;
        }
    }
}

// ---------------------------------------------------------------------------
// Exact-f32 dt as LDS-staged block GEMV. dta in BASE-2 log-decay.
// ---------------------------------------------------------------------------
__global__ __launch_bounds__(512) void dt_kernel(
    const float* __restrict__ x,
    const float* __restrict__ inw0, const float* __restrict__ inw1,
    const float* __restrict__ dtbias0, const float* __restrict__ dtbias1,
    const float* __restrict__ Alog0, const float* __restrict__ Alog1,
    float* __restrict__ dtb, float* __restrict__ dta)
{
    const int dir = blockIdx.y;
    const int r0  = blockIdx.x * 64;
    const int tid = threadIdx.x;

    __shared__ float wT[512 * 32];   // [k4][h][j], 64 KB
    __shared__ float sbias[NH], sa[NH];

    const float* __restrict__ w = (dir ? inw1 : inw0) + (size_t)(DINNER + CONVDIM) * 512;
    for (int i = tid; i < 4096; i += 512) {
        const int flat = i * 4;
        const int h = flat >> 9;
        const int k = flat & 511;
        const float4 v = *(const float4*)(w + flat);
        *(float4*)&wT[(k >> 2) * 128 + h * 4] = v;
    }
    if (tid < NH) {
        sbias[tid] = (dir ? dtbias1 : dtbias0)[tid];
        sa[tid] = -expf((dir ? Alog1 : Alog0)[tid]) * LOG2E;
    }
    __syncthreads();

    const int h  = tid & 31;
    const int rr = tid >> 5;
    const float bias = sbias[h];
    const float a = sa[h];

    for (int rp = 0; rp < 64; rp += 16) {
        const int row = r0 + rp + rr;
        const float4* __restrict__ xr = (const float4*)(x + (size_t)row * 512);
        float4 s4 = make_float4(0.f, 0.f, 0.f, 0.f);
#pragma unroll 8
        for (int k4 = 0; k4 < 128; ++k4) {
            const float4 xv = xr[k4];
            const float4 wv = *(const float4*)&wT[k4 * 128 + h * 4];
            s4.x = fmaf(xv.x, wv.x, s4.x);
            s4.y = fmaf(xv.y, wv.y, s4.y);
            s4.z = fmaf(xv.z, wv.z, s4.z);
            s4.w = fmaf(xv.w, wv.w, s4.w);
        }
        const float v = (s4.x + s4.y) + (s4.z + s4.w) + bias;
        const float sp = (v > 20.f) ? v : log1pf(expf(v));
        const size_t orow = (size_t)(dir * M_ROWS + row);
        dtb[orow * NH + h] = sp;
        dta[orow * NH + h] = sp * a;         // base-2 log-decay
    }
}

// ---------------------------------------------------------------------------
// S_raw = C @ B^T per (dir,b,chunk) — head-independent, computed once.
// ---------------------------------------------------------------------------
__global__ __launch_bounds__(256) void sraw_kernel(
    const u16* __restrict__ Bbf, const u16* __restrict__ Cbf,
    u16* __restrict__ Sraw)
{
    const int bx  = blockIdx.x;            // db*NCH + ch
    const int ch  = bx & (NCH - 1);
    const int db  = bx >> 4;               // dir*2+b
    const int dir = db >> 1, bb = db & 1;
    const int tid = threadIdx.x;
    const int wid = tid >> 6;
    const int lane = tid & 63;
    const int l15 = lane & 15, l4 = lane >> 4;
    const int t0  = ch * CHUNK;
    const size_t dbase = (size_t)(dir * M_ROWS + bb * L_SEQ);
    const size_t base  = ((size_t)bx) << 14;     // *128*128

    auto lidx = [&](int t) { return dir ? (L_SEQ - 1 - t) : t; };

    f32x4 accs[2][8];
#pragma unroll
    for (int m = 0; m < 2; ++m)
#pragma unroll
        for (int j = 0; j < 8; ++j) accs[m][j] = (f32x4)0.f;

    short8 af[2][4];
#pragma unroll
    for (int m = 0; m < 2; ++m) {
        const size_t crow = dbase + lidx(t0 + wid * 32 + m * 16 + l15);
#pragma unroll
        for (int kk = 0; kk < 4; ++kk)
            af[m][kk] = *(const short8*)(Cbf + crow * NST + kk * 32 + l4 * 8);
    }
#pragma unroll
    for (int j = 0; j < 8; ++j) {
        const size_t brow = dbase + lidx(t0 + j * 16 + l15);
        short8 bf_[4];
#pragma unroll
        for (int kk = 0; kk < 4; ++kk)
            bf_[kk] = *(const short8*)(Bbf + brow * NST + kk * 32 + l4 * 8);
#pragma unroll
        for (int m = 0; m < 2; ++m)
#pragma unroll
            for (int kk = 0; kk < 4; ++kk)
                accs[m][j] = __builtin_amdgcn_mfma_f32_16x16x32_bf16(
                    af[m][kk], bf_[kk], accs[m][j], 0, 0, 0);
    }

#pragma unroll
    for (int m = 0; m < 2; ++m)
#pragma unroll
        for (int j = 0; j < 8; ++j)
#pragma unroll
            for (int r = 0; r < 4; ++r) {
                const int t = wid * 32 + m * 16 + l4 * 4 + r;
                const int s = j * 16 + l15;
                Sraw[base + (size_t)t * 128 + s] = bf16bits(accs[m][j][r]);
            }
}

// ---------------------------------------------------------------------------
// SSD state pass: cumA prefix (-> betac) + chunk state = X~T @ (r∘B)^T.
// ---------------------------------------------------------------------------
__global__ __launch_bounds__(256) void ssd_state_kernel(
    const u16* __restrict__ xs, const u16* __restrict__ Bbf,
    const float* __restrict__ dtb, const float* __restrict__ dta,
    u16* __restrict__ stateC, float* __restrict__ betac)
{
    const int bx  = blockIdx.x;
    const int ch  = bx & (NCH - 1);
    const int bh  = bx >> 4;
    const int dir = bh >> 6;
    const int bb  = (bh >> 5) & 1;
    const int h   = bh & 31;
    const int tid = threadIdx.x;
    const int wid = tid >> 6;
    const int lane = tid & 63;
    const int l15 = lane & 15;
    const int l4  = lane >> 4;
    const int t0  = ch * CHUNK;
    const size_t dbase = (size_t)(dir * M_ROWS + bb * L_SEQ);

    __shared__ u16 XT[64 * 128];
    __shared__ u16 WBT[64 * 128];
    __shared__ float scum[CHUNK];
    __shared__ float sdt[CHUNK];

    auto lidx = [&](int t) { return dir ? (L_SEQ - 1 - t) : t; };

    // phase A: dt loads + base-2 cumA prefix-sum (wave 0)
    if (tid >= 128) {
        const int s = tid - 128;
        sdt[s] = dtb[(dbase + lidx(t0 + s)) * NH + h];
    }
    if (wid == 0) {
        float a0 = dta[(dbase + lidx(t0 + lane)) * NH + h];
        float a1 = dta[(dbase + lidx(t0 + 64 + lane)) * NH + h];
#pragma unroll
        for (int off = 1; off < 64; off <<= 1) {
            const float u0 = __shfl_up(a0, off);
            const float u1 = __shfl_up(a1, off);
            if (lane >= off) { a0 += u0; a1 += u1; }
        }
        a1 += __shfl(a0, 63);
        scum[lane] = a0; scum[64 + lane] = a1;
        betac[(size_t)bh * L_SEQ + t0 + lane] = a0;
        betac[(size_t)bh * L_SEQ + t0 + 64 + lane] = a1;
    }
    __syncthreads();

    // build X~T once
    {
        const int s = tid >> 1;
        const float dts = sdt[s];
        const size_t grow = dbase + lidx(t0 + s);
        const int p0 = (tid & 1) * 32;
        const u16* __restrict__ xp = xs + grow * DINNER + h * 64 + p0;
#pragma unroll
        for (int q = 0; q < 4; ++q) {
            short8 v = *(const short8*)(xp + q * 8);
#pragma unroll
            for (int j = 0; j < 8; ++j) {
                const int p = p0 + q * 8 + j;
                XT[sidx(p, s)] = bf16bits(dts * bits2f((u16)v[j]));
            }
        }
    }

    const size_t sbase = ((size_t)bh * NCH + ch) * 8192;

#pragma unroll
    for (int half = 0; half < 2; ++half) {
        const int noff = half * 64;
        {
            const int s = tid >> 1;
            const float rs = exp2f(scum[CHUNK - 1] - scum[s]);
            const size_t grow = dbase + lidx(t0 + s);
            const int n0l = (tid & 1) * 32;
            const u16* __restrict__ bp = Bbf + grow * NST + noff + n0l;
#pragma unroll
            for (int q = 0; q < 4; ++q) {
                short8 v = *(const short8*)(bp + q * 8);
#pragma unroll
                for (int j = 0; j < 8; ++j) {
                    const int nl = n0l + q * 8 + j;
                    WBT[sidx(nl, s)] = bf16bits(rs * bits2f((u16)v[j]));
                }
            }
        }
        __syncthreads();

        {
            const int pw = wid * 16;
            const int prow = pw + l15;
            short8 xa[4];
#pragma unroll
            for (int kk = 0; kk < 4; ++kk)
                xa[kk] = *(const short8*)(XT + sslot(prow, kk * 4 + l4));
#pragma unroll
            for (int jn = 0; jn < 4; ++jn) {
                const int nl = jn * 16 + l15;
                f32x4 acc = (f32x4)0.f;
#pragma unroll
                for (int kk = 0; kk < 4; ++kk) {
                    const short8 wb = *(const short8*)(WBT + sslot(nl, kk * 4 + l4));
                    acc = __builtin_amdgcn_mfma_f32_16x16x32_bf16(xa[kk], wb, acc, 0, 0, 0);
                }
#pragma unroll
                for (int r = 0; r < 4; ++r)
                    stateC[sbase + (size_t)(pw + l4 * 4 + r) * 128 + noff + jn * 16 + l15] =
                        bf16bits(acc[r]);
            }
        }
        __syncthreads();
    }
}

// ---------------------------------------------------------------------------
// Combine: sequential over NCH chunks per bh (in place on stateC).
// ---------------------------------------------------------------------------
__global__ __launch_bounds__(512) void combine_kernel(
    u16* __restrict__ stateC, const float* __restrict__ betac)
{
    const int bh  = blockIdx.x;
    const int tid = threadIdx.x;

    float hrun[16];
#pragma unroll
    for (int j = 0; j < 16; ++j) hrun[j] = 0.f;

    for (int s = 0; s < NCH; ++s) {
        const size_t off = ((size_t)bh * NCH + s) * 8192 + (size_t)tid * 16;
        float c[16];
#pragma unroll
        for (int j = 0; j < 16; ++j) c[j] = bits2f(stateC[off + j]);
#pragma unroll
        for (int j = 0; j < 16; ++j) stateC[off + j] = bf16bits(hrun[j]);
        const float alpha = exp2f(betac[(size_t)bh * L_SEQ + s * CHUNK + (CHUNK - 1)]);
#pragma unroll
        for (int j = 0; j < 16; ++j) hrun[j] = fmaf(alpha, hrun[j], c[j]);
    }
}

// ---------------------------------------------------------------------------
// SSD output pass: 512 threads / 8 waves (one 16-row m-group per wave),
// Sraw+C global loads issued at kernel top (latency hidden under XT build).
// Y = P~@X~^T + (2^cumA ∘ C)@h_in^T + D*x -> yb (bf16).
// ---------------------------------------------------------------------------
__global__ __launch_bounds__(512) void ssd_out_kernel(
    const u16* __restrict__ xs, const u16* __restrict__ Cbf,
    const u16* __restrict__ Sraw, const u16* __restrict__ stateC,
    const float* __restrict__ dtb, const float* __restrict__ betac,
    const float* __restrict__ D0, const float* __restrict__ D1,
    u16* __restrict__ yb)
{
    const int bx  = blockIdx.x;
    const int ch  = bx & (NCH - 1);
    const int bh  = bx >> 4;
    const int dir = bh >> 6;
    const int bb  = (bh >> 5) & 1;
    const int h   = bh & 31;
    const int tid = threadIdx.x;
    const int wid = tid >> 6;            // 0..7
    const int lane = tid & 63;
    const int l15 = lane & 15;
    const int l4  = lane >> 4;
    const int t0  = ch * CHUNK;
    const size_t dbase = (size_t)(dir * M_ROWS + bb * L_SEQ);
    const float Dv = (dir ? D1 : D0)[h];

    __shared__ u16 XT[64 * 128];
    __shared__ float scum[CHUNK];
    __shared__ float sdt[CHUNK];

    auto lidx = [&](int t) { return dir ? (L_SEQ - 1 - t) : t; };

    const int trow = wid * 16 + l15;     // this wave's t-row (0..127)
    const size_t sbraw = ((size_t)(((bh >> 5) * NCH) + ch)) << 14;
    const size_t crow = dbase + lidx(t0 + trow);

    // issue Sraw + C loads NOW (addresses LDS-independent); consumed after
    // phase A + XT build -> latency hidden.
    short8 sv[4], c8[4];
#pragma unroll
    for (int kk = 0; kk < 4; ++kk) {
        const int sb = kk * 32 + l4 * 8;
        sv[kk] = *(const short8*)(Sraw + sbraw + (size_t)trow * 128 + sb);
        c8[kk] = *(const short8*)(Cbf + crow * NST + sb);
    }

    // phase A: reload base-2 cumA (betac) + dt
    if (tid < 128) {
        scum[tid] = betac[(size_t)bh * L_SEQ + t0 + tid];
    } else if (tid < 256) {
        const int s = tid - 128;
        sdt[s] = dtb[(dbase + lidx(t0 + s)) * NH + h];
    }
    __syncthreads();

    // build X~T (512 threads: s = tid>>2, 16 p-elems each)
    {
        const int s = tid >> 2;
        const float dts = sdt[s];
        const size_t grow = dbase + lidx(t0 + s);
        const int p0 = (tid & 3) * 16;
        const u16* __restrict__ xp = xs + grow * DINNER + h * 64 + p0;
#pragma unroll
        for (int q = 0; q < 2; ++q) {
            short8 v = *(const short8*)(xp + q * 8);
#pragma unroll
            for (int j = 0; j < 8; ++j) {
                const int p = p0 + q * 8 + j;
                XT[sidx(p, s)] = bf16bits(dts * bits2f((u16)v[j]));
            }
        }
    }
    __syncthreads();

    u16* __restrict__ ybase = yb + (size_t)dir * M_ROWS * DINNER;
    const size_t sbase = ((size_t)bh * NCH + ch) * 8192;

    // Γ-scale the prefetched fragments in-register
    const float ct = scum[trow];
    const float gs = exp2f(ct);
    short8 pa[4], ga[4];
#pragma unroll
    for (int kk = 0; kk < 4; ++kk) {
        const int sb = kk * 32 + l4 * 8;
        short8 o, og;
#pragma unroll
        for (int j = 0; j < 8; ++j) {
            const float g = ((sb + j) <= trow) ? exp2f(ct - scum[sb + j]) : 0.f;
            o[j]  = (short)bf16bits(bits2f((u16)sv[kk][j]) * g);
            og[j] = (short)bf16bits(bits2f((u16)c8[kk][j]) * gs);
        }
        pa[kk] = o;
        ga[kk] = og;
    }

#pragma unroll
    for (int jp = 0; jp < 4; ++jp) {
        const int prow = jp * 16 + l15;
        short8 xb[4], hb[4];
#pragma unroll
        for (int kk = 0; kk < 4; ++kk) {
            xb[kk] = *(const short8*)(XT + sslot(prow, kk * 4 + l4));
            hb[kk] = *(const short8*)(stateC + sbase + (size_t)prow * 128 + kk * 32 + l4 * 8);
        }
        f32x4 acc = (f32x4)0.f;
#pragma unroll
        for (int kk = 0; kk < 4; ++kk)
            acc = __builtin_amdgcn_mfma_f32_16x16x32_bf16(
                pa[kk], xb[kk], acc, 0, 0, 0);
#pragma unroll
        for (int kk = 0; kk < 4; ++kk)
            acc = __builtin_amdgcn_mfma_f32_16x16x32_bf16(
                ga[kk], hb[kk], acc, 0, 0, 0);
#pragma unroll
        for (int r = 0; r < 4; ++r) {
            const int t = wid * 16 + l4 * 4 + r;
            const int lg = lidx(t0 + t);
            const float xv = bits2f(xs[(dbase + lg) * DINNER + h * 64 + prow]);
            ybase[(size_t)(bb * L_SEQ + lg) * DINNER + h * 64 + prow] =
                bf16bits(acc[r] + Dv * xv);
        }
    }
}

// ---------------------------------------------------------------------------
// gate + RMSNorm: reads bf16 z + bf16 y, writes bf16 into zx cols [2048,4096).
// ---------------------------------------------------------------------------
__global__ __launch_bounds__(256) void gatenorm_kernel(
    u16* __restrict__ zx, const u16* __restrict__ yb,
    const float* __restrict__ nw0, const float* __restrict__ nw1)
{
    const int dir = blockIdx.y;
    const int row = blockIdx.x;
    const float* __restrict__ nw = dir ? nw1 : nw0;
    u16* __restrict__ zrow = zx + (size_t)dir * M_ROWS * DPROJP + (size_t)row * DPROJP;
    const u16* __restrict__ yrow = yb + (size_t)dir * M_ROWS * DINNER + (size_t)row * DINNER;
    const int tid = threadIdx.x;
    const int c0 = tid * 8;

    const short8 zv = *(const short8*)(zrow + c0);
    const short8 yv8 = *(const short8*)(yrow + c0);

    float g[8];
#pragma unroll
    for (int j = 0; j < 8; ++j) {
        const float z = bits2f((u16)zv[j]);
        g[j] = bits2f((u16)yv8[j]) * (z / (1.f + expf(-z)));
    }

    float ss = 0.f;
#pragma unroll
    for (int j = 0; j < 8; ++j) ss = fmaf(g[j], g[j], ss);
#pragma unroll
    for (int off = 1; off < 64; off <<= 1) ss += __shfl_xor(ss, off);
    __shared__ float red[4];
    if ((tid & 63) == 0) red[tid >> 6] = ss;
    __syncthreads();
    const float total = red[0] + red[1] + red[2] + red[3];
    const float rs = rsqrtf(total * (1.f / (float)DINNER) + 1e-5f);

    const float4 w0 = *(const float4*)(nw + c0);
    const float4 w1 = *(const float4*)(nw + c0 + 4);
    const float wv[8] = {w0.x, w0.y, w0.z, w0.w, w1.x, w1.y, w1.z, w1.w};
    short8 outv;
#pragma unroll
    for (int j = 0; j < 8; ++j) outv[j] = (short)bf16bits(g[j] * rs * wv[j]);
    *(short8*)(zrow + DINNER + c0) = outv;
}

// ---------------------------------------------------------------------------
extern "C" void kernel_launch(void* const* d_in, const int* in_sizes, int n_in,
                              void* d_out, int out_size, void* d_ws, size_t ws_size,
                              hipStream_t stream)
{
    (void)in_sizes; (void)n_in; (void)out_size; (void)ws_size;
    const float* x        = (const float*)d_in[0];
    const float* f_in_w   = (const float*)d_in[1];
    const float* f_conv_w = (const float*)d_in[2];
    const float* f_conv_b = (const float*)d_in[3];
    const float* f_dtbias = (const float*)d_in[4];
    const float* f_Alog   = (const float*)d_in[5];
    const float* f_D      = (const float*)d_in[6];
    const float* f_nw     = (const float*)d_in[7];
    const float* f_out_w  = (const float*)d_in[8];
    const float* b_in_w   = (const float*)d_in[9];
    const float* b_conv_w = (const float*)d_in[10];
    const float* b_conv_b = (const float*)d_in[11];
    const float* b_dtbias = (const float*)d_in[12];
    const float* b_Alog   = (const float*)d_in[13];
    const float* b_D      = (const float*)d_in[14];
    const float* b_nw     = (const float*)d_in[15];
    const float* b_out_w  = (const float*)d_in[16];

    // Workspace (~201 MB)
    u16* zx  = (u16*)d_ws;
    u16* xs  = zx + (size_t)2 * M_ROWS * DPROJP;
    u16* Bbf = xs + (size_t)2 * M_ROWS * DINNER;
    u16* Cbf = Bbf + (size_t)2 * M_ROWS * NST;
    float* dtb = (float*)(Cbf + (size_t)2 * M_ROWS * NST);
    float* dta = dtb + (size_t)2 * M_ROWS * NH;
    u16* stateC = (u16*)(dta + (size_t)2 * M_ROWS * NH);
    float* betac = (float*)(stateC + (size_t)128 * NCH * 8192);
    u16* yb = (u16*)(betac + (size_t)128 * L_SEQ);
    u16* x_bf   = yb + (size_t)2 * M_ROWS * DINNER;
    u16* w_in_bf  = x_bf + (size_t)M_ROWS * 512;
    u16* w_out_bf = w_in_bf + (size_t)2 * DPROJP * 512;
    u16* Sraw = w_out_bf + (size_t)2 * 512 * DINNER;

    // 0) dtype conversions
    cvt_x_kernel<<<dim3(M_ROWS * 512 / 1024), 256, 0, stream>>>(x, x_bf);
    cvt_win_kernel<<<dim3(DPROJP * 512 / 1024, 2), 256, 0, stream>>>(f_in_w, b_in_w, w_in_bf);
    cvt_wout_kernel<<<dim3(512 * DINNER / 1024, 2), 256, 0, stream>>>(f_out_w, b_out_w, w_out_bf);

    // 1) in_proj (MFMA, bf16 out): zx[dir] = x @ in_w[dir]^T
    gemm_mfma<true><<<dim3(DPROJP / 128, M_ROWS / 128, 2), 256, 0, stream>>>(
        x_bf, x_bf, 512,
        w_in_bf, (long long)DPROJP * 512,
        nullptr, zx, (long long)M_ROWS * DPROJP, DPROJP,
        nullptr, 0, 512);

    // 2a) sliding-window conv + SiLU (bf16 in/out), CTR=32
    conv_kernel<<<dim3(CONVDIM / 256, 2 * NTILE, 2), 256, 0, stream>>>(
        zx, f_conv_w, b_conv_w, f_conv_b, b_conv_b, xs, Bbf, Cbf);

    // 2b) exact-f32 dt / base-2 log-decay (LDS-staged GEMV)
    dt_kernel<<<dim3(M_ROWS / 64, 2), 512, 0, stream>>>(
        x, f_in_w, b_in_w, f_dtbias, b_dtbias, f_Alog, b_Alog, dtb, dta);

    // 3a) head-independent S_raw = C @ B^T (once per dir,b,chunk)
    sraw_kernel<<<dim3(4 * NCH), 256, 0, stream>>>(Bbf, Cbf, Sraw);

    // 3b) state pass (cumA -> betac, chunk states -> stateC)
    ssd_state_kernel<<<dim3(128 * NCH), 256, 0, stream>>>(
        xs, Bbf, dtb, dta, stateC, betac);

    // 3c) combine chunk states (stateC becomes h_in per chunk)
    combine_kernel<<<dim3(128), 512, 0, stream>>>(stateC, betac);

    // 3d) output pass: local Y + fused correction + D-skip -> yb (bf16)
    ssd_out_kernel<<<dim3(128 * NCH), 512, 0, stream>>>(
        xs, Cbf, Sraw, stateC, dtb, betac, f_D, b_D, yb);

    // 4) gate + RMSNorm: bf16 result into zx cols [2048,4096)
    gatenorm_kernel<<<dim3(M_ROWS, 2), 256, 0, stream>>>(zx, yb, f_nw, b_nw);

    // 5) out_proj (MFMA, bf16 A from zx) + residual + concat
    gemm_mfma<false><<<dim3(512 / 128, M_ROWS / 128, 2), 256, 0, stream>>>(
        zx + DINNER, zx + (size_t)M_ROWS * DPROJP + DINNER, DPROJP,
        w_out_bf, (long long)512 * DINNER,
        (float*)d_out, nullptr, 512, 1024,
        x, 512, DINNER);
}

// Round 16
// 287.819 us; speedup vs baseline: 2.7804x; 1.0558x over previous
//
#include <hip/hip_runtime.h>
#include <hip/hip_bf16.h>
#include <math.h>

#define L_SEQ   2048
#define M_ROWS  4096            // B*L
#define DPROJ   4384
#define DPROJP  4480            // padded to 35*128 for MFMA GEMM
#define DINNER  2048
#define CONVDIM 2304
#define NST     128
#define NH      32
#define CHUNK   128             // SSD chunk length
#define NCH     16              // L_SEQ / CHUNK
#define CTR     32              // conv rows per tile
#define NTILE   (L_SEQ / CTR)   // 64
#define LOG2E   1.4426950408889634f

typedef __attribute__((ext_vector_type(8))) short short8;
typedef __attribute__((ext_vector_type(4))) float f32x4;
typedef unsigned short u16;

static __device__ __forceinline__ u16 bf16bits(float v) {
    __hip_bfloat16 t = __float2bfloat16(v);
    return *(u16*)&t;
}
static __device__ __forceinline__ float bits2f(u16 u) {
    return __uint_as_float((unsigned)u << 16);
}
// element index into a [rows][128] bf16 LDS buffer with 16B-slot XOR swizzle
static __device__ __forceinline__ int sidx(int row, int s) {
    return (row << 7) + ((((s >> 3) ^ (row & 7)) << 3) | (s & 7));
}
static __device__ __forceinline__ int sslot(int row, int ks) {  // ks = 16B slot 0..15
    return (row << 7) + ((ks ^ (row & 7)) << 3);
}
// async 16B global->LDS (wave-uniform LDS base + lane*16; source pre-swizzled)
static __device__ __forceinline__ void gload16(const void* g, void* l) {
    __builtin_amdgcn_global_load_lds(
        (const __attribute__((address_space(1))) void*)g,
        (__attribute__((address_space(3))) void*)l, 16, 0, 0);
}

// ---------------------------------------------------------------------------
// f32 -> bf16 conversion pre-passes
// ---------------------------------------------------------------------------
__global__ __launch_bounds__(256) void cvt_x_kernel(
    const float* __restrict__ x, u16* __restrict__ xbf)
{
    const int i = (blockIdx.x * 256 + threadIdx.x) * 4;
    const float4 v = *(const float4*)(x + i);
    xbf[i + 0] = bf16bits(v.x);
    xbf[i + 1] = bf16bits(v.y);
    xbf[i + 2] = bf16bits(v.z);
    xbf[i + 3] = bf16bits(v.w);
}

__global__ __launch_bounds__(256) void cvt_win_kernel(
    const float* __restrict__ w0, const float* __restrict__ w1,
    u16* __restrict__ dst)
{
    const int dir = blockIdx.y;
    const float* __restrict__ w = dir ? w1 : w0;
    u16* __restrict__ d = dst + (size_t)dir * DPROJP * 512;
    const int i = (blockIdx.x * 256 + threadIdx.x) * 4;
    const int row = i >> 9;
    if (row < DPROJ) {
        const float4 v = *(const float4*)(w + i);
        d[i + 0] = bf16bits(v.x);
        d[i + 1] = bf16bits(v.y);
        d[i + 2] = bf16bits(v.z);
        d[i + 3] = bf16bits(v.w);
    } else {
        d[i + 0] = 0; d[i + 1] = 0; d[i + 2] = 0; d[i + 3] = 0;
    }
}

__global__ __launch_bounds__(256) void cvt_wout_kernel(
    const float* __restrict__ w0, const float* __restrict__ w1,
    u16* __restrict__ dst)
{
    const int dir = blockIdx.y;
    const float* __restrict__ w = dir ? w1 : w0;
    u16* __restrict__ d = dst + (size_t)dir * 512 * DINNER;
    const int i = (blockIdx.x * 256 + threadIdx.x) * 4;
    const float4 v = *(const float4*)(w + i);
    d[i + 0] = bf16bits(v.x);
    d[i + 1] = bf16bits(v.y);
    d[i + 2] = bf16bits(v.z);
    d[i + 3] = bf16bits(v.w);
}

// ---------------------------------------------------------------------------
// MFMA bf16 GEMM: C[M][N] = A[M][K] @ B[N][K]^T. global_load_lds staging
// (linear LDS dest, inverse-swizzled source), XCD-aware block swizzle.
// ---------------------------------------------------------------------------
template<bool OUTBF>
__global__ __launch_bounds__(256) void gemm_mfma(
    const u16* __restrict__ A0, const u16* __restrict__ A1, int lda,
    const u16* __restrict__ Bw, long long b_dir_off,
    float* __restrict__ Cf, u16* __restrict__ Cb, long long c_dir_off, int ldc,
    const float* __restrict__ addsrc, int add_ld,
    int K)
{
    const int dir = blockIdx.z;
    const int nwg  = gridDim.x * gridDim.y;
    const int flat = blockIdx.y * gridDim.x + blockIdx.x;
    const int q = nwg >> 3, r = nwg & 7;
    const int xcd = flat & 7, idx = flat >> 3;
    const int wg = (xcd < r) ? xcd * (q + 1) + idx
                             : r * (q + 1) + (xcd - r) * q + idx;
    const int m0 = (wg / gridDim.x) * 128;
    const int n0 = (wg % gridDim.x) * 128;

    const u16* __restrict__ A = dir ? A1 : A0;
    const u16* __restrict__ B = Bw + (size_t)dir * b_dir_off;

    __shared__ u16 Asl[128 * 64];
    __shared__ u16 Bsl[128 * 64];

    const int tid  = threadIdx.x;
    const int lane = tid & 63;
    const int wid  = tid >> 6;
    const int wr   = (wid >> 1) << 6;
    const int wc   = (wid & 1) << 6;
    const int l15  = lane & 15;
    const int l4   = lane >> 4;

    f32x4 acc[4][4];
#pragma unroll
    for (int m = 0; m < 4; ++m)
#pragma unroll
        for (int n = 0; n < 4; ++n) acc[m][n] = (f32x4)0.f;

    for (int k0 = 0; k0 < K; k0 += 64) {
        __syncthreads();
#pragma unroll
        for (int i = 0; i < 4; ++i) {
            const int c    = tid + (i << 8);
            const int row  = c >> 3;
            const int scol = ((c & 7) ^ (row & 7)) << 3;
            gload16(A + (size_t)(m0 + row) * lda + k0 + scol, (char*)Asl + (c << 4));
            gload16(B + (size_t)(n0 + row) * K   + k0 + scol, (char*)Bsl + (c << 4));
        }
        __syncthreads();

#pragma unroll
        for (int kh = 0; kh < 2; ++kh) {
            const int ks = (kh << 2) + l4;
            short8 a[4], b[4];
#pragma unroll
            for (int m = 0; m < 4; ++m) {
                const int R = wr + (m << 4) + l15;
                a[m] = *(const short8*)((const char*)Asl + (R << 7) + ((ks ^ (R & 7)) << 4));
            }
#pragma unroll
            for (int n = 0; n < 4; ++n) {
                const int R = wc + (n << 4) + l15;
                b[n] = *(const short8*)((const char*)Bsl + (R << 7) + ((ks ^ (R & 7)) << 4));
            }
#pragma unroll
            for (int m = 0; m < 4; ++m)
#pragma unroll
                for (int n = 0; n < 4; ++n)
                    acc[m][n] = __builtin_amdgcn_mfma_f32_16x16x32_bf16(
                        a[m], b[n], acc[m][n], 0, 0, 0);
        }
    }

#pragma unroll
    for (int m = 0; m < 4; ++m) {
        const int row0 = m0 + wr + (m << 4) + (l4 << 2);
#pragma unroll
        for (int n = 0; n < 4; ++n) {
            const int col = n0 + wc + (n << 4) + l15;
#pragma unroll
            for (int r2 = 0; r2 < 4; ++r2) {
                if (OUTBF) {
                    Cb[(size_t)dir * c_dir_off + (size_t)(row0 + r2) * ldc + col] =
                        bf16bits(acc[m][n][r2]);
                } else {
                    float v = acc[m][n][r2];
                    if (addsrc) v += addsrc[(size_t)(row0 + r2) * add_ld + col];
                    Cf[(size_t)dir * c_dir_off + (size_t)(row0 + r2) * ldc + col] = v;
                }
            }
        }
    }
}

// ---------------------------------------------------------------------------
// Sliding-window depthwise conv(4) + SiLU over bf16 zx columns. CTR=32.
// ---------------------------------------------------------------------------
__global__ __launch_bounds__(256) void conv_kernel(
    const u16* __restrict__ zx,
    const float* __restrict__ cw0, const float* __restrict__ cw1,
    const float* __restrict__ cb0, const float* __restrict__ cb1,
    u16* __restrict__ xs, u16* __restrict__ Bbf, u16* __restrict__ Cbf)
{
    const int dir = blockIdx.z;
    const int c   = blockIdx.x * 256 + threadIdx.x;     // channel 0..2303
    const int b   = blockIdx.y >> 6;
    const int r0  = (blockIdx.y & (NTILE - 1)) * CTR;

    const float* __restrict__ cw = dir ? cw1 : cw0;
    const float w0 = cw[c * 4 + 0], w1 = cw[c * 4 + 1];
    const float w2 = cw[c * 4 + 2], w3 = cw[c * 4 + 3];
    const float bias = (dir ? cb1 : cb0)[c];

    const u16* __restrict__ zcol = zx + (size_t)dir * M_ROWS * DPROJP
        + (size_t)(b * L_SEQ) * DPROJP + DINNER + c;
    const size_t obase = (size_t)(dir * M_ROWS + b * L_SEQ);

    auto emit = [&](int l, float acc) {
        const float s = acc / (1.f + expf(-acc));
        const size_t orow = obase + l;
        if (c < DINNER)            xs[orow * DINNER + c] = bf16bits(s);
        else if (c < DINNER + NST) Bbf[orow * NST + (c - DINNER)] = bf16bits(s);
        else                       Cbf[orow * NST + (c - DINNER - NST)] = bf16bits(s);
    };

    if (dir == 0) {
        float h0 = (r0 - 3 >= 0) ? bits2f(zcol[(size_t)(r0 - 3) * DPROJP]) : 0.f;
        float h1 = (r0 - 2 >= 0) ? bits2f(zcol[(size_t)(r0 - 2) * DPROJP]) : 0.f;
        float h2 = (r0 - 1 >= 0) ? bits2f(zcol[(size_t)(r0 - 1) * DPROJP]) : 0.f;
#pragma unroll 8
        for (int l = r0; l < r0 + CTR; ++l) {
            const float zl = bits2f(zcol[(size_t)l * DPROJP]);
            float acc = bias;
            acc = fmaf(w0, h0, acc);
            acc = fmaf(w1, h1, acc);
            acc = fmaf(w2, h2, acc);
            acc = fmaf(w3, zl, acc);
            emit(l, acc);
            h0 = h1; h1 = h2; h2 = zl;
        }
    } else {
        const int le = r0 + CTR - 1;
        float h1 = (le + 1 < L_SEQ) ? bits2f(zcol[(size_t)(le + 1) * DPROJP]) : 0.f;
        float h2 = (le + 2 < L_SEQ) ? bits2f(zcol[(size_t)(le + 2) * DPROJP]) : 0.f;
        float h3 = (le + 3 < L_SEQ) ? bits2f(zcol[(size_t)(le + 3) * DPROJP]) : 0.f;
#pragma unroll 8
        for (int l = le; l >= r0; --l) {
            const float zl = bits2f(zcol[(size_t)l * DPROJP]);
            float acc = bias;
            acc = fmaf(w3, zl, acc);
            acc = fmaf(w2, h1, acc);
            acc = fmaf(w1, h2, acc);
            acc = fmaf(w0, h3, acc);
            emit(l, acc);
            h3 = h2; h2 = h1; h1 = zl;
        }
    }
}

// ---------------------------------------------------------------------------
// Exact-f32 dt as LDS-staged block GEMV. dta in BASE-2 log-decay.
// ---------------------------------------------------------------------------
__global__ __launch_bounds__(512) void dt_kernel(
    const float* __restrict__ x,
    const float* __restrict__ inw0, const float* __restrict__ inw1,
    const float* __restrict__ dtbias0, const float* __restrict__ dtbias1,
    const float* __restrict__ Alog0, const float* __restrict__ Alog1,
    float* __restrict__ dtb, float* __restrict__ dta)
{
    const int dir = blockIdx.y;
    const int r0  = blockIdx.x * 64;
    const int tid = threadIdx.x;

    __shared__ float wT[512 * 32];   // [k4][h][j], 64 KB
    __shared__ float sbias[NH], sa[NH];

    const float* __restrict__ w = (dir ? inw1 : inw0) + (size_t)(DINNER + CONVDIM) * 512;
    for (int i = tid; i < 4096; i += 512) {
        const int flat = i * 4;
        const int h = flat >> 9;
        const int k = flat & 511;
        const float4 v = *(const float4*)(w + flat);
        *(float4*)&wT[(k >> 2) * 128 + h * 4] = v;
    }
    if (tid < NH) {
        sbias[tid] = (dir ? dtbias1 : dtbias0)[tid];
        sa[tid] = -expf((dir ? Alog1 : Alog0)[tid]) * LOG2E;
    }
    __syncthreads();

    const int h  = tid & 31;
    const int rr = tid >> 5;
    const float bias = sbias[h];
    const float a = sa[h];

    for (int rp = 0; rp < 64; rp += 16) {
        const int row = r0 + rp + rr;
        const float4* __restrict__ xr = (const float4*)(x + (size_t)row * 512);
        float4 s4 = make_float4(0.f, 0.f, 0.f, 0.f);
#pragma unroll 8
        for (int k4 = 0; k4 < 128; ++k4) {
            const float4 xv = xr[k4];
            const float4 wv = *(const float4*)&wT[k4 * 128 + h * 4];
            s4.x = fmaf(xv.x, wv.x, s4.x);
            s4.y = fmaf(xv.y, wv.y, s4.y);
            s4.z = fmaf(xv.z, wv.z, s4.z);
            s4.w = fmaf(xv.w, wv.w, s4.w);
        }
        const float v = (s4.x + s4.y) + (s4.z + s4.w) + bias;
        const float sp = (v > 20.f) ? v : log1pf(expf(v));
        const size_t orow = (size_t)(dir * M_ROWS + row);
        dtb[orow * NH + h] = sp;
        dta[orow * NH + h] = sp * a;         // base-2 log-decay
    }
}

// ---------------------------------------------------------------------------
// S_raw = C @ B^T per (dir,b,chunk) — head-independent, computed once.
// ---------------------------------------------------------------------------
__global__ __launch_bounds__(256) void sraw_kernel(
    const u16* __restrict__ Bbf, const u16* __restrict__ Cbf,
    u16* __restrict__ Sraw)
{
    const int bx  = blockIdx.x;            // db*NCH + ch
    const int ch  = bx & (NCH - 1);
    const int db  = bx >> 4;               // dir*2+b
    const int dir = db >> 1, bb = db & 1;
    const int tid = threadIdx.x;
    const int wid = tid >> 6;
    const int lane = tid & 63;
    const int l15 = lane & 15, l4 = lane >> 4;
    const int t0  = ch * CHUNK;
    const size_t dbase = (size_t)(dir * M_ROWS + bb * L_SEQ);
    const size_t base  = ((size_t)bx) << 14;     // *128*128

    auto lidx = [&](int t) { return dir ? (L_SEQ - 1 - t) : t; };

    f32x4 accs[2][8];
#pragma unroll
    for (int m = 0; m < 2; ++m)
#pragma unroll
        for (int j = 0; j < 8; ++j) accs[m][j] = (f32x4)0.f;

    short8 af[2][4];
#pragma unroll
    for (int m = 0; m < 2; ++m) {
        const size_t crow = dbase + lidx(t0 + wid * 32 + m * 16 + l15);
#pragma unroll
        for (int kk = 0; kk < 4; ++kk)
            af[m][kk] = *(const short8*)(Cbf + crow * NST + kk * 32 + l4 * 8);
    }
#pragma unroll
    for (int j = 0; j < 8; ++j) {
        const size_t brow = dbase + lidx(t0 + j * 16 + l15);
        short8 bf_[4];
#pragma unroll
        for (int kk = 0; kk < 4; ++kk)
            bf_[kk] = *(const short8*)(Bbf + brow * NST + kk * 32 + l4 * 8);
#pragma unroll
        for (int m = 0; m < 2; ++m)
#pragma unroll
            for (int kk = 0; kk < 4; ++kk)
                accs[m][j] = __builtin_amdgcn_mfma_f32_16x16x32_bf16(
                    af[m][kk], bf_[kk], accs[m][j], 0, 0, 0);
    }

#pragma unroll
    for (int m = 0; m < 2; ++m)
#pragma unroll
        for (int j = 0; j < 8; ++j)
#pragma unroll
            for (int r = 0; r < 4; ++r) {
                const int t = wid * 32 + m * 16 + l4 * 4 + r;
                const int s = j * 16 + l15;
                Sraw[base + (size_t)t * 128 + s] = bf16bits(accs[m][j][r]);
            }
}

// ---------------------------------------------------------------------------
// SSD state pass: cumA prefix (-> betac) + chunk state = X~T @ (r∘B)^T.
// ---------------------------------------------------------------------------
__global__ __launch_bounds__(256) void ssd_state_kernel(
    const u16* __restrict__ xs, const u16* __restrict__ Bbf,
    const float* __restrict__ dtb, const float* __restrict__ dta,
    u16* __restrict__ stateC, float* __restrict__ betac)
{
    const int bx  = blockIdx.x;
    const int ch  = bx & (NCH - 1);
    const int bh  = bx >> 4;
    const int dir = bh >> 6;
    const int bb  = (bh >> 5) & 1;
    const int h   = bh & 31;
    const int tid = threadIdx.x;
    const int wid = tid >> 6;
    const int lane = tid & 63;
    const int l15 = lane & 15;
    const int l4  = lane >> 4;
    const int t0  = ch * CHUNK;
    const size_t dbase = (size_t)(dir * M_ROWS + bb * L_SEQ);

    __shared__ u16 XT[64 * 128];
    __shared__ u16 WBT[64 * 128];
    __shared__ float scum[CHUNK];
    __shared__ float sdt[CHUNK];

    auto lidx = [&](int t) { return dir ? (L_SEQ - 1 - t) : t; };

    // phase A: dt loads + base-2 cumA prefix-sum (wave 0)
    if (tid >= 128) {
        const int s = tid - 128;
        sdt[s] = dtb[(dbase + lidx(t0 + s)) * NH + h];
    }
    if (wid == 0) {
        float a0 = dta[(dbase + lidx(t0 + lane)) * NH + h];
        float a1 = dta[(dbase + lidx(t0 + 64 + lane)) * NH + h];
#pragma unroll
        for (int off = 1; off < 64; off <<= 1) {
            const float u0 = __shfl_up(a0, off);
            const float u1 = __shfl_up(a1, off);
            if (lane >= off) { a0 += u0; a1 += u1; }
        }
        a1 += __shfl(a0, 63);
        scum[lane] = a0; scum[64 + lane] = a1;
        betac[(size_t)bh * L_SEQ + t0 + lane] = a0;
        betac[(size_t)bh * L_SEQ + t0 + 64 + lane] = a1;
    }
    __syncthreads();

    // build X~T once
    {
        const int s = tid >> 1;
        const float dts = sdt[s];
        const size_t grow = dbase + lidx(t0 + s);
        const int p0 = (tid & 1) * 32;
        const u16* __restrict__ xp = xs + grow * DINNER + h * 64 + p0;
#pragma unroll
        for (int q = 0; q < 4; ++q) {
            short8 v = *(const short8*)(xp + q * 8);
#pragma unroll
            for (int j = 0; j < 8; ++j) {
                const int p = p0 + q * 8 + j;
                XT[sidx(p, s)] = bf16bits(dts * bits2f((u16)v[j]));
            }
        }
    }

    const size_t sbase = ((size_t)bh * NCH + ch) * 8192;

#pragma unroll
    for (int half = 0; half < 2; ++half) {
        const int noff = half * 64;
        {
            const int s = tid >> 1;
            const float rs = exp2f(scum[CHUNK - 1] - scum[s]);
            const size_t grow = dbase + lidx(t0 + s);
            const int n0l = (tid & 1) * 32;
            const u16* __restrict__ bp = Bbf + grow * NST + noff + n0l;
#pragma unroll
            for (int q = 0; q < 4; ++q) {
                short8 v = *(const short8*)(bp + q * 8);
#pragma unroll
                for (int j = 0; j < 8; ++j) {
                    const int nl = n0l + q * 8 + j;
                    WBT[sidx(nl, s)] = bf16bits(rs * bits2f((u16)v[j]));
                }
            }
        }
        __syncthreads();

        {
            const int pw = wid * 16;
            const int prow = pw + l15;
            short8 xa[4];
#pragma unroll
            for (int kk = 0; kk < 4; ++kk)
                xa[kk] = *(const short8*)(XT + sslot(prow, kk * 4 + l4));
#pragma unroll
            for (int jn = 0; jn < 4; ++jn) {
                const int nl = jn * 16 + l15;
                f32x4 acc = (f32x4)0.f;
#pragma unroll
                for (int kk = 0; kk < 4; ++kk) {
                    const short8 wb = *(const short8*)(WBT + sslot(nl, kk * 4 + l4));
                    acc = __builtin_amdgcn_mfma_f32_16x16x32_bf16(xa[kk], wb, acc, 0, 0, 0);
                }
#pragma unroll
                for (int r = 0; r < 4; ++r)
                    stateC[sbase + (size_t)(pw + l4 * 4 + r) * 128 + noff + jn * 16 + l15] =
                        bf16bits(acc[r]);
            }
        }
        __syncthreads();
    }
}

// ---------------------------------------------------------------------------
// Combine: sequential over NCH chunks per bh (in place on stateC).
// ---------------------------------------------------------------------------
__global__ __launch_bounds__(512) void combine_kernel(
    u16* __restrict__ stateC, const float* __restrict__ betac)
{
    const int bh  = blockIdx.x;
    const int tid = threadIdx.x;

    float hrun[16];
#pragma unroll
    for (int j = 0; j < 16; ++j) hrun[j] = 0.f;

    for (int s = 0; s < NCH; ++s) {
        const size_t off = ((size_t)bh * NCH + s) * 8192 + (size_t)tid * 16;
        float c[16];
#pragma unroll
        for (int j = 0; j < 16; ++j) c[j] = bits2f(stateC[off + j]);
#pragma unroll
        for (int j = 0; j < 16; ++j) stateC[off + j] = bf16bits(hrun[j]);
        const float alpha = exp2f(betac[(size_t)bh * L_SEQ + s * CHUNK + (CHUNK - 1)]);
#pragma unroll
        for (int j = 0; j < 16; ++j) hrun[j] = fmaf(alpha, hrun[j], c[j]);
    }
}

// ---------------------------------------------------------------------------
// SSD output pass: 512 threads / 8 waves, h_in staged ONCE per block into
// LDS (HS, shared by all waves — removes 8x redundant global fragment loads
// and the in-loop global dependency); Sraw/C/epilogue-xs prefetched at top.
// Y = P~@X~^T + (2^cumA ∘ C)@h_in^T + D*x -> yb (bf16).
// ---------------------------------------------------------------------------
__global__ __launch_bounds__(512) void ssd_out_kernel(
    const u16* __restrict__ xs, const u16* __restrict__ Cbf,
    const u16* __restrict__ Sraw, const u16* __restrict__ stateC,
    const float* __restrict__ dtb, const float* __restrict__ betac,
    const float* __restrict__ D0, const float* __restrict__ D1,
    u16* __restrict__ yb)
{
    const int bx  = blockIdx.x;
    const int ch  = bx & (NCH - 1);
    const int bh  = bx >> 4;
    const int dir = bh >> 6;
    const int bb  = (bh >> 5) & 1;
    const int h   = bh & 31;
    const int tid = threadIdx.x;
    const int wid = tid >> 6;            // 0..7
    const int lane = tid & 63;
    const int l15 = lane & 15;
    const int l4  = lane >> 4;
    const int t0  = ch * CHUNK;
    const size_t dbase = (size_t)(dir * M_ROWS + bb * L_SEQ);
    const float Dv = (dir ? D1 : D0)[h];

    __shared__ u16 XT[64 * 128];
    __shared__ u16 HS[64 * 128];         // h_in state, staged once per block
    __shared__ float scum[CHUNK];
    __shared__ float sdt[CHUNK];

    auto lidx = [&](int t) { return dir ? (L_SEQ - 1 - t) : t; };

    const int trow = wid * 16 + l15;     // this wave's t-row (0..127)
    const size_t sbraw = ((size_t)(((bh >> 5) * NCH) + ch)) << 14;
    const size_t crow = dbase + lidx(t0 + trow);
    const size_t sbase = ((size_t)bh * NCH + ch) * 8192;

    // ---- top prefetch (all addresses LDS-independent) ----
    short8 sv[4], c8[4];
#pragma unroll
    for (int kk = 0; kk < 4; ++kk) {
        const int sb = kk * 32 + l4 * 8;
        sv[kk] = *(const short8*)(Sraw + sbraw + (size_t)trow * 128 + sb);
        c8[kk] = *(const short8*)(Cbf + crow * NST + sb);
    }
    u16 xsv[16];
#pragma unroll
    for (int jp = 0; jp < 4; ++jp)
#pragma unroll
        for (int r = 0; r < 4; ++r) {
            const int t = wid * 16 + l4 * 4 + r;
            xsv[jp * 4 + r] =
                xs[(dbase + lidx(t0 + t)) * DINNER + h * 64 + jp * 16 + l15];
        }

    // ---- stage HS (coalesced, once per block) + phase A ----
#pragma unroll
    for (int i = 0; i < 2; ++i) {
        const int c = tid + (i << 9);          // 0..1023 16B slots
        const int row = c >> 4;                // 0..63
        const int sl  = c & 15;
        *(short8*)(HS + sslot(row, sl)) =
            *(const short8*)(stateC + sbase + (size_t)row * 128 + sl * 8);
    }
    if (tid < 128) {
        scum[tid] = betac[(size_t)bh * L_SEQ + t0 + tid];
    } else if (tid < 256) {
        const int s = tid - 128;
        sdt[s] = dtb[(dbase + lidx(t0 + s)) * NH + h];
    }
    __syncthreads();

    // build X~T (512 threads: s = tid>>2, 16 p-elems each)
    {
        const int s = tid >> 2;
        const float dts = sdt[s];
        const size_t grow = dbase + lidx(t0 + s);
        const int p0 = (tid & 3) * 16;
        const u16* __restrict__ xp = xs + grow * DINNER + h * 64 + p0;
#pragma unroll
        for (int q = 0; q < 2; ++q) {
            short8 v = *(const short8*)(xp + q * 8);
#pragma unroll
            for (int j = 0; j < 8; ++j) {
                const int p = p0 + q * 8 + j;
                XT[sidx(p, s)] = bf16bits(dts * bits2f((u16)v[j]));
            }
        }
    }
    __syncthreads();

    u16* __restrict__ ybase = yb + (size_t)dir * M_ROWS * DINNER;

    // Γ-scale the prefetched fragments in-register
    const float ct = scum[trow];
    const float gs = exp2f(ct);
    short8 pa[4], ga[4];
#pragma unroll
    for (int kk = 0; kk < 4; ++kk) {
        const int sb = kk * 32 + l4 * 8;
        short8 o, og;
#pragma unroll
        for (int j = 0; j < 8; ++j) {
            const float g = ((sb + j) <= trow) ? exp2f(ct - scum[sb + j]) : 0.f;
            o[j]  = (short)bf16bits(bits2f((u16)sv[kk][j]) * g);
            og[j] = (short)bf16bits(bits2f((u16)c8[kk][j]) * gs);
        }
        pa[kk] = o;
        ga[kk] = og;
    }

#pragma unroll
    for (int jp = 0; jp < 4; ++jp) {
        const int prow = jp * 16 + l15;
        short8 xb[4], hb[4];
#pragma unroll
        for (int kk = 0; kk < 4; ++kk) {
            xb[kk] = *(const short8*)(XT + sslot(prow, kk * 4 + l4));
            hb[kk] = *(const short8*)(HS + sslot(prow, kk * 4 + l4));
        }
        f32x4 acc = (f32x4)0.f;
#pragma unroll
        for (int kk = 0; kk < 4; ++kk)
            acc = __builtin_amdgcn_mfma_f32_16x16x32_bf16(
                pa[kk], xb[kk], acc, 0, 0, 0);
#pragma unroll
        for (int kk = 0; kk < 4; ++kk)
            acc = __builtin_amdgcn_mfma_f32_16x16x32_bf16(
                ga[kk], hb[kk], acc, 0, 0, 0);
#pragma unroll
        for (int r = 0; r < 4; ++r) {
            const int t = wid * 16 + l4 * 4 + r;
            const int lg = lidx(t0 + t);
            const float xv = bits2f(xsv[jp * 4 + r]);
            ybase[(size_t)(bb * L_SEQ + lg) * DINNER + h * 64 + prow] =
                bf16bits(acc[r] + Dv * xv);
        }
    }
}

// ---------------------------------------------------------------------------
// gate + RMSNorm: reads bf16 z + bf16 y, writes bf16 into zx cols [2048,4096).
// ---------------------------------------------------------------------------
__global__ __launch_bounds__(256) void gatenorm_kernel(
    u16* __restrict__ zx, const u16* __restrict__ yb,
    const float* __restrict__ nw0, const float* __restrict__ nw1)
{
    const int dir = blockIdx.y;
    const int row = blockIdx.x;
    const float* __restrict__ nw = dir ? nw1 : nw0;
    u16* __restrict__ zrow = zx + (size_t)dir * M_ROWS * DPROJP + (size_t)row * DPROJP;
    const u16* __restrict__ yrow = yb + (size_t)dir * M_ROWS * DINNER + (size_t)row * DINNER;
    const int tid = threadIdx.x;
    const int c0 = tid * 8;

    const short8 zv = *(const short8*)(zrow + c0);
    const short8 yv8 = *(const short8*)(yrow + c0);

    float g[8];
#pragma unroll
    for (int j = 0; j < 8; ++j) {
        const float z = bits2f((u16)zv[j]);
        g[j] = bits2f((u16)yv8[j]) * (z / (1.f + expf(-z)));
    }

    float ss = 0.f;
#pragma unroll
    for (int j = 0; j < 8; ++j) ss = fmaf(g[j], g[j], ss);
#pragma unroll
    for (int off = 1; off < 64; off <<= 1) ss += __shfl_xor(ss, off);
    __shared__ float red[4];
    if ((tid & 63) == 0) red[tid >> 6] = ss;
    __syncthreads();
    const float total = red[0] + red[1] + red[2] + red[3];
    const float rs = rsqrtf(total * (1.f / (float)DINNER) + 1e-5f);

    const float4 w0 = *(const float4*)(nw + c0);
    const float4 w1 = *(const float4*)(nw + c0 + 4);
    const float wv[8] = {w0.x, w0.y, w0.z, w0.w, w1.x, w1.y, w1.z, w1.w};
    short8 outv;
#pragma unroll
    for (int j = 0; j < 8; ++j) outv[j] = (short)bf16bits(g[j] * rs * wv[j]);
    *(short8*)(zrow + DINNER + c0) = outv;
}

// ---------------------------------------------------------------------------
extern "C" void kernel_launch(void* const* d_in, const int* in_sizes, int n_in,
                              void* d_out, int out_size, void* d_ws, size_t ws_size,
                              hipStream_t stream)
{
    (void)in_sizes; (void)n_in; (void)out_size; (void)ws_size;
    const float* x        = (const float*)d_in[0];
    const float* f_in_w   = (const float*)d_in[1];
    const float* f_conv_w = (const float*)d_in[2];
    const float* f_conv_b = (const float*)d_in[3];
    const float* f_dtbias = (const float*)d_in[4];
    const float* f_Alog   = (const float*)d_in[5];
    const float* f_D      = (const float*)d_in[6];
    const float* f_nw     = (const float*)d_in[7];
    const float* f_out_w  = (const float*)d_in[8];
    const float* b_in_w   = (const float*)d_in[9];
    const float* b_conv_w = (const float*)d_in[10];
    const float* b_conv_b = (const float*)d_in[11];
    const float* b_dtbias = (const float*)d_in[12];
    const float* b_Alog   = (const float*)d_in[13];
    const float* b_D      = (const float*)d_in[14];
    const float* b_nw     = (const float*)d_in[15];
    const float* b_out_w  = (const float*)d_in[16];

    // Workspace (~201 MB)
    u16* zx  = (u16*)d_ws;
    u16* xs  = zx + (size_t)2 * M_ROWS * DPROJP;
    u16* Bbf = xs + (size_t)2 * M_ROWS * DINNER;
    u16* Cbf = Bbf + (size_t)2 * M_ROWS * NST;
    float* dtb = (float*)(Cbf + (size_t)2 * M_ROWS * NST);
    float* dta = dtb + (size_t)2 * M_ROWS * NH;
    u16* stateC = (u16*)(dta + (size_t)2 * M_ROWS * NH);
    float* betac = (float*)(stateC + (size_t)128 * NCH * 8192);
    u16* yb = (u16*)(betac + (size_t)128 * L_SEQ);
    u16* x_bf   = yb + (size_t)2 * M_ROWS * DINNER;
    u16* w_in_bf  = x_bf + (size_t)M_ROWS * 512;
    u16* w_out_bf = w_in_bf + (size_t)2 * DPROJP * 512;
    u16* Sraw = w_out_bf + (size_t)2 * 512 * DINNER;

    // 0) dtype conversions
    cvt_x_kernel<<<dim3(M_ROWS * 512 / 1024), 256, 0, stream>>>(x, x_bf);
    cvt_win_kernel<<<dim3(DPROJP * 512 / 1024, 2), 256, 0, stream>>>(f_in_w, b_in_w, w_in_bf);
    cvt_wout_kernel<<<dim3(512 * DINNER / 1024, 2), 256, 0, stream>>>(f_out_w, b_out_w, w_out_bf);

    // 1) in_proj (MFMA, bf16 out): zx[dir] = x @ in_w[dir]^T
    gemm_mfma<true><<<dim3(DPROJP / 128, M_ROWS / 128, 2), 256, 0, stream>>>(
        x_bf, x_bf, 512,
        w_in_bf, (long long)DPROJP * 512,
        nullptr, zx, (long long)M_ROWS * DPROJP, DPROJP,
        nullptr, 0, 512);

    // 2a) sliding-window conv + SiLU (bf16 in/out), CTR=32
    conv_kernel<<<dim3(CONVDIM / 256, 2 * NTILE, 2), 256, 0, stream>>>(
        zx, f_conv_w, b_conv_w, f_conv_b, b_conv_b, xs, Bbf, Cbf);

    // 2b) exact-f32 dt / base-2 log-decay (LDS-staged GEMV)
    dt_kernel<<<dim3(M_ROWS / 64, 2), 512, 0, stream>>>(
        x, f_in_w, b_in_w, f_dtbias, b_dtbias, f_Alog, b_Alog, dtb, dta);

    // 3a) head-independent S_raw = C @ B^T (once per dir,b,chunk)
    sraw_kernel<<<dim3(4 * NCH), 256, 0, stream>>>(Bbf, Cbf, Sraw);

    // 3b) state pass (cumA -> betac, chunk states -> stateC)
    ssd_state_kernel<<<dim3(128 * NCH), 256, 0, stream>>>(
        xs, Bbf, dtb, dta, stateC, betac);

    // 3c) combine chunk states (stateC becomes h_in per chunk)
    combine_kernel<<<dim3(128), 512, 0, stream>>>(stateC, betac);

    // 3d) output pass: local Y + fused correction + D-skip -> yb (bf16)
    ssd_out_kernel<<<dim3(128 * NCH), 512, 0, stream>>>(
        xs, Cbf, Sraw, stateC, dtb, betac, f_D, b_D, yb);

    // 4) gate + RMSNorm: bf16 result into zx cols [2048,4096)
    gatenorm_kernel<<<dim3(M_ROWS, 2), 256, 0, stream>>>(zx, yb, f_nw, b_nw);

    // 5) out_proj (MFMA, bf16 A from zx) + residual + concat
    gemm_mfma<false><<<dim3(512 / 128, M_ROWS / 128, 2), 256, 0, stream>>>(
        zx + DINNER, zx + (size_t)M_ROWS * DPROJP + DINNER, DPROJP,
        w_out_bf, (long long)512 * DINNER,
        (float*)d_out, nullptr, 512, 1024,
        x, 512, DINNER);
}

// Round 17
// 260.955 us; speedup vs baseline: 3.0666x; 1.1029x over previous
//
#include <hip/hip_runtime.h>
#include <hip/hip_bf16.h>
#include <math.h>

#define L_SEQ   2048
#define M_ROWS  4096            // B*L
#define DPROJ   4384
#define DPROJP  4480            // padded to 35*128 for MFMA GEMM
#define DINNER  2048
#define CONVDIM 2304
#define NST     128
#define NH      32
#define CHUNK   128             // SSD chunk length
#define NCH     16              // L_SEQ / CHUNK
#define CTR     32              // conv rows per tile
#define NTILE   (L_SEQ / CTR)   // 64
#define LOG2E   1.4426950408889634f

typedef __attribute__((ext_vector_type(8))) short short8;
typedef __attribute__((ext_vector_type(4))) float f32x4;
typedef unsigned short u16;

static __device__ __forceinline__ u16 bf16bits(float v) {
    __hip_bfloat16 t = __float2bfloat16(v);
    return *(u16*)&t;
}
static __device__ __forceinline__ float bits2f(u16 u) {
    return __uint_as_float((unsigned)u << 16);
}
// element index into a [rows][128] bf16 LDS buffer with 16B-slot XOR swizzle
static __device__ __forceinline__ int sidx(int row, int s) {
    return (row << 7) + ((((s >> 3) ^ (row & 7)) << 3) | (s & 7));
}
static __device__ __forceinline__ int sslot(int row, int ks) {  // ks = 16B slot 0..15
    return (row << 7) + ((ks ^ (row & 7)) << 3);
}
// async 16B global->LDS (wave-uniform LDS base + lane*16; source pre-swizzled)
static __device__ __forceinline__ void gload16(const void* g, void* l) {
    __builtin_amdgcn_global_load_lds(
        (const __attribute__((address_space(1))) void*)g,
        (__attribute__((address_space(3))) void*)l, 16, 0, 0);
}

// ---------------------------------------------------------------------------
// f32 -> bf16 conversion pre-passes
// ---------------------------------------------------------------------------
__global__ __launch_bounds__(256) void cvt_x_kernel(
    const float* __restrict__ x, u16* __restrict__ xbf)
{
    const int i = (blockIdx.x * 256 + threadIdx.x) * 4;
    const float4 v = *(const float4*)(x + i);
    xbf[i + 0] = bf16bits(v.x);
    xbf[i + 1] = bf16bits(v.y);
    xbf[i + 2] = bf16bits(v.z);
    xbf[i + 3] = bf16bits(v.w);
}

__global__ __launch_bounds__(256) void cvt_win_kernel(
    const float* __restrict__ w0, const float* __restrict__ w1,
    u16* __restrict__ dst)
{
    const int dir = blockIdx.y;
    const float* __restrict__ w = dir ? w1 : w0;
    u16* __restrict__ d = dst + (size_t)dir * DPROJP * 512;
    const int i = (blockIdx.x * 256 + threadIdx.x) * 4;
    const int row = i >> 9;
    if (row < DPROJ) {
        const float4 v = *(const float4*)(w + i);
        d[i + 0] = bf16bits(v.x);
        d[i + 1] = bf16bits(v.y);
        d[i + 2] = bf16bits(v.z);
        d[i + 3] = bf16bits(v.w);
    } else {
        d[i + 0] = 0; d[i + 1] = 0; d[i + 2] = 0; d[i + 3] = 0;
    }
}

__global__ __launch_bounds__(256) void cvt_wout_kernel(
    const float* __restrict__ w0, const float* __restrict__ w1,
    u16* __restrict__ dst)
{
    const int dir = blockIdx.y;
    const float* __restrict__ w = dir ? w1 : w0;
    u16* __restrict__ d = dst + (size_t)dir * 512 * DINNER;
    const int i = (blockIdx.x * 256 + threadIdx.x) * 4;
    const float4 v = *(const float4*)(w + i);
    d[i + 0] = bf16bits(v.x);
    d[i + 1] = bf16bits(v.y);
    d[i + 2] = bf16bits(v.z);
    d[i + 3] = bf16bits(v.w);
}

// ---------------------------------------------------------------------------
// MFMA bf16 GEMM (128x128 tile), bf16 out — used for in_proj.
// global_load_lds staging, XCD-aware block swizzle.
// ---------------------------------------------------------------------------
__global__ __launch_bounds__(256) void gemm_mfma_in(
    const u16* __restrict__ A0, int lda,
    const u16* __restrict__ Bw, long long b_dir_off,
    u16* __restrict__ Cb, long long c_dir_off, int ldc,
    int K)
{
    const int dir = blockIdx.z;
    const int nwg  = gridDim.x * gridDim.y;
    const int flat = blockIdx.y * gridDim.x + blockIdx.x;
    const int q = nwg >> 3, r = nwg & 7;
    const int xcd = flat & 7, idx = flat >> 3;
    const int wg = (xcd < r) ? xcd * (q + 1) + idx
                             : r * (q + 1) + (xcd - r) * q + idx;
    const int m0 = (wg / gridDim.x) * 128;
    const int n0 = (wg % gridDim.x) * 128;

    const u16* __restrict__ A = A0;
    const u16* __restrict__ B = Bw + (size_t)dir * b_dir_off;

    __shared__ u16 Asl[128 * 64];
    __shared__ u16 Bsl[128 * 64];

    const int tid  = threadIdx.x;
    const int lane = tid & 63;
    const int wid  = tid >> 6;
    const int wr   = (wid >> 1) << 6;
    const int wc   = (wid & 1) << 6;
    const int l15  = lane & 15;
    const int l4   = lane >> 4;

    f32x4 acc[4][4];
#pragma unroll
    for (int m = 0; m < 4; ++m)
#pragma unroll
        for (int n = 0; n < 4; ++n) acc[m][n] = (f32x4)0.f;

    for (int k0 = 0; k0 < K; k0 += 64) {
        __syncthreads();
#pragma unroll
        for (int i = 0; i < 4; ++i) {
            const int c    = tid + (i << 8);
            const int row  = c >> 3;
            const int scol = ((c & 7) ^ (row & 7)) << 3;
            gload16(A + (size_t)(m0 + row) * lda + k0 + scol, (char*)Asl + (c << 4));
            gload16(B + (size_t)(n0 + row) * K   + k0 + scol, (char*)Bsl + (c << 4));
        }
        __syncthreads();

#pragma unroll
        for (int kh = 0; kh < 2; ++kh) {
            const int ks = (kh << 2) + l4;
            short8 a[4], b[4];
#pragma unroll
            for (int m = 0; m < 4; ++m) {
                const int R = wr + (m << 4) + l15;
                a[m] = *(const short8*)((const char*)Asl + (R << 7) + ((ks ^ (R & 7)) << 4));
            }
#pragma unroll
            for (int n = 0; n < 4; ++n) {
                const int R = wc + (n << 4) + l15;
                b[n] = *(const short8*)((const char*)Bsl + (R << 7) + ((ks ^ (R & 7)) << 4));
            }
#pragma unroll
            for (int m = 0; m < 4; ++m)
#pragma unroll
                for (int n = 0; n < 4; ++n)
                    acc[m][n] = __builtin_amdgcn_mfma_f32_16x16x32_bf16(
                        a[m], b[n], acc[m][n], 0, 0, 0);
        }
    }

#pragma unroll
    for (int m = 0; m < 4; ++m) {
        const int row0 = m0 + wr + (m << 4) + (l4 << 2);
#pragma unroll
        for (int n = 0; n < 4; ++n) {
            const int col = n0 + wc + (n << 4) + l15;
#pragma unroll
            for (int r2 = 0; r2 < 4; ++r2)
                Cb[(size_t)dir * c_dir_off + (size_t)(row0 + r2) * ldc + col] =
                    bf16bits(acc[m][n][r2]);
        }
    }
}

// ---------------------------------------------------------------------------
// out_proj GEMM: 128x64 tile (N=512 -> 8 n-tiles, 512 blocks = 2/CU).
// C[row][dir*512+col] = A @ B^T + x (residual). A = bf16 gated-y in zx.
// ---------------------------------------------------------------------------
__global__ __launch_bounds__(256) void gemm_out_kernel(
    const u16* __restrict__ Azx,           // zx base (y slice at +DINNER)
    const u16* __restrict__ Bw,            // w_out bf16, per-dir 512*2048
    const float* __restrict__ x,
    float* __restrict__ out)
{
    const int dir = blockIdx.z;
    const int nwg  = gridDim.x * gridDim.y;        // 8*32 = 256, %8==0
    const int flat = blockIdx.y * gridDim.x + blockIdx.x;
    const int q = nwg >> 3;
    const int xcd = flat & 7, idx = flat >> 3;
    const int wg = xcd * q + idx;
    const int m0 = (wg >> 3) * 128;                // n-fast within XCD chunk
    const int n0 = (wg & 7) * 64;

    const u16* __restrict__ A = Azx + (size_t)dir * M_ROWS * DPROJP + DINNER;
    const u16* __restrict__ B = Bw + (size_t)dir * 512 * DINNER;

    __shared__ u16 Asl[128 * 64];
    __shared__ u16 Bsl[64 * 64];

    const int tid  = threadIdx.x;
    const int lane = tid & 63;
    const int wid  = tid >> 6;
    const int wr   = (wid >> 1) << 6;      // 0 or 64  (m)
    const int wc   = (wid & 1) << 5;       // 0 or 32  (n)
    const int l15  = lane & 15;
    const int l4   = lane >> 4;

    f32x4 acc[4][2];
#pragma unroll
    for (int m = 0; m < 4; ++m)
#pragma unroll
        for (int n = 0; n < 2; ++n) acc[m][n] = (f32x4)0.f;

    for (int k0 = 0; k0 < DINNER; k0 += 64) {
        __syncthreads();
#pragma unroll
        for (int i = 0; i < 4; ++i) {
            const int c    = tid + (i << 8);       // 0..1023
            const int row  = c >> 3;
            const int scol = ((c & 7) ^ (row & 7)) << 3;
            gload16(A + (size_t)(m0 + row) * DPROJP + k0 + scol, (char*)Asl + (c << 4));
        }
#pragma unroll
        for (int i = 0; i < 2; ++i) {
            const int c    = tid + (i << 8);       // 0..511
            const int row  = c >> 3;
            const int scol = ((c & 7) ^ (row & 7)) << 3;
            gload16(B + (size_t)(n0 + row) * DINNER + k0 + scol, (char*)Bsl + (c << 4));
        }
        __syncthreads();

#pragma unroll
        for (int kh = 0; kh < 2; ++kh) {
            const int ks = (kh << 2) + l4;
            short8 a[4], b[2];
#pragma unroll
            for (int m = 0; m < 4; ++m) {
                const int R = wr + (m << 4) + l15;
                a[m] = *(const short8*)((const char*)Asl + (R << 7) + ((ks ^ (R & 7)) << 4));
            }
#pragma unroll
            for (int n = 0; n < 2; ++n) {
                const int R = wc + (n << 4) + l15;
                b[n] = *(const short8*)((const char*)Bsl + (R << 7) + ((ks ^ (R & 7)) << 4));
            }
#pragma unroll
            for (int m = 0; m < 4; ++m)
#pragma unroll
                for (int n = 0; n < 2; ++n)
                    acc[m][n] = __builtin_amdgcn_mfma_f32_16x16x32_bf16(
                        a[m], b[n], acc[m][n], 0, 0, 0);
        }
    }

#pragma unroll
    for (int m = 0; m < 4; ++m) {
        const int row0 = m0 + wr + (m << 4) + (l4 << 2);
#pragma unroll
        for (int n = 0; n < 2; ++n) {
            const int col = n0 + wc + (n << 4) + l15;
#pragma unroll
            for (int r2 = 0; r2 < 4; ++r2) {
                const float v = acc[m][n][r2] + x[(size_t)(row0 + r2) * 512 + col];
                out[(size_t)(row0 + r2) * 1024 + dir * 512 + col] = v;
            }
        }
    }
}

// ---------------------------------------------------------------------------
// Sliding-window depthwise conv(4) + SiLU over bf16 zx columns. CTR=32.
// ---------------------------------------------------------------------------
__global__ __launch_bounds__(256) void conv_kernel(
    const u16* __restrict__ zx,
    const float* __restrict__ cw0, const float* __restrict__ cw1,
    const float* __restrict__ cb0, const float* __restrict__ cb1,
    u16* __restrict__ xs, u16* __restrict__ Bbf, u16* __restrict__ Cbf)
{
    const int dir = blockIdx.z;
    const int c   = blockIdx.x * 256 + threadIdx.x;     // channel 0..2303
    const int b   = blockIdx.y >> 6;
    const int r0  = (blockIdx.y & (NTILE - 1)) * CTR;

    const float* __restrict__ cw = dir ? cw1 : cw0;
    const float w0 = cw[c * 4 + 0], w1 = cw[c * 4 + 1];
    const float w2 = cw[c * 4 + 2], w3 = cw[c * 4 + 3];
    const float bias = (dir ? cb1 : cb0)[c];

    const u16* __restrict__ zcol = zx + (size_t)dir * M_ROWS * DPROJP
        + (size_t)(b * L_SEQ) * DPROJP + DINNER + c;
    const size_t obase = (size_t)(dir * M_ROWS + b * L_SEQ);

    auto emit = [&](int l, float acc) {
        const float s = acc / (1.f + expf(-acc));
        const size_t orow = obase + l;
        if (c < DINNER)            xs[orow * DINNER + c] = bf16bits(s);
        else if (c < DINNER + NST) Bbf[orow * NST + (c - DINNER)] = bf16bits(s);
        else                       Cbf[orow * NST + (c - DINNER - NST)] = bf16bits(s);
    };

    if (dir == 0) {
        float h0 = (r0 - 3 >= 0) ? bits2f(zcol[(size_t)(r0 - 3) * DPROJP]) : 0.f;
        float h1 = (r0 - 2 >= 0) ? bits2f(zcol[(size_t)(r0 - 2) * DPROJP]) : 0.f;
        float h2 = (r0 - 1 >= 0) ? bits2f(zcol[(size_t)(r0 - 1) * DPROJP]) : 0.f;
#pragma unroll 8
        for (int l = r0; l < r0 + CTR; ++l) {
            const float zl = bits2f(zcol[(size_t)l * DPROJP]);
            float acc = bias;
            acc = fmaf(w0, h0, acc);
            acc = fmaf(w1, h1, acc);
            acc = fmaf(w2, h2, acc);
            acc = fmaf(w3, zl, acc);
            emit(l, acc);
            h0 = h1; h1 = h2; h2 = zl;
        }
    } else {
        const int le = r0 + CTR - 1;
        float h1 = (le + 1 < L_SEQ) ? bits2f(zcol[(size_t)(le + 1) * DPROJP]) : 0.f;
        float h2 = (le + 2 < L_SEQ) ? bits2f(zcol[(size_t)(le + 2) * DPROJP]) : 0.f;
        float h3 = (le + 3 < L_SEQ) ? bits2f(zcol[(size_t)(le + 3) * DPROJP]) : 0.f;
#pragma unroll 8
        for (int l = le; l >= r0; --l) {
            const float zl = bits2f(zcol[(size_t)l * DPROJP]);
            float acc = bias;
            acc = fmaf(w3, zl, acc);
            acc = fmaf(w2, h1, acc);
            acc = fmaf(w1, h2, acc);
            acc = fmaf(w0, h3, acc);
            emit(l, acc);
            h3 = h2; h2 = h1; h1 = zl;
        }
    }
}

// ---------------------------------------------------------------------------
// Exact-f32 dt as LDS-staged block GEMV. dta in BASE-2 log-decay.
// ---------------------------------------------------------------------------
__global__ __launch_bounds__(512) void dt_kernel(
    const float* __restrict__ x,
    const float* __restrict__ inw0, const float* __restrict__ inw1,
    const float* __restrict__ dtbias0, const float* __restrict__ dtbias1,
    const float* __restrict__ Alog0, const float* __restrict__ Alog1,
    float* __restrict__ dtb, float* __restrict__ dta)
{
    const int dir = blockIdx.y;
    const int r0  = blockIdx.x * 64;
    const int tid = threadIdx.x;

    __shared__ float wT[512 * 32];   // [k4][h][j], 64 KB
    __shared__ float sbias[NH], sa[NH];

    const float* __restrict__ w = (dir ? inw1 : inw0) + (size_t)(DINNER + CONVDIM) * 512;
    for (int i = tid; i < 4096; i += 512) {
        const int flat = i * 4;
        const int h = flat >> 9;
        const int k = flat & 511;
        const float4 v = *(const float4*)(w + flat);
        *(float4*)&wT[(k >> 2) * 128 + h * 4] = v;
    }
    if (tid < NH) {
        sbias[tid] = (dir ? dtbias1 : dtbias0)[tid];
        sa[tid] = -expf((dir ? Alog1 : Alog0)[tid]) * LOG2E;
    }
    __syncthreads();

    const int h  = tid & 31;
    const int rr = tid >> 5;
    const float bias = sbias[h];
    const float a = sa[h];

    for (int rp = 0; rp < 64; rp += 16) {
        const int row = r0 + rp + rr;
        const float4* __restrict__ xr = (const float4*)(x + (size_t)row * 512);
        float4 s4 = make_float4(0.f, 0.f, 0.f, 0.f);
#pragma unroll 8
        for (int k4 = 0; k4 < 128; ++k4) {
            const float4 xv = xr[k4];
            const float4 wv = *(const float4*)&wT[k4 * 128 + h * 4];
            s4.x = fmaf(xv.x, wv.x, s4.x);
            s4.y = fmaf(xv.y, wv.y, s4.y);
            s4.z = fmaf(xv.z, wv.z, s4.z);
            s4.w = fmaf(xv.w, wv.w, s4.w);
        }
        const float v = (s4.x + s4.y) + (s4.z + s4.w) + bias;
        const float sp = (v > 20.f) ? v : log1pf(expf(v));
        const size_t orow = (size_t)(dir * M_ROWS + row);
        dtb[orow * NH + h] = sp;
        dta[orow * NH + h] = sp * a;         // base-2 log-decay
    }
}

// ---------------------------------------------------------------------------
// S_raw = C @ B^T per (dir,b,chunk) — head-independent, computed once.
// ---------------------------------------------------------------------------
__global__ __launch_bounds__(256) void sraw_kernel(
    const u16* __restrict__ Bbf, const u16* __restrict__ Cbf,
    u16* __restrict__ Sraw)
{
    const int bx  = blockIdx.x;            // db*NCH + ch
    const int ch  = bx & (NCH - 1);
    const int db  = bx >> 4;               // dir*2+b
    const int dir = db >> 1, bb = db & 1;
    const int tid = threadIdx.x;
    const int wid = tid >> 6;
    const int lane = tid & 63;
    const int l15 = lane & 15, l4 = lane >> 4;
    const int t0  = ch * CHUNK;
    const size_t dbase = (size_t)(dir * M_ROWS + bb * L_SEQ);
    const size_t base  = ((size_t)bx) << 14;     // *128*128

    auto lidx = [&](int t) { return dir ? (L_SEQ - 1 - t) : t; };

    f32x4 accs[2][8];
#pragma unroll
    for (int m = 0; m < 2; ++m)
#pragma unroll
        for (int j = 0; j < 8; ++j) accs[m][j] = (f32x4)0.f;

    short8 af[2][4];
#pragma unroll
    for (int m = 0; m < 2; ++m) {
        const size_t crow = dbase + lidx(t0 + wid * 32 + m * 16 + l15);
#pragma unroll
        for (int kk = 0; kk < 4; ++kk)
            af[m][kk] = *(const short8*)(Cbf + crow * NST + kk * 32 + l4 * 8);
    }
#pragma unroll
    for (int j = 0; j < 8; ++j) {
        const size_t brow = dbase + lidx(t0 + j * 16 + l15);
        short8 bf_[4];
#pragma unroll
        for (int kk = 0; kk < 4; ++kk)
            bf_[kk] = *(const short8*)(Bbf + brow * NST + kk * 32 + l4 * 8);
#pragma unroll
        for (int m = 0; m < 2; ++m)
#pragma unroll
            for (int kk = 0; kk < 4; ++kk)
                accs[m][j] = __builtin_amdgcn_mfma_f32_16x16x32_bf16(
                    af[m][kk], bf_[kk], accs[m][j], 0, 0, 0);
    }

#pragma unroll
    for (int m = 0; m < 2; ++m)
#pragma unroll
        for (int j = 0; j < 8; ++j)
#pragma unroll
            for (int r = 0; r < 4; ++r) {
                const int t = wid * 32 + m * 16 + l4 * 4 + r;
                const int s = j * 16 + l15;
                Sraw[base + (size_t)t * 128 + s] = bf16bits(accs[m][j][r]);
            }
}

// ---------------------------------------------------------------------------
// SSD state pass: cumA prefix (-> betac) + chunk state = X~T @ (r∘B)^T.
// ---------------------------------------------------------------------------
__global__ __launch_bounds__(256) void ssd_state_kernel(
    const u16* __restrict__ xs, const u16* __restrict__ Bbf,
    const float* __restrict__ dtb, const float* __restrict__ dta,
    u16* __restrict__ stateC, float* __restrict__ betac)
{
    const int bx  = blockIdx.x;
    const int ch  = bx & (NCH - 1);
    const int bh  = bx >> 4;
    const int dir = bh >> 6;
    const int bb  = (bh >> 5) & 1;
    const int h   = bh & 31;
    const int tid = threadIdx.x;
    const int wid = tid >> 6;
    const int lane = tid & 63;
    const int l15 = lane & 15;
    const int l4  = lane >> 4;
    const int t0  = ch * CHUNK;
    const size_t dbase = (size_t)(dir * M_ROWS + bb * L_SEQ);

    __shared__ u16 XT[64 * 128];
    __shared__ u16 WBT[64 * 128];
    __shared__ float scum[CHUNK];
    __shared__ float sdt[CHUNK];

    auto lidx = [&](int t) { return dir ? (L_SEQ - 1 - t) : t; };

    // phase A: dt loads + base-2 cumA prefix-sum (wave 0)
    if (tid >= 128) {
        const int s = tid - 128;
        sdt[s] = dtb[(dbase + lidx(t0 + s)) * NH + h];
    }
    if (wid == 0) {
        float a0 = dta[(dbase + lidx(t0 + lane)) * NH + h];
        float a1 = dta[(dbase + lidx(t0 + 64 + lane)) * NH + h];
#pragma unroll
        for (int off = 1; off < 64; off <<= 1) {
            const float u0 = __shfl_up(a0, off);
            const float u1 = __shfl_up(a1, off);
            if (lane >= off) { a0 += u0; a1 += u1; }
        }
        a1 += __shfl(a0, 63);
        scum[lane] = a0; scum[64 + lane] = a1;
        betac[(size_t)bh * L_SEQ + t0 + lane] = a0;
        betac[(size_t)bh * L_SEQ + t0 + 64 + lane] = a1;
    }
    __syncthreads();

    // build X~T once
    {
        const int s = tid >> 1;
        const float dts = sdt[s];
        const size_t grow = dbase + lidx(t0 + s);
        const int p0 = (tid & 1) * 32;
        const u16* __restrict__ xp = xs + grow * DINNER + h * 64 + p0;
#pragma unroll
        for (int q = 0; q < 4; ++q) {
            short8 v = *(const short8*)(xp + q * 8);
#pragma unroll
            for (int j = 0; j < 8; ++j) {
                const int p = p0 + q * 8 + j;
                XT[sidx(p, s)] = bf16bits(dts * bits2f((u16)v[j]));
            }
        }
    }

    const size_t sbase = ((size_t)bh * NCH + ch) * 8192;

#pragma unroll
    for (int half = 0; half < 2; ++half) {
        const int noff = half * 64;
        {
            const int s = tid >> 1;
            const float rs = exp2f(scum[CHUNK - 1] - scum[s]);
            const size_t grow = dbase + lidx(t0 + s);
            const int n0l = (tid & 1) * 32;
            const u16* __restrict__ bp = Bbf + grow * NST + noff + n0l;
#pragma unroll
            for (int q = 0; q < 4; ++q) {
                short8 v = *(const short8*)(bp + q * 8);
#pragma unroll
                for (int j = 0; j < 8; ++j) {
                    const int nl = n0l + q * 8 + j;
                    WBT[sidx(nl, s)] = bf16bits(rs * bits2f((u16)v[j]));
                }
            }
        }
        __syncthreads();

        {
            const int pw = wid * 16;
            const int prow = pw + l15;
            short8 xa[4];
#pragma unroll
            for (int kk = 0; kk < 4; ++kk)
                xa[kk] = *(const short8*)(XT + sslot(prow, kk * 4 + l4));
#pragma unroll
            for (int jn = 0; jn < 4; ++jn) {
                const int nl = jn * 16 + l15;
                f32x4 acc = (f32x4)0.f;
#pragma unroll
                for (int kk = 0; kk < 4; ++kk) {
                    const short8 wb = *(const short8*)(WBT + sslot(nl, kk * 4 + l4));
                    acc = __builtin_amdgcn_mfma_f32_16x16x32_bf16(xa[kk], wb, acc, 0, 0, 0);
                }
#pragma unroll
                for (int r = 0; r < 4; ++r)
                    stateC[sbase + (size_t)(pw + l4 * 4 + r) * 128 + noff + jn * 16 + l15] =
                        bf16bits(acc[r]);
            }
        }
        __syncthreads();
    }
}

// ---------------------------------------------------------------------------
// Combine: sequential over NCH chunks per bh (in place on stateC).
// ---------------------------------------------------------------------------
__global__ __launch_bounds__(512) void combine_kernel(
    u16* __restrict__ stateC, const float* __restrict__ betac)
{
    const int bh  = blockIdx.x;
    const int tid = threadIdx.x;

    float hrun[16];
#pragma unroll
    for (int j = 0; j < 16; ++j) hrun[j] = 0.f;

    for (int s = 0; s < NCH; ++s) {
        const size_t off = ((size_t)bh * NCH + s) * 8192 + (size_t)tid * 16;
        float c[16];
#pragma unroll
        for (int j = 0; j < 16; ++j) c[j] = bits2f(stateC[off + j]);
#pragma unroll
        for (int j = 0; j < 16; ++j) stateC[off + j] = bf16bits(hrun[j]);
        const float alpha = exp2f(betac[(size_t)bh * L_SEQ + s * CHUNK + (CHUNK - 1)]);
#pragma unroll
        for (int j = 0; j < 16; ++j) hrun[j] = fmaf(alpha, hrun[j], c[j]);
    }
}

// ---------------------------------------------------------------------------
// SSD output pass: 512 threads / 8 waves, h_in staged once per block (HS),
// Sraw/C/epilogue-xs prefetched at top.
// Y = P~@X~^T + (2^cumA ∘ C)@h_in^T + D*x -> yb (bf16).
// ---------------------------------------------------------------------------
__global__ __launch_bounds__(512) void ssd_out_kernel(
    const u16* __restrict__ xs, const u16* __restrict__ Cbf,
    const u16* __restrict__ Sraw, const u16* __restrict__ stateC,
    const float* __restrict__ dtb, const float* __restrict__ betac,
    const float* __restrict__ D0, const float* __restrict__ D1,
    u16* __restrict__ yb)
{
    const int bx  = blockIdx.x;
    const int ch  = bx & (NCH - 1);
    const int bh  = bx >> 4;
    const int dir = bh >> 6;
    const int bb  = (bh >> 5) & 1;
    const int h   = bh & 31;
    const int tid = threadIdx.x;
    const int wid = tid >> 6;            // 0..7
    const int lane = tid & 63;
    const int l15 = lane & 15;
    const int l4  = lane >> 4;
    const int t0  = ch * CHUNK;
    const size_t dbase = (size_t)(dir * M_ROWS + bb * L_SEQ);
    const float Dv = (dir ? D1 : D0)[h];

    __shared__ u16 XT[64 * 128];
    __shared__ u16 HS[64 * 128];         // h_in state, staged once per block
    __shared__ float scum[CHUNK];
    __shared__ float sdt[CHUNK];

    auto lidx = [&](int t) { return dir ? (L_SEQ - 1 - t) : t; };

    const int trow = wid * 16 + l15;     // this wave's t-row (0..127)
    const size_t sbraw = ((size_t)(((bh >> 5) * NCH) + ch)) << 14;
    const size_t crow = dbase + lidx(t0 + trow);
    const size_t sbase = ((size_t)bh * NCH + ch) * 8192;

    // ---- top prefetch (all addresses LDS-independent) ----
    short8 sv[4], c8[4];
#pragma unroll
    for (int kk = 0; kk < 4; ++kk) {
        const int sb = kk * 32 + l4 * 8;
        sv[kk] = *(const short8*)(Sraw + sbraw + (size_t)trow * 128 + sb);
        c8[kk] = *(const short8*)(Cbf + crow * NST + sb);
    }
    u16 xsv[16];
#pragma unroll
    for (int jp = 0; jp < 4; ++jp)
#pragma unroll
        for (int r = 0; r < 4; ++r) {
            const int t = wid * 16 + l4 * 4 + r;
            xsv[jp * 4 + r] =
                xs[(dbase + lidx(t0 + t)) * DINNER + h * 64 + jp * 16 + l15];
        }

    // ---- stage HS (coalesced, once per block) + phase A ----
#pragma unroll
    for (int i = 0; i < 2; ++i) {
        const int c = tid + (i << 9);          // 0..1023 16B slots
        const int row = c >> 4;                // 0..63
        const int sl  = c & 15;
        *(short8*)(HS + sslot(row, sl)) =
            *(const short8*)(stateC + sbase + (size_t)row * 128 + sl * 8);
    }
    if (tid < 128) {
        scum[tid] = betac[(size_t)bh * L_SEQ + t0 + tid];
    } else if (tid < 256) {
        const int s = tid - 128;
        sdt[s] = dtb[(dbase + lidx(t0 + s)) * NH + h];
    }
    __syncthreads();

    // build X~T (512 threads: s = tid>>2, 16 p-elems each)
    {
        const int s = tid >> 2;
        const float dts = sdt[s];
        const size_t grow = dbase + lidx(t0 + s);
        const int p0 = (tid & 3) * 16;
        const u16* __restrict__ xp = xs + grow * DINNER + h * 64 + p0;
#pragma unroll
        for (int q = 0; q < 2; ++q) {
            short8 v = *(const short8*)(xp + q * 8);
#pragma unroll
            for (int j = 0; j < 8; ++j) {
                const int p = p0 + q * 8 + j;
                XT[sidx(p, s)] = bf16bits(dts * bits2f((u16)v[j]));
            }
        }
    }
    __syncthreads();

    u16* __restrict__ ybase = yb + (size_t)dir * M_ROWS * DINNER;

    // Γ-scale the prefetched fragments in-register
    const float ct = scum[trow];
    const float gs = exp2f(ct);
    short8 pa[4], ga[4];
#pragma unroll
    for (int kk = 0; kk < 4; ++kk) {
        const int sb = kk * 32 + l4 * 8;
        short8 o, og;
#pragma unroll
        for (int j = 0; j < 8; ++j) {
            const float g = ((sb + j) <= trow) ? exp2f(ct - scum[sb + j]) : 0.f;
            o[j]  = (short)bf16bits(bits2f((u16)sv[kk][j]) * g);
            og[j] = (short)bf16bits(bits2f((u16)c8[kk][j]) * gs);
        }
        pa[kk] = o;
        ga[kk] = og;
    }

#pragma unroll
    for (int jp = 0; jp < 4; ++jp) {
        const int prow = jp * 16 + l15;
        short8 xb[4], hb[4];
#pragma unroll
        for (int kk = 0; kk < 4; ++kk) {
            xb[kk] = *(const short8*)(XT + sslot(prow, kk * 4 + l4));
            hb[kk] = *(const short8*)(HS + sslot(prow, kk * 4 + l4));
        }
        f32x4 acc = (f32x4)0.f;
#pragma unroll
        for (int kk = 0; kk < 4; ++kk)
            acc = __builtin_amdgcn_mfma_f32_16x16x32_bf16(
                pa[kk], xb[kk], acc, 0, 0, 0);
#pragma unroll
        for (int kk = 0; kk < 4; ++kk)
            acc = __builtin_amdgcn_mfma_f32_16x16x32_bf16(
                ga[kk], hb[kk], acc, 0, 0, 0);
#pragma unroll
        for (int r = 0; r < 4; ++r) {
            const int t = wid * 16 + l4 * 4 + r;
            const int lg = lidx(t0 + t);
            const float xv = bits2f(xsv[jp * 4 + r]);
            ybase[(size_t)(bb * L_SEQ + lg) * DINNER + h * 64 + prow] =
                bf16bits(acc[r] + Dv * xv);
        }
    }
}

// ---------------------------------------------------------------------------
// gate + RMSNorm: reads bf16 z + bf16 y, writes bf16 into zx cols [2048,4096).
// ---------------------------------------------------------------------------
__global__ __launch_bounds__(256) void gatenorm_kernel(
    u16* __restrict__ zx, const u16* __restrict__ yb,
    const float* __restrict__ nw0, const float* __restrict__ nw1)
{
    const int dir = blockIdx.y;
    const int row = blockIdx.x;
    const float* __restrict__ nw = dir ? nw1 : nw0;
    u16* __restrict__ zrow = zx + (size_t)dir * M_ROWS * DPROJP + (size_t)row * DPROJP;
    const u16* __restrict__ yrow = yb + (size_t)dir * M_ROWS * DINNER + (size_t)row * DINNER;
    const int tid = threadIdx.x;
    const int c0 = tid * 8;

    const short8 zv = *(const short8*)(zrow + c0);
    const short8 yv8 = *(const short8*)(yrow + c0);

    float g[8];
#pragma unroll
    for (int j = 0; j < 8; ++j) {
        const float z = bits2f((u16)zv[j]);
        g[j] = bits2f((u16)yv8[j]) * (z / (1.f + expf(-z)));
    }

    float ss = 0.f;
#pragma unroll
    for (int j = 0; j < 8; ++j) ss = fmaf(g[j], g[j], ss);
#pragma unroll
    for (int off = 1; off < 64; off <<= 1) ss += __shfl_xor(ss, off);
    __shared__ float red[4];
    if ((tid & 63) == 0) red[tid >> 6] = ss;
    __syncthreads();
    const float total = red[0] + red[1] + red[2] + red[3];
    const float rs = rsqrtf(total * (1.f / (float)DINNER) + 1e-5f);

    const float4 w0 = *(const float4*)(nw + c0);
    const float4 w1 = *(const float4*)(nw + c0 + 4);
    const float wv[8] = {w0.x, w0.y, w0.z, w0.w, w1.x, w1.y, w1.z, w1.w};
    short8 outv;
#pragma unroll
    for (int j = 0; j < 8; ++j) outv[j] = (short)bf16bits(g[j] * rs * wv[j]);
    *(short8*)(zrow + DINNER + c0) = outv;
}

// ---------------------------------------------------------------------------
extern "C" void kernel_launch(void* const* d_in, const int* in_sizes, int n_in,
                              void* d_out, int out_size, void* d_ws, size_t ws_size,
                              hipStream_t stream)
{
    (void)in_sizes; (void)n_in; (void)out_size; (void)ws_size;
    const float* x        = (const float*)d_in[0];
    const float* f_in_w   = (const float*)d_in[1];
    const float* f_conv_w = (const float*)d_in[2];
    const float* f_conv_b = (const float*)d_in[3];
    const float* f_dtbias = (const float*)d_in[4];
    const float* f_Alog   = (const float*)d_in[5];
    const float* f_D      = (const float*)d_in[6];
    const float* f_nw     = (const float*)d_in[7];
    const float* f_out_w  = (const float*)d_in[8];
    const float* b_in_w   = (const float*)d_in[9];
    const float* b_conv_w = (const float*)d_in[10];
    const float* b_conv_b = (const float*)d_in[11];
    const float* b_dtbias = (const float*)d_in[12];
    const float* b_Alog   = (const float*)d_in[13];
    const float* b_D      = (const float*)d_in[14];
    const float* b_nw     = (const float*)d_in[15];
    const float* b_out_w  = (const float*)d_in[16];

    // Workspace (~201 MB)
    u16* zx  = (u16*)d_ws;
    u16* xs  = zx + (size_t)2 * M_ROWS * DPROJP;
    u16* Bbf = xs + (size_t)2 * M_ROWS * DINNER;
    u16* Cbf = Bbf + (size_t)2 * M_ROWS * NST;
    float* dtb = (float*)(Cbf + (size_t)2 * M_ROWS * NST);
    float* dta = dtb + (size_t)2 * M_ROWS * NH;
    u16* stateC = (u16*)(dta + (size_t)2 * M_ROWS * NH);
    float* betac = (float*)(stateC + (size_t)128 * NCH * 8192);
    u16* yb = (u16*)(betac + (size_t)128 * L_SEQ);
    u16* x_bf   = yb + (size_t)2 * M_ROWS * DINNER;
    u16* w_in_bf  = x_bf + (size_t)M_ROWS * 512;
    u16* w_out_bf = w_in_bf + (size_t)2 * DPROJP * 512;
    u16* Sraw = w_out_bf + (size_t)2 * 512 * DINNER;

    // 0) dtype conversions
    cvt_x_kernel<<<dim3(M_ROWS * 512 / 1024), 256, 0, stream>>>(x, x_bf);
    cvt_win_kernel<<<dim3(DPROJP * 512 / 1024, 2), 256, 0, stream>>>(f_in_w, b_in_w, w_in_bf);
    cvt_wout_kernel<<<dim3(512 * DINNER / 1024, 2), 256, 0, stream>>>(f_out_w, b_out_w, w_out_bf);

    // 1) in_proj (MFMA, bf16 out): zx[dir] = x @ in_w[dir]^T
    gemm_mfma_in<<<dim3(DPROJP / 128, M_ROWS / 128, 2), 256, 0, stream>>>(
        x_bf, 512,
        w_in_bf, (long long)DPROJP * 512,
        zx, (long long)M_ROWS * DPROJP, DPROJP,
        512);

    // 2a) sliding-window conv + SiLU (bf16 in/out), CTR=32
    conv_kernel<<<dim3(CONVDIM / 256, 2 * NTILE, 2), 256, 0, stream>>>(
        zx, f_conv_w, b_conv_w, f_conv_b, b_conv_b, xs, Bbf, Cbf);

    // 2b) exact-f32 dt / base-2 log-decay (LDS-staged GEMV)
    dt_kernel<<<dim3(M_ROWS / 64, 2), 512, 0, stream>>>(
        x, f_in_w, b_in_w, f_dtbias, b_dtbias, f_Alog, b_Alog, dtb, dta);

    // 3a) head-independent S_raw = C @ B^T (once per dir,b,chunk)
    sraw_kernel<<<dim3(4 * NCH), 256, 0, stream>>>(Bbf, Cbf, Sraw);

    // 3b) state pass (cumA -> betac, chunk states -> stateC)
    ssd_state_kernel<<<dim3(128 * NCH), 256, 0, stream>>>(
        xs, Bbf, dtb, dta, stateC, betac);

    // 3c) combine chunk states (stateC becomes h_in per chunk)
    combine_kernel<<<dim3(128), 512, 0, stream>>>(stateC, betac);

    // 3d) output pass: local Y + fused correction + D-skip -> yb (bf16)
    ssd_out_kernel<<<dim3(128 * NCH), 512, 0, stream>>>(
        xs, Cbf, Sraw, stateC, dtb, betac, f_D, b_D, yb);

    // 4) gate + RMSNorm: bf16 result into zx cols [2048,4096)
    gatenorm_kernel<<<dim3(M_ROWS, 2), 256, 0, stream>>>(zx, yb, f_nw, b_nw);

    // 5) out_proj (128x64 tiles, 512 blocks) + residual + concat
    gemm_out_kernel<<<dim3(8, 32, 2), 256, 0, stream>>>(
        zx, w_out_bf, x, (float*)d_out);
}